// Round 1
// baseline (16752.423 us; speedup 1.0000x reference)
//
#include <hip/hip_runtime.h>
#include <math.h>

#define DD 512
#define NHEAD 8
#define HDIM 64

// ---------------- weight ternary quant: two-stage deterministic mean|W| ----------------
__global__ void k_wabs_partial(const float* __restrict__ W, int n, float* __restrict__ part) {
    int t = threadIdx.x;
    float s = 0.f;
    for (int i = blockIdx.x * blockDim.x + t; i < n; i += blockDim.x * gridDim.x)
        s += fabsf(W[i]);
    __shared__ float red[4];
#pragma unroll
    for (int o = 32; o > 0; o >>= 1) s += __shfl_down(s, o);
    if ((t & 63) == 0) red[t >> 6] = s;
    __syncthreads();
    if (t == 0) part[blockIdx.x] = red[0] + red[1] + red[2] + red[3];
}

__global__ void k_wfinal(const float* __restrict__ part, float* __restrict__ scal) {
    int m = threadIdx.x;
    if (m < 6) {
        const int cnt[6] = {262144, 524288, 262144, 262144, 524288, 262144};
        float s = 0.f;
        for (int i = 0; i < 32; ++i) s += part[m * 32 + i];
        float mean = s / (float)cnt[m];
        scal[m] = 1.f / fmaxf(mean, 1e-5f);
    }
}

__global__ void k_wquant(const float* __restrict__ W, float* __restrict__ Wdq,
                         const float* __restrict__ scal, int n) {
    int i = blockIdx.x * 256 + threadIdx.x;
    if (i < n) {
        float sc = *scal;
        float t = rintf(W[i] * sc);
        t = fminf(fmaxf(t, -1.f), 1.f);
        Wdq[i] = t / sc;
    }
}

// ---------------- RMSNorm + per-token int8 absmax quant (dequantized fp32 out) ----------------
__global__ void k_rmsq(const float* __restrict__ X, const float* __restrict__ g,
                       float* __restrict__ out) {
    int row = blockIdx.x;
    int lane = threadIdx.x; // 64 threads, 8 elems each
    const float* xr = X + (size_t)row * DD;
    float4 a = *(const float4*)(xr + lane * 8);
    float4 b = *(const float4*)(xr + lane * 8 + 4);
    float ss = a.x*a.x + a.y*a.y + a.z*a.z + a.w*a.w
             + b.x*b.x + b.y*b.y + b.z*b.z + b.w*b.w;
#pragma unroll
    for (int o = 32; o > 0; o >>= 1) ss += __shfl_xor(ss, o);
    float rn = 1.f / sqrtf(ss * (1.f / 512.f) + 1e-8f);
    float4 ga = *(const float4*)(g + lane * 8);
    float4 gb = *(const float4*)(g + lane * 8 + 4);
    float v[8] = {a.x*rn*ga.x, a.y*rn*ga.y, a.z*rn*ga.z, a.w*rn*ga.w,
                  b.x*rn*gb.x, b.y*rn*gb.y, b.z*rn*gb.z, b.w*rn*gb.w};
    float amax = 0.f;
#pragma unroll
    for (int i = 0; i < 8; ++i) amax = fmaxf(amax, fabsf(v[i]));
#pragma unroll
    for (int o = 32; o > 0; o >>= 1) amax = fmaxf(amax, __shfl_xor(amax, o));
    float scale = 127.f / fmaxf(amax, 1e-5f);
    float q[8];
#pragma unroll
    for (int i = 0; i < 8; ++i) {
        float tq = rintf(v[i] * scale);
        tq = fminf(fmaxf(tq, -128.f), 127.f);
        q[i] = tq / scale;
    }
    float* orow = out + (size_t)row * DD + lane * 8;
    *(float4*)orow       = make_float4(q[0], q[1], q[2], q[3]);
    *(float4*)(orow + 4) = make_float4(q[4], q[5], q[6], q[7]);
}

// ---------------- DoRA low-rank delta ----------------
__global__ void k_lora1(const float* __restrict__ X, const float* __restrict__ Amat,
                        float* __restrict__ tmp) {
    int t = threadIdx.x;
    int r = blockIdx.x * 16 + (t >> 4);
    int cc = t & 15;
    const float4* xr = (const float4*)(X + (size_t)r * DD);
    const float4* ar = (const float4*)(Amat + (size_t)cc * DD);
    float acc = 0.f;
#pragma unroll 4
    for (int k = 0; k < 128; ++k) {
        float4 xa = xr[k], aa = ar[k];
        acc += xa.x*aa.x + xa.y*aa.y + xa.z*aa.z + xa.w*aa.w;
    }
    tmp[(size_t)r * 16 + cc] = acc;
}

__global__ void k_lora2(const float* __restrict__ tmp, const float* __restrict__ Bmat,
                        float* __restrict__ qf) {
    int idx = blockIdx.x * 256 + threadIdx.x;
    int m2 = idx >> 9, n2 = idx & 511;
    const float4* tr = (const float4*)(tmp + (size_t)m2 * 16);
    const float4* br = (const float4*)(Bmat + (size_t)n2 * 16);
    float acc = 0.f;
#pragma unroll
    for (int rr = 0; rr < 4; ++rr) {
        float4 ta = tr[rr], ba = br[rr];
        acc += ta.x*ba.x + ta.y*ba.y + ta.z*ba.z + ta.w*ba.w;
    }
    qf[idx] = acc;
}

// ---------------- fp32 tiled GEMM: C[M,N] = A[M,512] @ W[N,512]^T (+epilogues) ----------------
// MODE 0: plain store. MODE 1: C + mag[n/64]*Cout (in-place delta add). MODE 2: C + residual.
template <int MODE>
__global__ void k_gemm(const float* __restrict__ A, const float* __restrict__ Wt,
                       float* __restrict__ Cout, const float* __restrict__ Extra,
                       int M, int N) {
    __shared__ float sA[16][65];
    __shared__ float sB[16][65];
    int tx = threadIdx.x & 15, ty = threadIdx.x >> 4;
    int m0 = blockIdx.y * 64, n0 = blockIdx.x * 64;
    float acc[4][4] = {};
    int t = threadIdx.x;
    int lr = t >> 2, lc = t & 3;
    const float* Abase = A + (size_t)(m0 + lr) * DD + lc * 4;
    const float* Bbase = Wt + (size_t)(n0 + lr) * DD + lc * 4;
    for (int k0 = 0; k0 < DD; k0 += 16) {
        float4 av = *(const float4*)(Abase + k0);
        float4 bv = *(const float4*)(Bbase + k0);
        __syncthreads();
        sA[lc*4+0][lr] = av.x; sA[lc*4+1][lr] = av.y;
        sA[lc*4+2][lr] = av.z; sA[lc*4+3][lr] = av.w;
        sB[lc*4+0][lr] = bv.x; sB[lc*4+1][lr] = bv.y;
        sB[lc*4+2][lr] = bv.z; sB[lc*4+3][lr] = bv.w;
        __syncthreads();
#pragma unroll
        for (int k = 0; k < 16; ++k) {
            float ar[4], br[4];
#pragma unroll
            for (int i = 0; i < 4; ++i) ar[i] = sA[k][ty*4+i];
#pragma unroll
            for (int j = 0; j < 4; ++j) br[j] = sB[k][tx*4+j];
#pragma unroll
            for (int i = 0; i < 4; ++i)
#pragma unroll
                for (int j = 0; j < 4; ++j)
                    acc[i][j] = fmaf(ar[i], br[j], acc[i][j]);
        }
    }
#pragma unroll
    for (int i = 0; i < 4; ++i) {
        int mm = m0 + ty*4 + i;
#pragma unroll
        for (int j = 0; j < 4; ++j) {
            int nn = n0 + tx*4 + j;
            size_t idx = (size_t)mm * N + nn;
            if (MODE == 0)      Cout[idx] = acc[i][j];
            else if (MODE == 1) Cout[idx] = acc[i][j] + Extra[nn >> 6] * Cout[idx];
            else                Cout[idx] = acc[i][j] + Extra[idx];
        }
    }
}

// ---------------- attention: one block per (b, h, query-row) ----------------
__global__ void k_attn(const float* __restrict__ qf, const float* __restrict__ kv,
                       float* __restrict__ attn, int Nq, int Nc) {
    __shared__ float s_q[64];
    __shared__ float s_kt[64][65];
    __shared__ float s_sc[4096];
    __shared__ float s_part[256];
    __shared__ float s_red[8];
    int qi = blockIdx.x, h = blockIdx.y, b = blockIdx.z;
    int t = threadIdx.x;
    const float* qrow = qf + ((size_t)(b * Nq + qi)) * DD + h * HDIM;
    if (t < 64) s_q[t] = qrow[t];
    const float* kbase = kv + (size_t)b * Nc * 1024 + h * HDIM;
    __syncthreads();
    // scores
    for (int kt0 = 0; kt0 < Nc; kt0 += 64) {
#pragma unroll
        for (int i = 0; i < 4; ++i) {
            int f = t + i * 256;
            int rr = f >> 4, c4 = f & 15;
            float4 vv = *(const float4*)(kbase + (size_t)(kt0 + rr) * 1024 + c4 * 4);
            s_kt[rr][c4*4+0] = vv.x; s_kt[rr][c4*4+1] = vv.y;
            s_kt[rr][c4*4+2] = vv.z; s_kt[rr][c4*4+3] = vv.w;
        }
        __syncthreads();
        int kl = t & 63, dc = t >> 6;
        float p = 0.f;
#pragma unroll
        for (int i = 0; i < 16; ++i) p = fmaf(s_q[dc*16+i], s_kt[kl][dc*16+i], p);
        s_part[dc * 64 + kl] = p;
        __syncthreads();
        if (t < 64)
            s_sc[kt0 + t] = (s_part[t] + s_part[64+t] + s_part[128+t] + s_part[192+t]) * 0.125f;
        __syncthreads();
    }
    // softmax
    float mx = -1e30f;
    for (int k = t; k < Nc; k += 256) mx = fmaxf(mx, s_sc[k]);
#pragma unroll
    for (int o = 32; o > 0; o >>= 1) mx = fmaxf(mx, __shfl_xor(mx, o));
    if ((t & 63) == 0) s_red[t >> 6] = mx;
    __syncthreads();
    mx = fmaxf(fmaxf(s_red[0], s_red[1]), fmaxf(s_red[2], s_red[3]));
    float se = 0.f;
    for (int k = t; k < Nc; k += 256) { float e = expf(s_sc[k] - mx); s_sc[k] = e; se += e; }
#pragma unroll
    for (int o = 32; o > 0; o >>= 1) se += __shfl_xor(se, o);
    if ((t & 63) == 0) s_red[4 + (t >> 6)] = se;
    __syncthreads();
    float inv = 1.f / (s_red[4] + s_red[5] + s_red[6] + s_red[7]);
    // PV: wave ch handles Nc/4 keys for all 64 dims
    int d = t & 63, ch = t >> 6;
    const float* vbase = kv + (size_t)b * Nc * 1024 + 512 + h * HDIM + d;
    float acc = 0.f;
    int per = Nc >> 2;
    for (int k = ch * per; k < (ch + 1) * per; ++k)
        acc = fmaf(s_sc[k], vbase[(size_t)k * 1024], acc);
    __syncthreads();
    s_part[t] = acc;
    __syncthreads();
    if (t < 64)
        attn[((size_t)(b * Nq + qi)) * DD + h * HDIM + t] =
            (s_part[t] + s_part[64+t] + s_part[128+t] + s_part[192+t]) * inv;
}

// ---------------- host side ----------------
static void run_pass(const float* q_in, const float* ctx,
                     const float* Wq_dq, const float* gq,
                     const float* Wkv_dq, const float* gkv,
                     const float* Amat, const float* Bmat, const float* mag,
                     const float* Wp_dq, const float* gp,
                     int Mq, int Mc, int Nq, int Nc,
                     float* arena, float* outp, const float* resid, hipStream_t stream) {
    float* q_nq = arena;
    float* c_nq = q_nq + (size_t)Mq * 512;
    float* qf   = c_nq + (size_t)Mc * 512;
    float* kvb  = qf + (size_t)Mq * 512;
    float* attn = kvb + (size_t)Mc * 1024;
    float* tmp  = attn + (size_t)Mq * 512;

    k_rmsq<<<Mq, 64, 0, stream>>>(q_in, gq, q_nq);
    k_rmsq<<<Mc, 64, 0, stream>>>(ctx, gkv, c_nq);
    k_lora1<<<Mq / 16, 256, 0, stream>>>(q_in, Amat, tmp);
    k_lora2<<<(Mq * 512) / 256, 256, 0, stream>>>(tmp, Bmat, qf);
    k_gemm<1><<<dim3(512 / 64, Mq / 64), 256, 0, stream>>>(q_nq, Wq_dq, qf, mag, Mq, 512);
    k_gemm<0><<<dim3(1024 / 64, Mc / 64), 256, 0, stream>>>(c_nq, Wkv_dq, kvb, nullptr, Mc, 1024);
    k_attn<<<dim3(Nq, NHEAD, 4), 256, 0, stream>>>(qf, kvb, attn, Nq, Nc);
    k_rmsq<<<Mq, 64, 0, stream>>>(attn, gp, q_nq);  // reuse q_nq for normalized attn out
    k_gemm<2><<<dim3(512 / 64, Mq / 64), 256, 0, stream>>>(q_nq, Wp_dq, outp, resid, Mq, 512);
}

extern "C" void kernel_launch(void* const* d_in, const int* in_sizes, int n_in,
                              void* d_out, int out_size, void* d_ws, size_t ws_size,
                              hipStream_t stream) {
    const float* x     = (const float*)d_in[0];
    const float* c     = (const float*)d_in[1];
    const float* Wq_x  = (const float*)d_in[2];
    const float* g_qx  = (const float*)d_in[3];
    const float* Wkv_c = (const float*)d_in[4];
    const float* g_kvc = (const float*)d_in[5];
    const float* A_x   = (const float*)d_in[6];
    const float* B_x   = (const float*)d_in[7];
    const float* mag_x = (const float*)d_in[8];
    const float* Wp_x  = (const float*)d_in[9];
    const float* g_px  = (const float*)d_in[10];
    const float* Wq_c  = (const float*)d_in[11];
    const float* g_qc  = (const float*)d_in[12];
    const float* Wkv_x = (const float*)d_in[13];
    const float* g_kvx = (const float*)d_in[14];
    const float* A_c   = (const float*)d_in[15];
    const float* B_c   = (const float*)d_in[16];
    const float* mag_c = (const float*)d_in[17];
    const float* Wp_c  = (const float*)d_in[18];
    const float* g_pc  = (const float*)d_in[19];

    float* ws = (float*)d_ws;
    const float* Wsrc[6] = {Wq_x, Wkv_c, Wp_x, Wq_c, Wkv_x, Wp_c};
    const int    Wcnt[6] = {262144, 524288, 262144, 262144, 524288, 262144};
    const size_t Woff[6] = {0, 262144, 786432, 1048576, 1310720, 1835008};
    float* part  = ws + 2097152;
    float* scal  = part + 192;
    float* arena = ws + 2097152 + 1024;

    // workspace requirement check (~135 MB)
    size_t need1 = 3 * (size_t)16384 * 512 + (size_t)4096 * 512 + (size_t)4096 * 1024 + (size_t)16384 * 16;
    size_t need2 = 3 * (size_t)4096 * 512 + (size_t)16384 * 512 + (size_t)16384 * 1024 + (size_t)4096 * 16;
    size_t need = (2097152 + 1024 + (need1 > need2 ? need1 : need2)) * sizeof(float);
    if (ws_size < need) return;  // cannot run — fail cleanly

    for (int m = 0; m < 6; ++m)
        k_wabs_partial<<<32, 256, 0, stream>>>(Wsrc[m], Wcnt[m], part + m * 32);
    k_wfinal<<<1, 64, 0, stream>>>(part, scal);
    for (int m = 0; m < 6; ++m)
        k_wquant<<<(Wcnt[m] + 255) / 256, 256, 0, stream>>>(Wsrc[m], ws + Woff[m], scal + m, Wcnt[m]);

    float* outx = (float*)d_out;
    float* outc = outx + (size_t)4 * 4096 * 512;

    // pass 1: x queries attend to c
    run_pass(x, c, ws + Woff[0], g_qx, ws + Woff[1], g_kvc, A_x, B_x, mag_x, ws + Woff[2], g_px,
             16384, 4096, 4096, 1024, arena, outx, x, stream);
    // pass 2: c queries attend to x
    run_pass(c, x, ws + Woff[3], g_qc, ws + Woff[4], g_kvx, A_c, B_c, mag_c, ws + Woff[5], g_pc,
             4096, 16384, 1024, 4096, arena, outc, c, stream);
}

// Round 2
// 1442.770 us; speedup vs baseline: 11.6113x; 11.6113x over previous
//
#include <hip/hip_runtime.h>
#include <math.h>

#define DD 512
#define NHEAD 8
#define HDIM 64

typedef __bf16 bf16x8 __attribute__((ext_vector_type(8)));
typedef unsigned short u16x8 __attribute__((ext_vector_type(8)));
typedef float f32x4 __attribute__((ext_vector_type(4)));

static __device__ __forceinline__ unsigned short f2bf(float f) {
    unsigned u = __builtin_bit_cast(unsigned, f);
    u += 0x7fffu + ((u >> 16) & 1u);   // round-to-nearest-even
    return (unsigned short)(u >> 16);
}

// ---------------- weight ternary quant: two-stage deterministic mean|W| ----------------
__global__ void k_wabs_partial(const float* __restrict__ W, int n, float* __restrict__ part) {
    int t = threadIdx.x;
    float s = 0.f;
    for (int i = blockIdx.x * blockDim.x + t; i < n; i += blockDim.x * gridDim.x)
        s += fabsf(W[i]);
    __shared__ float red[4];
#pragma unroll
    for (int o = 32; o > 0; o >>= 1) s += __shfl_down(s, o);
    if ((t & 63) == 0) red[t >> 6] = s;
    __syncthreads();
    if (t == 0) part[blockIdx.x] = red[0] + red[1] + red[2] + red[3];
}

__global__ void k_wfinal(const float* __restrict__ part, float* __restrict__ scal) {
    int m = threadIdx.x;
    if (m < 6) {
        const int cnt[6] = {262144, 524288, 262144, 262144, 524288, 262144};
        float s = 0.f;
        for (int i = 0; i < 32; ++i) s += part[m * 32 + i];
        float mean = s / (float)cnt[m];
        scal[m] = 1.f / fmaxf(mean, 1e-5f);
    }
}

__global__ void k_wquant(const float* __restrict__ W, float* __restrict__ Wdq,
                         const float* __restrict__ scal, int n) {
    int i = blockIdx.x * 256 + threadIdx.x;
    if (i < n) {
        float sc = *scal;
        float t = rintf(W[i] * sc);
        t = fminf(fmaxf(t, -1.f), 1.f);
        Wdq[i] = t / sc;
    }
}

// ---------------- RMSNorm + per-token int8 absmax quant (dequantized fp32 out) ----------------
__global__ void k_rmsq(const float* __restrict__ X, const float* __restrict__ g,
                       float* __restrict__ out) {
    int row = blockIdx.x;
    int lane = threadIdx.x; // 64 threads, 8 elems each
    const float* xr = X + (size_t)row * DD;
    float4 a = *(const float4*)(xr + lane * 8);
    float4 b = *(const float4*)(xr + lane * 8 + 4);
    float ss = a.x*a.x + a.y*a.y + a.z*a.z + a.w*a.w
             + b.x*b.x + b.y*b.y + b.z*b.z + b.w*b.w;
#pragma unroll
    for (int o = 32; o > 0; o >>= 1) ss += __shfl_xor(ss, o);
    float rn = 1.f / sqrtf(ss * (1.f / 512.f) + 1e-8f);
    float4 ga = *(const float4*)(g + lane * 8);
    float4 gb = *(const float4*)(g + lane * 8 + 4);
    float v[8] = {a.x*rn*ga.x, a.y*rn*ga.y, a.z*rn*ga.z, a.w*rn*ga.w,
                  b.x*rn*gb.x, b.y*rn*gb.y, b.z*rn*gb.z, b.w*rn*gb.w};
    float amax = 0.f;
#pragma unroll
    for (int i = 0; i < 8; ++i) amax = fmaxf(amax, fabsf(v[i]));
#pragma unroll
    for (int o = 32; o > 0; o >>= 1) amax = fmaxf(amax, __shfl_xor(amax, o));
    float scale = 127.f / fmaxf(amax, 1e-5f);
    float q[8];
#pragma unroll
    for (int i = 0; i < 8; ++i) {
        float tq = rintf(v[i] * scale);
        tq = fminf(fmaxf(tq, -128.f), 127.f);
        q[i] = tq / scale;
    }
    float* orow = out + (size_t)row * DD + lane * 8;
    *(float4*)orow       = make_float4(q[0], q[1], q[2], q[3]);
    *(float4*)(orow + 4) = make_float4(q[4], q[5], q[6], q[7]);
}

// ---------------- DoRA low-rank delta ----------------
__global__ void k_lora1(const float* __restrict__ X, const float* __restrict__ Amat,
                        float* __restrict__ tmp) {
    int t = threadIdx.x;
    int r = blockIdx.x * 16 + (t >> 4);
    int cc = t & 15;
    const float4* xr = (const float4*)(X + (size_t)r * DD);
    const float4* ar = (const float4*)(Amat + (size_t)cc * DD);
    float acc = 0.f;
#pragma unroll 4
    for (int k = 0; k < 128; ++k) {
        float4 xa = xr[k], aa = ar[k];
        acc += xa.x*aa.x + xa.y*aa.y + xa.z*aa.z + xa.w*aa.w;
    }
    tmp[(size_t)r * 16 + cc] = acc;
}

__global__ void k_lora2(const float* __restrict__ tmp, const float* __restrict__ Bmat,
                        float* __restrict__ qf) {
    int idx = blockIdx.x * 256 + threadIdx.x;
    int m2 = idx >> 9, n2 = idx & 511;
    const float4* tr = (const float4*)(tmp + (size_t)m2 * 16);
    const float4* br = (const float4*)(Bmat + (size_t)n2 * 16);
    float acc = 0.f;
#pragma unroll
    for (int rr = 0; rr < 4; ++rr) {
        float4 ta = tr[rr], ba = br[rr];
        acc += ta.x*ba.x + ta.y*ba.y + ta.z*ba.z + ta.w*ba.w;
    }
    qf[idx] = acc;
}

// ---------------- fp32 tiled GEMM: C[M,N] = A[M,512] @ W[N,512]^T (+epilogues) ----------------
// MODE 0: plain store. MODE 1: C + mag[n/64]*Cout (in-place delta add). MODE 2: C + residual.
template <int MODE>
__global__ void k_gemm(const float* __restrict__ A, const float* __restrict__ Wt,
                       float* __restrict__ Cout, const float* __restrict__ Extra,
                       int M, int N) {
    __shared__ float sA[16][65];
    __shared__ float sB[16][65];
    int tx = threadIdx.x & 15, ty = threadIdx.x >> 4;
    int m0 = blockIdx.y * 64, n0 = blockIdx.x * 64;
    float acc[4][4] = {};
    int t = threadIdx.x;
    int lr = t >> 2, lc = t & 3;
    const float* Abase = A + (size_t)(m0 + lr) * DD + lc * 4;
    const float* Bbase = Wt + (size_t)(n0 + lr) * DD + lc * 4;
    for (int k0 = 0; k0 < DD; k0 += 16) {
        float4 av = *(const float4*)(Abase + k0);
        float4 bv = *(const float4*)(Bbase + k0);
        __syncthreads();
        sA[lc*4+0][lr] = av.x; sA[lc*4+1][lr] = av.y;
        sA[lc*4+2][lr] = av.z; sA[lc*4+3][lr] = av.w;
        sB[lc*4+0][lr] = bv.x; sB[lc*4+1][lr] = bv.y;
        sB[lc*4+2][lr] = bv.z; sB[lc*4+3][lr] = bv.w;
        __syncthreads();
#pragma unroll
        for (int k = 0; k < 16; ++k) {
            float ar[4], br[4];
#pragma unroll
            for (int i = 0; i < 4; ++i) ar[i] = sA[k][ty*4+i];
#pragma unroll
            for (int j = 0; j < 4; ++j) br[j] = sB[k][tx*4+j];
#pragma unroll
            for (int i = 0; i < 4; ++i)
#pragma unroll
                for (int j = 0; j < 4; ++j)
                    acc[i][j] = fmaf(ar[i], br[j], acc[i][j]);
        }
    }
#pragma unroll
    for (int i = 0; i < 4; ++i) {
        int mm = m0 + ty*4 + i;
#pragma unroll
        for (int j = 0; j < 4; ++j) {
            int nn = n0 + tx*4 + j;
            size_t idx = (size_t)mm * N + nn;
            if (MODE == 0)      Cout[idx] = acc[i][j];
            else if (MODE == 1) Cout[idx] = acc[i][j] + Extra[nn >> 6] * Cout[idx];
            else                Cout[idx] = acc[i][j] + Extra[idx];
        }
    }
}

// ---------------- bf16 conversion kernels ----------------
// qf [B*Nq][512] fp32 -> Qb [B][H][Nq][64] bf16
__global__ __launch_bounds__(256) void k_cvt_q(const float* __restrict__ qf,
                                               unsigned short* __restrict__ Qb, int Nq) {
    int tid = blockIdx.x * 256 + threadIdx.x;
    size_t e = (size_t)tid * 8;
    int rowi = (int)(e >> 9);
    int wr = (int)(e & 511);
    int b = rowi / Nq, q = rowi - b * Nq;
    int h = wr >> 6, d = wr & 63;
    const float4* src = reinterpret_cast<const float4*>(qf + e);
    float4 a = src[0], bb = src[1];
    u16x8 v;
    v[0]=f2bf(a.x); v[1]=f2bf(a.y); v[2]=f2bf(a.z); v[3]=f2bf(a.w);
    v[4]=f2bf(bb.x); v[5]=f2bf(bb.y); v[6]=f2bf(bb.z); v[7]=f2bf(bb.w);
    *reinterpret_cast<u16x8*>(Qb + ((size_t)(b * NHEAD + h) * Nq + q) * 64 + d) = v;
}

// kvb [B*Nc][1024] fp32 -> Kb [B][H][Nc][64] bf16, Vt [B][H][64][Nc] bf16 (V transposed)
__global__ __launch_bounds__(256) void k_cvt_kv(const float* __restrict__ kvb,
                                                unsigned short* __restrict__ Kb,
                                                unsigned short* __restrict__ Vt, int Nc) {
    __shared__ unsigned short sT[64][72];
    int t = threadIdx.x;
    int h = blockIdx.y, b = blockIdx.z;
    int kt0 = blockIdx.x * 64;
#pragma unroll
    for (int i = 0; i < 2; ++i) {
        int cc = t + i * 256;
        int key = cc >> 3, seg = cc & 7;
        const float* src = kvb + ((size_t)(b * Nc) + kt0 + key) * 1024 + h * 64 + seg * 8;
        u16x8 kq, vq;
#pragma unroll
        for (int j = 0; j < 8; ++j) { kq[j] = f2bf(src[j]); vq[j] = f2bf(src[512 + j]); }
        *reinterpret_cast<u16x8*>(Kb + ((size_t)(b * NHEAD + h) * Nc + kt0 + key) * 64 + seg * 8) = kq;
        *reinterpret_cast<u16x8*>(&sT[key][seg * 8]) = vq;
    }
    __syncthreads();
#pragma unroll
    for (int i = 0; i < 2; ++i) {
        int cc = t + i * 256;
        int d = cc >> 3, ks = cc & 7;
        u16x8 v;
#pragma unroll
        for (int j = 0; j < 8; ++j) v[j] = sT[ks * 8 + j][d];
        *reinterpret_cast<u16x8*>(Vt + ((size_t)(b * NHEAD + h) * 64 + d) * Nc + kt0 + ks * 8) = v;
    }
}

// ---------------- flash attention, bf16 MFMA 16x16x32 ----------------
// grid(Nq/64, H, B), 256 threads = 4 waves, each wave owns 16 query rows.
__global__ __launch_bounds__(256) void k_attn_mfma(
    const unsigned short* __restrict__ Qb, const unsigned short* __restrict__ Kb,
    const unsigned short* __restrict__ Vt, float* __restrict__ attn,
    int Nq, int Nc) {
    __shared__ unsigned short sK[64][72];   // [key][d], padded
    __shared__ unsigned short sVt[64][72];  // [d][key], padded
    __shared__ unsigned short sP[4][16][72]; // per-wave P tile [q][key]
    int t = threadIdx.x;
    int w = t >> 6, lane = t & 63;
    int lr = lane & 15, lg = lane >> 4;
    int h = blockIdx.y, b = blockIdx.z;
    int bh = b * NHEAD + h;
    int q0 = blockIdx.x * 64 + w * 16;

    // Q fragments (A layout: row = lane&15, k = (lane>>4)*8 + j)
    const unsigned short* qbase = Qb + ((size_t)bh * Nq + q0 + lr) * 64 + lg * 8;
    bf16x8 aq0 = *reinterpret_cast<const bf16x8*>(qbase);
    bf16x8 aq1 = *reinterpret_cast<const bf16x8*>(qbase + 32);

    f32x4 o[4] = {};
    float m[4] = {-1e30f, -1e30f, -1e30f, -1e30f};
    float lsum[4] = {0.f, 0.f, 0.f, 0.f};

    const unsigned short* kglob = Kb + (size_t)bh * Nc * 64;
    const unsigned short* vglob = Vt + (size_t)bh * 64 * (size_t)Nc;

    int srow = t >> 3, sseg = t & 7;
    for (int kt0 = 0; kt0 < Nc; kt0 += 64) {
        __syncthreads();  // previous iteration's LDS reads complete
#pragma unroll
        for (int i = 0; i < 2; ++i) {
            int r2 = srow + i * 32;
            *reinterpret_cast<bf16x8*>(&sK[r2][sseg * 8]) =
                *reinterpret_cast<const bf16x8*>(kglob + (size_t)(kt0 + r2) * 64 + sseg * 8);
            *reinterpret_cast<bf16x8*>(&sVt[r2][sseg * 8]) =
                *reinterpret_cast<const bf16x8*>(vglob + (size_t)r2 * Nc + kt0 + sseg * 8);
        }
        __syncthreads();
        // S = Q K^T * 0.125  (C layout: row=(lg*4+r) query, col=lr key)
        f32x4 s[4];
#pragma unroll
        for (int kt = 0; kt < 4; ++kt) {
            bf16x8 bk0 = *reinterpret_cast<const bf16x8*>(&sK[kt * 16 + lr][lg * 8]);
            bf16x8 bk1 = *reinterpret_cast<const bf16x8*>(&sK[kt * 16 + lr][32 + lg * 8]);
            f32x4 acc = {};
            acc = __builtin_amdgcn_mfma_f32_16x16x32_bf16(aq0, bk0, acc, 0, 0, 0);
            acc = __builtin_amdgcn_mfma_f32_16x16x32_bf16(aq1, bk1, acc, 0, 0, 0);
            s[kt] = acc * 0.125f;
        }
        // online softmax
        float mnew[4], alpha[4];
#pragma unroll
        for (int r = 0; r < 4; ++r) {
            float rm = fmaxf(fmaxf(s[0][r], s[1][r]), fmaxf(s[2][r], s[3][r]));
#pragma unroll
            for (int o2 = 8; o2 >= 1; o2 >>= 1) rm = fmaxf(rm, __shfl_xor(rm, o2));
            mnew[r] = fmaxf(m[r], rm);
            alpha[r] = __expf(m[r] - mnew[r]);
            m[r] = mnew[r];
        }
        float psum[4] = {0.f, 0.f, 0.f, 0.f};
#pragma unroll
        for (int kt = 0; kt < 4; ++kt) {
#pragma unroll
            for (int r = 0; r < 4; ++r) {
                float p = __expf(s[kt][r] - mnew[r]);
                psum[r] += p;
                sP[w][lg * 4 + r][kt * 16 + lr] = f2bf(p);
            }
        }
#pragma unroll
        for (int r = 0; r < 4; ++r) {
#pragma unroll
            for (int o2 = 8; o2 >= 1; o2 >>= 1) psum[r] += __shfl_xor(psum[r], o2);
            lsum[r] = lsum[r] * alpha[r] + psum[r];
        }
#pragma unroll
        for (int dt = 0; dt < 4; ++dt)
#pragma unroll
            for (int r = 0; r < 4; ++r) o[dt][r] *= alpha[r];
        __syncthreads();  // sP visible (cross-lane through LDS)
        // O += P @ V   (A = P from sP, B = V^T from sVt; same k-permutation both sides)
#pragma unroll
        for (int kg = 0; kg < 2; ++kg) {
            bf16x8 pa = *reinterpret_cast<const bf16x8*>(&sP[w][lr][kg * 32 + lg * 8]);
#pragma unroll
            for (int dt = 0; dt < 4; ++dt) {
                bf16x8 vb = *reinterpret_cast<const bf16x8*>(&sVt[dt * 16 + lr][kg * 32 + lg * 8]);
                o[dt] = __builtin_amdgcn_mfma_f32_16x16x32_bf16(pa, vb, o[dt], 0, 0, 0);
            }
        }
    }
    // epilogue: normalize and store fp32 [B*Nq][512]
    float* obase = attn + ((size_t)b * Nq + q0) * DD + h * HDIM;
#pragma unroll
    for (int dt = 0; dt < 4; ++dt)
#pragma unroll
        for (int r = 0; r < 4; ++r) {
            int qr = lg * 4 + r;
            obase[(size_t)qr * DD + dt * 16 + lr] = o[dt][r] / lsum[r];
        }
}

// ---------------- host side ----------------
static void run_pass(const float* q_in, const float* ctx,
                     const float* Wq_dq, const float* gq,
                     const float* Wkv_dq, const float* gkv,
                     const float* Amat, const float* Bmat, const float* mag,
                     const float* Wp_dq, const float* gp,
                     int Mq, int Mc, int Nq, int Nc,
                     float* arena, float* outp, const float* resid, hipStream_t stream) {
    float* q_nq = arena;
    float* c_nq = q_nq + (size_t)Mq * 512;
    float* qf   = c_nq + (size_t)Mc * 512;
    float* kvb  = qf + (size_t)Mq * 512;
    float* attn = kvb + (size_t)Mc * 1024;
    float* tmp  = attn + (size_t)Mq * 512;

    k_rmsq<<<Mq, 64, 0, stream>>>(q_in, gq, q_nq);
    k_rmsq<<<Mc, 64, 0, stream>>>(ctx, gkv, c_nq);
    k_lora1<<<Mq / 16, 256, 0, stream>>>(q_in, Amat, tmp);
    k_lora2<<<(Mq * 512) / 256, 256, 0, stream>>>(tmp, Bmat, qf);
    k_gemm<1><<<dim3(512 / 64, Mq / 64), 256, 0, stream>>>(q_nq, Wq_dq, qf, mag, Mq, 512);
    k_gemm<0><<<dim3(1024 / 64, Mc / 64), 256, 0, stream>>>(c_nq, Wkv_dq, kvb, nullptr, Mc, 1024);

    // bf16 buffers reuse dead fp32 regions (stream-ordered):
    // Qb over q_nq (dead after gemm1, rewritten by the later k_rmsq which covers it fully)
    // Kb+Vt over c_nq (dead after gemm2): Mc*512 bf16 + Mc*512 bf16 = Mc*512 floats exactly
    unsigned short* Qb = (unsigned short*)q_nq;
    unsigned short* Kb = (unsigned short*)c_nq;
    unsigned short* Vt = (unsigned short*)(c_nq + (size_t)Mc * 256);
    k_cvt_q<<<Mq / 4, 256, 0, stream>>>(qf, Qb, Nq);
    k_cvt_kv<<<dim3(Nc / 64, NHEAD, 4), 256, 0, stream>>>(kvb, Kb, Vt, Nc);
    k_attn_mfma<<<dim3(Nq / 64, NHEAD, 4), 256, 0, stream>>>(Qb, Kb, Vt, attn, Nq, Nc);

    k_rmsq<<<Mq, 64, 0, stream>>>(attn, gp, q_nq);  // overwrites Qb region (dead)
    k_gemm<2><<<dim3(512 / 64, Mq / 64), 256, 0, stream>>>(q_nq, Wp_dq, outp, resid, Mq, 512);
}

extern "C" void kernel_launch(void* const* d_in, const int* in_sizes, int n_in,
                              void* d_out, int out_size, void* d_ws, size_t ws_size,
                              hipStream_t stream) {
    const float* x     = (const float*)d_in[0];
    const float* c     = (const float*)d_in[1];
    const float* Wq_x  = (const float*)d_in[2];
    const float* g_qx  = (const float*)d_in[3];
    const float* Wkv_c = (const float*)d_in[4];
    const float* g_kvc = (const float*)d_in[5];
    const float* A_x   = (const float*)d_in[6];
    const float* B_x   = (const float*)d_in[7];
    const float* mag_x = (const float*)d_in[8];
    const float* Wp_x  = (const float*)d_in[9];
    const float* g_px  = (const float*)d_in[10];
    const float* Wq_c  = (const float*)d_in[11];
    const float* g_qc  = (const float*)d_in[12];
    const float* Wkv_x = (const float*)d_in[13];
    const float* g_kvx = (const float*)d_in[14];
    const float* A_c   = (const float*)d_in[15];
    const float* B_c   = (const float*)d_in[16];
    const float* mag_c = (const float*)d_in[17];
    const float* Wp_c  = (const float*)d_in[18];
    const float* g_pc  = (const float*)d_in[19];

    float* ws = (float*)d_ws;
    const float* Wsrc[6] = {Wq_x, Wkv_c, Wp_x, Wq_c, Wkv_x, Wp_c};
    const int    Wcnt[6] = {262144, 524288, 262144, 262144, 524288, 262144};
    const size_t Woff[6] = {0, 262144, 786432, 1048576, 1310720, 1835008};
    float* part  = ws + 2097152;
    float* scal  = part + 192;
    float* arena = ws + 2097152 + 1024;

    size_t need1 = 3 * (size_t)16384 * 512 + (size_t)4096 * 512 + (size_t)4096 * 1024 + (size_t)16384 * 16;
    size_t need2 = 3 * (size_t)4096 * 512 + (size_t)16384 * 512 + (size_t)16384 * 1024 + (size_t)4096 * 16;
    size_t need = (2097152 + 1024 + (need1 > need2 ? need1 : need2)) * sizeof(float);
    if (ws_size < need) return;

    for (int m = 0; m < 6; ++m)
        k_wabs_partial<<<32, 256, 0, stream>>>(Wsrc[m], Wcnt[m], part + m * 32);
    k_wfinal<<<1, 64, 0, stream>>>(part, scal);
    for (int m = 0; m < 6; ++m)
        k_wquant<<<(Wcnt[m] + 255) / 256, 256, 0, stream>>>(Wsrc[m], ws + Woff[m], scal + m, Wcnt[m]);

    float* outx = (float*)d_out;
    float* outc = outx + (size_t)4 * 4096 * 512;

    // pass 1: x queries attend to c
    run_pass(x, c, ws + Woff[0], g_qx, ws + Woff[1], g_kvc, A_x, B_x, mag_x, ws + Woff[2], g_px,
             16384, 4096, 4096, 1024, arena, outx, x, stream);
    // pass 2: c queries attend to x
    run_pass(c, x, ws + Woff[3], g_qc, ws + Woff[4], g_kvx, A_c, B_c, mag_c, ws + Woff[5], g_pc,
             4096, 16384, 1024, 4096, arena, outc, c, stream);
}

// Round 3
// 712.565 us; speedup vs baseline: 23.5100x; 2.0248x over previous
//
#include <hip/hip_runtime.h>
#include <math.h>

#define DD 512
#define NHEAD 8
#define HDIM 64

typedef __bf16 bf16x8 __attribute__((ext_vector_type(8)));
typedef unsigned short u16x8 __attribute__((ext_vector_type(8)));
typedef float f32x4 __attribute__((ext_vector_type(4)));

static __device__ __forceinline__ unsigned short f2bf(float f) {
    unsigned u = __builtin_bit_cast(unsigned, f);
    u += 0x7fffu + ((u >> 16) & 1u);   // round-to-nearest-even
    return (unsigned short)(u >> 16);
}

#define GLOAD16(g, l)                                                          \
    __builtin_amdgcn_global_load_lds(                                          \
        (__attribute__((address_space(1))) void*)(g),                          \
        (__attribute__((address_space(3))) void*)(l), 16, 0, 0)

// ---------------- weight ternary quant: two-stage deterministic mean|W| ----------------
__global__ void k_wabs_partial(const float* __restrict__ W, int n, float* __restrict__ part) {
    int t = threadIdx.x;
    float s = 0.f;
    for (int i = blockIdx.x * blockDim.x + t; i < n; i += blockDim.x * gridDim.x)
        s += fabsf(W[i]);
    __shared__ float red[4];
#pragma unroll
    for (int o = 32; o > 0; o >>= 1) s += __shfl_down(s, o);
    if ((t & 63) == 0) red[t >> 6] = s;
    __syncthreads();
    if (t == 0) part[blockIdx.x] = red[0] + red[1] + red[2] + red[3];
}

__global__ void k_wfinal(const float* __restrict__ part, float* __restrict__ scal,
                         float* __restrict__ winv) {
    int m = threadIdx.x;
    if (m < 6) {
        const int cnt[6] = {262144, 524288, 262144, 262144, 524288, 262144};
        float s = 0.f;
        for (int i = 0; i < 32; ++i) s += part[m * 32 + i];
        float mean = fmaxf(s / (float)cnt[m], 1e-5f);
        scal[m] = 1.f / mean;   // multiply scale
        winv[m] = mean;         // dequant factor (1/scale)
    }
}

// ternary weights as bf16 {-1,0,1}
__global__ void k_wquant(const float* __restrict__ W, unsigned short* __restrict__ Wq,
                         const float* __restrict__ scal, int n) {
    int i = blockIdx.x * 256 + threadIdx.x;
    if (i < n) {
        float sc = *scal;
        float t = rintf(W[i] * sc);
        t = fminf(fmaxf(t, -1.f), 1.f);
        Wq[i] = f2bf(t);   // exact: {-1,0,1}
    }
}

// ---------------- RMSNorm + per-token int8 absmax quant -> bf16 INTEGER activations ----------------
__global__ void k_rmsq(const float* __restrict__ X, const float* __restrict__ g,
                       unsigned short* __restrict__ out, float* __restrict__ a_inv) {
    int row = blockIdx.x;
    int lane = threadIdx.x; // 64 threads, 8 elems each
    const float* xr = X + (size_t)row * DD;
    float4 a = *(const float4*)(xr + lane * 8);
    float4 b = *(const float4*)(xr + lane * 8 + 4);
    float ss = a.x*a.x + a.y*a.y + a.z*a.z + a.w*a.w
             + b.x*b.x + b.y*b.y + b.z*b.z + b.w*b.w;
#pragma unroll
    for (int o = 32; o > 0; o >>= 1) ss += __shfl_xor(ss, o);
    float rn = 1.f / sqrtf(ss * (1.f / 512.f) + 1e-8f);
    float4 ga = *(const float4*)(g + lane * 8);
    float4 gb = *(const float4*)(g + lane * 8 + 4);
    float v[8] = {a.x*rn*ga.x, a.y*rn*ga.y, a.z*rn*ga.z, a.w*rn*ga.w,
                  b.x*rn*gb.x, b.y*rn*gb.y, b.z*rn*gb.z, b.w*rn*gb.w};
    float amax = 0.f;
#pragma unroll
    for (int i = 0; i < 8; ++i) amax = fmaxf(amax, fabsf(v[i]));
#pragma unroll
    for (int o = 32; o > 0; o >>= 1) amax = fmaxf(amax, __shfl_xor(amax, o));
    float mx = fmaxf(amax, 1e-5f);
    float scale = 127.f / mx;
    u16x8 qv;
#pragma unroll
    for (int i = 0; i < 8; ++i) {
        float tq = rintf(v[i] * scale);
        tq = fminf(fmaxf(tq, -128.f), 127.f);
        qv[i] = f2bf(tq);   // exact integer in bf16
    }
    *reinterpret_cast<u16x8*>(out + (size_t)row * DD + lane * 8) = qv;
    if (lane == 0) a_inv[row] = mx / 127.f;
}

// ---------------- DoRA low-rank delta ----------------
__global__ void k_lora1(const float* __restrict__ X, const float* __restrict__ Amat,
                        float* __restrict__ tmp) {
    int t = threadIdx.x;
    int r = blockIdx.x * 16 + (t >> 4);
    int cc = t & 15;
    const float4* xr = (const float4*)(X + (size_t)r * DD);
    const float4* ar = (const float4*)(Amat + (size_t)cc * DD);
    float acc = 0.f;
#pragma unroll 4
    for (int k = 0; k < 128; ++k) {
        float4 xa = xr[k], aa = ar[k];
        acc += xa.x*aa.x + xa.y*aa.y + xa.z*aa.z + xa.w*aa.w;
    }
    tmp[(size_t)r * 16 + cc] = acc;
}

__global__ void k_lora2(const float* __restrict__ tmp, const float* __restrict__ Bmat,
                        float* __restrict__ qf) {
    int idx = blockIdx.x * 256 + threadIdx.x;
    int m2 = idx >> 9, n2 = idx & 511;
    const float4* tr = (const float4*)(tmp + (size_t)m2 * 16);
    const float4* br = (const float4*)(Bmat + (size_t)n2 * 16);
    float acc = 0.f;
#pragma unroll
    for (int rr = 0; rr < 4; ++rr) {
        float4 ta = tr[rr], ba = br[rr];
        acc += ta.x*ba.x + ta.y*ba.y + ta.z*ba.z + ta.w*ba.w;
    }
    qf[idx] = acc;
}

// ---------------- bf16 MFMA GEMM: C[M,N] = (Aq[M,512] @ Wq[N,512]^T) * a_inv[m] * winv ----------------
// MODE 0: plain. MODE 1: val + mag[n>>6]*Cout (in-place delta add). MODE 2: val + residual.
// 256 thr = 4 waves (2x2), wave = 64x64 out (4x4 frags of 16x16), BK=32, m97-style staging.
template <int MODE>
__global__ __launch_bounds__(256) void k_gemm_mfma(
    const unsigned short* __restrict__ Aq, const unsigned short* __restrict__ Wq,
    float* __restrict__ Cout, const float* __restrict__ a_inv,
    const float* __restrict__ winv_p, const float* __restrict__ Extra,
    int M, int N) {
    __shared__ __align__(16) unsigned short sA[128 * 32];
    __shared__ __align__(16) unsigned short sB[128 * 32];
    int t = threadIdx.x;
    int w = t >> 6, lane = t & 63;
    int wm = w >> 1, wn = w & 1;
    int lr = lane & 15, lg = lane >> 4;
    int m0 = blockIdx.y * 128, n0 = blockIdx.x * 128;
    int row_st = t >> 2, chunk = t & 3;   // staging: idx=i*256+t -> row=i*64+row_st
    f32x4 acc[4][4] = {};

    for (int k0 = 0; k0 < 512; k0 += 32) {
        __syncthreads();   // prev-iter LDS reads complete before overwrite
#pragma unroll
        for (int i = 0; i < 2; ++i) {
            int row = i * 64 + row_st;
            GLOAD16(Aq + (size_t)(m0 + row) * 512 + k0 + chunk * 8, sA + ((size_t)i * 256 + t) * 8);
            GLOAD16(Wq + (size_t)(n0 + row) * 512 + k0 + chunk * 8, sB + ((size_t)i * 256 + t) * 8);
        }
        asm volatile("s_waitcnt vmcnt(0)" ::: "memory");
        __syncthreads();
        bf16x8 af[4], bfr[4];
#pragma unroll
        for (int mt = 0; mt < 4; ++mt)
            af[mt] = *reinterpret_cast<const bf16x8*>(&sA[(wm * 64 + mt * 16 + lr) * 32 + lg * 8]);
#pragma unroll
        for (int nt = 0; nt < 4; ++nt)
            bfr[nt] = *reinterpret_cast<const bf16x8*>(&sB[(wn * 64 + nt * 16 + lr) * 32 + lg * 8]);
#pragma unroll
        for (int mt = 0; mt < 4; ++mt)
#pragma unroll
            for (int nt = 0; nt < 4; ++nt)
                acc[mt][nt] = __builtin_amdgcn_mfma_f32_16x16x32_bf16(af[mt], bfr[nt], acc[mt][nt], 0, 0, 0);
    }

    float wv = *winv_p;
#pragma unroll
    for (int mt = 0; mt < 4; ++mt) {
#pragma unroll
        for (int r = 0; r < 4; ++r) {
            int m = m0 + wm * 64 + mt * 16 + lg * 4 + r;
            float as = a_inv[m] * wv;
#pragma unroll
            for (int nt = 0; nt < 4; ++nt) {
                int n = n0 + wn * 64 + nt * 16 + lr;
                size_t idx = (size_t)m * N + n;
                float val = acc[mt][nt][r] * as;
                if (MODE == 0)      Cout[idx] = val;
                else if (MODE == 1) Cout[idx] = val + Extra[n >> 6] * Cout[idx];
                else                Cout[idx] = val + Extra[idx];
            }
        }
    }
}

// ---------------- bf16 conversion kernels (attention inputs) ----------------
__global__ __launch_bounds__(256) void k_cvt_q(const float* __restrict__ qf,
                                               unsigned short* __restrict__ Qb, int Nq) {
    int tid = blockIdx.x * 256 + threadIdx.x;
    size_t e = (size_t)tid * 8;
    int rowi = (int)(e >> 9);
    int wr = (int)(e & 511);
    int b = rowi / Nq, q = rowi - b * Nq;
    int h = wr >> 6, d = wr & 63;
    const float4* src = reinterpret_cast<const float4*>(qf + e);
    float4 a = src[0], bb = src[1];
    u16x8 v;
    v[0]=f2bf(a.x); v[1]=f2bf(a.y); v[2]=f2bf(a.z); v[3]=f2bf(a.w);
    v[4]=f2bf(bb.x); v[5]=f2bf(bb.y); v[6]=f2bf(bb.z); v[7]=f2bf(bb.w);
    *reinterpret_cast<u16x8*>(Qb + ((size_t)(b * NHEAD + h) * Nq + q) * 64 + d) = v;
}

__global__ __launch_bounds__(256) void k_cvt_kv(const float* __restrict__ kvb,
                                                unsigned short* __restrict__ Kb,
                                                unsigned short* __restrict__ Vt, int Nc) {
    __shared__ unsigned short sT[64][72];
    int t = threadIdx.x;
    int h = blockIdx.y, b = blockIdx.z;
    int kt0 = blockIdx.x * 64;
#pragma unroll
    for (int i = 0; i < 2; ++i) {
        int cc = t + i * 256;
        int key = cc >> 3, seg = cc & 7;
        const float* src = kvb + ((size_t)(b * Nc) + kt0 + key) * 1024 + h * 64 + seg * 8;
        u16x8 kq, vq;
#pragma unroll
        for (int j = 0; j < 8; ++j) { kq[j] = f2bf(src[j]); vq[j] = f2bf(src[512 + j]); }
        *reinterpret_cast<u16x8*>(Kb + ((size_t)(b * NHEAD + h) * Nc + kt0 + key) * 64 + seg * 8) = kq;
        *reinterpret_cast<u16x8*>(&sT[key][seg * 8]) = vq;
    }
    __syncthreads();
#pragma unroll
    for (int i = 0; i < 2; ++i) {
        int cc = t + i * 256;
        int d = cc >> 3, ks = cc & 7;
        u16x8 v;
#pragma unroll
        for (int j = 0; j < 8; ++j) v[j] = sT[ks * 8 + j][d];
        *reinterpret_cast<u16x8*>(Vt + ((size_t)(b * NHEAD + h) * 64 + d) * Nc + kt0 + ks * 8) = v;
    }
}

// ---------------- flash attention, bf16 MFMA 16x16x32 ----------------
__global__ __launch_bounds__(256) void k_attn_mfma(
    const unsigned short* __restrict__ Qb, const unsigned short* __restrict__ Kb,
    const unsigned short* __restrict__ Vt, float* __restrict__ attn,
    int Nq, int Nc) {
    __shared__ unsigned short sK[64][72];
    __shared__ unsigned short sVt[64][72];
    __shared__ unsigned short sP[4][16][72];
    int t = threadIdx.x;
    int w = t >> 6, lane = t & 63;
    int lr = lane & 15, lg = lane >> 4;
    int h = blockIdx.y, b = blockIdx.z;
    int bh = b * NHEAD + h;
    int q0 = blockIdx.x * 64 + w * 16;

    const unsigned short* qbase = Qb + ((size_t)bh * Nq + q0 + lr) * 64 + lg * 8;
    bf16x8 aq0 = *reinterpret_cast<const bf16x8*>(qbase);
    bf16x8 aq1 = *reinterpret_cast<const bf16x8*>(qbase + 32);

    f32x4 o[4] = {};
    float m[4] = {-1e30f, -1e30f, -1e30f, -1e30f};
    float lsum[4] = {0.f, 0.f, 0.f, 0.f};

    const unsigned short* kglob = Kb + (size_t)bh * Nc * 64;
    const unsigned short* vglob = Vt + (size_t)bh * 64 * (size_t)Nc;

    int srow = t >> 3, sseg = t & 7;
    for (int kt0 = 0; kt0 < Nc; kt0 += 64) {
        __syncthreads();
#pragma unroll
        for (int i = 0; i < 2; ++i) {
            int r2 = srow + i * 32;
            *reinterpret_cast<bf16x8*>(&sK[r2][sseg * 8]) =
                *reinterpret_cast<const bf16x8*>(kglob + (size_t)(kt0 + r2) * 64 + sseg * 8);
            *reinterpret_cast<bf16x8*>(&sVt[r2][sseg * 8]) =
                *reinterpret_cast<const bf16x8*>(vglob + (size_t)r2 * Nc + kt0 + sseg * 8);
        }
        __syncthreads();
        f32x4 s[4];
#pragma unroll
        for (int kt = 0; kt < 4; ++kt) {
            bf16x8 bk0 = *reinterpret_cast<const bf16x8*>(&sK[kt * 16 + lr][lg * 8]);
            bf16x8 bk1 = *reinterpret_cast<const bf16x8*>(&sK[kt * 16 + lr][32 + lg * 8]);
            f32x4 acc = {};
            acc = __builtin_amdgcn_mfma_f32_16x16x32_bf16(aq0, bk0, acc, 0, 0, 0);
            acc = __builtin_amdgcn_mfma_f32_16x16x32_bf16(aq1, bk1, acc, 0, 0, 0);
            s[kt] = acc * 0.125f;
        }
        float mnew[4], alpha[4];
#pragma unroll
        for (int r = 0; r < 4; ++r) {
            float rm = fmaxf(fmaxf(s[0][r], s[1][r]), fmaxf(s[2][r], s[3][r]));
#pragma unroll
            for (int o2 = 8; o2 >= 1; o2 >>= 1) rm = fmaxf(rm, __shfl_xor(rm, o2));
            mnew[r] = fmaxf(m[r], rm);
            alpha[r] = __expf(m[r] - mnew[r]);
            m[r] = mnew[r];
        }
        float psum[4] = {0.f, 0.f, 0.f, 0.f};
#pragma unroll
        for (int kt = 0; kt < 4; ++kt) {
#pragma unroll
            for (int r = 0; r < 4; ++r) {
                float p = __expf(s[kt][r] - mnew[r]);
                psum[r] += p;
                sP[w][lg * 4 + r][kt * 16 + lr] = f2bf(p);
            }
        }
#pragma unroll
        for (int r = 0; r < 4; ++r) {
#pragma unroll
            for (int o2 = 8; o2 >= 1; o2 >>= 1) psum[r] += __shfl_xor(psum[r], o2);
            lsum[r] = lsum[r] * alpha[r] + psum[r];
        }
#pragma unroll
        for (int dt = 0; dt < 4; ++dt)
#pragma unroll
            for (int r = 0; r < 4; ++r) o[dt][r] *= alpha[r];
        __syncthreads();
#pragma unroll
        for (int kg = 0; kg < 2; ++kg) {
            bf16x8 pa = *reinterpret_cast<const bf16x8*>(&sP[w][lr][kg * 32 + lg * 8]);
#pragma unroll
            for (int dt = 0; dt < 4; ++dt) {
                bf16x8 vb = *reinterpret_cast<const bf16x8*>(&sVt[dt * 16 + lr][kg * 32 + lg * 8]);
                o[dt] = __builtin_amdgcn_mfma_f32_16x16x32_bf16(pa, vb, o[dt], 0, 0, 0);
            }
        }
    }
    float* obase = attn + ((size_t)b * Nq + q0) * DD + h * HDIM;
#pragma unroll
    for (int dt = 0; dt < 4; ++dt)
#pragma unroll
        for (int r = 0; r < 4; ++r) {
            int qr = lg * 4 + r;
            obase[(size_t)qr * DD + dt * 16 + lr] = o[dt][r] / lsum[r];
        }
}

// ---------------- host side ----------------
static void run_pass(const float* q_in, const float* ctx,
                     const unsigned short* Wq_t, const float* gq,
                     const unsigned short* Wkv_t, const float* gkv,
                     const float* Amat, const float* Bmat, const float* mag,
                     const unsigned short* Wp_t, const float* gp,
                     const float* winv_q, const float* winv_kv, const float* winv_p,
                     int Mq, int Mc, int Nq, int Nc,
                     float* arena, float* outp, const float* resid, hipStream_t stream) {
    float* q_nq = arena;
    float* c_nq = q_nq + (size_t)Mq * 512;
    float* qf   = c_nq + (size_t)Mc * 512;
    float* kvb  = qf + (size_t)Mq * 512;
    float* attn = kvb + (size_t)Mc * 1024;
    float* tmp  = attn + (size_t)Mq * 512;
    float* sc_q = tmp + (size_t)Mq * 16;
    float* sc_c = sc_q + Mq;
    float* sc_o = sc_c + Mc;

    unsigned short* q_act = (unsigned short*)q_nq;   // bf16 integer activations
    unsigned short* c_act = (unsigned short*)c_nq;

    k_rmsq<<<Mq, 64, 0, stream>>>(q_in, gq, q_act, sc_q);
    k_rmsq<<<Mc, 64, 0, stream>>>(ctx, gkv, c_act, sc_c);
    k_lora1<<<Mq / 16, 256, 0, stream>>>(q_in, Amat, tmp);
    k_lora2<<<(Mq * 512) / 256, 256, 0, stream>>>(tmp, Bmat, qf);
    k_gemm_mfma<1><<<dim3(512 / 128, Mq / 128), 256, 0, stream>>>(
        q_act, Wq_t, qf, sc_q, winv_q, mag, Mq, 512);
    k_gemm_mfma<0><<<dim3(1024 / 128, Mc / 128), 256, 0, stream>>>(
        c_act, Wkv_t, kvb, sc_c, winv_kv, nullptr, Mc, 1024);

    // bf16 attention buffers overlay dead activation regions (stream-ordered)
    unsigned short* Qb = (unsigned short*)q_nq;
    unsigned short* Kb = (unsigned short*)c_nq;
    unsigned short* Vt = (unsigned short*)(c_nq + (size_t)Mc * 256);
    k_cvt_q<<<Mq / 4, 256, 0, stream>>>(qf, Qb, Nq);
    k_cvt_kv<<<dim3(Nc / 64, NHEAD, 4), 256, 0, stream>>>(kvb, Kb, Vt, Nc);
    k_attn_mfma<<<dim3(Nq / 64, NHEAD, 4), 256, 0, stream>>>(Qb, Kb, Vt, attn, Nq, Nc);

    k_rmsq<<<Mq, 64, 0, stream>>>(attn, gp, q_act, sc_o);  // overwrites Qb (dead)
    k_gemm_mfma<2><<<dim3(512 / 128, Mq / 128), 256, 0, stream>>>(
        q_act, Wp_t, outp, sc_o, winv_p, resid, Mq, 512);
}

extern "C" void kernel_launch(void* const* d_in, const int* in_sizes, int n_in,
                              void* d_out, int out_size, void* d_ws, size_t ws_size,
                              hipStream_t stream) {
    const float* x     = (const float*)d_in[0];
    const float* c     = (const float*)d_in[1];
    const float* Wq_x  = (const float*)d_in[2];
    const float* g_qx  = (const float*)d_in[3];
    const float* Wkv_c = (const float*)d_in[4];
    const float* g_kvc = (const float*)d_in[5];
    const float* A_x   = (const float*)d_in[6];
    const float* B_x   = (const float*)d_in[7];
    const float* mag_x = (const float*)d_in[8];
    const float* Wp_x  = (const float*)d_in[9];
    const float* g_px  = (const float*)d_in[10];
    const float* Wq_c  = (const float*)d_in[11];
    const float* g_qc  = (const float*)d_in[12];
    const float* Wkv_x = (const float*)d_in[13];
    const float* g_kvx = (const float*)d_in[14];
    const float* A_c   = (const float*)d_in[15];
    const float* B_c   = (const float*)d_in[16];
    const float* mag_c = (const float*)d_in[17];
    const float* Wp_c  = (const float*)d_in[18];
    const float* g_pc  = (const float*)d_in[19];

    float* ws = (float*)d_ws;
    const float* Wsrc[6] = {Wq_x, Wkv_c, Wp_x, Wq_c, Wkv_x, Wp_c};
    const int    Wcnt[6] = {262144, 524288, 262144, 262144, 524288, 262144};
    const size_t Woff[6] = {0, 262144, 786432, 1048576, 1310720, 1835008};
    float* part  = ws + 2097152;
    float* scal  = part + 192;
    float* winv  = scal + 8;
    float* arena = ws + 2097152 + 1024;

    size_t need1 = 3 * (size_t)16384 * 512 + (size_t)4096 * 512 + (size_t)4096 * 1024
                 + (size_t)16384 * 16 + 2 * (size_t)16384 + 4096;
    size_t need2 = 3 * (size_t)4096 * 512 + (size_t)16384 * 512 + (size_t)16384 * 1024
                 + (size_t)4096 * 16 + 2 * (size_t)4096 + 16384;
    size_t need = (2097152 + 1024 + (need1 > need2 ? need1 : need2)) * sizeof(float);
    if (ws_size < need) return;

    for (int m = 0; m < 6; ++m)
        k_wabs_partial<<<32, 256, 0, stream>>>(Wsrc[m], Wcnt[m], part + m * 32);
    k_wfinal<<<1, 64, 0, stream>>>(part, scal, winv);
    for (int m = 0; m < 6; ++m)
        k_wquant<<<(Wcnt[m] + 255) / 256, 256, 0, stream>>>(
            Wsrc[m], (unsigned short*)(ws + Woff[m]), scal + m, Wcnt[m]);

    float* outx = (float*)d_out;
    float* outc = outx + (size_t)4 * 4096 * 512;

    // pass 1: x queries attend to c
    run_pass(x, c, (const unsigned short*)(ws + Woff[0]), g_qx,
             (const unsigned short*)(ws + Woff[1]), g_kvc, A_x, B_x, mag_x,
             (const unsigned short*)(ws + Woff[2]), g_px,
             winv + 0, winv + 1, winv + 2,
             16384, 4096, 4096, 1024, arena, outx, x, stream);
    // pass 2: c queries attend to x
    run_pass(c, x, (const unsigned short*)(ws + Woff[3]), g_qc,
             (const unsigned short*)(ws + Woff[4]), g_kvx, A_c, B_c, mag_c,
             (const unsigned short*)(ws + Woff[5]), g_pc,
             winv + 3, winv + 4, winv + 5,
             4096, 16384, 1024, 4096, arena, outc, c, stream);
}

// Round 4
// 608.348 us; speedup vs baseline: 27.5375x; 1.1713x over previous
//
#include <hip/hip_runtime.h>
#include <math.h>

#define DD 512
#define NHEAD 8
#define HDIM 64

typedef __bf16 bf16x8 __attribute__((ext_vector_type(8)));
typedef unsigned short u16x8 __attribute__((ext_vector_type(8)));
typedef float f32x4 __attribute__((ext_vector_type(4)));

static __device__ __forceinline__ unsigned short f2bf(float f) {
    unsigned u = __builtin_bit_cast(unsigned, f);
    u += 0x7fffu + ((u >> 16) & 1u);   // round-to-nearest-even
    return (unsigned short)(u >> 16);
}

#define GLOAD16(g, l)                                                          \
    __builtin_amdgcn_global_load_lds(                                          \
        (__attribute__((address_space(1))) void*)(g),                          \
        (__attribute__((address_space(3))) void*)(l), 16, 0, 0)

// ---------------- weight ternary quant: two-stage deterministic mean|W| ----------------
__global__ void k_wabs_partial(const float* __restrict__ W, int n, float* __restrict__ part) {
    int t = threadIdx.x;
    float s = 0.f;
    for (int i = blockIdx.x * blockDim.x + t; i < n; i += blockDim.x * gridDim.x)
        s += fabsf(W[i]);
    __shared__ float red[4];
#pragma unroll
    for (int o = 32; o > 0; o >>= 1) s += __shfl_down(s, o);
    if ((t & 63) == 0) red[t >> 6] = s;
    __syncthreads();
    if (t == 0) part[blockIdx.x] = red[0] + red[1] + red[2] + red[3];
}

__global__ void k_wfinal(const float* __restrict__ part, float* __restrict__ scal,
                         float* __restrict__ winv) {
    int m = threadIdx.x;
    if (m < 6) {
        const int cnt[6] = {262144, 524288, 262144, 262144, 524288, 262144};
        float s = 0.f;
        for (int i = 0; i < 32; ++i) s += part[m * 32 + i];
        float mean = fmaxf(s / (float)cnt[m], 1e-5f);
        scal[m] = 1.f / mean;   // multiply scale
        winv[m] = mean;         // dequant factor (1/scale)
    }
}

// ternary weights as bf16 {-1,0,1}
__global__ void k_wquant(const float* __restrict__ W, unsigned short* __restrict__ Wq,
                         const float* __restrict__ scal, int n) {
    int i = blockIdx.x * 256 + threadIdx.x;
    if (i < n) {
        float sc = *scal;
        float t = rintf(W[i] * sc);
        t = fminf(fmaxf(t, -1.f), 1.f);
        Wq[i] = f2bf(t);   // exact: {-1,0,1}
    }
}

// ---------------- RMSNorm + per-token int8 absmax quant -> bf16 INTEGER activations ----------------
__global__ void k_rmsq(const float* __restrict__ X, const float* __restrict__ g,
                       unsigned short* __restrict__ out, float* __restrict__ a_inv) {
    int row = blockIdx.x;
    int lane = threadIdx.x; // 64 threads, 8 elems each
    const float* xr = X + (size_t)row * DD;
    float4 a = *(const float4*)(xr + lane * 8);
    float4 b = *(const float4*)(xr + lane * 8 + 4);
    float ss = a.x*a.x + a.y*a.y + a.z*a.z + a.w*a.w
             + b.x*b.x + b.y*b.y + b.z*b.z + b.w*b.w;
#pragma unroll
    for (int o = 32; o > 0; o >>= 1) ss += __shfl_xor(ss, o);
    float rn = 1.f / sqrtf(ss * (1.f / 512.f) + 1e-8f);
    float4 ga = *(const float4*)(g + lane * 8);
    float4 gb = *(const float4*)(g + lane * 8 + 4);
    float v[8] = {a.x*rn*ga.x, a.y*rn*ga.y, a.z*rn*ga.z, a.w*rn*ga.w,
                  b.x*rn*gb.x, b.y*rn*gb.y, b.z*rn*gb.z, b.w*rn*gb.w};
    float amax = 0.f;
#pragma unroll
    for (int i = 0; i < 8; ++i) amax = fmaxf(amax, fabsf(v[i]));
#pragma unroll
    for (int o = 32; o > 0; o >>= 1) amax = fmaxf(amax, __shfl_xor(amax, o));
    float mx = fmaxf(amax, 1e-5f);
    float scale = 127.f / mx;
    u16x8 qv;
#pragma unroll
    for (int i = 0; i < 8; ++i) {
        float tq = rintf(v[i] * scale);
        tq = fminf(fmaxf(tq, -128.f), 127.f);
        qv[i] = f2bf(tq);   // exact integer in bf16
    }
    *reinterpret_cast<u16x8*>(out + (size_t)row * DD + lane * 8) = qv;
    if (lane == 0) a_inv[row] = mx / 127.f;
}

// ---------------- DoRA low-rank delta ----------------
__global__ void k_lora1(const float* __restrict__ X, const float* __restrict__ Amat,
                        float* __restrict__ tmp) {
    int t = threadIdx.x;
    int r = blockIdx.x * 16 + (t >> 4);
    int cc = t & 15;
    const float4* xr = (const float4*)(X + (size_t)r * DD);
    const float4* ar = (const float4*)(Amat + (size_t)cc * DD);
    float acc = 0.f;
#pragma unroll 4
    for (int k = 0; k < 128; ++k) {
        float4 xa = xr[k], aa = ar[k];
        acc += xa.x*aa.x + xa.y*aa.y + xa.z*aa.z + xa.w*aa.w;
    }
    tmp[(size_t)r * 16 + cc] = acc;
}

__global__ void k_lora2(const float* __restrict__ tmp, const float* __restrict__ Bmat,
                        float* __restrict__ qf) {
    int idx = blockIdx.x * 256 + threadIdx.x;
    int m2 = idx >> 9, n2 = idx & 511;
    const float4* tr = (const float4*)(tmp + (size_t)m2 * 16);
    const float4* br = (const float4*)(Bmat + (size_t)n2 * 16);
    float acc = 0.f;
#pragma unroll
    for (int rr = 0; rr < 4; ++rr) {
        float4 ta = tr[rr], ba = br[rr];
        acc += ta.x*ba.x + ta.y*ba.y + ta.z*ba.z + ta.w*ba.w;
    }
    qf[idx] = acc;
}

// ---------------- bf16 MFMA GEMM: C[M,N] = (Aq[M,512] @ Wq[N,512]^T) * a_inv[m] * winv ----------------
// MODE 0: plain. MODE 1: val + mag[n>>6]*Cout (in-place delta add). MODE 2: val + residual.
template <int MODE>
__global__ __launch_bounds__(256) void k_gemm_mfma(
    const unsigned short* __restrict__ Aq, const unsigned short* __restrict__ Wq,
    float* __restrict__ Cout, const float* __restrict__ a_inv,
    const float* __restrict__ winv_p, const float* __restrict__ Extra,
    int M, int N) {
    __shared__ __align__(16) unsigned short sA[128 * 32];
    __shared__ __align__(16) unsigned short sB[128 * 32];
    int t = threadIdx.x;
    int w = t >> 6, lane = t & 63;
    int wm = w >> 1, wn = w & 1;
    int lr = lane & 15, lg = lane >> 4;
    int m0 = blockIdx.y * 128, n0 = blockIdx.x * 128;
    int row_st = t >> 2, chunk = t & 3;   // staging: idx=i*256+t -> row=i*64+row_st
    f32x4 acc[4][4] = {};

    for (int k0 = 0; k0 < 512; k0 += 32) {
        __syncthreads();   // prev-iter LDS reads complete before overwrite
#pragma unroll
        for (int i = 0; i < 2; ++i) {
            int row = i * 64 + row_st;
            GLOAD16(Aq + (size_t)(m0 + row) * 512 + k0 + chunk * 8, sA + ((size_t)i * 256 + t) * 8);
            GLOAD16(Wq + (size_t)(n0 + row) * 512 + k0 + chunk * 8, sB + ((size_t)i * 256 + t) * 8);
        }
        asm volatile("s_waitcnt vmcnt(0)" ::: "memory");
        __syncthreads();
        bf16x8 af[4], bfr[4];
#pragma unroll
        for (int mt = 0; mt < 4; ++mt)
            af[mt] = *reinterpret_cast<const bf16x8*>(&sA[(wm * 64 + mt * 16 + lr) * 32 + lg * 8]);
#pragma unroll
        for (int nt = 0; nt < 4; ++nt)
            bfr[nt] = *reinterpret_cast<const bf16x8*>(&sB[(wn * 64 + nt * 16 + lr) * 32 + lg * 8]);
#pragma unroll
        for (int mt = 0; mt < 4; ++mt)
#pragma unroll
            for (int nt = 0; nt < 4; ++nt)
                acc[mt][nt] = __builtin_amdgcn_mfma_f32_16x16x32_bf16(af[mt], bfr[nt], acc[mt][nt], 0, 0, 0);
    }

    float wv = *winv_p;
#pragma unroll
    for (int mt = 0; mt < 4; ++mt) {
#pragma unroll
        for (int r = 0; r < 4; ++r) {
            int m = m0 + wm * 64 + mt * 16 + lg * 4 + r;
            float as = a_inv[m] * wv;
#pragma unroll
            for (int nt = 0; nt < 4; ++nt) {
                int n = n0 + wn * 64 + nt * 16 + lr;
                size_t idx = (size_t)m * N + n;
                float val = acc[mt][nt][r] * as;
                if (MODE == 0)      Cout[idx] = val;
                else if (MODE == 1) Cout[idx] = val + Extra[n >> 6] * Cout[idx];
                else                Cout[idx] = val + Extra[idx];
            }
        }
    }
}

// ---------------- bf16 conversion kernels (attention inputs) ----------------
// qf [B*Nq][512] fp32 -> Qb [B][H][Nq][64] bf16, PRE-SCALED by 1/8 (exact pow2)
__global__ __launch_bounds__(256) void k_cvt_q(const float* __restrict__ qf,
                                               unsigned short* __restrict__ Qb, int Nq) {
    int tid = blockIdx.x * 256 + threadIdx.x;
    size_t e = (size_t)tid * 8;
    int rowi = (int)(e >> 9);
    int wr = (int)(e & 511);
    int b = rowi / Nq, q = rowi - b * Nq;
    int h = wr >> 6, d = wr & 63;
    const float4* src = reinterpret_cast<const float4*>(qf + e);
    float4 a = src[0], bb = src[1];
    u16x8 v;
    v[0]=f2bf(a.x*0.125f); v[1]=f2bf(a.y*0.125f); v[2]=f2bf(a.z*0.125f); v[3]=f2bf(a.w*0.125f);
    v[4]=f2bf(bb.x*0.125f); v[5]=f2bf(bb.y*0.125f); v[6]=f2bf(bb.z*0.125f); v[7]=f2bf(bb.w*0.125f);
    *reinterpret_cast<u16x8*>(Qb + ((size_t)(b * NHEAD + h) * Nq + q) * 64 + d) = v;
}

__global__ __launch_bounds__(256) void k_cvt_kv(const float* __restrict__ kvb,
                                                unsigned short* __restrict__ Kb,
                                                unsigned short* __restrict__ Vt, int Nc) {
    __shared__ unsigned short sT[64][72];
    int t = threadIdx.x;
    int h = blockIdx.y, b = blockIdx.z;
    int kt0 = blockIdx.x * 64;
#pragma unroll
    for (int i = 0; i < 2; ++i) {
        int cc = t + i * 256;
        int key = cc >> 3, seg = cc & 7;
        const float* src = kvb + ((size_t)(b * Nc) + kt0 + key) * 1024 + h * 64 + seg * 8;
        u16x8 kq, vq;
#pragma unroll
        for (int j = 0; j < 8; ++j) { kq[j] = f2bf(src[j]); vq[j] = f2bf(src[512 + j]); }
        *reinterpret_cast<u16x8*>(Kb + ((size_t)(b * NHEAD + h) * Nc + kt0 + key) * 64 + seg * 8) = kq;
        *reinterpret_cast<u16x8*>(&sT[key][seg * 8]) = vq;
    }
    __syncthreads();
#pragma unroll
    for (int i = 0; i < 2; ++i) {
        int cc = t + i * 256;
        int d = cc >> 3, ks = cc & 7;
        u16x8 v;
#pragma unroll
        for (int j = 0; j < 8; ++j) v[j] = sT[ks * 8 + j][d];
        *reinterpret_cast<u16x8*>(Vt + ((size_t)(b * NHEAD + h) * 64 + d) * Nc + kt0 + ks * 8) = v;
    }
}

// ---------------- flash attention, bf16 MFMA 16x16x32 ----------------
// Plain (non-shifted) softmax: scores are O(1) for this model (unit-RMS acts x
// ternary weights); exp arg clamped at 30 as insurance (4096*e^30 << f32 max).
// Row-sum accumulated by an extra MFMA against a register-constant ones column.
__global__ __launch_bounds__(256) void k_attn_mfma(
    const unsigned short* __restrict__ Qb, const unsigned short* __restrict__ Kb,
    const unsigned short* __restrict__ Vt, float* __restrict__ attn,
    int Nq, int Nc) {
    __shared__ unsigned short sK[64][72];
    __shared__ unsigned short sVt[64][72];
    __shared__ unsigned short sP[4][16][76];   // stride 76: lg-groups hit distinct bank octets
    int t = threadIdx.x;
    int w = t >> 6, lane = t & 63;
    int lr = lane & 15, lg = lane >> 4;
    int h = blockIdx.y, b = blockIdx.z;
    int bh = b * NHEAD + h;
    int q0 = blockIdx.x * 64 + w * 16;

    // Q fragments (A layout: row = lane&15, k = (lane>>4)*8 + j), pre-scaled by 1/8
    const unsigned short* qbase = Qb + ((size_t)bh * Nq + q0 + lr) * 64 + lg * 8;
    bf16x8 aq0 = *reinterpret_cast<const bf16x8*>(qbase);
    bf16x8 aq1 = *reinterpret_cast<const bf16x8*>(qbase + 32);

    // ones-column B fragment: B col = lane&15; col 0 = 1.0, else 0 -> row sums in acc col 0
    u16x8 ou;
#pragma unroll
    for (int j = 0; j < 8; ++j) ou[j] = (lr == 0) ? 0x3F80 : 0;
    bf16x8 onesf = __builtin_bit_cast(bf16x8, ou);

    f32x4 o[4] = {};
    f32x4 osum = {};

    const unsigned short* kglob = Kb + (size_t)bh * Nc * 64;
    const unsigned short* vglob = Vt + (size_t)bh * 64 * (size_t)Nc;

    int srow = t >> 3, sseg = t & 7;
    for (int kt0 = 0; kt0 < Nc; kt0 += 64) {
        __syncthreads();   // prev-iter LDS reads (sK/sVt) complete before overwrite
#pragma unroll
        for (int i = 0; i < 2; ++i) {
            int r2 = srow + i * 32;
            *reinterpret_cast<bf16x8*>(&sK[r2][sseg * 8]) =
                *reinterpret_cast<const bf16x8*>(kglob + (size_t)(kt0 + r2) * 64 + sseg * 8);
            *reinterpret_cast<bf16x8*>(&sVt[r2][sseg * 8]) =
                *reinterpret_cast<const bf16x8*>(vglob + (size_t)r2 * Nc + kt0 + sseg * 8);
        }
        __syncthreads();
        // S = (Q/8) K^T   (C layout: row=(lg*4+r) query, col=lr key)
#pragma unroll
        for (int kt = 0; kt < 4; ++kt) {
            bf16x8 bk0 = *reinterpret_cast<const bf16x8*>(&sK[kt * 16 + lr][lg * 8]);
            bf16x8 bk1 = *reinterpret_cast<const bf16x8*>(&sK[kt * 16 + lr][32 + lg * 8]);
            f32x4 acc = {};
            acc = __builtin_amdgcn_mfma_f32_16x16x32_bf16(aq0, bk0, acc, 0, 0, 0);
            acc = __builtin_amdgcn_mfma_f32_16x16x32_bf16(aq1, bk1, acc, 0, 0, 0);
            // P = exp(S), unshifted (clamped)
#pragma unroll
            for (int r = 0; r < 4; ++r)
                sP[w][lg * 4 + r][kt * 16 + lr] = f2bf(__expf(fminf(acc[r], 30.f)));
        }
        // sP is per-wave: intra-wave ds ordering suffices, no barrier needed.
        // O += P @ V ; osum += P @ ones
#pragma unroll
        for (int kg = 0; kg < 2; ++kg) {
            bf16x8 pa = *reinterpret_cast<const bf16x8*>(&sP[w][lr][kg * 32 + lg * 8]);
#pragma unroll
            for (int dt = 0; dt < 4; ++dt) {
                bf16x8 vb = *reinterpret_cast<const bf16x8*>(&sVt[dt * 16 + lr][kg * 32 + lg * 8]);
                o[dt] = __builtin_amdgcn_mfma_f32_16x16x32_bf16(pa, vb, o[dt], 0, 0, 0);
            }
            osum = __builtin_amdgcn_mfma_f32_16x16x32_bf16(pa, onesf, osum, 0, 0, 0);
        }
    }
    // lsum for rows (lg*4+r) sits in osum[r] at lanes lr==0; broadcast within lg group
    float ls[4];
#pragma unroll
    for (int r = 0; r < 4; ++r) ls[r] = 1.f / __shfl(osum[r], lane & 48);
    float* obase = attn + ((size_t)b * Nq + q0) * DD + h * HDIM;
#pragma unroll
    for (int dt = 0; dt < 4; ++dt)
#pragma unroll
        for (int r = 0; r < 4; ++r) {
            int qr = lg * 4 + r;
            obase[(size_t)qr * DD + dt * 16 + lr] = o[dt][r] * ls[r];
        }
}

// ---------------- host side ----------------
static void run_pass(const float* q_in, const float* ctx,
                     const unsigned short* Wq_t, const float* gq,
                     const unsigned short* Wkv_t, const float* gkv,
                     const float* Amat, const float* Bmat, const float* mag,
                     const unsigned short* Wp_t, const float* gp,
                     const float* winv_q, const float* winv_kv, const float* winv_p,
                     int Mq, int Mc, int Nq, int Nc,
                     float* arena, float* outp, const float* resid, hipStream_t stream) {
    float* q_nq = arena;
    float* c_nq = q_nq + (size_t)Mq * 512;
    float* qf   = c_nq + (size_t)Mc * 512;
    float* kvb  = qf + (size_t)Mq * 512;
    float* attn = kvb + (size_t)Mc * 1024;
    float* tmp  = attn + (size_t)Mq * 512;
    float* sc_q = tmp + (size_t)Mq * 16;
    float* sc_c = sc_q + Mq;
    float* sc_o = sc_c + Mc;

    unsigned short* q_act = (unsigned short*)q_nq;   // bf16 integer activations
    unsigned short* c_act = (unsigned short*)c_nq;

    k_rmsq<<<Mq, 64, 0, stream>>>(q_in, gq, q_act, sc_q);
    k_rmsq<<<Mc, 64, 0, stream>>>(ctx, gkv, c_act, sc_c);
    k_lora1<<<Mq / 16, 256, 0, stream>>>(q_in, Amat, tmp);
    k_lora2<<<(Mq * 512) / 256, 256, 0, stream>>>(tmp, Bmat, qf);
    k_gemm_mfma<1><<<dim3(512 / 128, Mq / 128), 256, 0, stream>>>(
        q_act, Wq_t, qf, sc_q, winv_q, mag, Mq, 512);
    k_gemm_mfma<0><<<dim3(1024 / 128, Mc / 128), 256, 0, stream>>>(
        c_act, Wkv_t, kvb, sc_c, winv_kv, nullptr, Mc, 1024);

    // bf16 attention buffers overlay dead activation regions (stream-ordered)
    unsigned short* Qb = (unsigned short*)q_nq;
    unsigned short* Kb = (unsigned short*)c_nq;
    unsigned short* Vt = (unsigned short*)(c_nq + (size_t)Mc * 256);
    k_cvt_q<<<Mq / 4, 256, 0, stream>>>(qf, Qb, Nq);
    k_cvt_kv<<<dim3(Nc / 64, NHEAD, 4), 256, 0, stream>>>(kvb, Kb, Vt, Nc);
    k_attn_mfma<<<dim3(Nq / 64, NHEAD, 4), 256, 0, stream>>>(Qb, Kb, Vt, attn, Nq, Nc);

    k_rmsq<<<Mq, 64, 0, stream>>>(attn, gp, q_act, sc_o);  // overwrites Qb (dead)
    k_gemm_mfma<2><<<dim3(512 / 128, Mq / 128), 256, 0, stream>>>(
        q_act, Wp_t, outp, sc_o, winv_p, resid, Mq, 512);
}

extern "C" void kernel_launch(void* const* d_in, const int* in_sizes, int n_in,
                              void* d_out, int out_size, void* d_ws, size_t ws_size,
                              hipStream_t stream) {
    const float* x     = (const float*)d_in[0];
    const float* c     = (const float*)d_in[1];
    const float* Wq_x  = (const float*)d_in[2];
    const float* g_qx  = (const float*)d_in[3];
    const float* Wkv_c = (const float*)d_in[4];
    const float* g_kvc = (const float*)d_in[5];
    const float* A_x   = (const float*)d_in[6];
    const float* B_x   = (const float*)d_in[7];
    const float* mag_x = (const float*)d_in[8];
    const float* Wp_x  = (const float*)d_in[9];
    const float* g_px  = (const float*)d_in[10];
    const float* Wq_c  = (const float*)d_in[11];
    const float* g_qc  = (const float*)d_in[12];
    const float* Wkv_x = (const float*)d_in[13];
    const float* g_kvx = (const float*)d_in[14];
    const float* A_c   = (const float*)d_in[15];
    const float* B_c   = (const float*)d_in[16];
    const float* mag_c = (const float*)d_in[17];
    const float* Wp_c  = (const float*)d_in[18];
    const float* g_pc  = (const float*)d_in[19];

    float* ws = (float*)d_ws;
    const float* Wsrc[6] = {Wq_x, Wkv_c, Wp_x, Wq_c, Wkv_x, Wp_c};
    const int    Wcnt[6] = {262144, 524288, 262144, 262144, 524288, 262144};
    const size_t Woff[6] = {0, 262144, 786432, 1048576, 1310720, 1835008};
    float* part  = ws + 2097152;
    float* scal  = part + 192;
    float* winv  = scal + 8;
    float* arena = ws + 2097152 + 1024;

    size_t need1 = 3 * (size_t)16384 * 512 + (size_t)4096 * 512 + (size_t)4096 * 1024
                 + (size_t)16384 * 16 + 2 * (size_t)16384 + 4096;
    size_t need2 = 3 * (size_t)4096 * 512 + (size_t)16384 * 512 + (size_t)16384 * 1024
                 + (size_t)4096 * 16 + 2 * (size_t)4096 + 16384;
    size_t need = (2097152 + 1024 + (need1 > need2 ? need1 : need2)) * sizeof(float);
    if (ws_size < need) return;

    for (int m = 0; m < 6; ++m)
        k_wabs_partial<<<32, 256, 0, stream>>>(Wsrc[m], Wcnt[m], part + m * 32);
    k_wfinal<<<1, 64, 0, stream>>>(part, scal, winv);
    for (int m = 0; m < 6; ++m)
        k_wquant<<<(Wcnt[m] + 255) / 256, 256, 0, stream>>>(
            Wsrc[m], (unsigned short*)(ws + Woff[m]), scal + m, Wcnt[m]);

    float* outx = (float*)d_out;
    float* outc = outx + (size_t)4 * 4096 * 512;

    // pass 1: x queries attend to c
    run_pass(x, c, (const unsigned short*)(ws + Woff[0]), g_qx,
             (const unsigned short*)(ws + Woff[1]), g_kvc, A_x, B_x, mag_x,
             (const unsigned short*)(ws + Woff[2]), g_px,
             winv + 0, winv + 1, winv + 2,
             16384, 4096, 4096, 1024, arena, outx, x, stream);
    // pass 2: c queries attend to x
    run_pass(c, x, (const unsigned short*)(ws + Woff[3]), g_qc,
             (const unsigned short*)(ws + Woff[4]), g_kvx, A_c, B_c, mag_c,
             (const unsigned short*)(ws + Woff[5]), g_pc,
             winv + 3, winv + 4, winv + 5,
             4096, 16384, 1024, 4096, arena, outc, c, stream);
}

// Round 5
// 564.430 us; speedup vs baseline: 29.6803x; 1.0778x over previous
//
#include <hip/hip_runtime.h>
#include <math.h>

#define DD 512
#define NHEAD 8
#define HDIM 64

typedef __bf16 bf16x8 __attribute__((ext_vector_type(8)));
typedef unsigned short u16x8 __attribute__((ext_vector_type(8)));
typedef float f32x4 __attribute__((ext_vector_type(4)));

#if __has_builtin(__builtin_amdgcn_exp2f)
#define EXP2F(x) __builtin_amdgcn_exp2f(x)
#else
#define EXP2F(x) exp2f(x)
#endif

#define QSCALE 0.18033688f  /* (1/8) * log2(e): exp2 domain */

static __device__ __forceinline__ unsigned short f2bf(float f) {
    unsigned u = __builtin_bit_cast(unsigned, f);
    u += 0x7fffu + ((u >> 16) & 1u);   // round-to-nearest-even
    return (unsigned short)(u >> 16);
}

#define GLOAD16(g, l)                                                          \
    __builtin_amdgcn_global_load_lds(                                          \
        (__attribute__((address_space(1))) void*)(g),                          \
        (__attribute__((address_space(3))) void*)(l), 16, 0, 0)

// ---------------- weight ternary quant: two-stage deterministic mean|W| ----------------
__global__ void k_wabs_partial(const float* __restrict__ W, int n, float* __restrict__ part) {
    int t = threadIdx.x;
    float s = 0.f;
    for (int i = blockIdx.x * blockDim.x + t; i < n; i += blockDim.x * gridDim.x)
        s += fabsf(W[i]);
    __shared__ float red[4];
#pragma unroll
    for (int o = 32; o > 0; o >>= 1) s += __shfl_down(s, o);
    if ((t & 63) == 0) red[t >> 6] = s;
    __syncthreads();
    if (t == 0) part[blockIdx.x] = red[0] + red[1] + red[2] + red[3];
}

__global__ void k_wfinal(const float* __restrict__ part, float* __restrict__ scal,
                         float* __restrict__ winv) {
    int m = threadIdx.x;
    if (m < 6) {
        const int cnt[6] = {262144, 524288, 262144, 262144, 524288, 262144};
        float s = 0.f;
        for (int i = 0; i < 32; ++i) s += part[m * 32 + i];
        float mean = fmaxf(s / (float)cnt[m], 1e-5f);
        scal[m] = 1.f / mean;   // multiply scale
        winv[m] = mean;         // dequant factor (1/scale)
    }
}

// ternary weights as bf16 {-1,0,1}
__global__ void k_wquant(const float* __restrict__ W, unsigned short* __restrict__ Wq,
                         const float* __restrict__ scal, int n) {
    int i = blockIdx.x * 256 + threadIdx.x;
    if (i < n) {
        float sc = *scal;
        float t = rintf(W[i] * sc);
        t = fminf(fmaxf(t, -1.f), 1.f);
        Wq[i] = f2bf(t);   // exact: {-1,0,1}
    }
}

// ---------------- RMSNorm + per-token int8 absmax quant -> bf16 INTEGER activations ----------------
__global__ void k_rmsq(const float* __restrict__ X, const float* __restrict__ g,
                       unsigned short* __restrict__ out, float* __restrict__ a_inv) {
    int row = blockIdx.x;
    int lane = threadIdx.x; // 64 threads, 8 elems each
    const float* xr = X + (size_t)row * DD;
    float4 a = *(const float4*)(xr + lane * 8);
    float4 b = *(const float4*)(xr + lane * 8 + 4);
    float ss = a.x*a.x + a.y*a.y + a.z*a.z + a.w*a.w
             + b.x*b.x + b.y*b.y + b.z*b.z + b.w*b.w;
#pragma unroll
    for (int o = 32; o > 0; o >>= 1) ss += __shfl_xor(ss, o);
    float rn = 1.f / sqrtf(ss * (1.f / 512.f) + 1e-8f);
    float4 ga = *(const float4*)(g + lane * 8);
    float4 gb = *(const float4*)(g + lane * 8 + 4);
    float v[8] = {a.x*rn*ga.x, a.y*rn*ga.y, a.z*rn*ga.z, a.w*rn*ga.w,
                  b.x*rn*gb.x, b.y*rn*gb.y, b.z*rn*gb.z, b.w*rn*gb.w};
    float amax = 0.f;
#pragma unroll
    for (int i = 0; i < 8; ++i) amax = fmaxf(amax, fabsf(v[i]));
#pragma unroll
    for (int o = 32; o > 0; o >>= 1) amax = fmaxf(amax, __shfl_xor(amax, o));
    float mx = fmaxf(amax, 1e-5f);
    float scale = 127.f / mx;
    u16x8 qv;
#pragma unroll
    for (int i = 0; i < 8; ++i) {
        float tq = rintf(v[i] * scale);
        tq = fminf(fmaxf(tq, -128.f), 127.f);
        qv[i] = f2bf(tq);   // exact integer in bf16
    }
    *reinterpret_cast<u16x8*>(out + (size_t)row * DD + lane * 8) = qv;
    if (lane == 0) a_inv[row] = mx / 127.f;
}

// ---------------- DoRA low-rank delta ----------------
__global__ void k_lora1(const float* __restrict__ X, const float* __restrict__ Amat,
                        float* __restrict__ tmp) {
    int t = threadIdx.x;
    int r = blockIdx.x * 16 + (t >> 4);
    int cc = t & 15;
    const float4* xr = (const float4*)(X + (size_t)r * DD);
    const float4* ar = (const float4*)(Amat + (size_t)cc * DD);
    float acc = 0.f;
#pragma unroll 4
    for (int k = 0; k < 128; ++k) {
        float4 xa = xr[k], aa = ar[k];
        acc += xa.x*aa.x + xa.y*aa.y + xa.z*aa.z + xa.w*aa.w;
    }
    tmp[(size_t)r * 16 + cc] = acc;
}

__global__ void k_lora2(const float* __restrict__ tmp, const float* __restrict__ Bmat,
                        float* __restrict__ qf) {
    int idx = blockIdx.x * 256 + threadIdx.x;
    int m2 = idx >> 9, n2 = idx & 511;
    const float4* tr = (const float4*)(tmp + (size_t)m2 * 16);
    const float4* br = (const float4*)(Bmat + (size_t)n2 * 16);
    float acc = 0.f;
#pragma unroll
    for (int rr = 0; rr < 4; ++rr) {
        float4 ta = tr[rr], ba = br[rr];
        acc += ta.x*ba.x + ta.y*ba.y + ta.z*ba.z + ta.w*ba.w;
    }
    qf[idx] = acc;
}

// ---------------- bf16 MFMA GEMM: C[M,N] = (Aq[M,512] @ Wq[N,512]^T) * a_inv[m] * winv ----------------
// MODE 0: plain fp32 store. MODE 2: fp32 + residual. MODE 3: bf16 Q write:
//   Qout[b][h][q][d] = (val + mag[h]*Delta[m][n]) * QSCALE  (Delta = Cout, read-only)
template <int MODE>
__global__ __launch_bounds__(256) void k_gemm_mfma(
    const unsigned short* __restrict__ Aq, const unsigned short* __restrict__ Wq,
    float* __restrict__ Cout, const float* __restrict__ a_inv,
    const float* __restrict__ winv_p, const float* __restrict__ Extra,
    unsigned short* __restrict__ Qout, int lognq,
    int M, int N) {
    __shared__ __align__(16) unsigned short sA[128 * 32];
    __shared__ __align__(16) unsigned short sB[128 * 32];
    int t = threadIdx.x;
    int w = t >> 6, lane = t & 63;
    int wm = w >> 1, wn = w & 1;
    int lr = lane & 15, lg = lane >> 4;
    int m0 = blockIdx.y * 128, n0 = blockIdx.x * 128;
    int row_st = t >> 2, chunk = t & 3;   // staging: idx=i*256+t -> row=i*64+row_st
    f32x4 acc[4][4] = {};

    for (int k0 = 0; k0 < 512; k0 += 32) {
        __syncthreads();   // prev-iter LDS reads complete before overwrite
#pragma unroll
        for (int i = 0; i < 2; ++i) {
            int row = i * 64 + row_st;
            GLOAD16(Aq + (size_t)(m0 + row) * 512 + k0 + chunk * 8, sA + ((size_t)i * 256 + t) * 8);
            GLOAD16(Wq + (size_t)(n0 + row) * 512 + k0 + chunk * 8, sB + ((size_t)i * 256 + t) * 8);
        }
        asm volatile("s_waitcnt vmcnt(0)" ::: "memory");
        __syncthreads();
        bf16x8 af[4], bfr[4];
#pragma unroll
        for (int mt = 0; mt < 4; ++mt)
            af[mt] = *reinterpret_cast<const bf16x8*>(&sA[(wm * 64 + mt * 16 + lr) * 32 + lg * 8]);
#pragma unroll
        for (int nt = 0; nt < 4; ++nt)
            bfr[nt] = *reinterpret_cast<const bf16x8*>(&sB[(wn * 64 + nt * 16 + lr) * 32 + lg * 8]);
#pragma unroll
        for (int mt = 0; mt < 4; ++mt)
#pragma unroll
            for (int nt = 0; nt < 4; ++nt)
                acc[mt][nt] = __builtin_amdgcn_mfma_f32_16x16x32_bf16(af[mt], bfr[nt], acc[mt][nt], 0, 0, 0);
    }

    float wv = *winv_p;
#pragma unroll
    for (int mt = 0; mt < 4; ++mt) {
#pragma unroll
        for (int r = 0; r < 4; ++r) {
            int m = m0 + wm * 64 + mt * 16 + lg * 4 + r;
            float as = a_inv[m] * wv;
            if (MODE == 3) {
                int bb = m >> lognq, q = m & ((1 << lognq) - 1);
#pragma unroll
                for (int nt = 0; nt < 4; ++nt) {
                    int n = n0 + wn * 64 + nt * 16 + lr;
                    float val = acc[mt][nt][r] * as + Extra[n >> 6] * Cout[(size_t)m * N + n];
                    int h = n >> 6, d = n & 63;
                    Qout[((((size_t)(bb * NHEAD + h)) << lognq) + q) * 64 + d] =
                        f2bf(val * QSCALE);
                }
            } else {
#pragma unroll
                for (int nt = 0; nt < 4; ++nt) {
                    int n = n0 + wn * 64 + nt * 16 + lr;
                    size_t idx = (size_t)m * N + n;
                    float val = acc[mt][nt][r] * as;
                    if (MODE == 0) Cout[idx] = val;
                    else           Cout[idx] = val + Extra[idx];
                }
            }
        }
    }
}

// ---------------- K/V bf16 conversion (K row-major, V transposed) ----------------
__global__ __launch_bounds__(256) void k_cvt_kv(const float* __restrict__ kvb,
                                                unsigned short* __restrict__ Kb,
                                                unsigned short* __restrict__ Vt, int Nc) {
    __shared__ unsigned short sT[64][72];
    int t = threadIdx.x;
    int h = blockIdx.y, b = blockIdx.z;
    int kt0 = blockIdx.x * 64;
#pragma unroll
    for (int i = 0; i < 2; ++i) {
        int cc = t + i * 256;
        int key = cc >> 3, seg = cc & 7;
        const float* src = kvb + ((size_t)(b * Nc) + kt0 + key) * 1024 + h * 64 + seg * 8;
        u16x8 kq, vq;
#pragma unroll
        for (int j = 0; j < 8; ++j) { kq[j] = f2bf(src[j]); vq[j] = f2bf(src[512 + j]); }
        *reinterpret_cast<u16x8*>(Kb + ((size_t)(b * NHEAD + h) * Nc + kt0 + key) * 64 + seg * 8) = kq;
        *reinterpret_cast<u16x8*>(&sT[key][seg * 8]) = vq;
    }
    __syncthreads();
#pragma unroll
    for (int i = 0; i < 2; ++i) {
        int cc = t + i * 256;
        int d = cc >> 3, ks = cc & 7;
        u16x8 v;
#pragma unroll
        for (int j = 0; j < 8; ++j) v[j] = sT[ks * 8 + j][d];
        *reinterpret_cast<u16x8*>(Vt + ((size_t)(b * NHEAD + h) * 64 + d) * Nc + kt0 + ks * 8) = v;
    }
}

// ---------------- flash attention, bf16 MFMA 16x16x32 ----------------
// 512 threads = 8 waves, 128 queries/block (16/wave). Q pre-scaled by log2(e)/8 so
// P = exp2(S) is a single v_exp_f32. Plain softmax (scores O(1); clamp 43 insurance).
// Row sums via extra MFMA against a ones column. XCD-aware 1D grid: bid&7 = XCD,
// each XCD owns 4 (b,h) pairs -> its L2 keeps that K/V slice resident.
__global__ __launch_bounds__(512) void k_attn_mfma(
    const unsigned short* __restrict__ Qb, const unsigned short* __restrict__ Kb,
    const unsigned short* __restrict__ Vt, float* __restrict__ attn,
    int Nq, int Nc, int nqb_shift) {
    __shared__ unsigned short sK[64][72];   // [key][d]
    __shared__ unsigned short sVt[64][72];  // [d][key]
    __shared__ __bf16 sP[8][16][76];        // per-wave P tile [q][key]
    int t = threadIdx.x;
    int w = t >> 6, lane = t & 63;
    int lr = lane & 15, lg = lane >> 4;

    int bid = blockIdx.x;
    int j = bid >> 3;
    int qblk = j & ((1 << nqb_shift) - 1);
    int bh = ((bid & 7) << 2) | (j >> nqb_shift);   // 32 bh over 8 XCDs, 4 each
    int b = bh >> 3, h = bh & 7;
    int q0 = qblk * 128 + w * 16;

    // Q fragments (A layout: row = lane&15, k = (lane>>4)*8 + j), pre-scaled
    const unsigned short* qbase = Qb + ((size_t)bh * Nq + q0 + lr) * 64 + lg * 8;
    bf16x8 aq0 = *reinterpret_cast<const bf16x8*>(qbase);
    bf16x8 aq1 = *reinterpret_cast<const bf16x8*>(qbase + 32);

    // ones-column B fragment: col 0 = 1.0 -> row sums accumulate in acc col 0
    u16x8 ou;
#pragma unroll
    for (int jj = 0; jj < 8; ++jj) ou[jj] = (lr == 0) ? 0x3F80 : 0;
    bf16x8 onesf = __builtin_bit_cast(bf16x8, ou);

    f32x4 o[4] = {};
    f32x4 osum = {};

    const unsigned short* kglob = Kb + (size_t)bh * Nc * 64;
    const unsigned short* vglob = Vt + (size_t)bh * 64 * (size_t)Nc;

    int srow = t >> 3, sseg = t & 7;    // 512 threads stage 64x64 (1 b128 each)
    const unsigned short* kptr = kglob + (size_t)srow * 64 + sseg * 8;
    const unsigned short* vptr = vglob + (size_t)srow * Nc + sseg * 8;

    bf16x8 rK = *reinterpret_cast<const bf16x8*>(kptr);
    bf16x8 rV = *reinterpret_cast<const bf16x8*>(vptr);

    for (int kt0 = 0; kt0 < Nc; kt0 += 64) {
        __syncthreads();   // prev tile's LDS reads complete
        *reinterpret_cast<bf16x8*>(&sK[srow][sseg * 8]) = rK;
        *reinterpret_cast<bf16x8*>(&sVt[srow][sseg * 8]) = rV;
        __syncthreads();   // staging visible
        if (kt0 + 64 < Nc) {   // prefetch next tile; latency hides under compute
            rK = *reinterpret_cast<const bf16x8*>(kptr + (size_t)(kt0 + 64) * 64);
            rV = *reinterpret_cast<const bf16x8*>(vptr + kt0 + 64);
        }
        // S = Q K^T (log2 domain); P = exp2(S)
#pragma unroll
        for (int kt = 0; kt < 4; ++kt) {
            bf16x8 bk0 = *reinterpret_cast<const bf16x8*>(&sK[kt * 16 + lr][lg * 8]);
            bf16x8 bk1 = *reinterpret_cast<const bf16x8*>(&sK[kt * 16 + lr][32 + lg * 8]);
            f32x4 acc = {};
            acc = __builtin_amdgcn_mfma_f32_16x16x32_bf16(aq0, bk0, acc, 0, 0, 0);
            acc = __builtin_amdgcn_mfma_f32_16x16x32_bf16(aq1, bk1, acc, 0, 0, 0);
#pragma unroll
            for (int r = 0; r < 4; ++r)
                sP[w][lg * 4 + r][kt * 16 + lr] = (__bf16)EXP2F(fminf(acc[r], 43.f));
        }
        // sP per-wave: intra-wave LDS ordering suffices, no barrier.
        // O += P @ V ; osum += P @ ones
#pragma unroll
        for (int kg = 0; kg < 2; ++kg) {
            bf16x8 pa = *reinterpret_cast<const bf16x8*>(&sP[w][lr][kg * 32 + lg * 8]);
#pragma unroll
            for (int dt = 0; dt < 4; ++dt) {
                bf16x8 vb = *reinterpret_cast<const bf16x8*>(&sVt[dt * 16 + lr][kg * 32 + lg * 8]);
                o[dt] = __builtin_amdgcn_mfma_f32_16x16x32_bf16(pa, vb, o[dt], 0, 0, 0);
            }
            osum = __builtin_amdgcn_mfma_f32_16x16x32_bf16(pa, onesf, osum, 0, 0, 0);
        }
    }
    // row sums sit in osum[r] at lanes lr==0; broadcast within lg group
    float ls[4];
#pragma unroll
    for (int r = 0; r < 4; ++r) ls[r] = 1.f / __shfl(osum[r], lane & 48);
    float* obase = attn + ((size_t)b * Nq + q0) * DD + h * HDIM;
#pragma unroll
    for (int dt = 0; dt < 4; ++dt)
#pragma unroll
        for (int r = 0; r < 4; ++r) {
            int qr = lg * 4 + r;
            obase[(size_t)qr * DD + dt * 16 + lr] = o[dt][r] * ls[r];
        }
}

// ---------------- host side ----------------
static void run_pass(const float* q_in, const float* ctx,
                     const unsigned short* Wq_t, const float* gq,
                     const unsigned short* Wkv_t, const float* gkv,
                     const float* Amat, const float* Bmat, const float* mag,
                     const unsigned short* Wp_t, const float* gp,
                     const float* winv_q, const float* winv_kv, const float* winv_p,
                     int Mq, int Mc, int Nq, int Nc, int lognq,
                     float* arena, float* outp, const float* resid, hipStream_t stream) {
    float* q_nq = arena;
    float* c_nq = q_nq + (size_t)Mq * 512;
    float* qf   = c_nq + (size_t)Mc * 512;
    float* kvb  = qf + (size_t)Mq * 512;
    float* attn = kvb + (size_t)Mc * 1024;
    float* tmp  = attn + (size_t)Mq * 512;
    float* sc_q = tmp + (size_t)Mq * 16;
    float* sc_c = sc_q + Mq;
    float* sc_o = sc_c + Mc;

    unsigned short* q_act = (unsigned short*)q_nq;   // bf16 integer activations (half 1)
    unsigned short* Qb    = (unsigned short*)(q_nq + (size_t)Mq * 256);  // bf16 Q (half 2)
    unsigned short* c_act = (unsigned short*)c_nq;

    k_rmsq<<<Mq, 64, 0, stream>>>(q_in, gq, q_act, sc_q);
    k_rmsq<<<Mc, 64, 0, stream>>>(ctx, gkv, c_act, sc_c);
    k_lora1<<<Mq / 16, 256, 0, stream>>>(q_in, Amat, tmp);
    k_lora2<<<(Mq * 512) / 256, 256, 0, stream>>>(tmp, Bmat, qf);  // qf = DoRA delta
    // Q projection: reads q_act + delta, writes bf16 Q directly (fused k_cvt_q)
    k_gemm_mfma<3><<<dim3(512 / 128, Mq / 128), 256, 0, stream>>>(
        q_act, Wq_t, qf, sc_q, winv_q, mag, Qb, lognq, Mq, 512);
    k_gemm_mfma<0><<<dim3(1024 / 128, Mc / 128), 256, 0, stream>>>(
        c_act, Wkv_t, kvb, sc_c, winv_kv, nullptr, nullptr, 0, Mc, 1024);

    // Kb/Vt overlay c_nq region (c_act dead after kv GEMM)
    unsigned short* Kb = (unsigned short*)c_nq;
    unsigned short* Vt = (unsigned short*)(c_nq + (size_t)Mc * 256);
    k_cvt_kv<<<dim3(Nc / 64, NHEAD, 4), 256, 0, stream>>>(kvb, Kb, Vt, Nc);

    int nqb = Nq / 128;
    k_attn_mfma<<<dim3(32 * nqb), 512, 0, stream>>>(Qb, Kb, Vt, attn, Nq, Nc,
                                                    __builtin_ctz(nqb));

    k_rmsq<<<Mq, 64, 0, stream>>>(attn, gp, q_act, sc_o);
    k_gemm_mfma<2><<<dim3(512 / 128, Mq / 128), 256, 0, stream>>>(
        q_act, Wp_t, outp, sc_o, winv_p, resid, nullptr, 0, Mq, 512);
}

extern "C" void kernel_launch(void* const* d_in, const int* in_sizes, int n_in,
                              void* d_out, int out_size, void* d_ws, size_t ws_size,
                              hipStream_t stream) {
    const float* x     = (const float*)d_in[0];
    const float* c     = (const float*)d_in[1];
    const float* Wq_x  = (const float*)d_in[2];
    const float* g_qx  = (const float*)d_in[3];
    const float* Wkv_c = (const float*)d_in[4];
    const float* g_kvc = (const float*)d_in[5];
    const float* A_x   = (const float*)d_in[6];
    const float* B_x   = (const float*)d_in[7];
    const float* mag_x = (const float*)d_in[8];
    const float* Wp_x  = (const float*)d_in[9];
    const float* g_px  = (const float*)d_in[10];
    const float* Wq_c  = (const float*)d_in[11];
    const float* g_qc  = (const float*)d_in[12];
    const float* Wkv_x = (const float*)d_in[13];
    const float* g_kvx = (const float*)d_in[14];
    const float* A_c   = (const float*)d_in[15];
    const float* B_c   = (const float*)d_in[16];
    const float* mag_c = (const float*)d_in[17];
    const float* Wp_c  = (const float*)d_in[18];
    const float* g_pc  = (const float*)d_in[19];

    float* ws = (float*)d_ws;
    const float* Wsrc[6] = {Wq_x, Wkv_c, Wp_x, Wq_c, Wkv_x, Wp_c};
    const int    Wcnt[6] = {262144, 524288, 262144, 262144, 524288, 262144};
    const size_t Woff[6] = {0, 262144, 786432, 1048576, 1310720, 1835008};
    float* part  = ws + 2097152;
    float* scal  = part + 192;
    float* winv  = scal + 8;
    float* arena = ws + 2097152 + 1024;

    size_t need1 = 3 * (size_t)16384 * 512 + (size_t)4096 * 512 + (size_t)4096 * 1024
                 + (size_t)16384 * 16 + 2 * (size_t)16384 + 4096;
    size_t need2 = 3 * (size_t)4096 * 512 + (size_t)16384 * 512 + (size_t)16384 * 1024
                 + (size_t)4096 * 16 + 2 * (size_t)4096 + 16384;
    size_t need = (2097152 + 1024 + (need1 > need2 ? need1 : need2)) * sizeof(float);
    if (ws_size < need) return;

    for (int m = 0; m < 6; ++m)
        k_wabs_partial<<<32, 256, 0, stream>>>(Wsrc[m], Wcnt[m], part + m * 32);
    k_wfinal<<<1, 64, 0, stream>>>(part, scal, winv);
    for (int m = 0; m < 6; ++m)
        k_wquant<<<(Wcnt[m] + 255) / 256, 256, 0, stream>>>(
            Wsrc[m], (unsigned short*)(ws + Woff[m]), scal + m, Wcnt[m]);

    float* outx = (float*)d_out;
    float* outc = outx + (size_t)4 * 4096 * 512;

    // pass 1: x queries attend to c
    run_pass(x, c, (const unsigned short*)(ws + Woff[0]), g_qx,
             (const unsigned short*)(ws + Woff[1]), g_kvc, A_x, B_x, mag_x,
             (const unsigned short*)(ws + Woff[2]), g_px,
             winv + 0, winv + 1, winv + 2,
             16384, 4096, 4096, 1024, 12, arena, outx, x, stream);
    // pass 2: c queries attend to x
    run_pass(c, x, (const unsigned short*)(ws + Woff[3]), g_qc,
             (const unsigned short*)(ws + Woff[4]), g_kvx, A_c, B_c, mag_c,
             (const unsigned short*)(ws + Woff[5]), g_pc,
             winv + 3, winv + 4, winv + 5,
             4096, 16384, 1024, 4096, 10, arena, outc, c, stream);
}

// Round 6
// 455.607 us; speedup vs baseline: 36.7695x; 1.2389x over previous
//
#include <hip/hip_runtime.h>
#include <math.h>

#define DD 512
#define NHEAD 8
#define HDIM 64

typedef __bf16 bf16x8 __attribute__((ext_vector_type(8)));
typedef unsigned short u16x8 __attribute__((ext_vector_type(8)));
typedef float f32x4 __attribute__((ext_vector_type(4)));

#if __has_builtin(__builtin_amdgcn_exp2f)
#define EXP2F(x) __builtin_amdgcn_exp2f(x)
#else
#define EXP2F(x) exp2f(x)
#endif

#define QSCALE 0.18033688f  /* (1/8) * log2(e): exp2 domain */

static __device__ __forceinline__ unsigned short f2bf(float f) {
    unsigned u = __builtin_bit_cast(unsigned, f);
    u += 0x7fffu + ((u >> 16) & 1u);   // round-to-nearest-even
    return (unsigned short)(u >> 16);
}
static __device__ __forceinline__ float bf2f(unsigned short u) {
    return __builtin_bit_cast(float, (unsigned)u << 16);
}

#define GLOAD16(g, l)                                                          \
    __builtin_amdgcn_global_load_lds(                                          \
        (__attribute__((address_space(1))) void*)(g),                          \
        (__attribute__((address_space(3))) void*)(l), 16, 0, 0)

// ---------------- weight ternary quant: consolidated prep ----------------
// grid 192: block b handles matrix b>>5, sub-block b&31
__global__ void k_wabs_all(const float* __restrict__ W0, const float* __restrict__ W1,
                           const float* __restrict__ W2, const float* __restrict__ W3,
                           const float* __restrict__ W4, const float* __restrict__ W5,
                           float* __restrict__ part) {
    const float* Ws[6] = {W0, W1, W2, W3, W4, W5};
    const int cnt[6] = {262144, 524288, 262144, 262144, 524288, 262144};
    int mid = blockIdx.x >> 5, lb = blockIdx.x & 31;
    const float* W = Ws[mid];
    int n = cnt[mid];
    int t = threadIdx.x;
    float s = 0.f;
    for (int i = lb * 256 + t; i < n; i += 32 * 256) s += fabsf(W[i]);
    __shared__ float red[4];
#pragma unroll
    for (int o = 32; o > 0; o >>= 1) s += __shfl_down(s, o);
    if ((t & 63) == 0) red[t >> 6] = s;
    __syncthreads();
    if (t == 0) part[blockIdx.x] = red[0] + red[1] + red[2] + red[3];
}

__global__ void k_wfinal(const float* __restrict__ part, float* __restrict__ scal,
                         float* __restrict__ winv) {
    int m = threadIdx.x;
    if (m < 6) {
        const int cnt[6] = {262144, 524288, 262144, 262144, 524288, 262144};
        float s = 0.f;
        for (int i = 0; i < 32; ++i) s += part[m * 32 + i];
        float mean = fmaxf(s / (float)cnt[m], 1e-5f);
        scal[m] = 1.f / mean;
        winv[m] = mean;
    }
}

// one pass over all 6 matrices -> bf16 {-1,0,1} at fixed offsets
__global__ void k_wquant_all(const float* __restrict__ W0, const float* __restrict__ W1,
                             const float* __restrict__ W2, const float* __restrict__ W3,
                             const float* __restrict__ W4, const float* __restrict__ W5,
                             unsigned short* __restrict__ Wq, const float* __restrict__ scal) {
    int e = blockIdx.x * 256 + threadIdx.x;
    const float* Ws[6] = {W0, W1, W2, W3, W4, W5};
    int mid, base;
    if (e < 262144)       { mid = 0; base = 0; }
    else if (e < 786432)  { mid = 1; base = 262144; }
    else if (e < 1048576) { mid = 2; base = 786432; }
    else if (e < 1310720) { mid = 3; base = 1048576; }
    else if (e < 1835008) { mid = 4; base = 1310720; }
    else                  { mid = 5; base = 1835008; }
    float sc = scal[mid];
    float t = rintf(Ws[mid][e - base] * sc);
    t = fminf(fmaxf(t, -1.f), 1.f);
    Wq[e] = f2bf(t);
}

// ---------------- RMSNorm + int8 absmax quant -> bf16 INTEGER activations ----------------
// dual: one read of X, two (g, out, scale) sets
__global__ void k_rmsq_dual(const float* __restrict__ X,
                            const float* __restrict__ g1, const float* __restrict__ g2,
                            unsigned short* __restrict__ o1, unsigned short* __restrict__ o2,
                            float* __restrict__ s1, float* __restrict__ s2) {
    int row = blockIdx.x;
    int lane = threadIdx.x;
    const float* xr = X + (size_t)row * DD;
    float4 a = *(const float4*)(xr + lane * 8);
    float4 b = *(const float4*)(xr + lane * 8 + 4);
    float ss = a.x*a.x + a.y*a.y + a.z*a.z + a.w*a.w
             + b.x*b.x + b.y*b.y + b.z*b.z + b.w*b.w;
#pragma unroll
    for (int o = 32; o > 0; o >>= 1) ss += __shfl_xor(ss, o);
    float rn = 1.f / sqrtf(ss * (1.f / 512.f) + 1e-8f);
    const float* gs[2] = {g1, g2};
    unsigned short* os[2] = {o1, o2};
    float* scs[2] = {s1, s2};
#pragma unroll
    for (int pass = 0; pass < 2; ++pass) {
        float4 ga = *(const float4*)(gs[pass] + lane * 8);
        float4 gb = *(const float4*)(gs[pass] + lane * 8 + 4);
        float v[8] = {a.x*rn*ga.x, a.y*rn*ga.y, a.z*rn*ga.z, a.w*rn*ga.w,
                      b.x*rn*gb.x, b.y*rn*gb.y, b.z*rn*gb.z, b.w*rn*gb.w};
        float amax = 0.f;
#pragma unroll
        for (int i = 0; i < 8; ++i) amax = fmaxf(amax, fabsf(v[i]));
#pragma unroll
        for (int o = 32; o > 0; o >>= 1) amax = fmaxf(amax, __shfl_xor(amax, o));
        float mx = fmaxf(amax, 1e-5f);
        float scale = 127.f / mx;
        u16x8 qv;
#pragma unroll
        for (int i = 0; i < 8; ++i) {
            float tq = rintf(v[i] * scale);
            tq = fminf(fmaxf(tq, -128.f), 127.f);
            qv[i] = f2bf(tq);
        }
        *reinterpret_cast<u16x8*>(os[pass] + (size_t)row * DD + lane * 8) = qv;
        if (lane == 0) scs[pass][row] = mx / 127.f;
    }
}

__global__ void k_rmsq(const float* __restrict__ X, const float* __restrict__ g,
                       unsigned short* __restrict__ out, float* __restrict__ a_inv) {
    int row = blockIdx.x;
    int lane = threadIdx.x;
    const float* xr = X + (size_t)row * DD;
    float4 a = *(const float4*)(xr + lane * 8);
    float4 b = *(const float4*)(xr + lane * 8 + 4);
    float ss = a.x*a.x + a.y*a.y + a.z*a.z + a.w*a.w
             + b.x*b.x + b.y*b.y + b.z*b.z + b.w*b.w;
#pragma unroll
    for (int o = 32; o > 0; o >>= 1) ss += __shfl_xor(ss, o);
    float rn = 1.f / sqrtf(ss * (1.f / 512.f) + 1e-8f);
    float4 ga = *(const float4*)(g + lane * 8);
    float4 gb = *(const float4*)(g + lane * 8 + 4);
    float v[8] = {a.x*rn*ga.x, a.y*rn*ga.y, a.z*rn*ga.z, a.w*rn*ga.w,
                  b.x*rn*gb.x, b.y*rn*gb.y, b.z*rn*gb.z, b.w*rn*gb.w};
    float amax = 0.f;
#pragma unroll
    for (int i = 0; i < 8; ++i) amax = fmaxf(amax, fabsf(v[i]));
#pragma unroll
    for (int o = 32; o > 0; o >>= 1) amax = fmaxf(amax, __shfl_xor(amax, o));
    float mx = fmaxf(amax, 1e-5f);
    float scale = 127.f / mx;
    u16x8 qv;
#pragma unroll
    for (int i = 0; i < 8; ++i) {
        float tq = rintf(v[i] * scale);
        tq = fminf(fmaxf(tq, -128.f), 127.f);
        qv[i] = f2bf(tq);
    }
    *reinterpret_cast<u16x8*>(out + (size_t)row * DD + lane * 8) = qv;
    if (lane == 0) a_inv[row] = mx / 127.f;
}

// ---------------- DoRA low-rank delta ----------------
__global__ void k_lora1(const float* __restrict__ X, const float* __restrict__ Amat,
                        float* __restrict__ tmp) {
    int t = threadIdx.x;
    int r = blockIdx.x * 16 + (t >> 4);
    int cc = t & 15;
    const float4* xr = (const float4*)(X + (size_t)r * DD);
    const float4* ar = (const float4*)(Amat + (size_t)cc * DD);
    float acc = 0.f;
#pragma unroll 4
    for (int k = 0; k < 128; ++k) {
        float4 xa = xr[k], aa = ar[k];
        acc += xa.x*aa.x + xa.y*aa.y + xa.z*aa.z + xa.w*aa.w;
    }
    tmp[(size_t)r * 16 + cc] = acc;
}

// delta -> bf16 (small additive term)
__global__ void k_lora2(const float* __restrict__ tmp, const float* __restrict__ Bmat,
                        unsigned short* __restrict__ qf) {
    int idx = blockIdx.x * 256 + threadIdx.x;
    int m2 = idx >> 9, n2 = idx & 511;
    const float4* tr = (const float4*)(tmp + (size_t)m2 * 16);
    const float4* br = (const float4*)(Bmat + (size_t)n2 * 16);
    float acc = 0.f;
#pragma unroll
    for (int rr = 0; rr < 4; ++rr) {
        float4 ta = tr[rr], ba = br[rr];
        acc += ta.x*ba.x + ta.y*ba.y + ta.z*ba.z + ta.w*ba.w;
    }
    qf[idx] = f2bf(acc);
}

// ---------------- bf16 MFMA GEMM: acc = Aq[M,512] @ Wq[N,512]^T, scaled epilogue ----------------
// MODE 2: OutF = acc*as + Extra(resid fp32)
// MODE 3: OutB(Qb bf16 [b][h][q][64]) = (acc*as + Extra[h]*Dlt) * QSCALE   (fused Q cvt)
// MODE 4: OutB = Kb bf16 [b][h][key][64]; OutB2 = Vt bf16 [b][h][d][key]   (fused KV cvt)
template <int MODE>
__global__ __launch_bounds__(256) void k_gemm_mfma(
    const unsigned short* __restrict__ Aq, const unsigned short* __restrict__ Wq,
    const float* __restrict__ a_inv, const float* __restrict__ winv_p,
    const float* __restrict__ Extra, const unsigned short* __restrict__ Dlt,
    float* __restrict__ OutF, unsigned short* __restrict__ OutB,
    unsigned short* __restrict__ OutB2,
    int logn, int M, int N) {
    __shared__ __align__(16) unsigned short sA[128 * 32];
    __shared__ __align__(16) unsigned short sB[128 * 32];
    int t = threadIdx.x;
    int w = t >> 6, lane = t & 63;
    int wm = w >> 1, wn = w & 1;
    int lr = lane & 15, lg = lane >> 4;
    int m0 = blockIdx.y * 128, n0 = blockIdx.x * 128;
    int row_st = t >> 2, chunk = t & 3;
    f32x4 acc[4][4] = {};

    for (int k0 = 0; k0 < 512; k0 += 32) {
        __syncthreads();
#pragma unroll
        for (int i = 0; i < 2; ++i) {
            int row = i * 64 + row_st;
            GLOAD16(Aq + (size_t)(m0 + row) * 512 + k0 + chunk * 8, sA + ((size_t)i * 256 + t) * 8);
            GLOAD16(Wq + (size_t)(n0 + row) * 512 + k0 + chunk * 8, sB + ((size_t)i * 256 + t) * 8);
        }
        asm volatile("s_waitcnt vmcnt(0)" ::: "memory");
        __syncthreads();
        bf16x8 af[4], bfr[4];
#pragma unroll
        for (int mt = 0; mt < 4; ++mt)
            af[mt] = *reinterpret_cast<const bf16x8*>(&sA[(wm * 64 + mt * 16 + lr) * 32 + lg * 8]);
#pragma unroll
        for (int nt = 0; nt < 4; ++nt)
            bfr[nt] = *reinterpret_cast<const bf16x8*>(&sB[(wn * 64 + nt * 16 + lr) * 32 + lg * 8]);
#pragma unroll
        for (int mt = 0; mt < 4; ++mt)
#pragma unroll
            for (int nt = 0; nt < 4; ++nt)
                acc[mt][nt] = __builtin_amdgcn_mfma_f32_16x16x32_bf16(af[mt], bfr[nt], acc[mt][nt], 0, 0, 0);
    }

    float wv = *winv_p;
    if (MODE == 4) {
        const bool isV = (n0 >= 512);
        const int Nc = 1 << logn;
#pragma unroll
        for (int mt = 0; mt < 4; ++mt) {
            int mb = m0 + wm * 64 + mt * 16 + lg * 4;
            int b = mb >> logn, key = mb & (Nc - 1);
            float as_[4];
#pragma unroll
            for (int r = 0; r < 4; ++r) as_[r] = a_inv[mb + r] * wv;
#pragma unroll
            for (int nt = 0; nt < 4; ++nt) {
                int n = n0 + wn * 64 + nt * 16 + lr;
                int n2 = isV ? (n - 512) : n;
                int h = n2 >> 6, dd = n2 & 63;
                if (isV) {
                    ushort4 v;
                    v.x = f2bf(acc[mt][nt][0] * as_[0]);
                    v.y = f2bf(acc[mt][nt][1] * as_[1]);
                    v.z = f2bf(acc[mt][nt][2] * as_[2]);
                    v.w = f2bf(acc[mt][nt][3] * as_[3]);
                    *reinterpret_cast<ushort4*>(
                        OutB2 + ((size_t)(b * NHEAD + h) * 64 + dd) * Nc + key) = v;
                } else {
#pragma unroll
                    for (int r = 0; r < 4; ++r)
                        OutB[((size_t)(b * NHEAD + h) * Nc + key + r) * 64 + dd] =
                            f2bf(acc[mt][nt][r] * as_[r]);
                }
            }
        }
    } else {
#pragma unroll
        for (int mt = 0; mt < 4; ++mt) {
#pragma unroll
            for (int r = 0; r < 4; ++r) {
                int m = m0 + wm * 64 + mt * 16 + lg * 4 + r;
                float as = a_inv[m] * wv;
                if (MODE == 3) {
                    int b = m >> logn, q = m & ((1 << logn) - 1);
#pragma unroll
                    for (int nt = 0; nt < 4; ++nt) {
                        int n = n0 + wn * 64 + nt * 16 + lr;
                        float dl = bf2f(Dlt[(size_t)m * 512 + n]);
                        float val = acc[mt][nt][r] * as + Extra[n >> 6] * dl;
                        int h = n >> 6, d = n & 63;
                        OutB[((((size_t)(b * NHEAD + h)) << logn) + q) * 64 + d] =
                            f2bf(val * QSCALE);
                    }
                } else {
#pragma unroll
                    for (int nt = 0; nt < 4; ++nt) {
                        int n = n0 + wn * 64 + nt * 16 + lr;
                        size_t idx = (size_t)m * N + n;
                        OutF[idx] = acc[mt][nt][r] * as + Extra[idx];
                    }
                }
            }
        }
    }
}

// ---------------- flash attention, bf16 MFMA 16x16x32 ----------------
__global__ __launch_bounds__(512) void k_attn_mfma(
    const unsigned short* __restrict__ Qb, const unsigned short* __restrict__ Kb,
    const unsigned short* __restrict__ Vt, float* __restrict__ attn,
    int Nq, int Nc, int nqb_shift) {
    __shared__ unsigned short sK[64][72];
    __shared__ unsigned short sVt[64][72];
    __shared__ __bf16 sP[8][16][76];
    int t = threadIdx.x;
    int w = t >> 6, lane = t & 63;
    int lr = lane & 15, lg = lane >> 4;

    int bid = blockIdx.x;
    int j = bid >> 3;
    int qblk = j & ((1 << nqb_shift) - 1);
    int bh = ((bid & 7) << 2) | (j >> nqb_shift);
    int b = bh >> 3, h = bh & 7;
    int q0 = qblk * 128 + w * 16;

    const unsigned short* qbase = Qb + ((size_t)bh * Nq + q0 + lr) * 64 + lg * 8;
    bf16x8 aq0 = *reinterpret_cast<const bf16x8*>(qbase);
    bf16x8 aq1 = *reinterpret_cast<const bf16x8*>(qbase + 32);

    u16x8 ou;
#pragma unroll
    for (int jj = 0; jj < 8; ++jj) ou[jj] = (lr == 0) ? 0x3F80 : 0;
    bf16x8 onesf = __builtin_bit_cast(bf16x8, ou);

    f32x4 o[4] = {};
    f32x4 osum = {};

    const unsigned short* kglob = Kb + (size_t)bh * Nc * 64;
    const unsigned short* vglob = Vt + (size_t)bh * 64 * (size_t)Nc;

    int srow = t >> 3, sseg = t & 7;
    const unsigned short* kptr = kglob + (size_t)srow * 64 + sseg * 8;
    const unsigned short* vptr = vglob + (size_t)srow * Nc + sseg * 8;

    bf16x8 rK = *reinterpret_cast<const bf16x8*>(kptr);
    bf16x8 rV = *reinterpret_cast<const bf16x8*>(vptr);

    for (int kt0 = 0; kt0 < Nc; kt0 += 64) {
        __syncthreads();
        *reinterpret_cast<bf16x8*>(&sK[srow][sseg * 8]) = rK;
        *reinterpret_cast<bf16x8*>(&sVt[srow][sseg * 8]) = rV;
        __syncthreads();
        if (kt0 + 64 < Nc) {
            rK = *reinterpret_cast<const bf16x8*>(kptr + (size_t)(kt0 + 64) * 64);
            rV = *reinterpret_cast<const bf16x8*>(vptr + kt0 + 64);
        }
#pragma unroll
        for (int kt = 0; kt < 4; ++kt) {
            bf16x8 bk0 = *reinterpret_cast<const bf16x8*>(&sK[kt * 16 + lr][lg * 8]);
            bf16x8 bk1 = *reinterpret_cast<const bf16x8*>(&sK[kt * 16 + lr][32 + lg * 8]);
            f32x4 acc = {};
            __builtin_amdgcn_s_setprio(1);
            acc = __builtin_amdgcn_mfma_f32_16x16x32_bf16(aq0, bk0, acc, 0, 0, 0);
            acc = __builtin_amdgcn_mfma_f32_16x16x32_bf16(aq1, bk1, acc, 0, 0, 0);
            __builtin_amdgcn_s_setprio(0);
#pragma unroll
            for (int r = 0; r < 4; ++r)
                sP[w][lg * 4 + r][kt * 16 + lr] = (__bf16)EXP2F(fminf(acc[r], 43.f));
        }
        // sP per-wave: intra-wave LDS ordering suffices, no barrier.
#pragma unroll
        for (int kg = 0; kg < 2; ++kg) {
            bf16x8 pa = *reinterpret_cast<const bf16x8*>(&sP[w][lr][kg * 32 + lg * 8]);
            __builtin_amdgcn_s_setprio(1);
#pragma unroll
            for (int dt = 0; dt < 4; ++dt) {
                bf16x8 vb = *reinterpret_cast<const bf16x8*>(&sVt[dt * 16 + lr][kg * 32 + lg * 8]);
                o[dt] = __builtin_amdgcn_mfma_f32_16x16x32_bf16(pa, vb, o[dt], 0, 0, 0);
            }
            osum = __builtin_amdgcn_mfma_f32_16x16x32_bf16(pa, onesf, osum, 0, 0, 0);
            __builtin_amdgcn_s_setprio(0);
        }
    }
    float ls[4];
#pragma unroll
    for (int r = 0; r < 4; ++r) ls[r] = 1.f / __shfl(osum[r], lane & 48);
    float* obase = attn + ((size_t)b * Nq + q0) * DD + h * HDIM;
#pragma unroll
    for (int dt = 0; dt < 4; ++dt)
#pragma unroll
        for (int r = 0; r < 4; ++r) {
            int qr = lg * 4 + r;
            obase[(size_t)qr * DD + dt * 16 + lr] = o[dt][r] * ls[r];
        }
}

// ---------------- host side ----------------
static void run_pass(const float* q_in,
                     const unsigned short* act_q, const float* sc_q,
                     const unsigned short* act_kv, const float* sc_kv,
                     const unsigned short* Wq_t, const unsigned short* Wkv_t,
                     const unsigned short* Wp_t,
                     const float* Amat, const float* Bmat, const float* mag,
                     const float* gp,
                     const float* winv_q, const float* winv_kv, const float* winv_p,
                     int Mq, int Mc, int Nq, int Nc, int lognq, int lognc,
                     float* arena, float* sc_o, float* outp, const float* resid,
                     hipStream_t stream) {
    float* qf_f  = arena;                          // bf16 delta / later act_o
    float* Qb_f  = qf_f + (size_t)Mq * 256;
    float* Kb_f  = Qb_f + (size_t)Mq * 256;
    float* Vt_f  = Kb_f + (size_t)Mc * 256;
    float* attnO = Vt_f + (size_t)Mc * 256;
    float* tmp   = attnO + (size_t)Mq * 512;

    unsigned short* qf = (unsigned short*)qf_f;
    unsigned short* Qb = (unsigned short*)Qb_f;
    unsigned short* Kb = (unsigned short*)Kb_f;
    unsigned short* Vt = (unsigned short*)Vt_f;

    k_lora1<<<Mq / 16, 256, 0, stream>>>(q_in, Amat, tmp);
    k_lora2<<<(Mq * 512) / 256, 256, 0, stream>>>(tmp, Bmat, qf);
    // Q projection + DoRA add + bf16 Q layout (fused)
    k_gemm_mfma<3><<<dim3(4, Mq / 128), 256, 0, stream>>>(
        act_q, Wq_t, sc_q, winv_q, mag, qf, nullptr, Qb, nullptr, lognq, Mq, 512);
    // KV projection + bf16 K + transposed bf16 V (fused)
    k_gemm_mfma<4><<<dim3(8, Mc / 128), 256, 0, stream>>>(
        act_kv, Wkv_t, sc_kv, winv_kv, nullptr, nullptr, nullptr, Kb, Vt, lognc, Mc, 1024);

    int nqb = Nq / 128;
    k_attn_mfma<<<dim3(32 * nqb), 512, 0, stream>>>(Qb, Kb, Vt, attnO, Nq, Nc,
                                                    __builtin_ctz(nqb));

    unsigned short* act_o = qf;  // delta region dead after MODE3
    k_rmsq<<<Mq, 64, 0, stream>>>(attnO, gp, act_o, sc_o);
    k_gemm_mfma<2><<<dim3(4, Mq / 128), 256, 0, stream>>>(
        act_o, Wp_t, sc_o, winv_p, resid, nullptr, outp, nullptr, nullptr, 0, Mq, 512);
}

extern "C" void kernel_launch(void* const* d_in, const int* in_sizes, int n_in,
                              void* d_out, int out_size, void* d_ws, size_t ws_size,
                              hipStream_t stream) {
    const float* x     = (const float*)d_in[0];
    const float* c     = (const float*)d_in[1];
    const float* Wq_x  = (const float*)d_in[2];
    const float* g_qx  = (const float*)d_in[3];
    const float* Wkv_c = (const float*)d_in[4];
    const float* g_kvc = (const float*)d_in[5];
    const float* A_x   = (const float*)d_in[6];
    const float* B_x   = (const float*)d_in[7];
    const float* mag_x = (const float*)d_in[8];
    const float* Wp_x  = (const float*)d_in[9];
    const float* g_px  = (const float*)d_in[10];
    const float* Wq_c  = (const float*)d_in[11];
    const float* g_qc  = (const float*)d_in[12];
    const float* Wkv_x = (const float*)d_in[13];
    const float* g_kvx = (const float*)d_in[14];
    const float* A_c   = (const float*)d_in[15];
    const float* B_c   = (const float*)d_in[16];
    const float* mag_c = (const float*)d_in[17];
    const float* Wp_c  = (const float*)d_in[18];
    const float* g_pc  = (const float*)d_in[19];

    float* ws = (float*)d_ws;
    // layout (floats):
    // [0, 1048576)              bf16 weights (2097152 u16)
    // [1048576, 1049600)        part(192) + scal(8) + winv(8) + pad
    // [1049600, 1115136)        per-row scales
    // [1115136, 11600896)       activations (4 bf16 tensors)
    // [11600896, ...)           per-pass arena (max 19,136,512 floats)
    unsigned short* Wb = (unsigned short*)ws;
    const size_t Woff[6] = {0, 262144, 786432, 1048576, 1310720, 1835008}; // u16 units
    float* part = ws + 1048576;
    float* scal = part + 192;
    float* winv = scal + 8;
    float* scb = ws + 1049600;
    float* sc_xq  = scb;
    float* sc_xkv = scb + 16384;
    float* sc_cq  = scb + 32768;
    float* sc_ckv = scb + 36864;
    float* sc_o1  = scb + 40960;
    float* sc_o2  = scb + 57344;
    unsigned short* act_xq  = (unsigned short*)(ws + 1115136);
    unsigned short* act_xkv = (unsigned short*)(ws + 5309440);
    unsigned short* act_cq  = (unsigned short*)(ws + 9503744);
    unsigned short* act_ckv = (unsigned short*)(ws + 10552320);
    float* arena = ws + 11600896;

    size_t need = (size_t)30737408 * sizeof(float);   // ~123 MB
    if (ws_size < need) return;

    // weight prep (3 launches)
    k_wabs_all<<<192, 256, 0, stream>>>(Wq_x, Wkv_c, Wp_x, Wq_c, Wkv_x, Wp_c, part);
    k_wfinal<<<1, 64, 0, stream>>>(part, scal, winv);
    k_wquant_all<<<8192, 256, 0, stream>>>(Wq_x, Wkv_c, Wp_x, Wq_c, Wkv_x, Wp_c, Wb, scal);

    // all activations up-front; x/c each read once
    k_rmsq_dual<<<16384, 64, 0, stream>>>(x, g_qx, g_kvx, act_xq, act_xkv, sc_xq, sc_xkv);
    k_rmsq_dual<<<4096, 64, 0, stream>>>(c, g_qc, g_kvc, act_cq, act_ckv, sc_cq, sc_ckv);

    float* outx = (float*)d_out;
    float* outc = outx + (size_t)4 * 4096 * 512;

    // pass 1: x queries attend to c
    run_pass(x, act_xq, sc_xq, act_ckv, sc_ckv,
             Wb + Woff[0], Wb + Woff[1], Wb + Woff[2],
             A_x, B_x, mag_x, g_px, winv + 0, winv + 1, winv + 2,
             16384, 4096, 4096, 1024, 12, 10, arena, sc_o1, outx, x, stream);
    // pass 2: c queries attend to x
    run_pass(c, act_cq, sc_cq, act_xkv, sc_xkv,
             Wb + Woff[3], Wb + Woff[4], Wb + Woff[5],
             A_c, B_c, mag_c, g_pc, winv + 3, winv + 4, winv + 5,
             4096, 16384, 1024, 4096, 10, 12, arena, sc_o2, outc, c, stream);
}

// Round 7
// 437.052 us; speedup vs baseline: 38.3305x; 1.0425x over previous
//
#include <hip/hip_runtime.h>
#include <math.h>

#define DD 512
#define NHEAD 8
#define HDIM 64

typedef __bf16 bf16x8 __attribute__((ext_vector_type(8)));
typedef unsigned short u16x8 __attribute__((ext_vector_type(8)));
typedef float f32x4 __attribute__((ext_vector_type(4)));

#if __has_builtin(__builtin_amdgcn_exp2f)
#define EXP2F(x) __builtin_amdgcn_exp2f(x)
#else
#define EXP2F(x) exp2f(x)
#endif

#define QSCALE 0.18033688f  /* (1/8) * log2(e): exp2 domain */

static __device__ __forceinline__ unsigned short f2bf(float f) {
    unsigned u = __builtin_bit_cast(unsigned, f);
    u += 0x7fffu + ((u >> 16) & 1u);   // round-to-nearest-even
    return (unsigned short)(u >> 16);
}
static __device__ __forceinline__ float bf2f(unsigned short u) {
    return __builtin_bit_cast(float, (unsigned)u << 16);
}

#define GLOAD16(g, l)                                                          \
    __builtin_amdgcn_global_load_lds(                                          \
        (__attribute__((address_space(1))) void*)(g),                          \
        (__attribute__((address_space(3))) void*)(l), 16, 0, 0)

// ---------------- weight ternary quant: consolidated prep ----------------
__global__ void k_wabs_all(const float* __restrict__ W0, const float* __restrict__ W1,
                           const float* __restrict__ W2, const float* __restrict__ W3,
                           const float* __restrict__ W4, const float* __restrict__ W5,
                           float* __restrict__ part) {
    const float* Ws[6] = {W0, W1, W2, W3, W4, W5};
    const int cnt[6] = {262144, 524288, 262144, 262144, 524288, 262144};
    int mid = blockIdx.x >> 5, lb = blockIdx.x & 31;
    const float* W = Ws[mid];
    int n = cnt[mid];
    int t = threadIdx.x;
    float s = 0.f;
    for (int i = lb * 256 + t; i < n; i += 32 * 256) s += fabsf(W[i]);
    __shared__ float red[4];
#pragma unroll
    for (int o = 32; o > 0; o >>= 1) s += __shfl_down(s, o);
    if ((t & 63) == 0) red[t >> 6] = s;
    __syncthreads();
    if (t == 0) part[blockIdx.x] = red[0] + red[1] + red[2] + red[3];
}

__global__ void k_wfinal(const float* __restrict__ part, float* __restrict__ scal,
                         float* __restrict__ winv) {
    int m = threadIdx.x;
    if (m < 6) {
        const int cnt[6] = {262144, 524288, 262144, 262144, 524288, 262144};
        float s = 0.f;
        for (int i = 0; i < 32; ++i) s += part[m * 32 + i];
        float mean = fmaxf(s / (float)cnt[m], 1e-5f);
        scal[m] = 1.f / mean;
        winv[m] = mean;
    }
}

__global__ void k_wquant_all(const float* __restrict__ W0, const float* __restrict__ W1,
                             const float* __restrict__ W2, const float* __restrict__ W3,
                             const float* __restrict__ W4, const float* __restrict__ W5,
                             unsigned short* __restrict__ Wq, const float* __restrict__ scal) {
    int e = blockIdx.x * 256 + threadIdx.x;
    const float* Ws[6] = {W0, W1, W2, W3, W4, W5};
    int mid, base;
    if (e < 262144)       { mid = 0; base = 0; }
    else if (e < 786432)  { mid = 1; base = 262144; }
    else if (e < 1048576) { mid = 2; base = 786432; }
    else if (e < 1310720) { mid = 3; base = 1048576; }
    else if (e < 1835008) { mid = 4; base = 1310720; }
    else                  { mid = 5; base = 1835008; }
    float sc = scal[mid];
    float t = rintf(Ws[mid][e - base] * sc);
    t = fminf(fmaxf(t, -1.f), 1.f);
    Wq[e] = f2bf(t);
}

// ---------------- RMSNorm + int8 absmax quant -> bf16 INTEGER activations ----------------
__global__ void k_rmsq_dual(const float* __restrict__ X,
                            const float* __restrict__ g1, const float* __restrict__ g2,
                            unsigned short* __restrict__ o1, unsigned short* __restrict__ o2,
                            float* __restrict__ s1, float* __restrict__ s2) {
    int row = blockIdx.x;
    int lane = threadIdx.x;
    const float* xr = X + (size_t)row * DD;
    float4 a = *(const float4*)(xr + lane * 8);
    float4 b = *(const float4*)(xr + lane * 8 + 4);
    float ss = a.x*a.x + a.y*a.y + a.z*a.z + a.w*a.w
             + b.x*b.x + b.y*b.y + b.z*b.z + b.w*b.w;
#pragma unroll
    for (int o = 32; o > 0; o >>= 1) ss += __shfl_xor(ss, o);
    float rn = 1.f / sqrtf(ss * (1.f / 512.f) + 1e-8f);
    const float* gs[2] = {g1, g2};
    unsigned short* os[2] = {o1, o2};
    float* scs[2] = {s1, s2};
#pragma unroll
    for (int pass = 0; pass < 2; ++pass) {
        float4 ga = *(const float4*)(gs[pass] + lane * 8);
        float4 gb = *(const float4*)(gs[pass] + lane * 8 + 4);
        float v[8] = {a.x*rn*ga.x, a.y*rn*ga.y, a.z*rn*ga.z, a.w*rn*ga.w,
                      b.x*rn*gb.x, b.y*rn*gb.y, b.z*rn*gb.z, b.w*rn*gb.w};
        float amax = 0.f;
#pragma unroll
        for (int i = 0; i < 8; ++i) amax = fmaxf(amax, fabsf(v[i]));
#pragma unroll
        for (int o = 32; o > 0; o >>= 1) amax = fmaxf(amax, __shfl_xor(amax, o));
        float mx = fmaxf(amax, 1e-5f);
        float scale = 127.f / mx;
        u16x8 qv;
#pragma unroll
        for (int i = 0; i < 8; ++i) {
            float tq = rintf(v[i] * scale);
            tq = fminf(fmaxf(tq, -128.f), 127.f);
            qv[i] = f2bf(tq);
        }
        *reinterpret_cast<u16x8*>(os[pass] + (size_t)row * DD + lane * 8) = qv;
        if (lane == 0) scs[pass][row] = mx / 127.f;
    }
}

// ---------------- combine attn partials + RMSNorm + quant ----------------
// Opart[s][b][q][512] unnormalized, Lpart[s][b][h][q] row sums; v = (Sum O)/(Sum l)
template <int S>
__global__ void k_rmsq_combine(const float* __restrict__ Opart, const float* __restrict__ Lpart,
                               const float* __restrict__ g, unsigned short* __restrict__ out,
                               float* __restrict__ a_inv, int lognq) {
    int row = blockIdx.x;              // b*Nq + q
    int lane = threadIdx.x;            // 64 threads x 8 elems
    int Nq = 1 << lognq;
    int b = row >> lognq, q = row & (Nq - 1);
    int h = lane >> 3;
    float l = 0.f;
    float u[8] = {};
#pragma unroll
    for (int s = 0; s < S; ++s) {
        l += Lpart[((size_t)(s * 4 + b) * 8 + h) * Nq + q];
        const float* orow = Opart + ((size_t)(s * 4 + b) * Nq + q) * 512 + lane * 8;
        float4 a = *(const float4*)orow;
        float4 bb = *(const float4*)(orow + 4);
        u[0] += a.x; u[1] += a.y; u[2] += a.z; u[3] += a.w;
        u[4] += bb.x; u[5] += bb.y; u[6] += bb.z; u[7] += bb.w;
    }
    float invl = 1.f / l;
#pragma unroll
    for (int i = 0; i < 8; ++i) u[i] *= invl;
    float ss = 0.f;
#pragma unroll
    for (int i = 0; i < 8; ++i) ss += u[i] * u[i];
#pragma unroll
    for (int o = 32; o > 0; o >>= 1) ss += __shfl_xor(ss, o);
    float rn = 1.f / sqrtf(ss * (1.f / 512.f) + 1e-8f);
    float4 ga = *(const float4*)(g + lane * 8);
    float4 gb = *(const float4*)(g + lane * 8 + 4);
    float v[8] = {u[0]*rn*ga.x, u[1]*rn*ga.y, u[2]*rn*ga.z, u[3]*rn*ga.w,
                  u[4]*rn*gb.x, u[5]*rn*gb.y, u[6]*rn*gb.z, u[7]*rn*gb.w};
    float amax = 0.f;
#pragma unroll
    for (int i = 0; i < 8; ++i) amax = fmaxf(amax, fabsf(v[i]));
#pragma unroll
    for (int o = 32; o > 0; o >>= 1) amax = fmaxf(amax, __shfl_xor(amax, o));
    float mx = fmaxf(amax, 1e-5f);
    float scale = 127.f / mx;
    u16x8 qv;
#pragma unroll
    for (int i = 0; i < 8; ++i) {
        float tq = rintf(v[i] * scale);
        tq = fminf(fmaxf(tq, -128.f), 127.f);
        qv[i] = f2bf(tq);
    }
    *reinterpret_cast<u16x8*>(out + (size_t)row * DD + lane * 8) = qv;
    if (lane == 0) a_inv[row] = mx / 127.f;
}

// ---------------- DoRA low-rank delta ----------------
__global__ void k_lora1(const float* __restrict__ X, const float* __restrict__ Amat,
                        float* __restrict__ tmp) {
    int t = threadIdx.x;
    int r = blockIdx.x * 16 + (t >> 4);
    int cc = t & 15;
    const float4* xr = (const float4*)(X + (size_t)r * DD);
    const float4* ar = (const float4*)(Amat + (size_t)cc * DD);
    float acc = 0.f;
#pragma unroll 4
    for (int k = 0; k < 128; ++k) {
        float4 xa = xr[k], aa = ar[k];
        acc += xa.x*aa.x + xa.y*aa.y + xa.z*aa.z + xa.w*aa.w;
    }
    tmp[(size_t)r * 16 + cc] = acc;
}

__global__ void k_lora2(const float* __restrict__ tmp, const float* __restrict__ Bmat,
                        unsigned short* __restrict__ qf) {
    int idx = blockIdx.x * 256 + threadIdx.x;
    int m2 = idx >> 9, n2 = idx & 511;
    const float4* tr = (const float4*)(tmp + (size_t)m2 * 16);
    const float4* br = (const float4*)(Bmat + (size_t)n2 * 16);
    float acc = 0.f;
#pragma unroll
    for (int rr = 0; rr < 4; ++rr) {
        float4 ta = tr[rr], ba = br[rr];
        acc += ta.x*ba.x + ta.y*ba.y + ta.z*ba.z + ta.w*ba.w;
    }
    qf[idx] = f2bf(acc);
}

// ---------------- bf16 MFMA GEMM: acc = Aq[M,512] @ Wq[N,512]^T, scaled epilogue ----------------
// MODE 2: OutF = acc*as + Extra(resid fp32)
// MODE 3: OutB(Qb bf16 [b][h][q][64]) = (acc*as + Extra[h]*Dlt) * QSCALE
// MODE 4: OutB = Kb bf16 [b][h][key][64]; OutB2 = Vt bf16 [b][h][d][key]
template <int MODE>
__global__ __launch_bounds__(256) void k_gemm_mfma(
    const unsigned short* __restrict__ Aq, const unsigned short* __restrict__ Wq,
    const float* __restrict__ a_inv, const float* __restrict__ winv_p,
    const float* __restrict__ Extra, const unsigned short* __restrict__ Dlt,
    float* __restrict__ OutF, unsigned short* __restrict__ OutB,
    unsigned short* __restrict__ OutB2,
    int logn, int M, int N) {
    __shared__ __align__(16) unsigned short sA[128 * 32];
    __shared__ __align__(16) unsigned short sB[128 * 32];
    int t = threadIdx.x;
    int w = t >> 6, lane = t & 63;
    int wm = w >> 1, wn = w & 1;
    int lr = lane & 15, lg = lane >> 4;
    int m0 = blockIdx.y * 128, n0 = blockIdx.x * 128;
    int row_st = t >> 2, chunk = t & 3;
    f32x4 acc[4][4] = {};

    for (int k0 = 0; k0 < 512; k0 += 32) {
        __syncthreads();
#pragma unroll
        for (int i = 0; i < 2; ++i) {
            int row = i * 64 + row_st;
            GLOAD16(Aq + (size_t)(m0 + row) * 512 + k0 + chunk * 8, sA + ((size_t)i * 256 + t) * 8);
            GLOAD16(Wq + (size_t)(n0 + row) * 512 + k0 + chunk * 8, sB + ((size_t)i * 256 + t) * 8);
        }
        asm volatile("s_waitcnt vmcnt(0)" ::: "memory");
        __syncthreads();
        bf16x8 af[4], bfr[4];
#pragma unroll
        for (int mt = 0; mt < 4; ++mt)
            af[mt] = *reinterpret_cast<const bf16x8*>(&sA[(wm * 64 + mt * 16 + lr) * 32 + lg * 8]);
#pragma unroll
        for (int nt = 0; nt < 4; ++nt)
            bfr[nt] = *reinterpret_cast<const bf16x8*>(&sB[(wn * 64 + nt * 16 + lr) * 32 + lg * 8]);
#pragma unroll
        for (int mt = 0; mt < 4; ++mt)
#pragma unroll
            for (int nt = 0; nt < 4; ++nt)
                acc[mt][nt] = __builtin_amdgcn_mfma_f32_16x16x32_bf16(af[mt], bfr[nt], acc[mt][nt], 0, 0, 0);
    }

    float wv = *winv_p;
    if (MODE == 4) {
        const bool isV = (n0 >= 512);
        const int Nc = 1 << logn;
#pragma unroll
        for (int mt = 0; mt < 4; ++mt) {
            int mb = m0 + wm * 64 + mt * 16 + lg * 4;
            int b = mb >> logn, key = mb & (Nc - 1);
            float as_[4];
#pragma unroll
            for (int r = 0; r < 4; ++r) as_[r] = a_inv[mb + r] * wv;
#pragma unroll
            for (int nt = 0; nt < 4; ++nt) {
                int n = n0 + wn * 64 + nt * 16 + lr;
                int n2 = isV ? (n - 512) : n;
                int h = n2 >> 6, dd = n2 & 63;
                if (isV) {
                    ushort4 v;
                    v.x = f2bf(acc[mt][nt][0] * as_[0]);
                    v.y = f2bf(acc[mt][nt][1] * as_[1]);
                    v.z = f2bf(acc[mt][nt][2] * as_[2]);
                    v.w = f2bf(acc[mt][nt][3] * as_[3]);
                    *reinterpret_cast<ushort4*>(
                        OutB2 + ((size_t)(b * NHEAD + h) * 64 + dd) * Nc + key) = v;
                } else {
#pragma unroll
                    for (int r = 0; r < 4; ++r)
                        OutB[((size_t)(b * NHEAD + h) * Nc + key + r) * 64 + dd] =
                            f2bf(acc[mt][nt][r] * as_[r]);
                }
            }
        }
    } else {
#pragma unroll
        for (int mt = 0; mt < 4; ++mt) {
#pragma unroll
            for (int r = 0; r < 4; ++r) {
                int m = m0 + wm * 64 + mt * 16 + lg * 4 + r;
                float as = a_inv[m] * wv;
                if (MODE == 3) {
                    int b = m >> logn, q = m & ((1 << logn) - 1);
#pragma unroll
                    for (int nt = 0; nt < 4; ++nt) {
                        int n = n0 + wn * 64 + nt * 16 + lr;
                        float dl = bf2f(Dlt[(size_t)m * 512 + n]);
                        float val = acc[mt][nt][r] * as + Extra[n >> 6] * dl;
                        int h = n >> 6, d = n & 63;
                        OutB[((((size_t)(b * NHEAD + h)) << logn) + q) * 64 + d] =
                            f2bf(val * QSCALE);
                    }
                } else {
#pragma unroll
                    for (int nt = 0; nt < 4; ++nt) {
                        int n = n0 + wn * 64 + nt * 16 + lr;
                        size_t idx = (size_t)m * N + n;
                        OutF[idx] = acc[mt][nt][r] * as + Extra[idx];
                    }
                }
            }
        }
    }
}

// ---------------- flash attention, bf16 MFMA, 32 queries/wave ----------------
// 512 threads = 8 waves, QBLK=256 (32 q/wave as 2x16 subtiles sharing K/V LDS reads).
// Plain softmax in exp2 domain -> partials over key-splits are exactly additive:
// template S = number of key-splits; block s covers keys [s*Nc/S, (s+1)*Nc/S).
// Writes unnormalized Opart + row-sum Lpart; k_rmsq_combine folds normalize.
template <int S>
__global__ __launch_bounds__(512) void k_attn_mfma(
    const unsigned short* __restrict__ Qb, const unsigned short* __restrict__ Kb,
    const unsigned short* __restrict__ Vt, float* __restrict__ Opart,
    float* __restrict__ Lpart, int Nq, int Nc, int nqb_shift) {
    __shared__ unsigned short sK[64][72];
    __shared__ unsigned short sVt[64][72];
    __shared__ __bf16 sP[8][32][76];
    constexpr int LOGS = (S == 2) ? 1 : 0;
    int t = threadIdx.x;
    int w = t >> 6, lane = t & 63;
    int lr = lane & 15, lg = lane >> 4;

    int bid = blockIdx.x;
    int j = bid >> 3;
    int s = j & (S - 1);
    int j2 = j >> LOGS;
    int qblk = j2 & ((1 << nqb_shift) - 1);
    int bh = ((bid & 7) << 2) | (j2 >> nqb_shift);   // XCD-local bh groups
    int b = bh >> 3, h = bh & 7;
    int q0 = qblk * 256 + w * 32;

    // Q fragments: 2 q-subtiles x 2 k-halves (A layout: row=lane&15, k=(lane>>4)*8+j)
    bf16x8 aq[2][2];
#pragma unroll
    for (int qt = 0; qt < 2; ++qt) {
        const unsigned short* qbase = Qb + ((size_t)bh * Nq + q0 + qt * 16 + lr) * 64 + lg * 8;
        aq[qt][0] = *reinterpret_cast<const bf16x8*>(qbase);
        aq[qt][1] = *reinterpret_cast<const bf16x8*>(qbase + 32);
    }

    u16x8 ou;
#pragma unroll
    for (int jj = 0; jj < 8; ++jj) ou[jj] = (lr == 0) ? 0x3F80 : 0;
    bf16x8 onesf = __builtin_bit_cast(bf16x8, ou);

    f32x4 o[2][4] = {};
    f32x4 osum[2] = {};

    const unsigned short* kglob = Kb + (size_t)bh * Nc * 64;
    const unsigned short* vglob = Vt + (size_t)bh * 64 * (size_t)Nc;

    int srow = t >> 3, sseg = t & 7;    // 512 threads stage 64x64 (1 b128 each)
    const unsigned short* kptr = kglob + (size_t)srow * 64 + sseg * 8;
    const unsigned short* vptr = vglob + (size_t)srow * Nc + sseg * 8;

    int kts = s * (Nc >> LOGS);
    int kte = kts + (Nc >> LOGS);

    bf16x8 rK = *reinterpret_cast<const bf16x8*>(kptr + (size_t)kts * 64);
    bf16x8 rV = *reinterpret_cast<const bf16x8*>(vptr + kts);

    for (int kt0 = kts; kt0 < kte; kt0 += 64) {
        __syncthreads();
        *reinterpret_cast<bf16x8*>(&sK[srow][sseg * 8]) = rK;
        *reinterpret_cast<bf16x8*>(&sVt[srow][sseg * 8]) = rV;
        __syncthreads();
        if (kt0 + 64 < kte) {   // prefetch next tile under compute
            rK = *reinterpret_cast<const bf16x8*>(kptr + (size_t)(kt0 + 64) * 64);
            rV = *reinterpret_cast<const bf16x8*>(vptr + kt0 + 64);
        }
        // S = Q K^T (exp2 domain), both q-subtiles share bk reads
#pragma unroll
        for (int kt = 0; kt < 4; ++kt) {
            bf16x8 bk0 = *reinterpret_cast<const bf16x8*>(&sK[kt * 16 + lr][lg * 8]);
            bf16x8 bk1 = *reinterpret_cast<const bf16x8*>(&sK[kt * 16 + lr][32 + lg * 8]);
            f32x4 a0 = {}, a1 = {};
            __builtin_amdgcn_s_setprio(1);
            a0 = __builtin_amdgcn_mfma_f32_16x16x32_bf16(aq[0][0], bk0, a0, 0, 0, 0);
            a1 = __builtin_amdgcn_mfma_f32_16x16x32_bf16(aq[1][0], bk0, a1, 0, 0, 0);
            a0 = __builtin_amdgcn_mfma_f32_16x16x32_bf16(aq[0][1], bk1, a0, 0, 0, 0);
            a1 = __builtin_amdgcn_mfma_f32_16x16x32_bf16(aq[1][1], bk1, a1, 0, 0, 0);
            __builtin_amdgcn_s_setprio(0);
#pragma unroll
            for (int r = 0; r < 4; ++r) {
                sP[w][lg * 4 + r][kt * 16 + lr] = (__bf16)EXP2F(fminf(a0[r], 43.f));
                sP[w][16 + lg * 4 + r][kt * 16 + lr] = (__bf16)EXP2F(fminf(a1[r], 43.f));
            }
        }
        // sP per-wave: intra-wave LDS ordering suffices, no barrier.
        // O += P @ V ; osum += P @ ones   (vb shared across q-subtiles)
#pragma unroll
        for (int kg = 0; kg < 2; ++kg) {
            bf16x8 pa0 = *reinterpret_cast<const bf16x8*>(&sP[w][lr][kg * 32 + lg * 8]);
            bf16x8 pa1 = *reinterpret_cast<const bf16x8*>(&sP[w][16 + lr][kg * 32 + lg * 8]);
            __builtin_amdgcn_s_setprio(1);
#pragma unroll
            for (int dt = 0; dt < 4; ++dt) {
                bf16x8 vb = *reinterpret_cast<const bf16x8*>(&sVt[dt * 16 + lr][kg * 32 + lg * 8]);
                o[0][dt] = __builtin_amdgcn_mfma_f32_16x16x32_bf16(pa0, vb, o[0][dt], 0, 0, 0);
                o[1][dt] = __builtin_amdgcn_mfma_f32_16x16x32_bf16(pa1, vb, o[1][dt], 0, 0, 0);
            }
            osum[0] = __builtin_amdgcn_mfma_f32_16x16x32_bf16(pa0, onesf, osum[0], 0, 0, 0);
            osum[1] = __builtin_amdgcn_mfma_f32_16x16x32_bf16(pa1, onesf, osum[1], 0, 0, 0);
            __builtin_amdgcn_s_setprio(0);
        }
    }
    // write unnormalized partials
    float* obase = Opart + ((size_t)(s * 4 + b) * Nq + q0) * 512 + h * 64;
#pragma unroll
    for (int qt = 0; qt < 2; ++qt)
#pragma unroll
        for (int dt = 0; dt < 4; ++dt)
#pragma unroll
            for (int r = 0; r < 4; ++r)
                obase[(size_t)(qt * 16 + lg * 4 + r) * 512 + dt * 16 + lr] = o[qt][dt][r];
    if (lr == 0) {
        float* lbase = Lpart + ((size_t)(s * 4 + b) * 8 + h) * Nq + q0;
#pragma unroll
        for (int qt = 0; qt < 2; ++qt)
#pragma unroll
            for (int r = 0; r < 4; ++r)
                lbase[qt * 16 + lg * 4 + r] = osum[qt][r];
    }
}

// ---------------- host side ----------------
static void run_pass(const float* q_in,
                     const unsigned short* act_q, const float* sc_q,
                     const unsigned short* act_kv, const float* sc_kv,
                     const unsigned short* Wq_t, const unsigned short* Wkv_t,
                     const unsigned short* Wp_t,
                     const float* Amat, const float* Bmat, const float* mag,
                     const float* gp,
                     const float* winv_q, const float* winv_kv, const float* winv_p,
                     int Mq, int Mc, int Nq, int Nc, int lognq, int lognc, int S,
                     float* arena, float* sc_o, float* outp, const float* resid,
                     hipStream_t stream) {
    float* qf_f  = arena;
    float* Qb_f  = qf_f + (size_t)Mq * 256;
    float* Kb_f  = Qb_f + (size_t)Mq * 256;
    float* Vt_f  = Kb_f + (size_t)Mc * 256;
    float* Opart = Vt_f + (size_t)Mc * 256;
    float* Lpart = Opart + (size_t)8388608;
    float* tmp   = Lpart + 131072;

    unsigned short* qf = (unsigned short*)qf_f;
    unsigned short* Qb = (unsigned short*)Qb_f;
    unsigned short* Kb = (unsigned short*)Kb_f;
    unsigned short* Vt = (unsigned short*)Vt_f;

    k_lora1<<<Mq / 16, 256, 0, stream>>>(q_in, Amat, tmp);
    k_lora2<<<(Mq * 512) / 256, 256, 0, stream>>>(tmp, Bmat, qf);
    k_gemm_mfma<3><<<dim3(4, Mq / 128), 256, 0, stream>>>(
        act_q, Wq_t, sc_q, winv_q, mag, qf, nullptr, Qb, nullptr, lognq, Mq, 512);
    k_gemm_mfma<4><<<dim3(8, Mc / 128), 256, 0, stream>>>(
        act_kv, Wkv_t, sc_kv, winv_kv, nullptr, nullptr, nullptr, Kb, Vt, lognc, Mc, 1024);

    int nqb = Nq / 256;
    int nqs = __builtin_ctz(nqb);
    if (S == 1)
        k_attn_mfma<1><<<dim3(32 * nqb), 512, 0, stream>>>(Qb, Kb, Vt, Opart, Lpart, Nq, Nc, nqs);
    else
        k_attn_mfma<2><<<dim3(32 * nqb * 2), 512, 0, stream>>>(Qb, Kb, Vt, Opart, Lpart, Nq, Nc, nqs);

    unsigned short* act_o = qf;  // delta region dead after MODE3
    if (S == 1)
        k_rmsq_combine<1><<<Mq, 64, 0, stream>>>(Opart, Lpart, gp, act_o, sc_o, lognq);
    else
        k_rmsq_combine<2><<<Mq, 64, 0, stream>>>(Opart, Lpart, gp, act_o, sc_o, lognq);
    k_gemm_mfma<2><<<dim3(4, Mq / 128), 256, 0, stream>>>(
        act_o, Wp_t, sc_o, winv_p, resid, nullptr, outp, nullptr, nullptr, 0, Mq, 512);
}

extern "C" void kernel_launch(void* const* d_in, const int* in_sizes, int n_in,
                              void* d_out, int out_size, void* d_ws, size_t ws_size,
                              hipStream_t stream) {
    const float* x     = (const float*)d_in[0];
    const float* c     = (const float*)d_in[1];
    const float* Wq_x  = (const float*)d_in[2];
    const float* g_qx  = (const float*)d_in[3];
    const float* Wkv_c = (const float*)d_in[4];
    const float* g_kvc = (const float*)d_in[5];
    const float* A_x   = (const float*)d_in[6];
    const float* B_x   = (const float*)d_in[7];
    const float* mag_x = (const float*)d_in[8];
    const float* Wp_x  = (const float*)d_in[9];
    const float* g_px  = (const float*)d_in[10];
    const float* Wq_c  = (const float*)d_in[11];
    const float* g_qc  = (const float*)d_in[12];
    const float* Wkv_x = (const float*)d_in[13];
    const float* g_kvx = (const float*)d_in[14];
    const float* A_c   = (const float*)d_in[15];
    const float* B_c   = (const float*)d_in[16];
    const float* mag_c = (const float*)d_in[17];
    const float* Wp_c  = (const float*)d_in[18];
    const float* g_pc  = (const float*)d_in[19];

    float* ws = (float*)d_ws;
    unsigned short* Wb = (unsigned short*)ws;
    const size_t Woff[6] = {0, 262144, 786432, 1048576, 1310720, 1835008}; // u16 units
    float* part = ws + 1048576;
    float* scal = part + 192;
    float* winv = scal + 8;
    float* scb = ws + 1049600;
    float* sc_xq  = scb;
    float* sc_xkv = scb + 16384;
    float* sc_cq  = scb + 32768;
    float* sc_ckv = scb + 36864;
    float* sc_o1  = scb + 40960;
    float* sc_o2  = scb + 57344;
    unsigned short* act_xq  = (unsigned short*)(ws + 1115136);
    unsigned short* act_xkv = (unsigned short*)(ws + 5309440);
    unsigned short* act_cq  = (unsigned short*)(ws + 9503744);
    unsigned short* act_ckv = (unsigned short*)(ws + 10552320);
    float* arena = ws + 11600896;

    size_t need = (size_t)30868480 * sizeof(float);   // ~124 MB
    if (ws_size < need) return;

    k_wabs_all<<<192, 256, 0, stream>>>(Wq_x, Wkv_c, Wp_x, Wq_c, Wkv_x, Wp_c, part);
    k_wfinal<<<1, 64, 0, stream>>>(part, scal, winv);
    k_wquant_all<<<8192, 256, 0, stream>>>(Wq_x, Wkv_c, Wp_x, Wq_c, Wkv_x, Wp_c, Wb, scal);

    k_rmsq_dual<<<16384, 64, 0, stream>>>(x, g_qx, g_kvx, act_xq, act_xkv, sc_xq, sc_xkv);
    k_rmsq_dual<<<4096, 64, 0, stream>>>(c, g_qc, g_kvc, act_cq, act_ckv, sc_cq, sc_ckv);

    float* outx = (float*)d_out;
    float* outc = outx + (size_t)4 * 4096 * 512;

    // pass 1: x queries attend to c (S=1 key-split)
    run_pass(x, act_xq, sc_xq, act_ckv, sc_ckv,
             Wb + Woff[0], Wb + Woff[1], Wb + Woff[2],
             A_x, B_x, mag_x, g_px, winv + 0, winv + 1, winv + 2,
             16384, 4096, 4096, 1024, 12, 10, 1, arena, sc_o1, outx, x, stream);
    // pass 2: c queries attend to x (S=2 key-splits to fill the grid)
    run_pass(c, act_cq, sc_cq, act_xkv, sc_xkv,
             Wb + Woff[3], Wb + Woff[4], Wb + Woff[5],
             A_c, B_c, mag_c, g_pc, winv + 3, winv + 4, winv + 5,
             4096, 16384, 1024, 4096, 10, 12, 2, arena, sc_o2, outc, c, stream);
}

// Round 8
// 363.522 us; speedup vs baseline: 46.0836x; 1.2023x over previous
//
#include <hip/hip_runtime.h>
#include <math.h>

#define DD 512
#define NHEAD 8
#define HDIM 64

typedef __bf16 bf16x8 __attribute__((ext_vector_type(8)));
typedef unsigned short u16x8 __attribute__((ext_vector_type(8)));
typedef float f32x4 __attribute__((ext_vector_type(4)));

#if __has_builtin(__builtin_amdgcn_exp2f)
#define EXP2F(x) __builtin_amdgcn_exp2f(x)
#else
#define EXP2F(x) exp2f(x)
#endif

#define QSCALE 0.18033688f  /* (1/8) * log2(e): exp2 domain */

static __device__ __forceinline__ unsigned short f2bf(float f) {
    unsigned u = __builtin_bit_cast(unsigned, f);
    u += 0x7fffu + ((u >> 16) & 1u);   // round-to-nearest-even
    return (unsigned short)(u >> 16);
}
static __device__ __forceinline__ float bf2f(unsigned short u) {
    return __builtin_bit_cast(float, (unsigned)u << 16);
}

#define GLOAD16(g, l)                                                          \
    __builtin_amdgcn_global_load_lds(                                          \
        (__attribute__((address_space(1))) void*)(g),                          \
        (__attribute__((address_space(3))) void*)(l), 16, 0, 0)

// ---------------- weight ternary quant: consolidated prep ----------------
__global__ void k_wabs_all(const float* __restrict__ W0, const float* __restrict__ W1,
                           const float* __restrict__ W2, const float* __restrict__ W3,
                           const float* __restrict__ W4, const float* __restrict__ W5,
                           float* __restrict__ part) {
    const float* Ws[6] = {W0, W1, W2, W3, W4, W5};
    const int cnt[6] = {262144, 524288, 262144, 262144, 524288, 262144};
    int mid = blockIdx.x >> 5, lb = blockIdx.x & 31;
    const float* W = Ws[mid];
    int n = cnt[mid];
    int t = threadIdx.x;
    float s = 0.f;
    for (int i = lb * 256 + t; i < n; i += 32 * 256) s += fabsf(W[i]);
    __shared__ float red[4];
#pragma unroll
    for (int o = 32; o > 0; o >>= 1) s += __shfl_down(s, o);
    if ((t & 63) == 0) red[t >> 6] = s;
    __syncthreads();
    if (t == 0) part[blockIdx.x] = red[0] + red[1] + red[2] + red[3];
}

__global__ void k_wfinal(const float* __restrict__ part, float* __restrict__ scal,
                         float* __restrict__ winv) {
    int m = threadIdx.x;
    if (m < 6) {
        const int cnt[6] = {262144, 524288, 262144, 262144, 524288, 262144};
        float s = 0.f;
        for (int i = 0; i < 32; ++i) s += part[m * 32 + i];
        float mean = fmaxf(s / (float)cnt[m], 1e-5f);
        scal[m] = 1.f / mean;
        winv[m] = mean;
    }
}

__global__ void k_wquant_all(const float* __restrict__ W0, const float* __restrict__ W1,
                             const float* __restrict__ W2, const float* __restrict__ W3,
                             const float* __restrict__ W4, const float* __restrict__ W5,
                             unsigned short* __restrict__ Wq, const float* __restrict__ scal) {
    int e = blockIdx.x * 256 + threadIdx.x;
    const float* Ws[6] = {W0, W1, W2, W3, W4, W5};
    int mid, base;
    if (e < 262144)       { mid = 0; base = 0; }
    else if (e < 786432)  { mid = 1; base = 262144; }
    else if (e < 1048576) { mid = 2; base = 786432; }
    else if (e < 1310720) { mid = 3; base = 1048576; }
    else if (e < 1835008) { mid = 4; base = 1310720; }
    else                  { mid = 5; base = 1835008; }
    float sc = scal[mid];
    float t = rintf(Ws[mid][e - base] * sc);
    t = fminf(fmaxf(t, -1.f), 1.f);
    Wq[e] = f2bf(t);
}

// ---------------- RMSNorm + int8 quant (dual g) + fused DoRA X@A^T ----------------
// One read of X row: emits act_q, act_kv (bf16 integer) and tmp[row][16] = X.A^T.
// Multi-value butterfly: 17 shuffles reduce 16 dots across 64 lanes.
#define BSTEP(s, hc)                                                           \
    {                                                                          \
        _Pragma("unroll")                                                      \
        for (int i = 0; i < (hc); ++i) {                                       \
            float send = (lane & (s)) ? p[i] : p[i + (hc)];                    \
            float recv = __shfl_xor(send, (s));                                \
            p[i] = ((lane & (s)) ? p[i + (hc)] : p[i]) + recv;                 \
        }                                                                      \
    }

__global__ void k_rmsq_dual(const float* __restrict__ X,
                            const float* __restrict__ g1, const float* __restrict__ g2,
                            unsigned short* __restrict__ o1, unsigned short* __restrict__ o2,
                            float* __restrict__ s1, float* __restrict__ s2,
                            const float* __restrict__ Amat, float* __restrict__ tmp) {
    int row = blockIdx.x;
    int lane = threadIdx.x;
    const float* xr = X + (size_t)row * DD;
    float4 a = *(const float4*)(xr + lane * 8);
    float4 b = *(const float4*)(xr + lane * 8 + 4);
    // DoRA dots on raw X (in registers)
    float p[16];
#pragma unroll
    for (int cc = 0; cc < 16; ++cc) {
        const float4* ar = (const float4*)(Amat + (size_t)cc * DD + lane * 8);
        float4 aa = ar[0], ab = ar[1];
        p[cc] = a.x*aa.x + a.y*aa.y + a.z*aa.z + a.w*aa.w
              + b.x*ab.x + b.y*ab.y + b.z*ab.z + b.w*ab.w;
    }
    BSTEP(1, 8) BSTEP(2, 4) BSTEP(4, 2) BSTEP(8, 1)
    p[0] += __shfl_xor(p[0], 16);
    p[0] += __shfl_xor(p[0], 32);
    if (lane < 16) {
        int cidx = ((lane & 1) << 3) | ((lane & 2) << 1) | ((lane & 4) >> 1) | ((lane & 8) >> 3);
        tmp[(size_t)row * 16 + cidx] = p[0];
    }
    // RMS + dual quant
    float ss = a.x*a.x + a.y*a.y + a.z*a.z + a.w*a.w
             + b.x*b.x + b.y*b.y + b.z*b.z + b.w*b.w;
#pragma unroll
    for (int o = 32; o > 0; o >>= 1) ss += __shfl_xor(ss, o);
    float rn = 1.f / sqrtf(ss * (1.f / 512.f) + 1e-8f);
    const float* gs[2] = {g1, g2};
    unsigned short* os[2] = {o1, o2};
    float* scs[2] = {s1, s2};
#pragma unroll
    for (int pass = 0; pass < 2; ++pass) {
        float4 ga = *(const float4*)(gs[pass] + lane * 8);
        float4 gb = *(const float4*)(gs[pass] + lane * 8 + 4);
        float v[8] = {a.x*rn*ga.x, a.y*rn*ga.y, a.z*rn*ga.z, a.w*rn*ga.w,
                      b.x*rn*gb.x, b.y*rn*gb.y, b.z*rn*gb.z, b.w*rn*gb.w};
        float amax = 0.f;
#pragma unroll
        for (int i = 0; i < 8; ++i) amax = fmaxf(amax, fabsf(v[i]));
#pragma unroll
        for (int o = 32; o > 0; o >>= 1) amax = fmaxf(amax, __shfl_xor(amax, o));
        float mx = fmaxf(amax, 1e-5f);
        float scale = 127.f / mx;
        u16x8 qv;
#pragma unroll
        for (int i = 0; i < 8; ++i) {
            float tq = rintf(v[i] * scale);
            tq = fminf(fmaxf(tq, -128.f), 127.f);
            qv[i] = f2bf(tq);
        }
        *reinterpret_cast<u16x8*>(os[pass] + (size_t)row * DD + lane * 8) = qv;
        if (lane == 0) scs[pass][row] = mx / 127.f;
    }
}

// ---------------- combine attn partials + RMSNorm + quant ----------------
template <int S>
__global__ void k_rmsq_combine(const float* __restrict__ Opart, const float* __restrict__ Lpart,
                               const float* __restrict__ g, unsigned short* __restrict__ out,
                               float* __restrict__ a_inv, int lognq) {
    int row = blockIdx.x;              // b*Nq + q
    int lane = threadIdx.x;            // 64 threads x 8 elems
    int Nq = 1 << lognq;
    int b = row >> lognq, q = row & (Nq - 1);
    int h = lane >> 3;
    float l = 0.f;
    float u[8] = {};
#pragma unroll
    for (int s = 0; s < S; ++s) {
        l += Lpart[((size_t)(s * 4 + b) * 8 + h) * Nq + q];
        const float* orow = Opart + ((size_t)(s * 4 + b) * Nq + q) * 512 + lane * 8;
        float4 a = *(const float4*)orow;
        float4 bb = *(const float4*)(orow + 4);
        u[0] += a.x; u[1] += a.y; u[2] += a.z; u[3] += a.w;
        u[4] += bb.x; u[5] += bb.y; u[6] += bb.z; u[7] += bb.w;
    }
    float invl = 1.f / l;
#pragma unroll
    for (int i = 0; i < 8; ++i) u[i] *= invl;
    float ss = 0.f;
#pragma unroll
    for (int i = 0; i < 8; ++i) ss += u[i] * u[i];
#pragma unroll
    for (int o = 32; o > 0; o >>= 1) ss += __shfl_xor(ss, o);
    float rn = 1.f / sqrtf(ss * (1.f / 512.f) + 1e-8f);
    float4 ga = *(const float4*)(g + lane * 8);
    float4 gb = *(const float4*)(g + lane * 8 + 4);
    float v[8] = {u[0]*rn*ga.x, u[1]*rn*ga.y, u[2]*rn*ga.z, u[3]*rn*ga.w,
                  u[4]*rn*gb.x, u[5]*rn*gb.y, u[6]*rn*gb.z, u[7]*rn*gb.w};
    float amax = 0.f;
#pragma unroll
    for (int i = 0; i < 8; ++i) amax = fmaxf(amax, fabsf(v[i]));
#pragma unroll
    for (int o = 32; o > 0; o >>= 1) amax = fmaxf(amax, __shfl_xor(amax, o));
    float mx = fmaxf(amax, 1e-5f);
    float scale = 127.f / mx;
    u16x8 qv;
#pragma unroll
    for (int i = 0; i < 8; ++i) {
        float tq = rintf(v[i] * scale);
        tq = fminf(fmaxf(tq, -128.f), 127.f);
        qv[i] = f2bf(tq);
    }
    *reinterpret_cast<u16x8*>(out + (size_t)row * DD + lane * 8) = qv;
    if (lane == 0) a_inv[row] = mx / 127.f;
}

// ---------------- DoRA delta: qf = tmp @ B^T (bf16 out) ----------------
__global__ void k_lora2(const float* __restrict__ tmp, const float* __restrict__ Bmat,
                        unsigned short* __restrict__ qf) {
    int idx = blockIdx.x * 256 + threadIdx.x;
    int m2 = idx >> 9, n2 = idx & 511;
    const float4* tr = (const float4*)(tmp + (size_t)m2 * 16);
    const float4* br = (const float4*)(Bmat + (size_t)n2 * 16);
    float acc = 0.f;
#pragma unroll
    for (int rr = 0; rr < 4; ++rr) {
        float4 ta = tr[rr], ba = br[rr];
        acc += ta.x*ba.x + ta.y*ba.y + ta.z*ba.z + ta.w*ba.w;
    }
    qf[idx] = f2bf(acc);
}

// ---------------- bf16 MFMA GEMM: acc = Aq[M,512] @ Wq[N,512]^T, scaled epilogue ----------------
// MODE 2: OutF = acc*as + Extra(resid fp32)
// MODE 3: OutB(Qb bf16 [b][h][q][64]) = (acc*as + Extra[h]*Dlt) * QSCALE
// MODE 4: OutB = Kb bf16 [b][h][key][64]; OutB2 = Vt bf16 [b][h][d][key]
template <int MODE>
__global__ __launch_bounds__(256) void k_gemm_mfma(
    const unsigned short* __restrict__ Aq, const unsigned short* __restrict__ Wq,
    const float* __restrict__ a_inv, const float* __restrict__ winv_p,
    const float* __restrict__ Extra, const unsigned short* __restrict__ Dlt,
    float* __restrict__ OutF, unsigned short* __restrict__ OutB,
    unsigned short* __restrict__ OutB2,
    int logn, int M, int N) {
    __shared__ __align__(16) unsigned short sA[128 * 32];
    __shared__ __align__(16) unsigned short sB[128 * 32];
    int t = threadIdx.x;
    int w = t >> 6, lane = t & 63;
    int wm = w >> 1, wn = w & 1;
    int lr = lane & 15, lg = lane >> 4;
    int m0 = blockIdx.y * 128, n0 = blockIdx.x * 128;
    int row_st = t >> 2, chunk = t & 3;
    f32x4 acc[4][4] = {};

    for (int k0 = 0; k0 < 512; k0 += 32) {
        __syncthreads();
#pragma unroll
        for (int i = 0; i < 2; ++i) {
            int row = i * 64 + row_st;
            GLOAD16(Aq + (size_t)(m0 + row) * 512 + k0 + chunk * 8, sA + ((size_t)i * 256 + t) * 8);
            GLOAD16(Wq + (size_t)(n0 + row) * 512 + k0 + chunk * 8, sB + ((size_t)i * 256 + t) * 8);
        }
        asm volatile("s_waitcnt vmcnt(0)" ::: "memory");
        __syncthreads();
        bf16x8 af[4], bfr[4];
#pragma unroll
        for (int mt = 0; mt < 4; ++mt)
            af[mt] = *reinterpret_cast<const bf16x8*>(&sA[(wm * 64 + mt * 16 + lr) * 32 + lg * 8]);
#pragma unroll
        for (int nt = 0; nt < 4; ++nt)
            bfr[nt] = *reinterpret_cast<const bf16x8*>(&sB[(wn * 64 + nt * 16 + lr) * 32 + lg * 8]);
#pragma unroll
        for (int mt = 0; mt < 4; ++mt)
#pragma unroll
            for (int nt = 0; nt < 4; ++nt)
                acc[mt][nt] = __builtin_amdgcn_mfma_f32_16x16x32_bf16(af[mt], bfr[nt], acc[mt][nt], 0, 0, 0);
    }

    float wv = *winv_p;
    if (MODE == 4) {
        const bool isV = (n0 >= 512);
        const int Nc = 1 << logn;
#pragma unroll
        for (int mt = 0; mt < 4; ++mt) {
            int mb = m0 + wm * 64 + mt * 16 + lg * 4;
            int b = mb >> logn, key = mb & (Nc - 1);
            float as_[4];
#pragma unroll
            for (int r = 0; r < 4; ++r) as_[r] = a_inv[mb + r] * wv;
#pragma unroll
            for (int nt = 0; nt < 4; ++nt) {
                int n = n0 + wn * 64 + nt * 16 + lr;
                int n2 = isV ? (n - 512) : n;
                int h = n2 >> 6, dd = n2 & 63;
                if (isV) {
                    ushort4 v;
                    v.x = f2bf(acc[mt][nt][0] * as_[0]);
                    v.y = f2bf(acc[mt][nt][1] * as_[1]);
                    v.z = f2bf(acc[mt][nt][2] * as_[2]);
                    v.w = f2bf(acc[mt][nt][3] * as_[3]);
                    *reinterpret_cast<ushort4*>(
                        OutB2 + ((size_t)(b * NHEAD + h) * 64 + dd) * Nc + key) = v;
                } else {
#pragma unroll
                    for (int r = 0; r < 4; ++r)
                        OutB[((size_t)(b * NHEAD + h) * Nc + key + r) * 64 + dd] =
                            f2bf(acc[mt][nt][r] * as_[r]);
                }
            }
        }
    } else {
#pragma unroll
        for (int mt = 0; mt < 4; ++mt) {
#pragma unroll
            for (int r = 0; r < 4; ++r) {
                int m = m0 + wm * 64 + mt * 16 + lg * 4 + r;
                float as = a_inv[m] * wv;
                if (MODE == 3) {
                    int b = m >> logn, q = m & ((1 << logn) - 1);
#pragma unroll
                    for (int nt = 0; nt < 4; ++nt) {
                        int n = n0 + wn * 64 + nt * 16 + lr;
                        float dl = bf2f(Dlt[(size_t)m * 512 + n]);
                        float val = acc[mt][nt][r] * as + Extra[n >> 6] * dl;
                        int h = n >> 6, d = n & 63;
                        OutB[((((size_t)(b * NHEAD + h)) << logn) + q) * 64 + d] =
                            f2bf(val * QSCALE);
                    }
                } else {
#pragma unroll
                    for (int nt = 0; nt < 4; ++nt) {
                        int n = n0 + wn * 64 + nt * 16 + lr;
                        size_t idx = (size_t)m * N + n;
                        OutF[idx] = acc[mt][nt][r] * as + Extra[idx];
                    }
                }
            }
        }
    }
}

// ---------------- flash attention, bf16 MFMA, 32 queries/wave ----------------
// 512 threads = 8 waves, QBLK=256 (32 q/wave as 2x16 subtiles sharing K/V LDS reads).
// Plain softmax in exp2 domain -> partials over key-splits are exactly additive.
template <int S>
__global__ __launch_bounds__(512) void k_attn_mfma(
    const unsigned short* __restrict__ Qb, const unsigned short* __restrict__ Kb,
    const unsigned short* __restrict__ Vt, float* __restrict__ Opart,
    float* __restrict__ Lpart, int Nq, int Nc, int nqb_shift) {
    __shared__ unsigned short sK[64][72];
    __shared__ unsigned short sVt[64][72];
    __shared__ __bf16 sP[8][32][76];
    constexpr int LOGS = (S == 2) ? 1 : 0;
    int t = threadIdx.x;
    int w = t >> 6, lane = t & 63;
    int lr = lane & 15, lg = lane >> 4;

    int bid = blockIdx.x;
    int j = bid >> 3;
    int s = j & (S - 1);
    int j2 = j >> LOGS;
    int qblk = j2 & ((1 << nqb_shift) - 1);
    int bh = ((bid & 7) << 2) | (j2 >> nqb_shift);   // XCD-local bh groups
    int b = bh >> 3, h = bh & 7;
    int q0 = qblk * 256 + w * 32;

    bf16x8 aq[2][2];
#pragma unroll
    for (int qt = 0; qt < 2; ++qt) {
        const unsigned short* qbase = Qb + ((size_t)bh * Nq + q0 + qt * 16 + lr) * 64 + lg * 8;
        aq[qt][0] = *reinterpret_cast<const bf16x8*>(qbase);
        aq[qt][1] = *reinterpret_cast<const bf16x8*>(qbase + 32);
    }

    u16x8 ou;
#pragma unroll
    for (int jj = 0; jj < 8; ++jj) ou[jj] = (lr == 0) ? 0x3F80 : 0;
    bf16x8 onesf = __builtin_bit_cast(bf16x8, ou);

    f32x4 o[2][4] = {};
    f32x4 osum[2] = {};

    const unsigned short* kglob = Kb + (size_t)bh * Nc * 64;
    const unsigned short* vglob = Vt + (size_t)bh * 64 * (size_t)Nc;

    int srow = t >> 3, sseg = t & 7;
    const unsigned short* kptr = kglob + (size_t)srow * 64 + sseg * 8;
    const unsigned short* vptr = vglob + (size_t)srow * Nc + sseg * 8;

    int kts = s * (Nc >> LOGS);
    int kte = kts + (Nc >> LOGS);

    bf16x8 rK = *reinterpret_cast<const bf16x8*>(kptr + (size_t)kts * 64);
    bf16x8 rV = *reinterpret_cast<const bf16x8*>(vptr + kts);

    for (int kt0 = kts; kt0 < kte; kt0 += 64) {
        __syncthreads();
        *reinterpret_cast<bf16x8*>(&sK[srow][sseg * 8]) = rK;
        *reinterpret_cast<bf16x8*>(&sVt[srow][sseg * 8]) = rV;
        __syncthreads();
        if (kt0 + 64 < kte) {
            rK = *reinterpret_cast<const bf16x8*>(kptr + (size_t)(kt0 + 64) * 64);
            rV = *reinterpret_cast<const bf16x8*>(vptr + kt0 + 64);
        }
#pragma unroll
        for (int kt = 0; kt < 4; ++kt) {
            bf16x8 bk0 = *reinterpret_cast<const bf16x8*>(&sK[kt * 16 + lr][lg * 8]);
            bf16x8 bk1 = *reinterpret_cast<const bf16x8*>(&sK[kt * 16 + lr][32 + lg * 8]);
            f32x4 a0 = {}, a1 = {};
            __builtin_amdgcn_s_setprio(1);
            a0 = __builtin_amdgcn_mfma_f32_16x16x32_bf16(aq[0][0], bk0, a0, 0, 0, 0);
            a1 = __builtin_amdgcn_mfma_f32_16x16x32_bf16(aq[1][0], bk0, a1, 0, 0, 0);
            a0 = __builtin_amdgcn_mfma_f32_16x16x32_bf16(aq[0][1], bk1, a0, 0, 0, 0);
            a1 = __builtin_amdgcn_mfma_f32_16x16x32_bf16(aq[1][1], bk1, a1, 0, 0, 0);
            __builtin_amdgcn_s_setprio(0);
#pragma unroll
            for (int r = 0; r < 4; ++r) {
                sP[w][lg * 4 + r][kt * 16 + lr] = (__bf16)EXP2F(fminf(a0[r], 43.f));
                sP[w][16 + lg * 4 + r][kt * 16 + lr] = (__bf16)EXP2F(fminf(a1[r], 43.f));
            }
        }
#pragma unroll
        for (int kg = 0; kg < 2; ++kg) {
            bf16x8 pa0 = *reinterpret_cast<const bf16x8*>(&sP[w][lr][kg * 32 + lg * 8]);
            bf16x8 pa1 = *reinterpret_cast<const bf16x8*>(&sP[w][16 + lr][kg * 32 + lg * 8]);
            __builtin_amdgcn_s_setprio(1);
#pragma unroll
            for (int dt = 0; dt < 4; ++dt) {
                bf16x8 vb = *reinterpret_cast<const bf16x8*>(&sVt[dt * 16 + lr][kg * 32 + lg * 8]);
                o[0][dt] = __builtin_amdgcn_mfma_f32_16x16x32_bf16(pa0, vb, o[0][dt], 0, 0, 0);
                o[1][dt] = __builtin_amdgcn_mfma_f32_16x16x32_bf16(pa1, vb, o[1][dt], 0, 0, 0);
            }
            osum[0] = __builtin_amdgcn_mfma_f32_16x16x32_bf16(pa0, onesf, osum[0], 0, 0, 0);
            osum[1] = __builtin_amdgcn_mfma_f32_16x16x32_bf16(pa1, onesf, osum[1], 0, 0, 0);
            __builtin_amdgcn_s_setprio(0);
        }
    }
    float* obase = Opart + ((size_t)(s * 4 + b) * Nq + q0) * 512 + h * 64;
#pragma unroll
    for (int qt = 0; qt < 2; ++qt)
#pragma unroll
        for (int dt = 0; dt < 4; ++dt)
#pragma unroll
            for (int r = 0; r < 4; ++r)
                obase[(size_t)(qt * 16 + lg * 4 + r) * 512 + dt * 16 + lr] = o[qt][dt][r];
    if (lr == 0) {
        float* lbase = Lpart + ((size_t)(s * 4 + b) * 8 + h) * Nq + q0;
#pragma unroll
        for (int qt = 0; qt < 2; ++qt)
#pragma unroll
            for (int r = 0; r < 4; ++r)
                lbase[qt * 16 + lg * 4 + r] = osum[qt][r];
    }
}

// ---------------- host side ----------------
static void run_pass(const float* tmp,
                     const unsigned short* act_q, const float* sc_q,
                     const unsigned short* act_kv, const float* sc_kv,
                     const unsigned short* Wq_t, const unsigned short* Wkv_t,
                     const unsigned short* Wp_t,
                     const float* Bmat, const float* mag, const float* gp,
                     const float* winv_q, const float* winv_kv, const float* winv_p,
                     int Mq, int Mc, int Nq, int Nc, int lognq, int lognc, int S,
                     float* arena, float* sc_o, float* outp, const float* resid,
                     hipStream_t stream) {
    float* qf_f  = arena;
    float* Qb_f  = qf_f + (size_t)Mq * 256;
    float* Kb_f  = Qb_f + (size_t)Mq * 256;
    float* Vt_f  = Kb_f + (size_t)Mc * 256;
    float* Opart = Vt_f + (size_t)Mc * 256;
    float* Lpart = Opart + (size_t)8388608;

    unsigned short* qf = (unsigned short*)qf_f;
    unsigned short* Qb = (unsigned short*)Qb_f;
    unsigned short* Kb = (unsigned short*)Kb_f;
    unsigned short* Vt = (unsigned short*)Vt_f;

    k_lora2<<<(Mq * 512) / 256, 256, 0, stream>>>(tmp, Bmat, qf);
    k_gemm_mfma<3><<<dim3(4, Mq / 128), 256, 0, stream>>>(
        act_q, Wq_t, sc_q, winv_q, mag, qf, nullptr, Qb, nullptr, lognq, Mq, 512);
    k_gemm_mfma<4><<<dim3(8, Mc / 128), 256, 0, stream>>>(
        act_kv, Wkv_t, sc_kv, winv_kv, nullptr, nullptr, nullptr, Kb, Vt, lognc, Mc, 1024);

    int nqb = Nq / 256;
    int nqs = __builtin_ctz(nqb);
    if (S == 1)
        k_attn_mfma<1><<<dim3(32 * nqb), 512, 0, stream>>>(Qb, Kb, Vt, Opart, Lpart, Nq, Nc, nqs);
    else
        k_attn_mfma<2><<<dim3(32 * nqb * 2), 512, 0, stream>>>(Qb, Kb, Vt, Opart, Lpart, Nq, Nc, nqs);

    unsigned short* act_o = qf;  // delta region dead after MODE3
    if (S == 1)
        k_rmsq_combine<1><<<Mq, 64, 0, stream>>>(Opart, Lpart, gp, act_o, sc_o, lognq);
    else
        k_rmsq_combine<2><<<Mq, 64, 0, stream>>>(Opart, Lpart, gp, act_o, sc_o, lognq);
    k_gemm_mfma<2><<<dim3(4, Mq / 128), 256, 0, stream>>>(
        act_o, Wp_t, sc_o, winv_p, resid, nullptr, outp, nullptr, nullptr, 0, Mq, 512);
}

extern "C" void kernel_launch(void* const* d_in, const int* in_sizes, int n_in,
                              void* d_out, int out_size, void* d_ws, size_t ws_size,
                              hipStream_t stream) {
    const float* x     = (const float*)d_in[0];
    const float* c     = (const float*)d_in[1];
    const float* Wq_x  = (const float*)d_in[2];
    const float* g_qx  = (const float*)d_in[3];
    const float* Wkv_c = (const float*)d_in[4];
    const float* g_kvc = (const float*)d_in[5];
    const float* A_x   = (const float*)d_in[6];
    const float* B_x   = (const float*)d_in[7];
    const float* mag_x = (const float*)d_in[8];
    const float* Wp_x  = (const float*)d_in[9];
    const float* g_px  = (const float*)d_in[10];
    const float* Wq_c  = (const float*)d_in[11];
    const float* g_qc  = (const float*)d_in[12];
    const float* Wkv_x = (const float*)d_in[13];
    const float* g_kvx = (const float*)d_in[14];
    const float* A_c   = (const float*)d_in[15];
    const float* B_c   = (const float*)d_in[16];
    const float* mag_c = (const float*)d_in[17];
    const float* Wp_c  = (const float*)d_in[18];
    const float* g_pc  = (const float*)d_in[19];

    float* ws = (float*)d_ws;
    unsigned short* Wb = (unsigned short*)ws;
    const size_t Woff[6] = {0, 262144, 786432, 1048576, 1310720, 1835008}; // u16 units
    float* part = ws + 1048576;
    float* scal = part + 192;
    float* winv = scal + 8;
    float* scb = ws + 1049600;
    float* sc_xq  = scb;
    float* sc_xkv = scb + 16384;
    float* sc_cq  = scb + 32768;
    float* sc_ckv = scb + 36864;
    float* sc_o1  = scb + 40960;
    float* sc_o2  = scb + 57344;
    unsigned short* act_xq  = (unsigned short*)(ws + 1115136);
    unsigned short* act_xkv = (unsigned short*)(ws + 5309440);
    unsigned short* act_cq  = (unsigned short*)(ws + 9503744);
    unsigned short* act_ckv = (unsigned short*)(ws + 10552320);
    float* tmp_x = ws + 11600896;   // 16384*16
    float* tmp_c = ws + 11863040;   // 4096*16
    float* arena = ws + 11928576;

    size_t need = (size_t)30934016 * sizeof(float);   // ~124 MB
    if (ws_size < need) return;

    k_wabs_all<<<192, 256, 0, stream>>>(Wq_x, Wkv_c, Wp_x, Wq_c, Wkv_x, Wp_c, part);
    k_wfinal<<<1, 64, 0, stream>>>(part, scal, winv);
    k_wquant_all<<<8192, 256, 0, stream>>>(Wq_x, Wkv_c, Wp_x, Wq_c, Wkv_x, Wp_c, Wb, scal);

    // one read of x / c each: both activation sets + DoRA tmp
    k_rmsq_dual<<<16384, 64, 0, stream>>>(x, g_qx, g_kvx, act_xq, act_xkv, sc_xq, sc_xkv,
                                          A_x, tmp_x);
    k_rmsq_dual<<<4096, 64, 0, stream>>>(c, g_qc, g_kvc, act_cq, act_ckv, sc_cq, sc_ckv,
                                         A_c, tmp_c);

    float* outx = (float*)d_out;
    float* outc = outx + (size_t)4 * 4096 * 512;

    // pass 1: x queries attend to c (S=1 key-split)
    run_pass(tmp_x, act_xq, sc_xq, act_ckv, sc_ckv,
             Wb + Woff[0], Wb + Woff[1], Wb + Woff[2],
             B_x, mag_x, g_px, winv + 0, winv + 1, winv + 2,
             16384, 4096, 4096, 1024, 12, 10, 1, arena, sc_o1, outx, x, stream);
    // pass 2: c queries attend to x (S=2 key-splits to fill the grid)
    run_pass(tmp_c, act_cq, sc_cq, act_xkv, sc_xkv,
             Wb + Woff[3], Wb + Woff[4], Wb + Woff[5],
             B_c, mag_c, g_pc, winv + 3, winv + 4, winv + 5,
             4096, 16384, 1024, 4096, 10, 12, 2, arena, sc_o2, outc, c, stream);
}

// Round 9
// 353.074 us; speedup vs baseline: 47.4474x; 1.0296x over previous
//
#include <hip/hip_runtime.h>
#include <math.h>

#define DD 512
#define NHEAD 8
#define HDIM 64

typedef __bf16 bf16x8 __attribute__((ext_vector_type(8)));
typedef unsigned short u16x8 __attribute__((ext_vector_type(8)));
typedef float f32x4 __attribute__((ext_vector_type(4)));

#if __has_builtin(__builtin_amdgcn_exp2f)
#define EXP2F(x) __builtin_amdgcn_exp2f(x)
#else
#define EXP2F(x) exp2f(x)
#endif

#define QSCALE 0.18033688f  /* (1/8) * log2(e): exp2 domain */

static __device__ __forceinline__ unsigned short f2bf(float f) {
    unsigned u = __builtin_bit_cast(unsigned, f);
    u += 0x7fffu + ((u >> 16) & 1u);   // round-to-nearest-even
    return (unsigned short)(u >> 16);
}
static __device__ __forceinline__ float bf2f(unsigned short u) {
    return __builtin_bit_cast(float, (unsigned)u << 16);
}

#define GLOAD16(g, l)                                                          \
    __builtin_amdgcn_global_load_lds(                                          \
        (__attribute__((address_space(1))) void*)(g),                          \
        (__attribute__((address_space(3))) void*)(l), 16, 0, 0)

// ---------------- weight ternary quant: consolidated prep ----------------
__global__ void k_wabs_all(const float* __restrict__ W0, const float* __restrict__ W1,
                           const float* __restrict__ W2, const float* __restrict__ W3,
                           const float* __restrict__ W4, const float* __restrict__ W5,
                           float* __restrict__ part) {
    const float* Ws[6] = {W0, W1, W2, W3, W4, W5};
    const int cnt[6] = {262144, 524288, 262144, 262144, 524288, 262144};
    int mid = blockIdx.x >> 5, lb = blockIdx.x & 31;
    const float* W = Ws[mid];
    int n = cnt[mid];
    int t = threadIdx.x;
    float s = 0.f;
    for (int i = lb * 256 + t; i < n; i += 32 * 256) s += fabsf(W[i]);
    __shared__ float red[4];
#pragma unroll
    for (int o = 32; o > 0; o >>= 1) s += __shfl_down(s, o);
    if ((t & 63) == 0) red[t >> 6] = s;
    __syncthreads();
    if (t == 0) part[blockIdx.x] = red[0] + red[1] + red[2] + red[3];
}

__global__ void k_wfinal(const float* __restrict__ part, float* __restrict__ scal,
                         float* __restrict__ winv) {
    int m = threadIdx.x;
    if (m < 6) {
        const int cnt[6] = {262144, 524288, 262144, 262144, 524288, 262144};
        float s = 0.f;
        for (int i = 0; i < 32; ++i) s += part[m * 32 + i];
        float mean = fmaxf(s / (float)cnt[m], 1e-5f);
        scal[m] = 1.f / mean;
        winv[m] = mean;
    }
}

__global__ void k_wquant_all(const float* __restrict__ W0, const float* __restrict__ W1,
                             const float* __restrict__ W2, const float* __restrict__ W3,
                             const float* __restrict__ W4, const float* __restrict__ W5,
                             unsigned short* __restrict__ Wq, const float* __restrict__ scal) {
    int e = blockIdx.x * 256 + threadIdx.x;
    const float* Ws[6] = {W0, W1, W2, W3, W4, W5};
    int mid, base;
    if (e < 262144)       { mid = 0; base = 0; }
    else if (e < 786432)  { mid = 1; base = 262144; }
    else if (e < 1048576) { mid = 2; base = 786432; }
    else if (e < 1310720) { mid = 3; base = 1048576; }
    else if (e < 1835008) { mid = 4; base = 1310720; }
    else                  { mid = 5; base = 1835008; }
    float sc = scal[mid];
    float t = rintf(Ws[mid][e - base] * sc);
    t = fminf(fmaxf(t, -1.f), 1.f);
    Wq[e] = f2bf(t);
}

// ---------------- RMSNorm + int8 quant (dual g) + fused DoRA X@A^T, both passes ----------------
#define BSTEP(s, hc)                                                           \
    {                                                                          \
        _Pragma("unroll")                                                      \
        for (int i = 0; i < (hc); ++i) {                                       \
            float send = (lane & (s)) ? p[i] : p[i + (hc)];                    \
            float recv = __shfl_xor(send, (s));                                \
            p[i] = ((lane & (s)) ? p[i + (hc)] : p[i]) + recv;                 \
        }                                                                      \
    }

__global__ void k_rmsq_dual(const float* __restrict__ x, const float* __restrict__ c,
                            const float* __restrict__ g_qx, const float* __restrict__ g_kvx,
                            const float* __restrict__ g_qc, const float* __restrict__ g_kvc,
                            unsigned short* __restrict__ a_xq, unsigned short* __restrict__ a_xkv,
                            unsigned short* __restrict__ a_cq, unsigned short* __restrict__ a_ckv,
                            float* __restrict__ s_xq, float* __restrict__ s_xkv,
                            float* __restrict__ s_cq, float* __restrict__ s_ckv,
                            const float* __restrict__ A_x, const float* __restrict__ A_c,
                            float* __restrict__ tmp_x, float* __restrict__ tmp_c) {
    int row = blockIdx.x;
    int lane = threadIdx.x;
    bool pc = (row >= 16384);
    int r = pc ? row - 16384 : row;
    const float* xr = (pc ? c : x) + (size_t)r * DD;
    const float* G1 = pc ? g_qc : g_qx;
    const float* G2 = pc ? g_kvc : g_kvx;
    unsigned short* O1 = pc ? a_cq : a_xq;
    unsigned short* O2 = pc ? a_ckv : a_xkv;
    float* S1 = pc ? s_cq : s_xq;
    float* S2 = pc ? s_ckv : s_xkv;
    const float* AM = pc ? A_c : A_x;
    float* TMP = pc ? tmp_c : tmp_x;

    float4 a = *(const float4*)(xr + lane * 8);
    float4 b = *(const float4*)(xr + lane * 8 + 4);
    // DoRA dots on raw input (in registers)
    float p[16];
#pragma unroll
    for (int cc = 0; cc < 16; ++cc) {
        const float4* ar = (const float4*)(AM + (size_t)cc * DD + lane * 8);
        float4 aa = ar[0], ab = ar[1];
        p[cc] = a.x*aa.x + a.y*aa.y + a.z*aa.z + a.w*aa.w
              + b.x*ab.x + b.y*ab.y + b.z*ab.z + b.w*ab.w;
    }
    BSTEP(1, 8) BSTEP(2, 4) BSTEP(4, 2) BSTEP(8, 1)
    p[0] += __shfl_xor(p[0], 16);
    p[0] += __shfl_xor(p[0], 32);
    if (lane < 16) {
        int cidx = ((lane & 1) << 3) | ((lane & 2) << 1) | ((lane & 4) >> 1) | ((lane & 8) >> 3);
        TMP[(size_t)r * 16 + cidx] = p[0];
    }
    float ss = a.x*a.x + a.y*a.y + a.z*a.z + a.w*a.w
             + b.x*b.x + b.y*b.y + b.z*b.z + b.w*b.w;
#pragma unroll
    for (int o = 32; o > 0; o >>= 1) ss += __shfl_xor(ss, o);
    float rn = 1.f / sqrtf(ss * (1.f / 512.f) + 1e-8f);
    const float* gs[2] = {G1, G2};
    unsigned short* os[2] = {O1, O2};
    float* scs[2] = {S1, S2};
#pragma unroll
    for (int pass = 0; pass < 2; ++pass) {
        float4 ga = *(const float4*)(gs[pass] + lane * 8);
        float4 gb = *(const float4*)(gs[pass] + lane * 8 + 4);
        float v[8] = {a.x*rn*ga.x, a.y*rn*ga.y, a.z*rn*ga.z, a.w*rn*ga.w,
                      b.x*rn*gb.x, b.y*rn*gb.y, b.z*rn*gb.z, b.w*rn*gb.w};
        float amax = 0.f;
#pragma unroll
        for (int i = 0; i < 8; ++i) amax = fmaxf(amax, fabsf(v[i]));
#pragma unroll
        for (int o = 32; o > 0; o >>= 1) amax = fmaxf(amax, __shfl_xor(amax, o));
        float mx = fmaxf(amax, 1e-5f);
        float scale = 127.f / mx;
        u16x8 qv;
#pragma unroll
        for (int i = 0; i < 8; ++i) {
            float tq = rintf(v[i] * scale);
            tq = fminf(fmaxf(tq, -128.f), 127.f);
            qv[i] = f2bf(tq);
        }
        *reinterpret_cast<u16x8*>(os[pass] + (size_t)r * DD + lane * 8) = qv;
        if (lane == 0) scs[pass][r] = mx / 127.f;
    }
}

// ---------------- DoRA delta: qf = tmp @ B^T (bf16 out), both passes ----------------
__global__ void k_lora2(const float* __restrict__ tmp_x, const float* __restrict__ tmp_c,
                        const float* __restrict__ B_x, const float* __restrict__ B_c,
                        unsigned short* __restrict__ qf1, unsigned short* __restrict__ qf2) {
    int idx = blockIdx.x * 256 + threadIdx.x;   // over 20480*512
    int m2 = idx >> 9, n2 = idx & 511;
    const float* tr;
    const float* br;
    unsigned short* out;
    if (m2 < 16384) {
        tr = tmp_x + (size_t)m2 * 16; br = B_x + (size_t)n2 * 16; out = qf1 + idx;
    } else {
        tr = tmp_c + (size_t)(m2 - 16384) * 16; br = B_c + (size_t)n2 * 16;
        out = qf2 + (idx - 8388608);
    }
    const float4* t4 = (const float4*)tr;
    const float4* b4 = (const float4*)br;
    float acc = 0.f;
#pragma unroll
    for (int rr = 0; rr < 4; ++rr) {
        float4 ta = t4[rr], ba = b4[rr];
        acc += ta.x*ba.x + ta.y*ba.y + ta.z*ba.z + ta.w*ba.w;
    }
    *out = f2bf(acc);
}

// ---------------- combine attn partials + RMSNorm + quant, both passes ----------------
__global__ void k_rmsq_combine(const float* __restrict__ Op_a, const float* __restrict__ Lp_a,
                               const float* __restrict__ g_a, unsigned short* __restrict__ out_a,
                               float* __restrict__ sc_a,
                               const float* __restrict__ Op_b, const float* __restrict__ Lp_b,
                               const float* __restrict__ g_b, unsigned short* __restrict__ out_b,
                               float* __restrict__ sc_b) {
    int row = blockIdx.x;
    int lane = threadIdx.x;
    bool pb = (row >= 16384);
    int r = pb ? row - 16384 : row;
    int S = pb ? 2 : 1;
    int lognq = pb ? 10 : 12;
    const float* Op = pb ? Op_b : Op_a;
    const float* Lp = pb ? Lp_b : Lp_a;
    const float* g  = pb ? g_b : g_a;
    unsigned short* out = pb ? out_b : out_a;
    float* a_inv = pb ? sc_b : sc_a;

    int Nq = 1 << lognq;
    int b = r >> lognq, q = r & (Nq - 1);
    int h = lane >> 3;
    float l = 0.f;
    float u[8] = {};
    for (int s = 0; s < S; ++s) {
        l += Lp[((size_t)(s * 4 + b) * 8 + h) * Nq + q];
        const float* orow = Op + ((size_t)(s * 4 + b) * Nq + q) * 512 + lane * 8;
        float4 a = *(const float4*)orow;
        float4 bb = *(const float4*)(orow + 4);
        u[0] += a.x; u[1] += a.y; u[2] += a.z; u[3] += a.w;
        u[4] += bb.x; u[5] += bb.y; u[6] += bb.z; u[7] += bb.w;
    }
    float invl = 1.f / l;
#pragma unroll
    for (int i = 0; i < 8; ++i) u[i] *= invl;
    float ss = 0.f;
#pragma unroll
    for (int i = 0; i < 8; ++i) ss += u[i] * u[i];
#pragma unroll
    for (int o = 32; o > 0; o >>= 1) ss += __shfl_xor(ss, o);
    float rn = 1.f / sqrtf(ss * (1.f / 512.f) + 1e-8f);
    float4 ga = *(const float4*)(g + lane * 8);
    float4 gb = *(const float4*)(g + lane * 8 + 4);
    float v[8] = {u[0]*rn*ga.x, u[1]*rn*ga.y, u[2]*rn*ga.z, u[3]*rn*ga.w,
                  u[4]*rn*gb.x, u[5]*rn*gb.y, u[6]*rn*gb.z, u[7]*rn*gb.w};
    float amax = 0.f;
#pragma unroll
    for (int i = 0; i < 8; ++i) amax = fmaxf(amax, fabsf(v[i]));
#pragma unroll
    for (int o = 32; o > 0; o >>= 1) amax = fmaxf(amax, __shfl_xor(amax, o));
    float mx = fmaxf(amax, 1e-5f);
    float scale = 127.f / mx;
    u16x8 qv;
#pragma unroll
    for (int i = 0; i < 8; ++i) {
        float tq = rintf(v[i] * scale);
        tq = fminf(fmaxf(tq, -128.f), 127.f);
        qv[i] = f2bf(tq);
    }
    *reinterpret_cast<u16x8*>(out + (size_t)r * DD + lane * 8) = qv;
    if (lane == 0) a_inv[r] = mx / 127.f;
}

// ---------------- bf16 MFMA GEMM, both passes in one launch (split at Y0) ----------------
// MODE 2: OutF = acc*as + Ex(resid fp32).  MODE 3: Qb bf16 = (acc*as + Ex[h]*Dlt)*QSCALE.
// MODE 4: Kb bf16 [b][h][key][64] + Vt bf16 [b][h][d][key].
template <int MODE>
__global__ __launch_bounds__(256) void k_gemm_mfma(
    const unsigned short* __restrict__ Aq_a, const unsigned short* __restrict__ Aq_b,
    const unsigned short* __restrict__ Wq_a, const unsigned short* __restrict__ Wq_b,
    const float* __restrict__ ai_a, const float* __restrict__ ai_b,
    const float* __restrict__ winv, int wi_a, int wi_b,
    const float* __restrict__ Ex_a, const float* __restrict__ Ex_b,
    const unsigned short* __restrict__ Dl_a, const unsigned short* __restrict__ Dl_b,
    float* __restrict__ OF_a, float* __restrict__ OF_b,
    unsigned short* __restrict__ OB_a, unsigned short* __restrict__ OB_b,
    unsigned short* __restrict__ OB2_a, unsigned short* __restrict__ OB2_b,
    int logn_a, int logn_b, int Y0, int N) {
    __shared__ __align__(16) unsigned short sA[128 * 32];
    __shared__ __align__(16) unsigned short sB[128 * 32];
    bool pb = ((int)blockIdx.y >= Y0);
    const unsigned short* Aq = pb ? Aq_b : Aq_a;
    const unsigned short* Wq = pb ? Wq_b : Wq_a;
    const float* a_inv = pb ? ai_b : ai_a;
    const float* Extra = pb ? Ex_b : Ex_a;
    const unsigned short* Dlt = pb ? Dl_b : Dl_a;
    float* OutF = pb ? OF_b : OF_a;
    unsigned short* OutB = pb ? OB_b : OB_a;
    unsigned short* OutB2 = pb ? OB2_b : OB2_a;
    int logn = pb ? logn_b : logn_a;
    float wv = winv[pb ? wi_b : wi_a];
    int m0 = (pb ? ((int)blockIdx.y - Y0) : (int)blockIdx.y) * 128;

    int t = threadIdx.x;
    int w = t >> 6, lane = t & 63;
    int wm = w >> 1, wn = w & 1;
    int lr = lane & 15, lg = lane >> 4;
    int n0 = blockIdx.x * 128;
    int row_st = t >> 2, chunk = t & 3;
    f32x4 acc[4][4] = {};

    for (int k0 = 0; k0 < 512; k0 += 32) {
        __syncthreads();
#pragma unroll
        for (int i = 0; i < 2; ++i) {
            int row = i * 64 + row_st;
            GLOAD16(Aq + (size_t)(m0 + row) * 512 + k0 + chunk * 8, sA + ((size_t)i * 256 + t) * 8);
            GLOAD16(Wq + (size_t)(n0 + row) * 512 + k0 + chunk * 8, sB + ((size_t)i * 256 + t) * 8);
        }
        asm volatile("s_waitcnt vmcnt(0)" ::: "memory");
        __syncthreads();
        bf16x8 af[4], bfr[4];
#pragma unroll
        for (int mt = 0; mt < 4; ++mt)
            af[mt] = *reinterpret_cast<const bf16x8*>(&sA[(wm * 64 + mt * 16 + lr) * 32 + lg * 8]);
#pragma unroll
        for (int nt = 0; nt < 4; ++nt)
            bfr[nt] = *reinterpret_cast<const bf16x8*>(&sB[(wn * 64 + nt * 16 + lr) * 32 + lg * 8]);
#pragma unroll
        for (int mt = 0; mt < 4; ++mt)
#pragma unroll
            for (int nt = 0; nt < 4; ++nt)
                acc[mt][nt] = __builtin_amdgcn_mfma_f32_16x16x32_bf16(af[mt], bfr[nt], acc[mt][nt], 0, 0, 0);
    }

    if (MODE == 4) {
        const bool isV = (n0 >= 512);
        const int Nc = 1 << logn;
#pragma unroll
        for (int mt = 0; mt < 4; ++mt) {
            int mb = m0 + wm * 64 + mt * 16 + lg * 4;
            int b = mb >> logn, key = mb & (Nc - 1);
            float as_[4];
#pragma unroll
            for (int r = 0; r < 4; ++r) as_[r] = a_inv[mb + r] * wv;
#pragma unroll
            for (int nt = 0; nt < 4; ++nt) {
                int n = n0 + wn * 64 + nt * 16 + lr;
                int n2 = isV ? (n - 512) : n;
                int h = n2 >> 6, dd = n2 & 63;
                if (isV) {
                    ushort4 v;
                    v.x = f2bf(acc[mt][nt][0] * as_[0]);
                    v.y = f2bf(acc[mt][nt][1] * as_[1]);
                    v.z = f2bf(acc[mt][nt][2] * as_[2]);
                    v.w = f2bf(acc[mt][nt][3] * as_[3]);
                    *reinterpret_cast<ushort4*>(
                        OutB2 + ((size_t)(b * NHEAD + h) * 64 + dd) * Nc + key) = v;
                } else {
#pragma unroll
                    for (int r = 0; r < 4; ++r)
                        OutB[((size_t)(b * NHEAD + h) * Nc + key + r) * 64 + dd] =
                            f2bf(acc[mt][nt][r] * as_[r]);
                }
            }
        }
    } else {
#pragma unroll
        for (int mt = 0; mt < 4; ++mt) {
#pragma unroll
            for (int r = 0; r < 4; ++r) {
                int m = m0 + wm * 64 + mt * 16 + lg * 4 + r;
                float as = a_inv[m] * wv;
                if (MODE == 3) {
                    int b = m >> logn, q = m & ((1 << logn) - 1);
#pragma unroll
                    for (int nt = 0; nt < 4; ++nt) {
                        int n = n0 + wn * 64 + nt * 16 + lr;
                        float dl = bf2f(Dlt[(size_t)m * 512 + n]);
                        float val = acc[mt][nt][r] * as + Extra[n >> 6] * dl;
                        int h = n >> 6, d = n & 63;
                        OutB[((((size_t)(b * NHEAD + h)) << logn) + q) * 64 + d] =
                            f2bf(val * QSCALE);
                    }
                } else {
#pragma unroll
                    for (int nt = 0; nt < 4; ++nt) {
                        int n = n0 + wn * 64 + nt * 16 + lr;
                        size_t idx = (size_t)m * N + n;
                        OutF[idx] = acc[mt][nt][r] * as + Extra[idx];
                    }
                }
            }
        }
    }
}

// ---------------- flash attention, both passes in one launch ----------------
// 768 blocks: bid<256 = pass2 (Nq=1024, Nc=4096, S=2 key-splits; 32 tiles) dispatched
// FIRST (heavy blocks start early, light pass-1 blocks backfill). bid>=256 = pass1
// (Nq=4096, Nc=1024, S=1; 16 tiles). 512 threads = 8 waves, 32 q/wave.
__global__ __launch_bounds__(512) void k_attn_mfma(
    const unsigned short* __restrict__ Qb_a, const unsigned short* __restrict__ Kb_a,
    const unsigned short* __restrict__ Vt_a, float* __restrict__ Op_a, float* __restrict__ Lp_a,
    const unsigned short* __restrict__ Qb_b, const unsigned short* __restrict__ Kb_b,
    const unsigned short* __restrict__ Vt_b, float* __restrict__ Op_b, float* __restrict__ Lp_b) {
    __shared__ unsigned short sK[64][72];
    __shared__ unsigned short sVt[64][72];
    __shared__ __bf16 sP[8][32][76];
    int t = threadIdx.x;
    int w = t >> 6, lane = t & 63;
    int lr = lane & 15, lg = lane >> 4;

    int bid = blockIdx.x;
    bool pb = (bid < 256);
    int lb = pb ? bid : bid - 256;
    const unsigned short* Qb = pb ? Qb_b : Qb_a;
    const unsigned short* Kb = pb ? Kb_b : Kb_a;
    const unsigned short* Vt = pb ? Vt_b : Vt_a;
    float* Opart = pb ? Op_b : Op_a;
    float* Lpart = pb ? Lp_b : Lp_a;
    int Nq = pb ? 1024 : 4096;
    int Nc = pb ? 4096 : 1024;
    int S = pb ? 2 : 1;
    int LOGS = pb ? 1 : 0;
    int nqs = pb ? 2 : 4;

    int j = lb >> 3;
    int s = j & (S - 1);
    int j2 = j >> LOGS;
    int qblk = j2 & ((1 << nqs) - 1);
    int bh = ((lb & 7) << 2) | (j2 >> nqs);   // XCD-local bh groups
    int b = bh >> 3, h = bh & 7;
    int q0 = qblk * 256 + w * 32;

    bf16x8 aq[2][2];
#pragma unroll
    for (int qt = 0; qt < 2; ++qt) {
        const unsigned short* qbase = Qb + ((size_t)bh * Nq + q0 + qt * 16 + lr) * 64 + lg * 8;
        aq[qt][0] = *reinterpret_cast<const bf16x8*>(qbase);
        aq[qt][1] = *reinterpret_cast<const bf16x8*>(qbase + 32);
    }

    u16x8 ou;
#pragma unroll
    for (int jj = 0; jj < 8; ++jj) ou[jj] = (lr == 0) ? 0x3F80 : 0;
    bf16x8 onesf = __builtin_bit_cast(bf16x8, ou);

    f32x4 o[2][4] = {};
    f32x4 osum[2] = {};

    const unsigned short* kglob = Kb + (size_t)bh * Nc * 64;
    const unsigned short* vglob = Vt + (size_t)bh * 64 * (size_t)Nc;

    int srow = t >> 3, sseg = t & 7;
    const unsigned short* kptr = kglob + (size_t)srow * 64 + sseg * 8;
    const unsigned short* vptr = vglob + (size_t)srow * Nc + sseg * 8;

    int kts = s * (Nc >> LOGS);
    int kte = kts + (Nc >> LOGS);

    bf16x8 rK = *reinterpret_cast<const bf16x8*>(kptr + (size_t)kts * 64);
    bf16x8 rV = *reinterpret_cast<const bf16x8*>(vptr + kts);

    for (int kt0 = kts; kt0 < kte; kt0 += 64) {
        __syncthreads();
        *reinterpret_cast<bf16x8*>(&sK[srow][sseg * 8]) = rK;
        *reinterpret_cast<bf16x8*>(&sVt[srow][sseg * 8]) = rV;
        __syncthreads();
        if (kt0 + 64 < kte) {
            rK = *reinterpret_cast<const bf16x8*>(kptr + (size_t)(kt0 + 64) * 64);
            rV = *reinterpret_cast<const bf16x8*>(vptr + kt0 + 64);
        }
#pragma unroll
        for (int kt = 0; kt < 4; ++kt) {
            bf16x8 bk0 = *reinterpret_cast<const bf16x8*>(&sK[kt * 16 + lr][lg * 8]);
            bf16x8 bk1 = *reinterpret_cast<const bf16x8*>(&sK[kt * 16 + lr][32 + lg * 8]);
            f32x4 a0 = {}, a1 = {};
            __builtin_amdgcn_s_setprio(1);
            a0 = __builtin_amdgcn_mfma_f32_16x16x32_bf16(aq[0][0], bk0, a0, 0, 0, 0);
            a1 = __builtin_amdgcn_mfma_f32_16x16x32_bf16(aq[1][0], bk0, a1, 0, 0, 0);
            a0 = __builtin_amdgcn_mfma_f32_16x16x32_bf16(aq[0][1], bk1, a0, 0, 0, 0);
            a1 = __builtin_amdgcn_mfma_f32_16x16x32_bf16(aq[1][1], bk1, a1, 0, 0, 0);
            __builtin_amdgcn_s_setprio(0);
#pragma unroll
            for (int r = 0; r < 4; ++r) {
                sP[w][lg * 4 + r][kt * 16 + lr] = (__bf16)EXP2F(fminf(a0[r], 43.f));
                sP[w][16 + lg * 4 + r][kt * 16 + lr] = (__bf16)EXP2F(fminf(a1[r], 43.f));
            }
        }
#pragma unroll
        for (int kg = 0; kg < 2; ++kg) {
            bf16x8 pa0 = *reinterpret_cast<const bf16x8*>(&sP[w][lr][kg * 32 + lg * 8]);
            bf16x8 pa1 = *reinterpret_cast<const bf16x8*>(&sP[w][16 + lr][kg * 32 + lg * 8]);
            __builtin_amdgcn_s_setprio(1);
#pragma unroll
            for (int dt = 0; dt < 4; ++dt) {
                bf16x8 vb = *reinterpret_cast<const bf16x8*>(&sVt[dt * 16 + lr][kg * 32 + lg * 8]);
                o[0][dt] = __builtin_amdgcn_mfma_f32_16x16x32_bf16(pa0, vb, o[0][dt], 0, 0, 0);
                o[1][dt] = __builtin_amdgcn_mfma_f32_16x16x32_bf16(pa1, vb, o[1][dt], 0, 0, 0);
            }
            osum[0] = __builtin_amdgcn_mfma_f32_16x16x32_bf16(pa0, onesf, osum[0], 0, 0, 0);
            osum[1] = __builtin_amdgcn_mfma_f32_16x16x32_bf16(pa1, onesf, osum[1], 0, 0, 0);
            __builtin_amdgcn_s_setprio(0);
        }
    }
    float* obase = Opart + ((size_t)(s * 4 + b) * Nq + q0) * 512 + h * 64;
#pragma unroll
    for (int qt = 0; qt < 2; ++qt)
#pragma unroll
        for (int dt = 0; dt < 4; ++dt)
#pragma unroll
            for (int r = 0; r < 4; ++r)
                obase[(size_t)(qt * 16 + lg * 4 + r) * 512 + dt * 16 + lr] = o[qt][dt][r];
    if (lr == 0) {
        float* lbase = Lpart + ((size_t)(s * 4 + b) * 8 + h) * Nq + q0;
#pragma unroll
        for (int qt = 0; qt < 2; ++qt)
#pragma unroll
            for (int r = 0; r < 4; ++r)
                lbase[qt * 16 + lg * 4 + r] = osum[qt][r];
    }
}

// ---------------- host side ----------------
extern "C" void kernel_launch(void* const* d_in, const int* in_sizes, int n_in,
                              void* d_out, int out_size, void* d_ws, size_t ws_size,
                              hipStream_t stream) {
    const float* x     = (const float*)d_in[0];
    const float* c     = (const float*)d_in[1];
    const float* Wq_x  = (const float*)d_in[2];
    const float* g_qx  = (const float*)d_in[3];
    const float* Wkv_c = (const float*)d_in[4];
    const float* g_kvc = (const float*)d_in[5];
    const float* A_x   = (const float*)d_in[6];
    const float* B_x   = (const float*)d_in[7];
    const float* mag_x = (const float*)d_in[8];
    const float* Wp_x  = (const float*)d_in[9];
    const float* g_px  = (const float*)d_in[10];
    const float* Wq_c  = (const float*)d_in[11];
    const float* g_qc  = (const float*)d_in[12];
    const float* Wkv_x = (const float*)d_in[13];
    const float* g_kvx = (const float*)d_in[14];
    const float* A_c   = (const float*)d_in[15];
    const float* B_c   = (const float*)d_in[16];
    const float* mag_c = (const float*)d_in[17];
    const float* Wp_c  = (const float*)d_in[18];
    const float* g_pc  = (const float*)d_in[19];

    float* ws = (float*)d_ws;
    unsigned short* Wb = (unsigned short*)ws;
    const size_t Woff[6] = {0, 262144, 786432, 1048576, 1310720, 1835008}; // u16 units
    // layout (floats)
    float* part  = ws + 1048576;
    float* scal  = part + 192;
    float* winv  = scal + 8;
    float* sc_xq  = ws + 1049600;
    float* sc_xkv = sc_xq + 16384;
    float* sc_cq  = sc_xkv + 16384;
    float* sc_ckv = sc_cq + 4096;
    float* sc_o1  = sc_ckv + 4096;
    float* sc_o2  = sc_o1 + 16384;
    float* tmp_x  = ws + 1111040;                    // 262144
    float* tmp_c  = tmp_x + 262144;                  // 65536  -> ends 1438720
    float* actblk = ws + 1438720;                    // acts / Opart1 overlay
    unsigned short* act_xq  = (unsigned short*)actblk;                  // 4194304 f
    unsigned short* act_xkv = (unsigned short*)(actblk + 4194304);      // 4194304 f
    unsigned short* act_cq  = (unsigned short*)(actblk + 8388608);      // 1048576 f
    unsigned short* act_ckv = (unsigned short*)(actblk + 9437184);      // 1048576 f
    float* Opart1 = actblk;                          // 8388608 f over act_xq+act_xkv
    float* qf1_f  = ws + 11924480;                   // 4194304 f
    float* Opart2 = qf1_f;                           // 4194304 f (qf1 dead by attn)
    float* qf2_f  = ws + 16118784;                   // 1048576 f
    float* Qb1_f  = ws + 17167360;                   // 4194304 f (-> act_o1)
    float* Qb2_f  = ws + 21361664;                   // 1048576 f (-> act_o2)
    float* Kb1_f  = ws + 22410240;                   // 1048576 f
    float* Vt1_f  = ws + 23458816;                   // 1048576 f
    float* Kb2_f  = ws + 24507392;                   // 4194304 f
    float* Vt2_f  = ws + 28701696;                   // 4194304 f
    float* Lpart1 = ws + 32896000;                   // 131072 f
    float* Lpart2 = ws + 33027072;                   // 65536 f -> ends 33092608

    unsigned short* qf1 = (unsigned short*)qf1_f;
    unsigned short* qf2 = (unsigned short*)qf2_f;
    unsigned short* Qb1 = (unsigned short*)Qb1_f;
    unsigned short* Qb2 = (unsigned short*)Qb2_f;
    unsigned short* Kb1 = (unsigned short*)Kb1_f;
    unsigned short* Vt1 = (unsigned short*)Vt1_f;
    unsigned short* Kb2 = (unsigned short*)Kb2_f;
    unsigned short* Vt2 = (unsigned short*)Vt2_f;
    unsigned short* act_o1 = Qb1;
    unsigned short* act_o2 = Qb2;

    size_t need = (size_t)33092608 * sizeof(float);   // ~132.4 MB
    if (ws_size < need) return;

    float* outx = (float*)d_out;
    float* outc = outx + (size_t)4 * 4096 * 512;

    // weight prep (3 launches)
    k_wabs_all<<<192, 256, 0, stream>>>(Wq_x, Wkv_c, Wp_x, Wq_c, Wkv_x, Wp_c, part);
    k_wfinal<<<1, 64, 0, stream>>>(part, scal, winv);
    k_wquant_all<<<8192, 256, 0, stream>>>(Wq_x, Wkv_c, Wp_x, Wq_c, Wkv_x, Wp_c, Wb, scal);

    // all activations + DoRA tmp for BOTH passes (one launch)
    k_rmsq_dual<<<20480, 64, 0, stream>>>(x, c, g_qx, g_kvx, g_qc, g_kvc,
                                          act_xq, act_xkv, act_cq, act_ckv,
                                          sc_xq, sc_xkv, sc_cq, sc_ckv,
                                          A_x, A_c, tmp_x, tmp_c);
    // DoRA deltas, both passes
    k_lora2<<<40960, 256, 0, stream>>>(tmp_x, tmp_c, B_x, B_c, qf1, qf2);

    // Q projections, both passes (pass1 y:[0,128), pass2 y:[128,160))
    k_gemm_mfma<3><<<dim3(4, 160), 256, 0, stream>>>(
        act_xq, act_cq, Wb + Woff[0], Wb + Woff[3], sc_xq, sc_cq, winv, 0, 3,
        mag_x, mag_c, qf1, qf2, nullptr, nullptr, Qb1, Qb2, nullptr, nullptr,
        12, 10, 128, 512);
    // KV projections, both passes (pass1 y:[0,32), pass2 y:[32,160))
    k_gemm_mfma<4><<<dim3(8, 160), 256, 0, stream>>>(
        act_ckv, act_xkv, Wb + Woff[1], Wb + Woff[4], sc_ckv, sc_xkv, winv, 1, 4,
        nullptr, nullptr, nullptr, nullptr, nullptr, nullptr, Kb1, Kb2, Vt1, Vt2,
        10, 12, 32, 1024);

    // attention, both passes (heavy pass2 blocks first)
    k_attn_mfma<<<768, 512, 0, stream>>>(Qb1, Kb1, Vt1, Opart1, Lpart1,
                                         Qb2, Kb2, Vt2, Opart2, Lpart2);

    // combine + RMSNorm + quant, both passes
    k_rmsq_combine<<<20480, 64, 0, stream>>>(Opart1, Lpart1, g_px, act_o1, sc_o1,
                                             Opart2, Lpart2, g_pc, act_o2, sc_o2);

    // output projections + residual, both passes
    k_gemm_mfma<2><<<dim3(4, 160), 256, 0, stream>>>(
        act_o1, act_o2, Wb + Woff[2], Wb + Woff[5], sc_o1, sc_o2, winv, 2, 5,
        x, c, nullptr, nullptr, outx, outc, nullptr, nullptr, nullptr, nullptr,
        12, 10, 128, 512);
}

// Round 10
// 337.826 us; speedup vs baseline: 49.5888x; 1.0451x over previous
//
#include <hip/hip_runtime.h>
#include <math.h>

#define DD 512
#define NHEAD 8
#define HDIM 64

typedef __bf16 bf16x8 __attribute__((ext_vector_type(8)));
typedef unsigned short u16x8 __attribute__((ext_vector_type(8)));
typedef float f32x4 __attribute__((ext_vector_type(4)));

#if __has_builtin(__builtin_amdgcn_exp2f)
#define EXP2F(x) __builtin_amdgcn_exp2f(x)
#else
#define EXP2F(x) exp2f(x)
#endif

#define QSCALE 0.18033688f  /* (1/8) * log2(e): exp2 domain */

static __device__ __forceinline__ unsigned short f2bf(float f) {
    unsigned u = __builtin_bit_cast(unsigned, f);
    u += 0x7fffu + ((u >> 16) & 1u);   // round-to-nearest-even
    return (unsigned short)(u >> 16);
}
static __device__ __forceinline__ float bf2f(unsigned short u) {
    return __builtin_bit_cast(float, (unsigned)u << 16);
}

#define GLOAD16(g, l)                                                          \
    __builtin_amdgcn_global_load_lds(                                          \
        (__attribute__((address_space(1))) void*)(g),                          \
        (__attribute__((address_space(3))) void*)(l), 16, 0, 0)

// ---------------- weight ternary quant: consolidated prep ----------------
__global__ void k_wabs_all(const float* __restrict__ W0, const float* __restrict__ W1,
                           const float* __restrict__ W2, const float* __restrict__ W3,
                           const float* __restrict__ W4, const float* __restrict__ W5,
                           float* __restrict__ part) {
    const float* Ws[6] = {W0, W1, W2, W3, W4, W5};
    const int cnt[6] = {262144, 524288, 262144, 262144, 524288, 262144};
    int mid = blockIdx.x >> 5, lb = blockIdx.x & 31;
    const float* W = Ws[mid];
    int n = cnt[mid];
    int t = threadIdx.x;
    float s = 0.f;
    for (int i = lb * 256 + t; i < n; i += 32 * 256) s += fabsf(W[i]);
    __shared__ float red[4];
#pragma unroll
    for (int o = 32; o > 0; o >>= 1) s += __shfl_down(s, o);
    if ((t & 63) == 0) red[t >> 6] = s;
    __syncthreads();
    if (t == 0) part[blockIdx.x] = red[0] + red[1] + red[2] + red[3];
}

__global__ void k_wfinal(const float* __restrict__ part, float* __restrict__ scal,
                         float* __restrict__ winv) {
    int m = threadIdx.x;
    if (m < 6) {
        const int cnt[6] = {262144, 524288, 262144, 262144, 524288, 262144};
        float s = 0.f;
        for (int i = 0; i < 32; ++i) s += part[m * 32 + i];
        float mean = fmaxf(s / (float)cnt[m], 1e-5f);
        scal[m] = 1.f / mean;
        winv[m] = mean;
    }
}

__global__ void k_wquant_all(const float* __restrict__ W0, const float* __restrict__ W1,
                             const float* __restrict__ W2, const float* __restrict__ W3,
                             const float* __restrict__ W4, const float* __restrict__ W5,
                             unsigned short* __restrict__ Wq, const float* __restrict__ scal) {
    int e = blockIdx.x * 256 + threadIdx.x;
    const float* Ws[6] = {W0, W1, W2, W3, W4, W5};
    int mid, base;
    if (e < 262144)       { mid = 0; base = 0; }
    else if (e < 786432)  { mid = 1; base = 262144; }
    else if (e < 1048576) { mid = 2; base = 786432; }
    else if (e < 1310720) { mid = 3; base = 1048576; }
    else if (e < 1835008) { mid = 4; base = 1310720; }
    else                  { mid = 5; base = 1835008; }
    float sc = scal[mid];
    float t = rintf(Ws[mid][e - base] * sc);
    t = fminf(fmaxf(t, -1.f), 1.f);
    Wq[e] = f2bf(t);
}

// ---------------- RMSNorm + int8 quant (dual g) + fused DoRA X@A^T, both passes ----------------
#define BSTEP(s, hc)                                                           \
    {                                                                          \
        _Pragma("unroll")                                                      \
        for (int i = 0; i < (hc); ++i) {                                       \
            float send = (lane & (s)) ? p[i] : p[i + (hc)];                    \
            float recv = __shfl_xor(send, (s));                                \
            p[i] = ((lane & (s)) ? p[i + (hc)] : p[i]) + recv;                 \
        }                                                                      \
    }

__global__ void k_rmsq_dual(const float* __restrict__ x, const float* __restrict__ c,
                            const float* __restrict__ g_qx, const float* __restrict__ g_kvx,
                            const float* __restrict__ g_qc, const float* __restrict__ g_kvc,
                            unsigned short* __restrict__ a_xq, unsigned short* __restrict__ a_xkv,
                            unsigned short* __restrict__ a_cq, unsigned short* __restrict__ a_ckv,
                            float* __restrict__ s_xq, float* __restrict__ s_xkv,
                            float* __restrict__ s_cq, float* __restrict__ s_ckv,
                            const float* __restrict__ A_x, const float* __restrict__ A_c,
                            float* __restrict__ tmp_x, float* __restrict__ tmp_c) {
    int row = blockIdx.x;
    int lane = threadIdx.x;
    bool pc = (row >= 16384);
    int r = pc ? row - 16384 : row;
    const float* xr = (pc ? c : x) + (size_t)r * DD;
    const float* G1 = pc ? g_qc : g_qx;
    const float* G2 = pc ? g_kvc : g_kvx;
    unsigned short* O1 = pc ? a_cq : a_xq;
    unsigned short* O2 = pc ? a_ckv : a_xkv;
    float* S1 = pc ? s_cq : s_xq;
    float* S2 = pc ? s_ckv : s_xkv;
    const float* AM = pc ? A_c : A_x;
    float* TMP = pc ? tmp_c : tmp_x;

    float4 a = *(const float4*)(xr + lane * 8);
    float4 b = *(const float4*)(xr + lane * 8 + 4);
    // DoRA dots on raw input (in registers)
    float p[16];
#pragma unroll
    for (int cc = 0; cc < 16; ++cc) {
        const float4* ar = (const float4*)(AM + (size_t)cc * DD + lane * 8);
        float4 aa = ar[0], ab = ar[1];
        p[cc] = a.x*aa.x + a.y*aa.y + a.z*aa.z + a.w*aa.w
              + b.x*ab.x + b.y*ab.y + b.z*ab.z + b.w*ab.w;
    }
    BSTEP(1, 8) BSTEP(2, 4) BSTEP(4, 2) BSTEP(8, 1)
    p[0] += __shfl_xor(p[0], 16);
    p[0] += __shfl_xor(p[0], 32);
    if (lane < 16) {
        int cidx = ((lane & 1) << 3) | ((lane & 2) << 1) | ((lane & 4) >> 1) | ((lane & 8) >> 3);
        TMP[(size_t)r * 16 + cidx] = p[0];
    }
    float ss = a.x*a.x + a.y*a.y + a.z*a.z + a.w*a.w
             + b.x*b.x + b.y*b.y + b.z*b.z + b.w*b.w;
#pragma unroll
    for (int o = 32; o > 0; o >>= 1) ss += __shfl_xor(ss, o);
    float rn = 1.f / sqrtf(ss * (1.f / 512.f) + 1e-8f);
    const float* gs[2] = {G1, G2};
    unsigned short* os[2] = {O1, O2};
    float* scs[2] = {S1, S2};
#pragma unroll
    for (int pass = 0; pass < 2; ++pass) {
        float4 ga = *(const float4*)(gs[pass] + lane * 8);
        float4 gb = *(const float4*)(gs[pass] + lane * 8 + 4);
        float v[8] = {a.x*rn*ga.x, a.y*rn*ga.y, a.z*rn*ga.z, a.w*rn*ga.w,
                      b.x*rn*gb.x, b.y*rn*gb.y, b.z*rn*gb.z, b.w*rn*gb.w};
        float amax = 0.f;
#pragma unroll
        for (int i = 0; i < 8; ++i) amax = fmaxf(amax, fabsf(v[i]));
#pragma unroll
        for (int o = 32; o > 0; o >>= 1) amax = fmaxf(amax, __shfl_xor(amax, o));
        float mx = fmaxf(amax, 1e-5f);
        float scale = 127.f / mx;
        u16x8 qv;
#pragma unroll
        for (int i = 0; i < 8; ++i) {
            float tq = rintf(v[i] * scale);
            tq = fminf(fmaxf(tq, -128.f), 127.f);
            qv[i] = f2bf(tq);
        }
        *reinterpret_cast<u16x8*>(os[pass] + (size_t)r * DD + lane * 8) = qv;
        if (lane == 0) scs[pass][r] = mx / 127.f;
    }
}

// ---------------- DoRA delta: qf = tmp @ B^T (bf16 out), both passes ----------------
__global__ void k_lora2(const float* __restrict__ tmp_x, const float* __restrict__ tmp_c,
                        const float* __restrict__ B_x, const float* __restrict__ B_c,
                        unsigned short* __restrict__ qf1, unsigned short* __restrict__ qf2) {
    int idx = blockIdx.x * 256 + threadIdx.x;   // over 20480*512
    int m2 = idx >> 9, n2 = idx & 511;
    const float* tr;
    const float* br;
    unsigned short* out;
    if (m2 < 16384) {
        tr = tmp_x + (size_t)m2 * 16; br = B_x + (size_t)n2 * 16; out = qf1 + idx;
    } else {
        tr = tmp_c + (size_t)(m2 - 16384) * 16; br = B_c + (size_t)n2 * 16;
        out = qf2 + (idx - 8388608);
    }
    const float4* t4 = (const float4*)tr;
    const float4* b4 = (const float4*)br;
    float acc = 0.f;
#pragma unroll
    for (int rr = 0; rr < 4; ++rr) {
        float4 ta = t4[rr], ba = b4[rr];
        acc += ta.x*ba.x + ta.y*ba.y + ta.z*ba.z + ta.w*ba.w;
    }
    *out = f2bf(acc);
}

// ---------------- combine attn partials + RMSNorm + quant, both passes ----------------
__global__ void k_rmsq_combine(const float* __restrict__ Op_a, const float* __restrict__ Lp_a,
                               const float* __restrict__ g_a, unsigned short* __restrict__ out_a,
                               float* __restrict__ sc_a,
                               const float* __restrict__ Op_b, const float* __restrict__ Lp_b,
                               const float* __restrict__ g_b, unsigned short* __restrict__ out_b,
                               float* __restrict__ sc_b) {
    int row = blockIdx.x;
    int lane = threadIdx.x;
    bool pb = (row >= 16384);
    int r = pb ? row - 16384 : row;
    int S = pb ? 2 : 1;
    int lognq = pb ? 10 : 12;
    const float* Op = pb ? Op_b : Op_a;
    const float* Lp = pb ? Lp_b : Lp_a;
    const float* g  = pb ? g_b : g_a;
    unsigned short* out = pb ? out_b : out_a;
    float* a_inv = pb ? sc_b : sc_a;

    int Nq = 1 << lognq;
    int b = r >> lognq, q = r & (Nq - 1);
    int h = lane >> 3;
    float l = 0.f;
    float u[8] = {};
    for (int s = 0; s < S; ++s) {
        l += Lp[((size_t)(s * 4 + b) * 8 + h) * Nq + q];
        const float* orow = Op + ((size_t)(s * 4 + b) * Nq + q) * 512 + lane * 8;
        float4 a = *(const float4*)orow;
        float4 bb = *(const float4*)(orow + 4);
        u[0] += a.x; u[1] += a.y; u[2] += a.z; u[3] += a.w;
        u[4] += bb.x; u[5] += bb.y; u[6] += bb.z; u[7] += bb.w;
    }
    float invl = 1.f / l;
#pragma unroll
    for (int i = 0; i < 8; ++i) u[i] *= invl;
    float ss = 0.f;
#pragma unroll
    for (int i = 0; i < 8; ++i) ss += u[i] * u[i];
#pragma unroll
    for (int o = 32; o > 0; o >>= 1) ss += __shfl_xor(ss, o);
    float rn = 1.f / sqrtf(ss * (1.f / 512.f) + 1e-8f);
    float4 ga = *(const float4*)(g + lane * 8);
    float4 gb = *(const float4*)(g + lane * 8 + 4);
    float v[8] = {u[0]*rn*ga.x, u[1]*rn*ga.y, u[2]*rn*ga.z, u[3]*rn*ga.w,
                  u[4]*rn*gb.x, u[5]*rn*gb.y, u[6]*rn*gb.z, u[7]*rn*gb.w};
    float amax = 0.f;
#pragma unroll
    for (int i = 0; i < 8; ++i) amax = fmaxf(amax, fabsf(v[i]));
#pragma unroll
    for (int o = 32; o > 0; o >>= 1) amax = fmaxf(amax, __shfl_xor(amax, o));
    float mx = fmaxf(amax, 1e-5f);
    float scale = 127.f / mx;
    u16x8 qv;
#pragma unroll
    for (int i = 0; i < 8; ++i) {
        float tq = rintf(v[i] * scale);
        tq = fminf(fmaxf(tq, -128.f), 127.f);
        qv[i] = f2bf(tq);
    }
    *reinterpret_cast<u16x8*>(out + (size_t)r * DD + lane * 8) = qv;
    if (lane == 0) a_inv[r] = mx / 127.f;
}

// ---------------- bf16 MFMA GEMM, both passes in one launch (split at Y0) ----------------
// MODE 2: OutF = acc*as + Ex(resid fp32).  MODE 3: Qb bf16 = (acc*as + Ex[h]*Dlt)*QSCALE.
// MODE 4: Kb bf16 [b][h][key][64] + Vt bf16 [b][h][d][keyp] (key-permuted within 32-groups
//         to match the attn kernel's swapped-QK^T in-register P fragment layout).
template <int MODE>
__global__ __launch_bounds__(256) void k_gemm_mfma(
    const unsigned short* __restrict__ Aq_a, const unsigned short* __restrict__ Aq_b,
    const unsigned short* __restrict__ Wq_a, const unsigned short* __restrict__ Wq_b,
    const float* __restrict__ ai_a, const float* __restrict__ ai_b,
    const float* __restrict__ winv, int wi_a, int wi_b,
    const float* __restrict__ Ex_a, const float* __restrict__ Ex_b,
    const unsigned short* __restrict__ Dl_a, const unsigned short* __restrict__ Dl_b,
    float* __restrict__ OF_a, float* __restrict__ OF_b,
    unsigned short* __restrict__ OB_a, unsigned short* __restrict__ OB_b,
    unsigned short* __restrict__ OB2_a, unsigned short* __restrict__ OB2_b,
    int logn_a, int logn_b, int Y0, int N) {
    __shared__ __align__(16) unsigned short sA[128 * 32];
    __shared__ __align__(16) unsigned short sB[128 * 32];
    bool pb = ((int)blockIdx.y >= Y0);
    const unsigned short* Aq = pb ? Aq_b : Aq_a;
    const unsigned short* Wq = pb ? Wq_b : Wq_a;
    const float* a_inv = pb ? ai_b : ai_a;
    const float* Extra = pb ? Ex_b : Ex_a;
    const unsigned short* Dlt = pb ? Dl_b : Dl_a;
    float* OutF = pb ? OF_b : OF_a;
    unsigned short* OutB = pb ? OB_b : OB_a;
    unsigned short* OutB2 = pb ? OB2_b : OB2_a;
    int logn = pb ? logn_b : logn_a;
    float wv = winv[pb ? wi_b : wi_a];
    int m0 = (pb ? ((int)blockIdx.y - Y0) : (int)blockIdx.y) * 128;

    int t = threadIdx.x;
    int w = t >> 6, lane = t & 63;
    int wm = w >> 1, wn = w & 1;
    int lr = lane & 15, lg = lane >> 4;
    int n0 = blockIdx.x * 128;
    int row_st = t >> 2, chunk = t & 3;
    f32x4 acc[4][4] = {};

    for (int k0 = 0; k0 < 512; k0 += 32) {
        __syncthreads();
#pragma unroll
        for (int i = 0; i < 2; ++i) {
            int row = i * 64 + row_st;
            GLOAD16(Aq + (size_t)(m0 + row) * 512 + k0 + chunk * 8, sA + ((size_t)i * 256 + t) * 8);
            GLOAD16(Wq + (size_t)(n0 + row) * 512 + k0 + chunk * 8, sB + ((size_t)i * 256 + t) * 8);
        }
        asm volatile("s_waitcnt vmcnt(0)" ::: "memory");
        __syncthreads();
        bf16x8 af[4], bfr[4];
#pragma unroll
        for (int mt = 0; mt < 4; ++mt)
            af[mt] = *reinterpret_cast<const bf16x8*>(&sA[(wm * 64 + mt * 16 + lr) * 32 + lg * 8]);
#pragma unroll
        for (int nt = 0; nt < 4; ++nt)
            bfr[nt] = *reinterpret_cast<const bf16x8*>(&sB[(wn * 64 + nt * 16 + lr) * 32 + lg * 8]);
#pragma unroll
        for (int mt = 0; mt < 4; ++mt)
#pragma unroll
            for (int nt = 0; nt < 4; ++nt)
                acc[mt][nt] = __builtin_amdgcn_mfma_f32_16x16x32_bf16(af[mt], bfr[nt], acc[mt][nt], 0, 0, 0);
    }

    if (MODE == 4) {
        const bool isV = (n0 >= 512);
        const int Nc = 1 << logn;
#pragma unroll
        for (int mt = 0; mt < 4; ++mt) {
            int mb = m0 + wm * 64 + mt * 16 + lg * 4;
            int b = mb >> logn, key = mb & (Nc - 1);
            float as_[4];
#pragma unroll
            for (int r = 0; r < 4; ++r) as_[r] = a_inv[mb + r] * wv;
#pragma unroll
            for (int nt = 0; nt < 4; ++nt) {
                int n = n0 + wn * 64 + nt * 16 + lr;
                int n2 = isV ? (n - 512) : n;
                int h = n2 >> 6, dd = n2 & 63;
                if (isV) {
                    // permuted key position within each 32-group (attn A-frag layout):
                    // p0 = ((key>>2)&3)*8 + ((key>>4)&1)*4
                    int i0 = key & 31;
                    int keyp = (key & ~31) | (((i0 >> 2) & 3) * 8 + ((i0 >> 4) & 1) * 4);
                    ushort4 v;
                    v.x = f2bf(acc[mt][nt][0] * as_[0]);
                    v.y = f2bf(acc[mt][nt][1] * as_[1]);
                    v.z = f2bf(acc[mt][nt][2] * as_[2]);
                    v.w = f2bf(acc[mt][nt][3] * as_[3]);
                    *reinterpret_cast<ushort4*>(
                        OutB2 + ((size_t)(b * NHEAD + h) * 64 + dd) * Nc + keyp) = v;
                } else {
#pragma unroll
                    for (int r = 0; r < 4; ++r)
                        OutB[((size_t)(b * NHEAD + h) * Nc + key + r) * 64 + dd] =
                            f2bf(acc[mt][nt][r] * as_[r]);
                }
            }
        }
    } else {
#pragma unroll
        for (int mt = 0; mt < 4; ++mt) {
#pragma unroll
            for (int r = 0; r < 4; ++r) {
                int m = m0 + wm * 64 + mt * 16 + lg * 4 + r;
                float as = a_inv[m] * wv;
                if (MODE == 3) {
                    int b = m >> logn, q = m & ((1 << logn) - 1);
#pragma unroll
                    for (int nt = 0; nt < 4; ++nt) {
                        int n = n0 + wn * 64 + nt * 16 + lr;
                        float dl = bf2f(Dlt[(size_t)m * 512 + n]);
                        float val = acc[mt][nt][r] * as + Extra[n >> 6] * dl;
                        int h = n >> 6, d = n & 63;
                        OutB[((((size_t)(b * NHEAD + h)) << logn) + q) * 64 + d] =
                            f2bf(val * QSCALE);
                    }
                } else {
#pragma unroll
                    for (int nt = 0; nt < 4; ++nt) {
                        int n = n0 + wn * 64 + nt * 16 + lr;
                        size_t idx = (size_t)m * N + n;
                        OutF[idx] = acc[mt][nt][r] * as + Extra[idx];
                    }
                }
            }
        }
    }
}

// ---------------- flash attention, swapped-QK^T, in-register P ----------------
// 768 blocks: bid<256 = pass2 (heavy, dispatched first), bid>=256 = pass1.
// 512 threads = 8 waves, 32 q/wave. S tile = mfma(K, Q): lane holds
// P[key=kt*16+lg*4+r][query=lr] -> after exp these ARE a PV A-fragment under the
// key permutation baked into Vt by the MODE-4 epilogue. No P LDS round-trip.
__global__ __launch_bounds__(512) void k_attn_mfma(
    const unsigned short* __restrict__ Qb_a, const unsigned short* __restrict__ Kb_a,
    const unsigned short* __restrict__ Vt_a, float* __restrict__ Op_a, float* __restrict__ Lp_a,
    const unsigned short* __restrict__ Qb_b, const unsigned short* __restrict__ Kb_b,
    const unsigned short* __restrict__ Vt_b, float* __restrict__ Op_b, float* __restrict__ Lp_b) {
    __shared__ unsigned short sK[64][72];
    __shared__ unsigned short sVt[64][72];
    int t = threadIdx.x;
    int w = t >> 6, lane = t & 63;
    int lr = lane & 15, lg = lane >> 4;

    int bid = blockIdx.x;
    bool pb = (bid < 256);
    int lb = pb ? bid : bid - 256;
    const unsigned short* Qb = pb ? Qb_b : Qb_a;
    const unsigned short* Kb = pb ? Kb_b : Kb_a;
    const unsigned short* Vt = pb ? Vt_b : Vt_a;
    float* Opart = pb ? Op_b : Op_a;
    float* Lpart = pb ? Lp_b : Lp_a;
    int Nq = pb ? 1024 : 4096;
    int Nc = pb ? 4096 : 1024;
    int S = pb ? 2 : 1;
    int LOGS = pb ? 1 : 0;
    int nqs = pb ? 2 : 4;

    int j = lb >> 3;
    int s = j & (S - 1);
    int j2 = j >> LOGS;
    int qblk = j2 & ((1 << nqs) - 1);
    int bh = ((lb & 7) << 2) | (j2 >> nqs);   // XCD-local bh groups
    int b = bh >> 3, h = bh & 7;
    int q0 = qblk * 256 + w * 32;

    bf16x8 aq[2][2];
#pragma unroll
    for (int qt = 0; qt < 2; ++qt) {
        const unsigned short* qbase = Qb + ((size_t)bh * Nq + q0 + qt * 16 + lr) * 64 + lg * 8;
        aq[qt][0] = *reinterpret_cast<const bf16x8*>(qbase);
        aq[qt][1] = *reinterpret_cast<const bf16x8*>(qbase + 32);
    }

    u16x8 ou;
#pragma unroll
    for (int jj = 0; jj < 8; ++jj) ou[jj] = (lr == 0) ? 0x3F80 : 0;
    bf16x8 onesf = __builtin_bit_cast(bf16x8, ou);

    f32x4 o[2][4] = {};
    f32x4 osum[2] = {};

    const unsigned short* kglob = Kb + (size_t)bh * Nc * 64;
    const unsigned short* vglob = Vt + (size_t)bh * 64 * (size_t)Nc;

    int srow = t >> 3, sseg = t & 7;
    const unsigned short* kptr = kglob + (size_t)srow * 64 + sseg * 8;
    const unsigned short* vptr = vglob + (size_t)srow * Nc + sseg * 8;

    int kts = s * (Nc >> LOGS);
    int kte = kts + (Nc >> LOGS);

    bf16x8 rK = *reinterpret_cast<const bf16x8*>(kptr + (size_t)kts * 64);
    bf16x8 rV = *reinterpret_cast<const bf16x8*>(vptr + kts);

    for (int kt0 = kts; kt0 < kte; kt0 += 64) {
        __syncthreads();
        *reinterpret_cast<bf16x8*>(&sK[srow][sseg * 8]) = rK;
        *reinterpret_cast<bf16x8*>(&sVt[srow][sseg * 8]) = rV;
        __syncthreads();
        if (kt0 + 64 < kte) {
            rK = *reinterpret_cast<const bf16x8*>(kptr + (size_t)(kt0 + 64) * 64);
            rV = *reinterpret_cast<const bf16x8*>(vptr + kt0 + 64);
        }
        // S = K Q^T (swapped): lane holds S[key=kt*16+lg*4+r][query=lr].
        // exp2 -> bf16 packs directly into PV A-fragments pa[qt][kg].
        bf16x8 pa0[2], pa1[2];
#pragma unroll
        for (int kt = 0; kt < 4; ++kt) {
            bf16x8 bk0 = *reinterpret_cast<const bf16x8*>(&sK[kt * 16 + lr][lg * 8]);
            bf16x8 bk1 = *reinterpret_cast<const bf16x8*>(&sK[kt * 16 + lr][32 + lg * 8]);
            f32x4 a0 = {}, a1 = {};
            __builtin_amdgcn_s_setprio(1);
            a0 = __builtin_amdgcn_mfma_f32_16x16x32_bf16(bk0, aq[0][0], a0, 0, 0, 0);
            a1 = __builtin_amdgcn_mfma_f32_16x16x32_bf16(bk0, aq[1][0], a1, 0, 0, 0);
            a0 = __builtin_amdgcn_mfma_f32_16x16x32_bf16(bk1, aq[0][1], a0, 0, 0, 0);
            a1 = __builtin_amdgcn_mfma_f32_16x16x32_bf16(bk1, aq[1][1], a1, 0, 0, 0);
            __builtin_amdgcn_s_setprio(0);
            const int kg = kt >> 1, hb = (kt & 1) * 4;
#pragma unroll
            for (int r = 0; r < 4; ++r) {
                if (kt < 2) {
                    pa0[0][hb + r] = (__bf16)EXP2F(fminf(a0[r], 43.f));
                    pa1[0][hb + r] = (__bf16)EXP2F(fminf(a1[r], 43.f));
                } else {
                    pa0[1][hb + r] = (__bf16)EXP2F(fminf(a0[r], 43.f));
                    pa1[1][hb + r] = (__bf16)EXP2F(fminf(a1[r], 43.f));
                }
            }
            (void)kg;
        }
        // O += P @ V ; osum += P @ ones  (Vt pre-permuted to match pa's key order)
#pragma unroll
        for (int kg = 0; kg < 2; ++kg) {
            __builtin_amdgcn_s_setprio(1);
#pragma unroll
            for (int dt = 0; dt < 4; ++dt) {
                bf16x8 vb = *reinterpret_cast<const bf16x8*>(&sVt[dt * 16 + lr][kg * 32 + lg * 8]);
                o[0][dt] = __builtin_amdgcn_mfma_f32_16x16x32_bf16(pa0[kg], vb, o[0][dt], 0, 0, 0);
                o[1][dt] = __builtin_amdgcn_mfma_f32_16x16x32_bf16(pa1[kg], vb, o[1][dt], 0, 0, 0);
            }
            osum[0] = __builtin_amdgcn_mfma_f32_16x16x32_bf16(pa0[kg], onesf, osum[0], 0, 0, 0);
            osum[1] = __builtin_amdgcn_mfma_f32_16x16x32_bf16(pa1[kg], onesf, osum[1], 0, 0, 0);
            __builtin_amdgcn_s_setprio(0);
        }
    }
    float* obase = Opart + ((size_t)(s * 4 + b) * Nq + q0) * 512 + h * 64;
#pragma unroll
    for (int qt = 0; qt < 2; ++qt)
#pragma unroll
        for (int dt = 0; dt < 4; ++dt)
#pragma unroll
            for (int r = 0; r < 4; ++r)
                obase[(size_t)(qt * 16 + lg * 4 + r) * 512 + dt * 16 + lr] = o[qt][dt][r];
    if (lr == 0) {
        float* lbase = Lpart + ((size_t)(s * 4 + b) * 8 + h) * Nq + q0;
#pragma unroll
        for (int qt = 0; qt < 2; ++qt)
#pragma unroll
            for (int r = 0; r < 4; ++r)
                lbase[qt * 16 + lg * 4 + r] = osum[qt][r];
    }
}

// ---------------- host side ----------------
extern "C" void kernel_launch(void* const* d_in, const int* in_sizes, int n_in,
                              void* d_out, int out_size, void* d_ws, size_t ws_size,
                              hipStream_t stream) {
    const float* x     = (const float*)d_in[0];
    const float* c     = (const float*)d_in[1];
    const float* Wq_x  = (const float*)d_in[2];
    const float* g_qx  = (const float*)d_in[3];
    const float* Wkv_c = (const float*)d_in[4];
    const float* g_kvc = (const float*)d_in[5];
    const float* A_x   = (const float*)d_in[6];
    const float* B_x   = (const float*)d_in[7];
    const float* mag_x = (const float*)d_in[8];
    const float* Wp_x  = (const float*)d_in[9];
    const float* g_px  = (const float*)d_in[10];
    const float* Wq_c  = (const float*)d_in[11];
    const float* g_qc  = (const float*)d_in[12];
    const float* Wkv_x = (const float*)d_in[13];
    const float* g_kvx = (const float*)d_in[14];
    const float* A_c   = (const float*)d_in[15];
    const float* B_c   = (const float*)d_in[16];
    const float* mag_c = (const float*)d_in[17];
    const float* Wp_c  = (const float*)d_in[18];
    const float* g_pc  = (const float*)d_in[19];

    float* ws = (float*)d_ws;
    unsigned short* Wb = (unsigned short*)ws;
    const size_t Woff[6] = {0, 262144, 786432, 1048576, 1310720, 1835008}; // u16 units
    float* part  = ws + 1048576;
    float* scal  = part + 192;
    float* winv  = scal + 8;
    float* sc_xq  = ws + 1049600;
    float* sc_xkv = sc_xq + 16384;
    float* sc_cq  = sc_xkv + 16384;
    float* sc_ckv = sc_cq + 4096;
    float* sc_o1  = sc_ckv + 4096;
    float* sc_o2  = sc_o1 + 16384;
    float* tmp_x  = ws + 1111040;                    // 262144
    float* tmp_c  = tmp_x + 262144;                  // 65536  -> ends 1438720
    float* actblk = ws + 1438720;                    // acts / Opart1 overlay
    unsigned short* act_xq  = (unsigned short*)actblk;                  // 4194304 f
    unsigned short* act_xkv = (unsigned short*)(actblk + 4194304);      // 4194304 f
    unsigned short* act_cq  = (unsigned short*)(actblk + 8388608);      // 1048576 f
    unsigned short* act_ckv = (unsigned short*)(actblk + 9437184);      // 1048576 f
    float* Opart1 = actblk;                          // 8388608 f over act_xq+act_xkv
    float* qf1_f  = ws + 11924480;                   // 4194304 f
    float* Opart2 = qf1_f;                           // 4194304 f (qf1 dead by attn)
    float* qf2_f  = ws + 16118784;                   // 1048576 f
    float* Qb1_f  = ws + 17167360;                   // 4194304 f (-> act_o1)
    float* Qb2_f  = ws + 21361664;                   // 1048576 f (-> act_o2)
    float* Kb1_f  = ws + 22410240;                   // 1048576 f
    float* Vt1_f  = ws + 23458816;                   // 1048576 f
    float* Kb2_f  = ws + 24507392;                   // 4194304 f
    float* Vt2_f  = ws + 28701696;                   // 4194304 f
    float* Lpart1 = ws + 32896000;                   // 131072 f
    float* Lpart2 = ws + 33027072;                   // 65536 f -> ends 33092608

    unsigned short* qf1 = (unsigned short*)qf1_f;
    unsigned short* qf2 = (unsigned short*)qf2_f;
    unsigned short* Qb1 = (unsigned short*)Qb1_f;
    unsigned short* Qb2 = (unsigned short*)Qb2_f;
    unsigned short* Kb1 = (unsigned short*)Kb1_f;
    unsigned short* Vt1 = (unsigned short*)Vt1_f;
    unsigned short* Kb2 = (unsigned short*)Kb2_f;
    unsigned short* Vt2 = (unsigned short*)Vt2_f;
    unsigned short* act_o1 = Qb1;
    unsigned short* act_o2 = Qb2;

    size_t need = (size_t)33092608 * sizeof(float);   // ~132.4 MB
    if (ws_size < need) return;

    float* outx = (float*)d_out;
    float* outc = outx + (size_t)4 * 4096 * 512;

    // weight prep (3 launches)
    k_wabs_all<<<192, 256, 0, stream>>>(Wq_x, Wkv_c, Wp_x, Wq_c, Wkv_x, Wp_c, part);
    k_wfinal<<<1, 64, 0, stream>>>(part, scal, winv);
    k_wquant_all<<<8192, 256, 0, stream>>>(Wq_x, Wkv_c, Wp_x, Wq_c, Wkv_x, Wp_c, Wb, scal);

    // all activations + DoRA tmp for BOTH passes (one launch)
    k_rmsq_dual<<<20480, 64, 0, stream>>>(x, c, g_qx, g_kvx, g_qc, g_kvc,
                                          act_xq, act_xkv, act_cq, act_ckv,
                                          sc_xq, sc_xkv, sc_cq, sc_ckv,
                                          A_x, A_c, tmp_x, tmp_c);
    // DoRA deltas, both passes
    k_lora2<<<40960, 256, 0, stream>>>(tmp_x, tmp_c, B_x, B_c, qf1, qf2);

    // Q projections, both passes (pass1 y:[0,128), pass2 y:[128,160))
    k_gemm_mfma<3><<<dim3(4, 160), 256, 0, stream>>>(
        act_xq, act_cq, Wb + Woff[0], Wb + Woff[3], sc_xq, sc_cq, winv, 0, 3,
        mag_x, mag_c, qf1, qf2, nullptr, nullptr, Qb1, Qb2, nullptr, nullptr,
        12, 10, 128, 512);
    // KV projections, both passes (pass1 y:[0,32), pass2 y:[32,160))
    k_gemm_mfma<4><<<dim3(8, 160), 256, 0, stream>>>(
        act_ckv, act_xkv, Wb + Woff[1], Wb + Woff[4], sc_ckv, sc_xkv, winv, 1, 4,
        nullptr, nullptr, nullptr, nullptr, nullptr, nullptr, Kb1, Kb2, Vt1, Vt2,
        10, 12, 32, 1024);

    // attention, both passes (heavy pass2 blocks first)
    k_attn_mfma<<<768, 512, 0, stream>>>(Qb1, Kb1, Vt1, Opart1, Lpart1,
                                         Qb2, Kb2, Vt2, Opart2, Lpart2);

    // combine + RMSNorm + quant, both passes
    k_rmsq_combine<<<20480, 64, 0, stream>>>(Opart1, Lpart1, g_px, act_o1, sc_o1,
                                             Opart2, Lpart2, g_pc, act_o2, sc_o2);

    // output projections + residual, both passes
    k_gemm_mfma<2><<<dim3(4, 160), 256, 0, stream>>>(
        act_o1, act_o2, Wb + Woff[2], Wb + Woff[5], sc_o1, sc_o2, winv, 2, 5,
        x, c, nullptr, nullptr, outx, outc, nullptr, nullptr, nullptr, nullptr,
        12, 10, 128, 512);
}

// Round 11
// 316.861 us; speedup vs baseline: 52.8700x; 1.0662x over previous
//
#include <hip/hip_runtime.h>
#include <math.h>

#define DD 512
#define NHEAD 8
#define HDIM 64

typedef __bf16 bf16x8 __attribute__((ext_vector_type(8)));
typedef unsigned short u16x8 __attribute__((ext_vector_type(8)));
typedef float f32x4 __attribute__((ext_vector_type(4)));

#if __has_builtin(__builtin_amdgcn_exp2f)
#define EXP2F(x) __builtin_amdgcn_exp2f(x)
#else
#define EXP2F(x) exp2f(x)
#endif

#define QSCALE 0.18033688f  /* (1/8) * log2(e): exp2 domain */

static __device__ __forceinline__ unsigned short f2bf(float f) {
    unsigned u = __builtin_bit_cast(unsigned, f);
    u += 0x7fffu + ((u >> 16) & 1u);   // round-to-nearest-even
    return (unsigned short)(u >> 16);
}
static __device__ __forceinline__ float bf2f(unsigned short u) {
    return __builtin_bit_cast(float, (unsigned)u << 16);
}

#define GLOAD16(g, l)                                                          \
    __builtin_amdgcn_global_load_lds(                                          \
        (__attribute__((address_space(1))) void*)(g),                          \
        (__attribute__((address_space(3))) void*)(l), 16, 0, 0)

// ---------------- weight ternary quant: consolidated prep ----------------
__global__ void k_wabs_all(const float* __restrict__ W0, const float* __restrict__ W1,
                           const float* __restrict__ W2, const float* __restrict__ W3,
                           const float* __restrict__ W4, const float* __restrict__ W5,
                           float* __restrict__ part) {
    const float* Ws[6] = {W0, W1, W2, W3, W4, W5};
    const int cnt[6] = {262144, 524288, 262144, 262144, 524288, 262144};
    int mid = blockIdx.x >> 5, lb = blockIdx.x & 31;
    const float* W = Ws[mid];
    int n = cnt[mid];
    int t = threadIdx.x;
    float s = 0.f;
    for (int i = lb * 256 + t; i < n; i += 32 * 256) s += fabsf(W[i]);
    __shared__ float red[4];
#pragma unroll
    for (int o = 32; o > 0; o >>= 1) s += __shfl_down(s, o);
    if ((t & 63) == 0) red[t >> 6] = s;
    __syncthreads();
    if (t == 0) part[blockIdx.x] = red[0] + red[1] + red[2] + red[3];
}

__global__ void k_wfinal(const float* __restrict__ part, float* __restrict__ scal,
                         float* __restrict__ winv) {
    int m = threadIdx.x;
    if (m < 6) {
        const int cnt[6] = {262144, 524288, 262144, 262144, 524288, 262144};
        float s = 0.f;
        for (int i = 0; i < 32; ++i) s += part[m * 32 + i];
        float mean = fmaxf(s / (float)cnt[m], 1e-5f);
        scal[m] = 1.f / mean;
        winv[m] = mean;
    }
}

__global__ void k_wquant_all(const float* __restrict__ W0, const float* __restrict__ W1,
                             const float* __restrict__ W2, const float* __restrict__ W3,
                             const float* __restrict__ W4, const float* __restrict__ W5,
                             unsigned short* __restrict__ Wq, const float* __restrict__ scal) {
    int e = blockIdx.x * 256 + threadIdx.x;
    const float* Ws[6] = {W0, W1, W2, W3, W4, W5};
    int mid, base;
    if (e < 262144)       { mid = 0; base = 0; }
    else if (e < 786432)  { mid = 1; base = 262144; }
    else if (e < 1048576) { mid = 2; base = 786432; }
    else if (e < 1310720) { mid = 3; base = 1048576; }
    else if (e < 1835008) { mid = 4; base = 1310720; }
    else                  { mid = 5; base = 1835008; }
    float sc = scal[mid];
    float t = rintf(Ws[mid][e - base] * sc);
    t = fminf(fmaxf(t, -1.f), 1.f);
    Wq[e] = f2bf(t);
}

// ---------------- RMSNorm + int8 quant (dual g) + fused DoRA X@A^T, both passes ----------------
#define BSTEP(s, hc)                                                           \
    {                                                                          \
        _Pragma("unroll")                                                      \
        for (int i = 0; i < (hc); ++i) {                                       \
            float send = (lane & (s)) ? p[i] : p[i + (hc)];                    \
            float recv = __shfl_xor(send, (s));                                \
            p[i] = ((lane & (s)) ? p[i + (hc)] : p[i]) + recv;                 \
        }                                                                      \
    }

__global__ void k_rmsq_dual(const float* __restrict__ x, const float* __restrict__ c,
                            const float* __restrict__ g_qx, const float* __restrict__ g_kvx,
                            const float* __restrict__ g_qc, const float* __restrict__ g_kvc,
                            unsigned short* __restrict__ a_xq, unsigned short* __restrict__ a_xkv,
                            unsigned short* __restrict__ a_cq, unsigned short* __restrict__ a_ckv,
                            float* __restrict__ s_xq, float* __restrict__ s_xkv,
                            float* __restrict__ s_cq, float* __restrict__ s_ckv,
                            const float* __restrict__ A_x, const float* __restrict__ A_c,
                            float* __restrict__ tmp_x, float* __restrict__ tmp_c) {
    int row = blockIdx.x;
    int lane = threadIdx.x;
    bool pc = (row >= 16384);
    int r = pc ? row - 16384 : row;
    const float* xr = (pc ? c : x) + (size_t)r * DD;
    const float* G1 = pc ? g_qc : g_qx;
    const float* G2 = pc ? g_kvc : g_kvx;
    unsigned short* O1 = pc ? a_cq : a_xq;
    unsigned short* O2 = pc ? a_ckv : a_xkv;
    float* S1 = pc ? s_cq : s_xq;
    float* S2 = pc ? s_ckv : s_xkv;
    const float* AM = pc ? A_c : A_x;
    float* TMP = pc ? tmp_c : tmp_x;

    float4 a = *(const float4*)(xr + lane * 8);
    float4 b = *(const float4*)(xr + lane * 8 + 4);
    // DoRA dots on raw input (in registers)
    float p[16];
#pragma unroll
    for (int cc = 0; cc < 16; ++cc) {
        const float4* ar = (const float4*)(AM + (size_t)cc * DD + lane * 8);
        float4 aa = ar[0], ab = ar[1];
        p[cc] = a.x*aa.x + a.y*aa.y + a.z*aa.z + a.w*aa.w
              + b.x*ab.x + b.y*ab.y + b.z*ab.z + b.w*ab.w;
    }
    BSTEP(1, 8) BSTEP(2, 4) BSTEP(4, 2) BSTEP(8, 1)
    p[0] += __shfl_xor(p[0], 16);
    p[0] += __shfl_xor(p[0], 32);
    if (lane < 16) {
        int cidx = ((lane & 1) << 3) | ((lane & 2) << 1) | ((lane & 4) >> 1) | ((lane & 8) >> 3);
        TMP[(size_t)r * 16 + cidx] = p[0];
    }
    float ss = a.x*a.x + a.y*a.y + a.z*a.z + a.w*a.w
             + b.x*b.x + b.y*b.y + b.z*b.z + b.w*b.w;
#pragma unroll
    for (int o = 32; o > 0; o >>= 1) ss += __shfl_xor(ss, o);
    float rn = 1.f / sqrtf(ss * (1.f / 512.f) + 1e-8f);
    const float* gs[2] = {G1, G2};
    unsigned short* os[2] = {O1, O2};
    float* scs[2] = {S1, S2};
#pragma unroll
    for (int pass = 0; pass < 2; ++pass) {
        float4 ga = *(const float4*)(gs[pass] + lane * 8);
        float4 gb = *(const float4*)(gs[pass] + lane * 8 + 4);
        float v[8] = {a.x*rn*ga.x, a.y*rn*ga.y, a.z*rn*ga.z, a.w*rn*ga.w,
                      b.x*rn*gb.x, b.y*rn*gb.y, b.z*rn*gb.z, b.w*rn*gb.w};
        float amax = 0.f;
#pragma unroll
        for (int i = 0; i < 8; ++i) amax = fmaxf(amax, fabsf(v[i]));
#pragma unroll
        for (int o = 32; o > 0; o >>= 1) amax = fmaxf(amax, __shfl_xor(amax, o));
        float mx = fmaxf(amax, 1e-5f);
        float scale = 127.f / mx;
        u16x8 qv;
#pragma unroll
        for (int i = 0; i < 8; ++i) {
            float tq = rintf(v[i] * scale);
            tq = fminf(fmaxf(tq, -128.f), 127.f);
            qv[i] = f2bf(tq);
        }
        *reinterpret_cast<u16x8*>(os[pass] + (size_t)r * DD + lane * 8) = qv;
        if (lane == 0) scs[pass][r] = mx / 127.f;
    }
}

// ---------------- DoRA delta: qf = tmp @ B^T (bf16 out), both passes ----------------
__global__ void k_lora2(const float* __restrict__ tmp_x, const float* __restrict__ tmp_c,
                        const float* __restrict__ B_x, const float* __restrict__ B_c,
                        unsigned short* __restrict__ qf1, unsigned short* __restrict__ qf2) {
    int idx = blockIdx.x * 256 + threadIdx.x;   // over 20480*512
    int m2 = idx >> 9, n2 = idx & 511;
    const float* tr;
    const float* br;
    unsigned short* out;
    if (m2 < 16384) {
        tr = tmp_x + (size_t)m2 * 16; br = B_x + (size_t)n2 * 16; out = qf1 + idx;
    } else {
        tr = tmp_c + (size_t)(m2 - 16384) * 16; br = B_c + (size_t)n2 * 16;
        out = qf2 + (idx - 8388608);
    }
    const float4* t4 = (const float4*)tr;
    const float4* b4 = (const float4*)br;
    float acc = 0.f;
#pragma unroll
    for (int rr = 0; rr < 4; ++rr) {
        float4 ta = t4[rr], ba = b4[rr];
        acc += ta.x*ba.x + ta.y*ba.y + ta.z*ba.z + ta.w*ba.w;
    }
    *out = f2bf(acc);
}

// ---------------- combine attn partials (bf16) + RMSNorm + quant, both passes ----------------
__global__ void k_rmsq_combine(const unsigned short* __restrict__ Op_a, const float* __restrict__ Lp_a,
                               const float* __restrict__ g_a, unsigned short* __restrict__ out_a,
                               float* __restrict__ sc_a,
                               const unsigned short* __restrict__ Op_b, const float* __restrict__ Lp_b,
                               const float* __restrict__ g_b, unsigned short* __restrict__ out_b,
                               float* __restrict__ sc_b) {
    int row = blockIdx.x;
    int lane = threadIdx.x;
    bool pb = (row >= 16384);
    int r = pb ? row - 16384 : row;
    int S = pb ? 2 : 1;
    int lognq = pb ? 10 : 12;
    const unsigned short* Op = pb ? Op_b : Op_a;
    const float* Lp = pb ? Lp_b : Lp_a;
    const float* g  = pb ? g_b : g_a;
    unsigned short* out = pb ? out_b : out_a;
    float* a_inv = pb ? sc_b : sc_a;

    int Nq = 1 << lognq;
    int b = r >> lognq, q = r & (Nq - 1);
    int h = lane >> 3;
    float l = 0.f;
    float u[8] = {};
    for (int s = 0; s < S; ++s) {
        l += Lp[((size_t)(s * 4 + b) * 8 + h) * Nq + q];
        u16x8 ov = *reinterpret_cast<const u16x8*>(
            Op + ((size_t)(s * 4 + b) * Nq + q) * 512 + lane * 8);
#pragma unroll
        for (int i = 0; i < 8; ++i) u[i] += bf2f(ov[i]);
    }
    float invl = 1.f / l;
#pragma unroll
    for (int i = 0; i < 8; ++i) u[i] *= invl;
    float ss = 0.f;
#pragma unroll
    for (int i = 0; i < 8; ++i) ss += u[i] * u[i];
#pragma unroll
    for (int o = 32; o > 0; o >>= 1) ss += __shfl_xor(ss, o);
    float rn = 1.f / sqrtf(ss * (1.f / 512.f) + 1e-8f);
    float4 ga = *(const float4*)(g + lane * 8);
    float4 gb = *(const float4*)(g + lane * 8 + 4);
    float v[8] = {u[0]*rn*ga.x, u[1]*rn*ga.y, u[2]*rn*ga.z, u[3]*rn*ga.w,
                  u[4]*rn*gb.x, u[5]*rn*gb.y, u[6]*rn*gb.z, u[7]*rn*gb.w};
    float amax = 0.f;
#pragma unroll
    for (int i = 0; i < 8; ++i) amax = fmaxf(amax, fabsf(v[i]));
#pragma unroll
    for (int o = 32; o > 0; o >>= 1) amax = fmaxf(amax, __shfl_xor(amax, o));
    float mx = fmaxf(amax, 1e-5f);
    float scale = 127.f / mx;
    u16x8 qv;
#pragma unroll
    for (int i = 0; i < 8; ++i) {
        float tq = rintf(v[i] * scale);
        tq = fminf(fmaxf(tq, -128.f), 127.f);
        qv[i] = f2bf(tq);
    }
    *reinterpret_cast<u16x8*>(out + (size_t)r * DD + lane * 8) = qv;
    if (lane == 0) a_inv[r] = mx / 127.f;
}

// ---------------- merged Q + KV projection GEMM (one launch, 1920 blocks) ----------------
// bid < 1280: KV-proj (MODE4): Kb [b][h][key][64], Vt [b][h][d][keyp] (key-permuted).
// bid >= 1280: Q-proj (MODE3): Qb bf16 = (acc*as + mag[h]*Dlt) * QSCALE.
__global__ __launch_bounds__(256) void k_gemm_qkv(
    const unsigned short* __restrict__ a3_a, const unsigned short* __restrict__ a3_b,
    const unsigned short* __restrict__ w3_a, const unsigned short* __restrict__ w3_b,
    const float* __restrict__ ai3_a, const float* __restrict__ ai3_b,
    const float* __restrict__ mag_a, const float* __restrict__ mag_b,
    const unsigned short* __restrict__ dl_a, const unsigned short* __restrict__ dl_b,
    unsigned short* __restrict__ Qb_a, unsigned short* __restrict__ Qb_b,
    const unsigned short* __restrict__ a4_a, const unsigned short* __restrict__ a4_b,
    const unsigned short* __restrict__ w4_a, const unsigned short* __restrict__ w4_b,
    const float* __restrict__ ai4_a, const float* __restrict__ ai4_b,
    unsigned short* __restrict__ Kb_a, unsigned short* __restrict__ Kb_b,
    unsigned short* __restrict__ Vt_a, unsigned short* __restrict__ Vt_b,
    const float* __restrict__ winv) {
    __shared__ __align__(16) unsigned short sA[128 * 32];
    __shared__ __align__(16) unsigned short sB[128 * 32];
    int bid = blockIdx.x;
    bool isQ = (bid >= 1280);
    const unsigned short *Aq, *Wq;
    const float* a_inv;
    float wv;
    int m0, n0, logn;
    bool pb;
    if (!isQ) {
        n0 = (bid & 7) * 128;
        int my = bid >> 3;              // 0..159
        pb = my >= 32;
        m0 = (pb ? my - 32 : my) * 128;
        Aq = pb ? a4_b : a4_a;  Wq = pb ? w4_b : w4_a;
        a_inv = pb ? ai4_b : ai4_a;
        logn = pb ? 12 : 10;
        wv = winv[pb ? 4 : 1];
    } else {
        int b2 = bid - 1280;
        n0 = (b2 & 3) * 128;
        int my = b2 >> 2;               // 0..159
        pb = my >= 128;
        m0 = (pb ? my - 128 : my) * 128;
        Aq = pb ? a3_b : a3_a;  Wq = pb ? w3_b : w3_a;
        a_inv = pb ? ai3_b : ai3_a;
        logn = pb ? 10 : 12;
        wv = winv[pb ? 3 : 0];
    }

    int t = threadIdx.x;
    int w = t >> 6, lane = t & 63;
    int wm = w >> 1, wn = w & 1;
    int lr = lane & 15, lg = lane >> 4;
    int row_st = t >> 2, chunk = t & 3;
    f32x4 acc[4][4] = {};

    for (int k0 = 0; k0 < 512; k0 += 32) {
        __syncthreads();
#pragma unroll
        for (int i = 0; i < 2; ++i) {
            int row = i * 64 + row_st;
            GLOAD16(Aq + (size_t)(m0 + row) * 512 + k0 + chunk * 8, sA + ((size_t)i * 256 + t) * 8);
            GLOAD16(Wq + (size_t)(n0 + row) * 512 + k0 + chunk * 8, sB + ((size_t)i * 256 + t) * 8);
        }
        asm volatile("s_waitcnt vmcnt(0)" ::: "memory");
        __syncthreads();
        bf16x8 af[4], bfr[4];
#pragma unroll
        for (int mt = 0; mt < 4; ++mt)
            af[mt] = *reinterpret_cast<const bf16x8*>(&sA[(wm * 64 + mt * 16 + lr) * 32 + lg * 8]);
#pragma unroll
        for (int nt = 0; nt < 4; ++nt)
            bfr[nt] = *reinterpret_cast<const bf16x8*>(&sB[(wn * 64 + nt * 16 + lr) * 32 + lg * 8]);
#pragma unroll
        for (int mt = 0; mt < 4; ++mt)
#pragma unroll
            for (int nt = 0; nt < 4; ++nt)
                acc[mt][nt] = __builtin_amdgcn_mfma_f32_16x16x32_bf16(af[mt], bfr[nt], acc[mt][nt], 0, 0, 0);
    }

    if (!isQ) {
        unsigned short* OutB = pb ? Kb_b : Kb_a;
        unsigned short* OutB2 = pb ? Vt_b : Vt_a;
        const bool isV = (n0 >= 512);
        const int Nc = 1 << logn;
#pragma unroll
        for (int mt = 0; mt < 4; ++mt) {
            int mb = m0 + wm * 64 + mt * 16 + lg * 4;
            int b = mb >> logn, key = mb & (Nc - 1);
            float as_[4];
#pragma unroll
            for (int r = 0; r < 4; ++r) as_[r] = a_inv[mb + r] * wv;
#pragma unroll
            for (int nt = 0; nt < 4; ++nt) {
                int n = n0 + wn * 64 + nt * 16 + lr;
                int n2 = isV ? (n - 512) : n;
                int h = n2 >> 6, dd = n2 & 63;
                if (isV) {
                    // permuted key position within each 32-group (attn A-frag layout)
                    int i0 = key & 31;
                    int keyp = (key & ~31) | (((i0 >> 2) & 3) * 8 + ((i0 >> 4) & 1) * 4);
                    ushort4 v;
                    v.x = f2bf(acc[mt][nt][0] * as_[0]);
                    v.y = f2bf(acc[mt][nt][1] * as_[1]);
                    v.z = f2bf(acc[mt][nt][2] * as_[2]);
                    v.w = f2bf(acc[mt][nt][3] * as_[3]);
                    *reinterpret_cast<ushort4*>(
                        OutB2 + ((size_t)(b * NHEAD + h) * 64 + dd) * Nc + keyp) = v;
                } else {
#pragma unroll
                    for (int r = 0; r < 4; ++r)
                        OutB[((size_t)(b * NHEAD + h) * Nc + key + r) * 64 + dd] =
                            f2bf(acc[mt][nt][r] * as_[r]);
                }
            }
        }
    } else {
        const float* Extra = pb ? mag_b : mag_a;
        const unsigned short* Dlt = pb ? dl_b : dl_a;
        unsigned short* OutB = pb ? Qb_b : Qb_a;
#pragma unroll
        for (int mt = 0; mt < 4; ++mt) {
#pragma unroll
            for (int r = 0; r < 4; ++r) {
                int m = m0 + wm * 64 + mt * 16 + lg * 4 + r;
                float as = a_inv[m] * wv;
                int b = m >> logn, q = m & ((1 << logn) - 1);
#pragma unroll
                for (int nt = 0; nt < 4; ++nt) {
                    int n = n0 + wn * 64 + nt * 16 + lr;
                    float dl = bf2f(Dlt[(size_t)m * 512 + n]);
                    float val = acc[mt][nt][r] * as + Extra[n >> 6] * dl;
                    int h = n >> 6, d = n & 63;
                    OutB[((((size_t)(b * NHEAD + h)) << logn) + q) * 64 + d] =
                        f2bf(val * QSCALE);
                }
            }
        }
    }
}

// ---------------- output projection GEMM + residual, both passes ----------------
__global__ __launch_bounds__(256) void k_gemm_out(
    const unsigned short* __restrict__ a_a, const unsigned short* __restrict__ a_b,
    const unsigned short* __restrict__ w_a, const unsigned short* __restrict__ w_b,
    const float* __restrict__ ai_a, const float* __restrict__ ai_b,
    const float* __restrict__ winv,
    const float* __restrict__ Ex_a, const float* __restrict__ Ex_b,
    float* __restrict__ OF_a, float* __restrict__ OF_b) {
    __shared__ __align__(16) unsigned short sA[128 * 32];
    __shared__ __align__(16) unsigned short sB[128 * 32];
    bool pb = ((int)blockIdx.y >= 128);
    const unsigned short* Aq = pb ? a_b : a_a;
    const unsigned short* Wq = pb ? w_b : w_a;
    const float* a_inv = pb ? ai_b : ai_a;
    const float* Extra = pb ? Ex_b : Ex_a;
    float* OutF = pb ? OF_b : OF_a;
    float wv = winv[pb ? 5 : 2];
    int m0 = (pb ? (int)blockIdx.y - 128 : (int)blockIdx.y) * 128;
    int n0 = blockIdx.x * 128;

    int t = threadIdx.x;
    int w = t >> 6, lane = t & 63;
    int wm = w >> 1, wn = w & 1;
    int lr = lane & 15, lg = lane >> 4;
    int row_st = t >> 2, chunk = t & 3;
    f32x4 acc[4][4] = {};

    for (int k0 = 0; k0 < 512; k0 += 32) {
        __syncthreads();
#pragma unroll
        for (int i = 0; i < 2; ++i) {
            int row = i * 64 + row_st;
            GLOAD16(Aq + (size_t)(m0 + row) * 512 + k0 + chunk * 8, sA + ((size_t)i * 256 + t) * 8);
            GLOAD16(Wq + (size_t)(n0 + row) * 512 + k0 + chunk * 8, sB + ((size_t)i * 256 + t) * 8);
        }
        asm volatile("s_waitcnt vmcnt(0)" ::: "memory");
        __syncthreads();
        bf16x8 af[4], bfr[4];
#pragma unroll
        for (int mt = 0; mt < 4; ++mt)
            af[mt] = *reinterpret_cast<const bf16x8*>(&sA[(wm * 64 + mt * 16 + lr) * 32 + lg * 8]);
#pragma unroll
        for (int nt = 0; nt < 4; ++nt)
            bfr[nt] = *reinterpret_cast<const bf16x8*>(&sB[(wn * 64 + nt * 16 + lr) * 32 + lg * 8]);
#pragma unroll
        for (int mt = 0; mt < 4; ++mt)
#pragma unroll
            for (int nt = 0; nt < 4; ++nt)
                acc[mt][nt] = __builtin_amdgcn_mfma_f32_16x16x32_bf16(af[mt], bfr[nt], acc[mt][nt], 0, 0, 0);
    }

#pragma unroll
    for (int mt = 0; mt < 4; ++mt) {
#pragma unroll
        for (int r = 0; r < 4; ++r) {
            int m = m0 + wm * 64 + mt * 16 + lg * 4 + r;
            float as = a_inv[m] * wv;
#pragma unroll
            for (int nt = 0; nt < 4; ++nt) {
                int n = n0 + wn * 64 + nt * 16 + lr;
                size_t idx = (size_t)m * 512 + n;
                OutF[idx] = acc[mt][nt][r] * as + Extra[idx];
            }
        }
    }
}

// ---------------- flash attention: swapped-QK^T, in-register P, double-buffered LDS ----------------
// 768 blocks: bid<256 = pass2 (heavy, dispatched first), bid>=256 = pass1.
// 512 threads = 8 waves, 32 q/wave. One barrier per 64-key tile (K/V double buffer).
// bf16 unnormalized O partials + f32 row sums; combine kernel normalizes.
__global__ __launch_bounds__(512) void k_attn_mfma(
    const unsigned short* __restrict__ Qb_a, const unsigned short* __restrict__ Kb_a,
    const unsigned short* __restrict__ Vt_a, unsigned short* __restrict__ Op_a,
    float* __restrict__ Lp_a,
    const unsigned short* __restrict__ Qb_b, const unsigned short* __restrict__ Kb_b,
    const unsigned short* __restrict__ Vt_b, unsigned short* __restrict__ Op_b,
    float* __restrict__ Lp_b) {
    __shared__ unsigned short sK[2][64][72];
    __shared__ unsigned short sVt[2][64][72];
    int t = threadIdx.x;
    int w = t >> 6, lane = t & 63;
    int lr = lane & 15, lg = lane >> 4;

    int bid = blockIdx.x;
    bool pb = (bid < 256);
    int lb = pb ? bid : bid - 256;
    const unsigned short* Qb = pb ? Qb_b : Qb_a;
    const unsigned short* Kb = pb ? Kb_b : Kb_a;
    const unsigned short* Vt = pb ? Vt_b : Vt_a;
    unsigned short* Opart = pb ? Op_b : Op_a;
    float* Lpart = pb ? Lp_b : Lp_a;
    int Nq = pb ? 1024 : 4096;
    int Nc = pb ? 4096 : 1024;
    int S = pb ? 2 : 1;
    int LOGS = pb ? 1 : 0;
    int nqs = pb ? 2 : 4;

    int j = lb >> 3;
    int s = j & (S - 1);
    int j2 = j >> LOGS;
    int qblk = j2 & ((1 << nqs) - 1);
    int bh = ((lb & 7) << 2) | (j2 >> nqs);   // XCD-local bh groups
    int b = bh >> 3, h = bh & 7;
    int q0 = qblk * 256 + w * 32;

    bf16x8 aq[2][2];
#pragma unroll
    for (int qt = 0; qt < 2; ++qt) {
        const unsigned short* qbase = Qb + ((size_t)bh * Nq + q0 + qt * 16 + lr) * 64 + lg * 8;
        aq[qt][0] = *reinterpret_cast<const bf16x8*>(qbase);
        aq[qt][1] = *reinterpret_cast<const bf16x8*>(qbase + 32);
    }

    u16x8 ou;
#pragma unroll
    for (int jj = 0; jj < 8; ++jj) ou[jj] = (lr == 0) ? 0x3F80 : 0;
    bf16x8 onesf = __builtin_bit_cast(bf16x8, ou);

    f32x4 o[2][4] = {};
    f32x4 osum[2] = {};

    const unsigned short* kglob = Kb + (size_t)bh * Nc * 64;
    const unsigned short* vglob = Vt + (size_t)bh * 64 * (size_t)Nc;

    int srow = t >> 3, sseg = t & 7;
    const unsigned short* kptr = kglob + (size_t)srow * 64 + sseg * 8;
    const unsigned short* vptr = vglob + (size_t)srow * Nc + sseg * 8;

    int kts = s * (Nc >> LOGS);
    int nt = (Nc >> LOGS) >> 6;   // 16 (pass1) or 32 (pass2)

    // prologue: tile 0 -> buf0; prefetch tile 1
    bf16x8 rK = *reinterpret_cast<const bf16x8*>(kptr + (size_t)kts * 64);
    bf16x8 rV = *reinterpret_cast<const bf16x8*>(vptr + kts);
    *reinterpret_cast<bf16x8*>(&sK[0][srow][sseg * 8]) = rK;
    *reinterpret_cast<bf16x8*>(&sVt[0][srow][sseg * 8]) = rV;
    rK = *reinterpret_cast<const bf16x8*>(kptr + (size_t)(kts + 64) * 64);
    rV = *reinterpret_cast<const bf16x8*>(vptr + kts + 64);
    __syncthreads();

    int cur = 0;
    for (int ti = 0; ti < nt; ++ti) {
        if (ti + 1 < nt) {
            // publish tile ti+1 into the other buffer; safe: all waves finished
            // reading it (as tile ti-1's buffer) at the previous barrier.
            *reinterpret_cast<bf16x8*>(&sK[cur ^ 1][srow][sseg * 8]) = rK;
            *reinterpret_cast<bf16x8*>(&sVt[cur ^ 1][srow][sseg * 8]) = rV;
            if (ti + 2 < nt) {
                int knext = kts + (ti + 2) * 64;
                rK = *reinterpret_cast<const bf16x8*>(kptr + (size_t)knext * 64);
                rV = *reinterpret_cast<const bf16x8*>(vptr + knext);
            }
        }
        // S = K Q^T (swapped): lane holds S[key=kt*16+lg*4+r][query=lr];
        // exp2 -> bf16 packs directly into PV A-fragments.
        bf16x8 pa0[2], pa1[2];
#pragma unroll
        for (int kt = 0; kt < 4; ++kt) {
            bf16x8 bk0 = *reinterpret_cast<const bf16x8*>(&sK[cur][kt * 16 + lr][lg * 8]);
            bf16x8 bk1 = *reinterpret_cast<const bf16x8*>(&sK[cur][kt * 16 + lr][32 + lg * 8]);
            f32x4 a0 = {}, a1 = {};
            __builtin_amdgcn_s_setprio(1);
            a0 = __builtin_amdgcn_mfma_f32_16x16x32_bf16(bk0, aq[0][0], a0, 0, 0, 0);
            a1 = __builtin_amdgcn_mfma_f32_16x16x32_bf16(bk0, aq[1][0], a1, 0, 0, 0);
            a0 = __builtin_amdgcn_mfma_f32_16x16x32_bf16(bk1, aq[0][1], a0, 0, 0, 0);
            a1 = __builtin_amdgcn_mfma_f32_16x16x32_bf16(bk1, aq[1][1], a1, 0, 0, 0);
            __builtin_amdgcn_s_setprio(0);
            const int hb = (kt & 1) * 4;
#pragma unroll
            for (int r = 0; r < 4; ++r) {
                if (kt < 2) {
                    pa0[0][hb + r] = (__bf16)EXP2F(fminf(a0[r], 43.f));
                    pa1[0][hb + r] = (__bf16)EXP2F(fminf(a1[r], 43.f));
                } else {
                    pa0[1][hb + r] = (__bf16)EXP2F(fminf(a0[r], 43.f));
                    pa1[1][hb + r] = (__bf16)EXP2F(fminf(a1[r], 43.f));
                }
            }
        }
        // O += P @ V ; osum += P @ ones  (Vt pre-permuted to match pa's key order)
#pragma unroll
        for (int kg = 0; kg < 2; ++kg) {
            __builtin_amdgcn_s_setprio(1);
#pragma unroll
            for (int dt = 0; dt < 4; ++dt) {
                bf16x8 vb = *reinterpret_cast<const bf16x8*>(&sVt[cur][dt * 16 + lr][kg * 32 + lg * 8]);
                o[0][dt] = __builtin_amdgcn_mfma_f32_16x16x32_bf16(pa0[kg], vb, o[0][dt], 0, 0, 0);
                o[1][dt] = __builtin_amdgcn_mfma_f32_16x16x32_bf16(pa1[kg], vb, o[1][dt], 0, 0, 0);
            }
            osum[0] = __builtin_amdgcn_mfma_f32_16x16x32_bf16(pa0[kg], onesf, osum[0], 0, 0, 0);
            osum[1] = __builtin_amdgcn_mfma_f32_16x16x32_bf16(pa1[kg], onesf, osum[1], 0, 0, 0);
            __builtin_amdgcn_s_setprio(0);
        }
        __syncthreads();
        cur ^= 1;
    }
    // write unnormalized bf16 partials
    unsigned short* obase = Opart + ((size_t)(s * 4 + b) * Nq + q0) * 512 + h * 64;
#pragma unroll
    for (int qt = 0; qt < 2; ++qt)
#pragma unroll
        for (int dt = 0; dt < 4; ++dt)
#pragma unroll
            for (int r = 0; r < 4; ++r)
                obase[(size_t)(qt * 16 + lg * 4 + r) * 512 + dt * 16 + lr] = f2bf(o[qt][dt][r]);
    if (lr == 0) {
        float* lbase = Lpart + ((size_t)(s * 4 + b) * 8 + h) * Nq + q0;
#pragma unroll
        for (int qt = 0; qt < 2; ++qt)
#pragma unroll
            for (int r = 0; r < 4; ++r)
                lbase[qt * 16 + lg * 4 + r] = osum[qt][r];
    }
}

// ---------------- host side ----------------
extern "C" void kernel_launch(void* const* d_in, const int* in_sizes, int n_in,
                              void* d_out, int out_size, void* d_ws, size_t ws_size,
                              hipStream_t stream) {
    const float* x     = (const float*)d_in[0];
    const float* c     = (const float*)d_in[1];
    const float* Wq_x  = (const float*)d_in[2];
    const float* g_qx  = (const float*)d_in[3];
    const float* Wkv_c = (const float*)d_in[4];
    const float* g_kvc = (const float*)d_in[5];
    const float* A_x   = (const float*)d_in[6];
    const float* B_x   = (const float*)d_in[7];
    const float* mag_x = (const float*)d_in[8];
    const float* Wp_x  = (const float*)d_in[9];
    const float* g_px  = (const float*)d_in[10];
    const float* Wq_c  = (const float*)d_in[11];
    const float* g_qc  = (const float*)d_in[12];
    const float* Wkv_x = (const float*)d_in[13];
    const float* g_kvx = (const float*)d_in[14];
    const float* A_c   = (const float*)d_in[15];
    const float* B_c   = (const float*)d_in[16];
    const float* mag_c = (const float*)d_in[17];
    const float* Wp_c  = (const float*)d_in[18];
    const float* g_pc  = (const float*)d_in[19];

    float* ws = (float*)d_ws;
    unsigned short* Wb = (unsigned short*)ws;
    const size_t Woff[6] = {0, 262144, 786432, 1048576, 1310720, 1835008}; // u16 units
    float* part  = ws + 1048576;
    float* scal  = part + 192;
    float* winv  = scal + 8;
    float* sc_xq  = ws + 1049600;
    float* sc_xkv = sc_xq + 16384;
    float* sc_cq  = sc_xkv + 16384;
    float* sc_ckv = sc_cq + 4096;
    float* sc_o1  = sc_ckv + 4096;
    float* sc_o2  = sc_o1 + 16384;
    float* tmp_x  = ws + 1111040;                    // 262144
    float* tmp_c  = tmp_x + 262144;                  // 65536  -> ends 1438720
    float* actblk = ws + 1438720;                    // acts / Opart1 overlay
    unsigned short* act_xq  = (unsigned short*)actblk;                  // 4194304 f
    unsigned short* act_xkv = (unsigned short*)(actblk + 4194304);      // 4194304 f
    unsigned short* act_cq  = (unsigned short*)(actblk + 8388608);      // 1048576 f
    unsigned short* act_ckv = (unsigned short*)(actblk + 9437184);      // 1048576 f
    unsigned short* Opart1 = (unsigned short*)actblk;  // 8.4M u16 over act_xq (dead)
    float* qf1_f  = ws + 11924480;                   // 4194304 f
    unsigned short* Opart2 = (unsigned short*)qf1_f; // 4.2M u16 (qf1 dead by attn)
    float* qf2_f  = ws + 16118784;                   // 1048576 f
    float* Qb1_f  = ws + 17167360;                   // 4194304 f (-> act_o1)
    float* Qb2_f  = ws + 21361664;                   // 1048576 f (-> act_o2)
    float* Kb1_f  = ws + 22410240;                   // 1048576 f
    float* Vt1_f  = ws + 23458816;                   // 1048576 f
    float* Kb2_f  = ws + 24507392;                   // 4194304 f
    float* Vt2_f  = ws + 28701696;                   // 4194304 f
    float* Lpart1 = ws + 32896000;                   // 131072 f
    float* Lpart2 = ws + 33027072;                   // 65536 f -> ends 33092608

    unsigned short* qf1 = (unsigned short*)qf1_f;
    unsigned short* qf2 = (unsigned short*)qf2_f;
    unsigned short* Qb1 = (unsigned short*)Qb1_f;
    unsigned short* Qb2 = (unsigned short*)Qb2_f;
    unsigned short* Kb1 = (unsigned short*)Kb1_f;
    unsigned short* Vt1 = (unsigned short*)Vt1_f;
    unsigned short* Kb2 = (unsigned short*)Kb2_f;
    unsigned short* Vt2 = (unsigned short*)Vt2_f;
    unsigned short* act_o1 = Qb1;
    unsigned short* act_o2 = Qb2;

    size_t need = (size_t)33092608 * sizeof(float);   // ~132.4 MB
    if (ws_size < need) return;

    float* outx = (float*)d_out;
    float* outc = outx + (size_t)4 * 4096 * 512;

    // weight prep (3 launches)
    k_wabs_all<<<192, 256, 0, stream>>>(Wq_x, Wkv_c, Wp_x, Wq_c, Wkv_x, Wp_c, part);
    k_wfinal<<<1, 64, 0, stream>>>(part, scal, winv);
    k_wquant_all<<<8192, 256, 0, stream>>>(Wq_x, Wkv_c, Wp_x, Wq_c, Wkv_x, Wp_c, Wb, scal);

    // all activations + DoRA tmp for BOTH passes (one launch)
    k_rmsq_dual<<<20480, 64, 0, stream>>>(x, c, g_qx, g_kvx, g_qc, g_kvc,
                                          act_xq, act_xkv, act_cq, act_ckv,
                                          sc_xq, sc_xkv, sc_cq, sc_ckv,
                                          A_x, A_c, tmp_x, tmp_c);
    // DoRA deltas, both passes
    k_lora2<<<40960, 256, 0, stream>>>(tmp_x, tmp_c, B_x, B_c, qf1, qf2);

    // merged Q + KV projections, both passes (KV blocks first)
    k_gemm_qkv<<<1920, 256, 0, stream>>>(
        act_xq, act_cq, Wb + Woff[0], Wb + Woff[3], sc_xq, sc_cq,
        mag_x, mag_c, qf1, qf2, Qb1, Qb2,
        act_ckv, act_xkv, Wb + Woff[1], Wb + Woff[4], sc_ckv, sc_xkv,
        Kb1, Kb2, Vt1, Vt2, winv);

    // attention, both passes (heavy pass2 blocks first)
    k_attn_mfma<<<768, 512, 0, stream>>>(Qb1, Kb1, Vt1, Opart1, Lpart1,
                                         Qb2, Kb2, Vt2, Opart2, Lpart2);

    // combine + RMSNorm + quant, both passes
    k_rmsq_combine<<<20480, 64, 0, stream>>>(Opart1, Lpart1, g_px, act_o1, sc_o1,
                                             Opart2, Lpart2, g_pc, act_o2, sc_o2);

    // output projections + residual, both passes
    k_gemm_out<<<dim3(4, 160), 256, 0, stream>>>(
        act_o1, act_o2, Wb + Woff[2], Wb + Woff[5], sc_o1, sc_o2, winv,
        x, c, outx, outc);
}

// Round 12
// 283.937 us; speedup vs baseline: 59.0006x; 1.1160x over previous
//
#include <hip/hip_runtime.h>
#include <math.h>

#define DD 512
#define NHEAD 8
#define HDIM 64

typedef __bf16 bf16x8 __attribute__((ext_vector_type(8)));
typedef unsigned short u16x8 __attribute__((ext_vector_type(8)));
typedef float f32x4 __attribute__((ext_vector_type(4)));

#if __has_builtin(__builtin_amdgcn_exp2f)
#define EXP2F(x) __builtin_amdgcn_exp2f(x)
#else
#define EXP2F(x) exp2f(x)
#endif

#define QSCALE 0.18033688f  /* (1/8) * log2(e): exp2 domain */

static __device__ __forceinline__ unsigned short f2bf(float f) {
    unsigned u = __builtin_bit_cast(unsigned, f);
    u += 0x7fffu + ((u >> 16) & 1u);   // round-to-nearest-even
    return (unsigned short)(u >> 16);
}
static __device__ __forceinline__ float bf2f(unsigned short u) {
    return __builtin_bit_cast(float, (unsigned)u << 16);
}

// sum of part[mid*32 .. +31] via wave butterfly; deterministic, same order everywhere
static __device__ __forceinline__ float wsum32(const float* __restrict__ part, int mid) {
    int l = threadIdx.x & 63;
    float v = (l < 32) ? part[mid * 32 + l] : 0.f;
#pragma unroll
    for (int o = 16; o > 0; o >>= 1) v += __shfl_xor(v, o);
    return __shfl(v, 0);
}

#define GLOAD16(g, l)                                                          \
    __builtin_amdgcn_global_load_lds(                                          \
        (__attribute__((address_space(1))) void*)(g),                          \
        (__attribute__((address_space(3))) void*)(l), 16, 0, 0)

#define BSTEP(s, hc)                                                           \
    {                                                                          \
        _Pragma("unroll")                                                      \
        for (int i = 0; i < (hc); ++i) {                                       \
            float send = (lane & (s)) ? p[i] : p[i + (hc)];                    \
            float recv = __shfl_xor(send, (s));                                \
            p[i] = ((lane & (s)) ? p[i + (hc)] : p[i]) + recv;                 \
        }                                                                      \
    }

// ---------------- prep1: weight |.| partials (192 blocks) + RMSNorm/quant/DoRA (5120 blocks) ----------------
__global__ __launch_bounds__(256) void k_prep1(
    const float* __restrict__ W0, const float* __restrict__ W1,
    const float* __restrict__ W2, const float* __restrict__ W3,
    const float* __restrict__ W4, const float* __restrict__ W5,
    float* __restrict__ part,
    const float* __restrict__ x, const float* __restrict__ c,
    const float* __restrict__ g_qx, const float* __restrict__ g_kvx,
    const float* __restrict__ g_qc, const float* __restrict__ g_kvc,
    unsigned short* __restrict__ a_xq, unsigned short* __restrict__ a_xkv,
    unsigned short* __restrict__ a_cq, unsigned short* __restrict__ a_ckv,
    float* __restrict__ s_xq, float* __restrict__ s_xkv,
    float* __restrict__ s_cq, float* __restrict__ s_ckv,
    const float* __restrict__ A_x, const float* __restrict__ A_c,
    float* __restrict__ tmp_x, float* __restrict__ tmp_c) {
    int t = threadIdx.x;
    if (blockIdx.x < 192) {
        const float* Ws[6] = {W0, W1, W2, W3, W4, W5};
        const int cnt[6] = {262144, 524288, 262144, 262144, 524288, 262144};
        int mid = blockIdx.x >> 5, lb = blockIdx.x & 31;
        const float* W = Ws[mid];
        int n = cnt[mid];
        float s = 0.f;
        for (int i = lb * 256 + t; i < n; i += 32 * 256) s += fabsf(W[i]);
        __shared__ float red[4];
#pragma unroll
        for (int o = 32; o > 0; o >>= 1) s += __shfl_down(s, o);
        if ((t & 63) == 0) red[t >> 6] = s;
        __syncthreads();
        if (t == 0) part[blockIdx.x] = red[0] + red[1] + red[2] + red[3];
        return;
    }
    int w = t >> 6, lane = t & 63;
    int row = (int)(blockIdx.x - 192) * 4 + w;
    bool pc = (row >= 16384);
    int r = pc ? row - 16384 : row;
    const float* xr = (pc ? c : x) + (size_t)r * DD;
    const float* G1 = pc ? g_qc : g_qx;
    const float* G2 = pc ? g_kvc : g_kvx;
    unsigned short* O1 = pc ? a_cq : a_xq;
    unsigned short* O2 = pc ? a_ckv : a_xkv;
    float* S1 = pc ? s_cq : s_xq;
    float* S2 = pc ? s_ckv : s_xkv;
    const float* AM = pc ? A_c : A_x;
    float* TMP = pc ? tmp_c : tmp_x;

    float4 a = *(const float4*)(xr + lane * 8);
    float4 b = *(const float4*)(xr + lane * 8 + 4);
    float p[16];
#pragma unroll
    for (int cc = 0; cc < 16; ++cc) {
        const float4* ar = (const float4*)(AM + (size_t)cc * DD + lane * 8);
        float4 aa = ar[0], ab = ar[1];
        p[cc] = a.x*aa.x + a.y*aa.y + a.z*aa.z + a.w*aa.w
              + b.x*ab.x + b.y*ab.y + b.z*ab.z + b.w*ab.w;
    }
    BSTEP(1, 8) BSTEP(2, 4) BSTEP(4, 2) BSTEP(8, 1)
    p[0] += __shfl_xor(p[0], 16);
    p[0] += __shfl_xor(p[0], 32);
    if (lane < 16) {
        int cidx = ((lane & 1) << 3) | ((lane & 2) << 1) | ((lane & 4) >> 1) | ((lane & 8) >> 3);
        TMP[(size_t)r * 16 + cidx] = p[0];
    }
    float ss = a.x*a.x + a.y*a.y + a.z*a.z + a.w*a.w
             + b.x*b.x + b.y*b.y + b.z*b.z + b.w*b.w;
#pragma unroll
    for (int o = 32; o > 0; o >>= 1) ss += __shfl_xor(ss, o);
    float rn = 1.f / sqrtf(ss * (1.f / 512.f) + 1e-8f);
    const float* gs[2] = {G1, G2};
    unsigned short* os[2] = {O1, O2};
    float* scs[2] = {S1, S2};
#pragma unroll
    for (int pass = 0; pass < 2; ++pass) {
        float4 ga = *(const float4*)(gs[pass] + lane * 8);
        float4 gb = *(const float4*)(gs[pass] + lane * 8 + 4);
        float v[8] = {a.x*rn*ga.x, a.y*rn*ga.y, a.z*rn*ga.z, a.w*rn*ga.w,
                      b.x*rn*gb.x, b.y*rn*gb.y, b.z*rn*gb.z, b.w*rn*gb.w};
        float amax = 0.f;
#pragma unroll
        for (int i = 0; i < 8; ++i) amax = fmaxf(amax, fabsf(v[i]));
#pragma unroll
        for (int o = 32; o > 0; o >>= 1) amax = fmaxf(amax, __shfl_xor(amax, o));
        float mx = fmaxf(amax, 1e-5f);
        float scale = 127.f / mx;
        u16x8 qv;
#pragma unroll
        for (int i = 0; i < 8; ++i) {
            float tq = rintf(v[i] * scale);
            tq = fminf(fmaxf(tq, -128.f), 127.f);
            qv[i] = f2bf(tq);
        }
        *reinterpret_cast<u16x8*>(os[pass] + (size_t)r * DD + lane * 8) = qv;
        if (lane == 0) scs[pass][r] = mx / 127.f;
    }
}

// ---------------- prep2: weight ternarize (8192 blocks) + DoRA delta (40960 blocks) ----------------
__global__ __launch_bounds__(256) void k_prep2(
    const float* __restrict__ W0, const float* __restrict__ W1,
    const float* __restrict__ W2, const float* __restrict__ W3,
    const float* __restrict__ W4, const float* __restrict__ W5,
    const float* __restrict__ part, unsigned short* __restrict__ Wq,
    const float* __restrict__ tmp_x, const float* __restrict__ tmp_c,
    const float* __restrict__ B_x, const float* __restrict__ B_c,
    unsigned short* __restrict__ qf1, unsigned short* __restrict__ qf2) {
    if (blockIdx.x < 8192) {
        int e = blockIdx.x * 256 + threadIdx.x;
        const float* Ws[6] = {W0, W1, W2, W3, W4, W5};
        int mid, base;
        if (e < 262144)       { mid = 0; base = 0; }
        else if (e < 786432)  { mid = 1; base = 262144; }
        else if (e < 1048576) { mid = 2; base = 786432; }
        else if (e < 1310720) { mid = 3; base = 1048576; }
        else if (e < 1835008) { mid = 4; base = 1310720; }
        else                  { mid = 5; base = 1835008; }
        float cnt = (mid == 1 || mid == 4) ? 524288.f : 262144.f;
        float mean = fmaxf(wsum32(part, mid) / cnt, 1e-5f);
        float sc = 1.f / mean;
        float t = rintf(Ws[mid][e - base] * sc);
        t = fminf(fmaxf(t, -1.f), 1.f);
        Wq[e] = f2bf(t);
        return;
    }
    int idx = (int)(blockIdx.x - 8192) * 256 + threadIdx.x;   // over 20480*512
    int m2 = idx >> 9, n2 = idx & 511;
    const float* tr;
    const float* br;
    unsigned short* out;
    if (m2 < 16384) {
        tr = tmp_x + (size_t)m2 * 16; br = B_x + (size_t)n2 * 16; out = qf1 + idx;
    } else {
        tr = tmp_c + (size_t)(m2 - 16384) * 16; br = B_c + (size_t)n2 * 16;
        out = qf2 + (idx - 8388608);
    }
    const float4* t4 = (const float4*)tr;
    const float4* b4 = (const float4*)br;
    float acc = 0.f;
#pragma unroll
    for (int rr = 0; rr < 4; ++rr) {
        float4 ta = t4[rr], ba = b4[rr];
        acc += ta.x*ba.x + ta.y*ba.y + ta.z*ba.z + ta.w*ba.w;
    }
    *out = f2bf(acc);
}

// ---------------- combine attn partials (bf16) + RMSNorm + quant, both passes, 4 rows/block ----------------
__global__ __launch_bounds__(256) void k_rmsq_combine(
    const unsigned short* __restrict__ Op_a, const float* __restrict__ Lp_a,
    const float* __restrict__ g_a, unsigned short* __restrict__ out_a,
    float* __restrict__ sc_a,
    const unsigned short* __restrict__ Op_b, const float* __restrict__ Lp_b,
    const float* __restrict__ g_b, unsigned short* __restrict__ out_b,
    float* __restrict__ sc_b) {
    int w = threadIdx.x >> 6, lane = threadIdx.x & 63;
    int row = (int)blockIdx.x * 4 + w;
    bool pb = (row >= 16384);
    int r = pb ? row - 16384 : row;
    int S = pb ? 4 : 1;
    int lognq = pb ? 10 : 12;
    const unsigned short* Op = pb ? Op_b : Op_a;
    const float* Lp = pb ? Lp_b : Lp_a;
    const float* g  = pb ? g_b : g_a;
    unsigned short* out = pb ? out_b : out_a;
    float* a_inv = pb ? sc_b : sc_a;

    int Nq = 1 << lognq;
    int b = r >> lognq, q = r & (Nq - 1);
    int h = lane >> 3;
    float l = 0.f;
    float u[8] = {};
    for (int s = 0; s < S; ++s) {
        l += Lp[((size_t)(s * 4 + b) * 8 + h) * Nq + q];
        u16x8 ov = *reinterpret_cast<const u16x8*>(
            Op + ((size_t)(s * 4 + b) * Nq + q) * 512 + lane * 8);
#pragma unroll
        for (int i = 0; i < 8; ++i) u[i] += bf2f(ov[i]);
    }
    float invl = 1.f / l;
#pragma unroll
    for (int i = 0; i < 8; ++i) u[i] *= invl;
    float ss = 0.f;
#pragma unroll
    for (int i = 0; i < 8; ++i) ss += u[i] * u[i];
#pragma unroll
    for (int o = 32; o > 0; o >>= 1) ss += __shfl_xor(ss, o);
    float rn = 1.f / sqrtf(ss * (1.f / 512.f) + 1e-8f);
    float4 ga = *(const float4*)(g + lane * 8);
    float4 gb = *(const float4*)(g + lane * 8 + 4);
    float v[8] = {u[0]*rn*ga.x, u[1]*rn*ga.y, u[2]*rn*ga.z, u[3]*rn*ga.w,
                  u[4]*rn*gb.x, u[5]*rn*gb.y, u[6]*rn*gb.z, u[7]*rn*gb.w};
    float amax = 0.f;
#pragma unroll
    for (int i = 0; i < 8; ++i) amax = fmaxf(amax, fabsf(v[i]));
#pragma unroll
    for (int o = 32; o > 0; o >>= 1) amax = fmaxf(amax, __shfl_xor(amax, o));
    float mx = fmaxf(amax, 1e-5f);
    float scale = 127.f / mx;
    u16x8 qv;
#pragma unroll
    for (int i = 0; i < 8; ++i) {
        float tq = rintf(v[i] * scale);
        tq = fminf(fmaxf(tq, -128.f), 127.f);
        qv[i] = f2bf(tq);
    }
    *reinterpret_cast<u16x8*>(out + (size_t)r * DD + lane * 8) = qv;
    if (lane == 0) a_inv[r] = mx / 127.f;
}

// ---------------- merged Q + KV projection GEMM (one launch, 1920 blocks) ----------------
__global__ __launch_bounds__(256) void k_gemm_qkv(
    const unsigned short* __restrict__ a3_a, const unsigned short* __restrict__ a3_b,
    const unsigned short* __restrict__ w3_a, const unsigned short* __restrict__ w3_b,
    const float* __restrict__ ai3_a, const float* __restrict__ ai3_b,
    const float* __restrict__ mag_a, const float* __restrict__ mag_b,
    const unsigned short* __restrict__ dl_a, const unsigned short* __restrict__ dl_b,
    unsigned short* __restrict__ Qb_a, unsigned short* __restrict__ Qb_b,
    const unsigned short* __restrict__ a4_a, const unsigned short* __restrict__ a4_b,
    const unsigned short* __restrict__ w4_a, const unsigned short* __restrict__ w4_b,
    const float* __restrict__ ai4_a, const float* __restrict__ ai4_b,
    unsigned short* __restrict__ Kb_a, unsigned short* __restrict__ Kb_b,
    unsigned short* __restrict__ Vt_a, unsigned short* __restrict__ Vt_b,
    const float* __restrict__ part) {
    __shared__ __align__(16) unsigned short sA[128 * 32];
    __shared__ __align__(16) unsigned short sB[128 * 32];
    int bid = blockIdx.x;
    bool isQ = (bid >= 1280);
    const unsigned short *Aq, *Wq;
    const float* a_inv;
    int m0, n0, logn, mid;
    float cnt;
    bool pb;
    if (!isQ) {
        n0 = (bid & 7) * 128;
        int my = bid >> 3;              // 0..159
        pb = my >= 32;
        m0 = (pb ? my - 32 : my) * 128;
        Aq = pb ? a4_b : a4_a;  Wq = pb ? w4_b : w4_a;
        a_inv = pb ? ai4_b : ai4_a;
        logn = pb ? 12 : 10;
        mid = pb ? 4 : 1; cnt = 524288.f;
    } else {
        int b2 = bid - 1280;
        n0 = (b2 & 3) * 128;
        int my = b2 >> 2;               // 0..159
        pb = my >= 128;
        m0 = (pb ? my - 128 : my) * 128;
        Aq = pb ? a3_b : a3_a;  Wq = pb ? w3_b : w3_a;
        a_inv = pb ? ai3_b : ai3_a;
        logn = pb ? 10 : 12;
        mid = pb ? 3 : 0; cnt = 262144.f;
    }
    float wv = fmaxf(wsum32(part, mid) / cnt, 1e-5f);

    int t = threadIdx.x;
    int w = t >> 6, lane = t & 63;
    int wm = w >> 1, wn = w & 1;
    int lr = lane & 15, lg = lane >> 4;
    int row_st = t >> 2, chunk = t & 3;
    f32x4 acc[4][4] = {};

    for (int k0 = 0; k0 < 512; k0 += 32) {
        __syncthreads();
#pragma unroll
        for (int i = 0; i < 2; ++i) {
            int row = i * 64 + row_st;
            GLOAD16(Aq + (size_t)(m0 + row) * 512 + k0 + chunk * 8, sA + ((size_t)i * 256 + t) * 8);
            GLOAD16(Wq + (size_t)(n0 + row) * 512 + k0 + chunk * 8, sB + ((size_t)i * 256 + t) * 8);
        }
        asm volatile("s_waitcnt vmcnt(0)" ::: "memory");
        __syncthreads();
        bf16x8 af[4], bfr[4];
#pragma unroll
        for (int mt = 0; mt < 4; ++mt)
            af[mt] = *reinterpret_cast<const bf16x8*>(&sA[(wm * 64 + mt * 16 + lr) * 32 + lg * 8]);
#pragma unroll
        for (int nt = 0; nt < 4; ++nt)
            bfr[nt] = *reinterpret_cast<const bf16x8*>(&sB[(wn * 64 + nt * 16 + lr) * 32 + lg * 8]);
#pragma unroll
        for (int mt = 0; mt < 4; ++mt)
#pragma unroll
            for (int nt = 0; nt < 4; ++nt)
                acc[mt][nt] = __builtin_amdgcn_mfma_f32_16x16x32_bf16(af[mt], bfr[nt], acc[mt][nt], 0, 0, 0);
    }

    if (!isQ) {
        unsigned short* OutB = pb ? Kb_b : Kb_a;
        unsigned short* OutB2 = pb ? Vt_b : Vt_a;
        const bool isV = (n0 >= 512);
        const int Nc = 1 << logn;
#pragma unroll
        for (int mt = 0; mt < 4; ++mt) {
            int mb = m0 + wm * 64 + mt * 16 + lg * 4;
            int b = mb >> logn, key = mb & (Nc - 1);
            float as_[4];
#pragma unroll
            for (int r = 0; r < 4; ++r) as_[r] = a_inv[mb + r] * wv;
#pragma unroll
            for (int nt = 0; nt < 4; ++nt) {
                int n = n0 + wn * 64 + nt * 16 + lr;
                int n2 = isV ? (n - 512) : n;
                int h = n2 >> 6, dd = n2 & 63;
                if (isV) {
                    int i0 = key & 31;
                    int keyp = (key & ~31) | (((i0 >> 2) & 3) * 8 + ((i0 >> 4) & 1) * 4);
                    ushort4 v;
                    v.x = f2bf(acc[mt][nt][0] * as_[0]);
                    v.y = f2bf(acc[mt][nt][1] * as_[1]);
                    v.z = f2bf(acc[mt][nt][2] * as_[2]);
                    v.w = f2bf(acc[mt][nt][3] * as_[3]);
                    *reinterpret_cast<ushort4*>(
                        OutB2 + ((size_t)(b * NHEAD + h) * 64 + dd) * Nc + keyp) = v;
                } else {
#pragma unroll
                    for (int r = 0; r < 4; ++r)
                        OutB[((size_t)(b * NHEAD + h) * Nc + key + r) * 64 + dd] =
                            f2bf(acc[mt][nt][r] * as_[r]);
                }
            }
        }
    } else {
        const float* Extra = pb ? mag_b : mag_a;
        const unsigned short* Dlt = pb ? dl_b : dl_a;
        unsigned short* OutB = pb ? Qb_b : Qb_a;
#pragma unroll
        for (int mt = 0; mt < 4; ++mt) {
#pragma unroll
            for (int r = 0; r < 4; ++r) {
                int m = m0 + wm * 64 + mt * 16 + lg * 4 + r;
                float as = a_inv[m] * wv;
                int b = m >> logn, q = m & ((1 << logn) - 1);
#pragma unroll
                for (int nt = 0; nt < 4; ++nt) {
                    int n = n0 + wn * 64 + nt * 16 + lr;
                    float dl = bf2f(Dlt[(size_t)m * 512 + n]);
                    float val = acc[mt][nt][r] * as + Extra[n >> 6] * dl;
                    int h = n >> 6, d = n & 63;
                    OutB[((((size_t)(b * NHEAD + h)) << logn) + q) * 64 + d] =
                        f2bf(val * QSCALE);
                }
            }
        }
    }
}

// ---------------- output projection GEMM + residual, both passes ----------------
__global__ __launch_bounds__(256) void k_gemm_out(
    const unsigned short* __restrict__ a_a, const unsigned short* __restrict__ a_b,
    const unsigned short* __restrict__ w_a, const unsigned short* __restrict__ w_b,
    const float* __restrict__ ai_a, const float* __restrict__ ai_b,
    const float* __restrict__ part,
    const float* __restrict__ Ex_a, const float* __restrict__ Ex_b,
    float* __restrict__ OF_a, float* __restrict__ OF_b) {
    __shared__ __align__(16) unsigned short sA[128 * 32];
    __shared__ __align__(16) unsigned short sB[128 * 32];
    bool pb = ((int)blockIdx.y >= 128);
    const unsigned short* Aq = pb ? a_b : a_a;
    const unsigned short* Wq = pb ? w_b : w_a;
    const float* a_inv = pb ? ai_b : ai_a;
    const float* Extra = pb ? Ex_b : Ex_a;
    float* OutF = pb ? OF_b : OF_a;
    float wv = fmaxf(wsum32(part, pb ? 5 : 2) / 262144.f, 1e-5f);
    int m0 = (pb ? (int)blockIdx.y - 128 : (int)blockIdx.y) * 128;
    int n0 = blockIdx.x * 128;

    int t = threadIdx.x;
    int w = t >> 6, lane = t & 63;
    int wm = w >> 1, wn = w & 1;
    int lr = lane & 15, lg = lane >> 4;
    int row_st = t >> 2, chunk = t & 3;
    f32x4 acc[4][4] = {};

    for (int k0 = 0; k0 < 512; k0 += 32) {
        __syncthreads();
#pragma unroll
        for (int i = 0; i < 2; ++i) {
            int row = i * 64 + row_st;
            GLOAD16(Aq + (size_t)(m0 + row) * 512 + k0 + chunk * 8, sA + ((size_t)i * 256 + t) * 8);
            GLOAD16(Wq + (size_t)(n0 + row) * 512 + k0 + chunk * 8, sB + ((size_t)i * 256 + t) * 8);
        }
        asm volatile("s_waitcnt vmcnt(0)" ::: "memory");
        __syncthreads();
        bf16x8 af[4], bfr[4];
#pragma unroll
        for (int mt = 0; mt < 4; ++mt)
            af[mt] = *reinterpret_cast<const bf16x8*>(&sA[(wm * 64 + mt * 16 + lr) * 32 + lg * 8]);
#pragma unroll
        for (int nt = 0; nt < 4; ++nt)
            bfr[nt] = *reinterpret_cast<const bf16x8*>(&sB[(wn * 64 + nt * 16 + lr) * 32 + lg * 8]);
#pragma unroll
        for (int mt = 0; mt < 4; ++mt)
#pragma unroll
            for (int nt = 0; nt < 4; ++nt)
                acc[mt][nt] = __builtin_amdgcn_mfma_f32_16x16x32_bf16(af[mt], bfr[nt], acc[mt][nt], 0, 0, 0);
    }

#pragma unroll
    for (int mt = 0; mt < 4; ++mt) {
#pragma unroll
        for (int r = 0; r < 4; ++r) {
            int m = m0 + wm * 64 + mt * 16 + lg * 4 + r;
            float as = a_inv[m] * wv;
#pragma unroll
            for (int nt = 0; nt < 4; ++nt) {
                int n = n0 + wn * 64 + nt * 16 + lr;
                size_t idx = (size_t)m * 512 + n;
                OutF[idx] = acc[mt][nt][r] * as + Extra[idx];
            }
        }
    }
}

// ---------------- flash attention: swapped-QK^T, in-register P, dbuf LDS ----------------
// 1024 uniform blocks (16 tiles each, 4 blocks/CU): bid<512 = pass2 (S=4 key-splits),
// bid>=512 = pass1 (S=1). 512 threads = 8 waves, 32 q/wave. Per-tile body interleaves
// {QK kt01 -> exp -> PV kg0 -> QK kt23 -> exp -> PV kg1} so PV MFMAs overlap exp VALU.
__global__ __launch_bounds__(512) void k_attn_mfma(
    const unsigned short* __restrict__ Qb_a, const unsigned short* __restrict__ Kb_a,
    const unsigned short* __restrict__ Vt_a, unsigned short* __restrict__ Op_a,
    float* __restrict__ Lp_a,
    const unsigned short* __restrict__ Qb_b, const unsigned short* __restrict__ Kb_b,
    const unsigned short* __restrict__ Vt_b, unsigned short* __restrict__ Op_b,
    float* __restrict__ Lp_b) {
    __shared__ unsigned short sK[2][64][72];
    __shared__ unsigned short sVt[2][64][72];
    int t = threadIdx.x;
    int w = t >> 6, lane = t & 63;
    int lr = lane & 15, lg = lane >> 4;

    int bid = blockIdx.x;
    bool pb = (bid < 512);
    int lb = pb ? bid : bid - 512;
    const unsigned short* Qb = pb ? Qb_b : Qb_a;
    const unsigned short* Kb = pb ? Kb_b : Kb_a;
    const unsigned short* Vt = pb ? Vt_b : Vt_a;
    unsigned short* Opart = pb ? Op_b : Op_a;
    float* Lpart = pb ? Lp_b : Lp_a;
    int Nq = pb ? 1024 : 4096;
    int Nc = pb ? 4096 : 1024;
    int S = pb ? 4 : 1;
    int LOGS = pb ? 2 : 0;
    int nqs = pb ? 2 : 4;

    int j = lb >> 3;
    int s = j & (S - 1);
    int j2 = j >> LOGS;
    int qblk = j2 & ((1 << nqs) - 1);
    int bh = ((lb & 7) << 2) | (j2 >> nqs);   // XCD-local bh groups
    int b = bh >> 3, h = bh & 7;
    int q0 = qblk * 256 + w * 32;

    bf16x8 aq[2][2];
#pragma unroll
    for (int qt = 0; qt < 2; ++qt) {
        const unsigned short* qbase = Qb + ((size_t)bh * Nq + q0 + qt * 16 + lr) * 64 + lg * 8;
        aq[qt][0] = *reinterpret_cast<const bf16x8*>(qbase);
        aq[qt][1] = *reinterpret_cast<const bf16x8*>(qbase + 32);
    }

    u16x8 ou;
#pragma unroll
    for (int jj = 0; jj < 8; ++jj) ou[jj] = (lr == 0) ? 0x3F80 : 0;
    bf16x8 onesf = __builtin_bit_cast(bf16x8, ou);

    f32x4 o[2][4] = {};
    f32x4 osum[2] = {};

    const unsigned short* kglob = Kb + (size_t)bh * Nc * 64;
    const unsigned short* vglob = Vt + (size_t)bh * 64 * (size_t)Nc;

    int srow = t >> 3, sseg = t & 7;
    const unsigned short* kptr = kglob + (size_t)srow * 64 + sseg * 8;
    const unsigned short* vptr = vglob + (size_t)srow * Nc + sseg * 8;

    int kts = s * (Nc >> LOGS);
    int nt = (Nc >> LOGS) >> 6;   // 16 for both passes

    // prologue: tile 0 -> buf0; prefetch tile 1
    bf16x8 rK = *reinterpret_cast<const bf16x8*>(kptr + (size_t)kts * 64);
    bf16x8 rV = *reinterpret_cast<const bf16x8*>(vptr + kts);
    *reinterpret_cast<bf16x8*>(&sK[0][srow][sseg * 8]) = rK;
    *reinterpret_cast<bf16x8*>(&sVt[0][srow][sseg * 8]) = rV;
    rK = *reinterpret_cast<const bf16x8*>(kptr + (size_t)(kts + 64) * 64);
    rV = *reinterpret_cast<const bf16x8*>(vptr + kts + 64);
    __syncthreads();

    int cur = 0;
    for (int ti = 0; ti < nt; ++ti) {
        if (ti + 1 < nt) {
            *reinterpret_cast<bf16x8*>(&sK[cur ^ 1][srow][sseg * 8]) = rK;
            *reinterpret_cast<bf16x8*>(&sVt[cur ^ 1][srow][sseg * 8]) = rV;
            if (ti + 2 < nt) {
                int knext = kts + (ti + 2) * 64;
                rK = *reinterpret_cast<const bf16x8*>(kptr + (size_t)knext * 64);
                rV = *reinterpret_cast<const bf16x8*>(vptr + knext);
            }
        }
        // per-half: QK (swapped operands) -> exp2 -> PV, so the next half's exp
        // overlaps this half's PV MFMAs in-wave.
#pragma unroll
        for (int half = 0; half < 2; ++half) {
            bf16x8 pa0, pa1;
#pragma unroll
            for (int ki = 0; ki < 2; ++ki) {
                int kt = half * 2 + ki;
                bf16x8 bk0 = *reinterpret_cast<const bf16x8*>(&sK[cur][kt * 16 + lr][lg * 8]);
                bf16x8 bk1 = *reinterpret_cast<const bf16x8*>(&sK[cur][kt * 16 + lr][32 + lg * 8]);
                f32x4 a0 = {}, a1 = {};
                __builtin_amdgcn_s_setprio(1);
                a0 = __builtin_amdgcn_mfma_f32_16x16x32_bf16(bk0, aq[0][0], a0, 0, 0, 0);
                a1 = __builtin_amdgcn_mfma_f32_16x16x32_bf16(bk0, aq[1][0], a1, 0, 0, 0);
                a0 = __builtin_amdgcn_mfma_f32_16x16x32_bf16(bk1, aq[0][1], a0, 0, 0, 0);
                a1 = __builtin_amdgcn_mfma_f32_16x16x32_bf16(bk1, aq[1][1], a1, 0, 0, 0);
                __builtin_amdgcn_s_setprio(0);
                const int hb = ki * 4;
#pragma unroll
                for (int r = 0; r < 4; ++r) {
                    pa0[hb + r] = (__bf16)EXP2F(a0[r]);
                    pa1[hb + r] = (__bf16)EXP2F(a1[r]);
                }
            }
            __builtin_amdgcn_s_setprio(1);
#pragma unroll
            for (int dt = 0; dt < 4; ++dt) {
                bf16x8 vb = *reinterpret_cast<const bf16x8*>(&sVt[cur][dt * 16 + lr][half * 32 + lg * 8]);
                o[0][dt] = __builtin_amdgcn_mfma_f32_16x16x32_bf16(pa0, vb, o[0][dt], 0, 0, 0);
                o[1][dt] = __builtin_amdgcn_mfma_f32_16x16x32_bf16(pa1, vb, o[1][dt], 0, 0, 0);
            }
            osum[0] = __builtin_amdgcn_mfma_f32_16x16x32_bf16(pa0, onesf, osum[0], 0, 0, 0);
            osum[1] = __builtin_amdgcn_mfma_f32_16x16x32_bf16(pa1, onesf, osum[1], 0, 0, 0);
            __builtin_amdgcn_s_setprio(0);
        }
        __syncthreads();
        cur ^= 1;
    }
    // write unnormalized bf16 partials
    unsigned short* obase = Opart + ((size_t)(s * 4 + b) * Nq + q0) * 512 + h * 64;
#pragma unroll
    for (int qt = 0; qt < 2; ++qt)
#pragma unroll
        for (int dt = 0; dt < 4; ++dt)
#pragma unroll
            for (int r = 0; r < 4; ++r)
                obase[(size_t)(qt * 16 + lg * 4 + r) * 512 + dt * 16 + lr] = f2bf(o[qt][dt][r]);
    if (lr == 0) {
        float* lbase = Lpart + ((size_t)(s * 4 + b) * 8 + h) * Nq + q0;
#pragma unroll
        for (int qt = 0; qt < 2; ++qt)
#pragma unroll
            for (int r = 0; r < 4; ++r)
                lbase[qt * 16 + lg * 4 + r] = osum[qt][r];
    }
}

// ---------------- host side ----------------
extern "C" void kernel_launch(void* const* d_in, const int* in_sizes, int n_in,
                              void* d_out, int out_size, void* d_ws, size_t ws_size,
                              hipStream_t stream) {
    const float* x     = (const float*)d_in[0];
    const float* c     = (const float*)d_in[1];
    const float* Wq_x  = (const float*)d_in[2];
    const float* g_qx  = (const float*)d_in[3];
    const float* Wkv_c = (const float*)d_in[4];
    const float* g_kvc = (const float*)d_in[5];
    const float* A_x   = (const float*)d_in[6];
    const float* B_x   = (const float*)d_in[7];
    const float* mag_x = (const float*)d_in[8];
    const float* Wp_x  = (const float*)d_in[9];
    const float* g_px  = (const float*)d_in[10];
    const float* Wq_c  = (const float*)d_in[11];
    const float* g_qc  = (const float*)d_in[12];
    const float* Wkv_x = (const float*)d_in[13];
    const float* g_kvx = (const float*)d_in[14];
    const float* A_c   = (const float*)d_in[15];
    const float* B_c   = (const float*)d_in[16];
    const float* mag_c = (const float*)d_in[17];
    const float* Wp_c  = (const float*)d_in[18];
    const float* g_pc  = (const float*)d_in[19];

    float* ws = (float*)d_ws;
    unsigned short* Wb = (unsigned short*)ws;
    const size_t Woff[6] = {0, 262144, 786432, 1048576, 1310720, 1835008}; // u16 units
    float* part  = ws + 1048576;
    float* sc_xq  = ws + 1049600;
    float* sc_xkv = sc_xq + 16384;
    float* sc_cq  = sc_xkv + 16384;
    float* sc_ckv = sc_cq + 4096;
    float* sc_o1  = sc_ckv + 4096;
    float* sc_o2  = sc_o1 + 16384;
    float* tmp_x  = ws + 1111040;                    // 262144
    float* tmp_c  = tmp_x + 262144;                  // 65536  -> ends 1438720
    float* actblk = ws + 1438720;                    // acts / Opart1 overlay
    unsigned short* act_xq  = (unsigned short*)actblk;                  // 4194304 f
    unsigned short* act_xkv = (unsigned short*)(actblk + 4194304);      // 4194304 f
    unsigned short* act_cq  = (unsigned short*)(actblk + 8388608);      // 1048576 f
    unsigned short* act_ckv = (unsigned short*)(actblk + 9437184);      // 1048576 f
    unsigned short* Opart1 = (unsigned short*)actblk;  // 8.4M u16 over act_xq (dead)
    float* qf1_f  = ws + 11924480;                   // 4194304 f
    unsigned short* Opart2 = (unsigned short*)qf1_f; // 8.4M u16 (S=4; qf1 dead by attn)
    float* qf2_f  = ws + 16118784;                   // 1048576 f
    float* Qb1_f  = ws + 17167360;                   // 4194304 f (-> act_o1)
    float* Qb2_f  = ws + 21361664;                   // 1048576 f (-> act_o2)
    float* Kb1_f  = ws + 22410240;                   // 1048576 f
    float* Vt1_f  = ws + 23458816;                   // 1048576 f
    float* Kb2_f  = ws + 24507392;                   // 4194304 f
    float* Vt2_f  = ws + 28701696;                   // 4194304 f
    float* Lpart1 = ws + 32896000;                   // 131072 f
    float* Lpart2 = ws + 33027072;                   // 131072 f -> ends 33158144

    unsigned short* qf1 = (unsigned short*)qf1_f;
    unsigned short* qf2 = (unsigned short*)qf2_f;
    unsigned short* Qb1 = (unsigned short*)Qb1_f;
    unsigned short* Qb2 = (unsigned short*)Qb2_f;
    unsigned short* Kb1 = (unsigned short*)Kb1_f;
    unsigned short* Vt1 = (unsigned short*)Vt1_f;
    unsigned short* Kb2 = (unsigned short*)Kb2_f;
    unsigned short* Vt2 = (unsigned short*)Vt2_f;
    unsigned short* act_o1 = Qb1;
    unsigned short* act_o2 = Qb2;

    size_t need = (size_t)33158144 * sizeof(float);   // ~132.6 MB (round-1 verified >= 135MB)
    if (ws_size < need) return;

    float* outx = (float*)d_out;
    float* outc = outx + (size_t)4 * 4096 * 512;

    // L1: weight |.| partials + RMSNorm/quant/DoRA-tmp for both passes
    k_prep1<<<5312, 256, 0, stream>>>(Wq_x, Wkv_c, Wp_x, Wq_c, Wkv_x, Wp_c, part,
                                      x, c, g_qx, g_kvx, g_qc, g_kvc,
                                      act_xq, act_xkv, act_cq, act_ckv,
                                      sc_xq, sc_xkv, sc_cq, sc_ckv,
                                      A_x, A_c, tmp_x, tmp_c);
    // L2: weight ternarize + DoRA delta
    k_prep2<<<49152, 256, 0, stream>>>(Wq_x, Wkv_c, Wp_x, Wq_c, Wkv_x, Wp_c, part, Wb,
                                       tmp_x, tmp_c, B_x, B_c, qf1, qf2);
    // L3: merged Q + KV projections, both passes (KV blocks first)
    k_gemm_qkv<<<1920, 256, 0, stream>>>(
        act_xq, act_cq, Wb + Woff[0], Wb + Woff[3], sc_xq, sc_cq,
        mag_x, mag_c, qf1, qf2, Qb1, Qb2,
        act_ckv, act_xkv, Wb + Woff[1], Wb + Woff[4], sc_ckv, sc_xkv,
        Kb1, Kb2, Vt1, Vt2, part);
    // L4: attention, both passes, 1024 uniform blocks
    k_attn_mfma<<<1024, 512, 0, stream>>>(Qb1, Kb1, Vt1, Opart1, Lpart1,
                                          Qb2, Kb2, Vt2, Opart2, Lpart2);
    // L5: combine + RMSNorm + quant
    k_rmsq_combine<<<5120, 256, 0, stream>>>(Opart1, Lpart1, g_px, act_o1, sc_o1,
                                             Opart2, Lpart2, g_pc, act_o2, sc_o2);
    // L6: output projections + residual
    k_gemm_out<<<dim3(4, 160), 256, 0, stream>>>(
        act_o1, act_o2, Wb + Woff[2], Wb + Woff[5], sc_o1, sc_o2, part,
        x, c, outx, outc);
}

// Round 13
// 272.403 us; speedup vs baseline: 61.4986x; 1.0423x over previous
//
#include <hip/hip_runtime.h>
#include <math.h>

#define DD 512
#define NHEAD 8
#define HDIM 64

typedef __bf16 bf16x8 __attribute__((ext_vector_type(8)));
typedef unsigned short u16x8 __attribute__((ext_vector_type(8)));
typedef float f32x4 __attribute__((ext_vector_type(4)));

#if __has_builtin(__builtin_amdgcn_exp2f)
#define EXP2F(x) __builtin_amdgcn_exp2f(x)
#else
#define EXP2F(x) exp2f(x)
#endif

#define QSCALE 0.18033688f  /* (1/8) * log2(e): exp2 domain */

static __device__ __forceinline__ unsigned short f2bf(float f) {
    unsigned u = __builtin_bit_cast(unsigned, f);
    u += 0x7fffu + ((u >> 16) & 1u);   // round-to-nearest-even
    return (unsigned short)(u >> 16);
}
static __device__ __forceinline__ float bf2f(unsigned short u) {
    return __builtin_bit_cast(float, (unsigned)u << 16);
}

// sum of part[mid*32 .. +31] via wave butterfly; deterministic, same order everywhere
static __device__ __forceinline__ float wsum32(const float* __restrict__ part, int mid) {
    int l = threadIdx.x & 63;
    float v = (l < 32) ? part[mid * 32 + l] : 0.f;
#pragma unroll
    for (int o = 16; o > 0; o >>= 1) v += __shfl_xor(v, o);
    return __shfl(v, 0);
}

#define GLOAD16(g, l)                                                          \
    __builtin_amdgcn_global_load_lds(                                          \
        (__attribute__((address_space(1))) void*)(g),                          \
        (__attribute__((address_space(3))) void*)(l), 16, 0, 0)

#define BSTEP(s, hc)                                                           \
    {                                                                          \
        _Pragma("unroll")                                                      \
        for (int i = 0; i < (hc); ++i) {                                       \
            float send = (lane & (s)) ? p[i] : p[i + (hc)];                    \
            float recv = __shfl_xor(send, (s));                                \
            p[i] = ((lane & (s)) ? p[i + (hc)] : p[i]) + recv;                 \
        }                                                                      \
    }

// ---------------- prep1: weight |.| partials (192 blocks) + RMSNorm/quant/DoRA (5120 blocks) ----------------
__global__ __launch_bounds__(256) void k_prep1(
    const float* __restrict__ W0, const float* __restrict__ W1,
    const float* __restrict__ W2, const float* __restrict__ W3,
    const float* __restrict__ W4, const float* __restrict__ W5,
    float* __restrict__ part,
    const float* __restrict__ x, const float* __restrict__ c,
    const float* __restrict__ g_qx, const float* __restrict__ g_kvx,
    const float* __restrict__ g_qc, const float* __restrict__ g_kvc,
    unsigned short* __restrict__ a_xq, unsigned short* __restrict__ a_xkv,
    unsigned short* __restrict__ a_cq, unsigned short* __restrict__ a_ckv,
    float* __restrict__ s_xq, float* __restrict__ s_xkv,
    float* __restrict__ s_cq, float* __restrict__ s_ckv,
    const float* __restrict__ A_x, const float* __restrict__ A_c,
    float* __restrict__ tmp_x, float* __restrict__ tmp_c) {
    int t = threadIdx.x;
    if (blockIdx.x < 192) {
        const float* Ws[6] = {W0, W1, W2, W3, W4, W5};
        const int cnt[6] = {262144, 524288, 262144, 262144, 524288, 262144};
        int mid = blockIdx.x >> 5, lb = blockIdx.x & 31;
        const float* W = Ws[mid];
        int n = cnt[mid];
        float s = 0.f;
        for (int i = lb * 256 + t; i < n; i += 32 * 256) s += fabsf(W[i]);
        __shared__ float red[4];
#pragma unroll
        for (int o = 32; o > 0; o >>= 1) s += __shfl_down(s, o);
        if ((t & 63) == 0) red[t >> 6] = s;
        __syncthreads();
        if (t == 0) part[blockIdx.x] = red[0] + red[1] + red[2] + red[3];
        return;
    }
    int w = t >> 6, lane = t & 63;
    int row = (int)(blockIdx.x - 192) * 4 + w;
    bool pc = (row >= 16384);
    int r = pc ? row - 16384 : row;
    const float* xr = (pc ? c : x) + (size_t)r * DD;
    const float* G1 = pc ? g_qc : g_qx;
    const float* G2 = pc ? g_kvc : g_kvx;
    unsigned short* O1 = pc ? a_cq : a_xq;
    unsigned short* O2 = pc ? a_ckv : a_xkv;
    float* S1 = pc ? s_cq : s_xq;
    float* S2 = pc ? s_ckv : s_xkv;
    const float* AM = pc ? A_c : A_x;
    float* TMP = pc ? tmp_c : tmp_x;

    float4 a = *(const float4*)(xr + lane * 8);
    float4 b = *(const float4*)(xr + lane * 8 + 4);
    float p[16];
#pragma unroll
    for (int cc = 0; cc < 16; ++cc) {
        const float4* ar = (const float4*)(AM + (size_t)cc * DD + lane * 8);
        float4 aa = ar[0], ab = ar[1];
        p[cc] = a.x*aa.x + a.y*aa.y + a.z*aa.z + a.w*aa.w
              + b.x*ab.x + b.y*ab.y + b.z*ab.z + b.w*ab.w;
    }
    BSTEP(1, 8) BSTEP(2, 4) BSTEP(4, 2) BSTEP(8, 1)
    p[0] += __shfl_xor(p[0], 16);
    p[0] += __shfl_xor(p[0], 32);
    if (lane < 16) {
        int cidx = ((lane & 1) << 3) | ((lane & 2) << 1) | ((lane & 4) >> 1) | ((lane & 8) >> 3);
        TMP[(size_t)r * 16 + cidx] = p[0];
    }
    float ss = a.x*a.x + a.y*a.y + a.z*a.z + a.w*a.w
             + b.x*b.x + b.y*b.y + b.z*b.z + b.w*b.w;
#pragma unroll
    for (int o = 32; o > 0; o >>= 1) ss += __shfl_xor(ss, o);
    float rn = 1.f / sqrtf(ss * (1.f / 512.f) + 1e-8f);
    const float* gs[2] = {G1, G2};
    unsigned short* os[2] = {O1, O2};
    float* scs[2] = {S1, S2};
#pragma unroll
    for (int pass = 0; pass < 2; ++pass) {
        float4 ga = *(const float4*)(gs[pass] + lane * 8);
        float4 gb = *(const float4*)(gs[pass] + lane * 8 + 4);
        float v[8] = {a.x*rn*ga.x, a.y*rn*ga.y, a.z*rn*ga.z, a.w*rn*ga.w,
                      b.x*rn*gb.x, b.y*rn*gb.y, b.z*rn*gb.z, b.w*rn*gb.w};
        float amax = 0.f;
#pragma unroll
        for (int i = 0; i < 8; ++i) amax = fmaxf(amax, fabsf(v[i]));
#pragma unroll
        for (int o = 32; o > 0; o >>= 1) amax = fmaxf(amax, __shfl_xor(amax, o));
        float mx = fmaxf(amax, 1e-5f);
        float scale = 127.f / mx;
        u16x8 qv;
#pragma unroll
        for (int i = 0; i < 8; ++i) {
            float tq = rintf(v[i] * scale);
            tq = fminf(fmaxf(tq, -128.f), 127.f);
            qv[i] = f2bf(tq);
        }
        *reinterpret_cast<u16x8*>(os[pass] + (size_t)r * DD + lane * 8) = qv;
        if (lane == 0) scs[pass][r] = mx / 127.f;
    }
}

// ---------------- prep2: weight ternarize (8192 blocks) + DoRA delta (40960 blocks) ----------------
__global__ __launch_bounds__(256) void k_prep2(
    const float* __restrict__ W0, const float* __restrict__ W1,
    const float* __restrict__ W2, const float* __restrict__ W3,
    const float* __restrict__ W4, const float* __restrict__ W5,
    const float* __restrict__ part, unsigned short* __restrict__ Wq,
    const float* __restrict__ tmp_x, const float* __restrict__ tmp_c,
    const float* __restrict__ B_x, const float* __restrict__ B_c,
    unsigned short* __restrict__ qf1, unsigned short* __restrict__ qf2) {
    if (blockIdx.x < 8192) {
        int e = blockIdx.x * 256 + threadIdx.x;
        const float* Ws[6] = {W0, W1, W2, W3, W4, W5};
        int mid, base;
        if (e < 262144)       { mid = 0; base = 0; }
        else if (e < 786432)  { mid = 1; base = 262144; }
        else if (e < 1048576) { mid = 2; base = 786432; }
        else if (e < 1310720) { mid = 3; base = 1048576; }
        else if (e < 1835008) { mid = 4; base = 1310720; }
        else                  { mid = 5; base = 1835008; }
        float cnt = (mid == 1 || mid == 4) ? 524288.f : 262144.f;
        float mean = fmaxf(wsum32(part, mid) / cnt, 1e-5f);
        float sc = 1.f / mean;
        float t = rintf(Ws[mid][e - base] * sc);
        t = fminf(fmaxf(t, -1.f), 1.f);
        Wq[e] = f2bf(t);
        return;
    }
    int idx = (int)(blockIdx.x - 8192) * 256 + threadIdx.x;   // over 20480*512
    int m2 = idx >> 9, n2 = idx & 511;
    const float* tr;
    const float* br;
    unsigned short* out;
    if (m2 < 16384) {
        tr = tmp_x + (size_t)m2 * 16; br = B_x + (size_t)n2 * 16; out = qf1 + idx;
    } else {
        tr = tmp_c + (size_t)(m2 - 16384) * 16; br = B_c + (size_t)n2 * 16;
        out = qf2 + (idx - 8388608);
    }
    const float4* t4 = (const float4*)tr;
    const float4* b4 = (const float4*)br;
    float acc = 0.f;
#pragma unroll
    for (int rr = 0; rr < 4; ++rr) {
        float4 ta = t4[rr], ba = b4[rr];
        acc += ta.x*ba.x + ta.y*ba.y + ta.z*ba.z + ta.w*ba.w;
    }
    *out = f2bf(acc);
}

// ---------------- combine attn partials (bf16) + RMSNorm + quant, both passes, 4 rows/block ----------------
__global__ __launch_bounds__(256) void k_rmsq_combine(
    const unsigned short* __restrict__ Op_a, const float* __restrict__ Lp_a,
    const float* __restrict__ g_a, unsigned short* __restrict__ out_a,
    float* __restrict__ sc_a,
    const unsigned short* __restrict__ Op_b, const float* __restrict__ Lp_b,
    const float* __restrict__ g_b, unsigned short* __restrict__ out_b,
    float* __restrict__ sc_b) {
    int w = threadIdx.x >> 6, lane = threadIdx.x & 63;
    int row = (int)blockIdx.x * 4 + w;
    bool pb = (row >= 16384);
    int r = pb ? row - 16384 : row;
    int S = pb ? 4 : 1;
    int lognq = pb ? 10 : 12;
    const unsigned short* Op = pb ? Op_b : Op_a;
    const float* Lp = pb ? Lp_b : Lp_a;
    const float* g  = pb ? g_b : g_a;
    unsigned short* out = pb ? out_b : out_a;
    float* a_inv = pb ? sc_b : sc_a;

    int Nq = 1 << lognq;
    int b = r >> lognq, q = r & (Nq - 1);
    int h = lane >> 3;
    float l = 0.f;
    float u[8] = {};
    for (int s = 0; s < S; ++s) {
        l += Lp[((size_t)(s * 4 + b) * 8 + h) * Nq + q];
        u16x8 ov = *reinterpret_cast<const u16x8*>(
            Op + ((size_t)(s * 4 + b) * Nq + q) * 512 + lane * 8);
#pragma unroll
        for (int i = 0; i < 8; ++i) u[i] += bf2f(ov[i]);
    }
    float invl = 1.f / l;
#pragma unroll
    for (int i = 0; i < 8; ++i) u[i] *= invl;
    float ss = 0.f;
#pragma unroll
    for (int i = 0; i < 8; ++i) ss += u[i] * u[i];
#pragma unroll
    for (int o = 32; o > 0; o >>= 1) ss += __shfl_xor(ss, o);
    float rn = 1.f / sqrtf(ss * (1.f / 512.f) + 1e-8f);
    float4 ga = *(const float4*)(g + lane * 8);
    float4 gb = *(const float4*)(g + lane * 8 + 4);
    float v[8] = {u[0]*rn*ga.x, u[1]*rn*ga.y, u[2]*rn*ga.z, u[3]*rn*ga.w,
                  u[4]*rn*gb.x, u[5]*rn*gb.y, u[6]*rn*gb.z, u[7]*rn*gb.w};
    float amax = 0.f;
#pragma unroll
    for (int i = 0; i < 8; ++i) amax = fmaxf(amax, fabsf(v[i]));
#pragma unroll
    for (int o = 32; o > 0; o >>= 1) amax = fmaxf(amax, __shfl_xor(amax, o));
    float mx = fmaxf(amax, 1e-5f);
    float scale = 127.f / mx;
    u16x8 qv;
#pragma unroll
    for (int i = 0; i < 8; ++i) {
        float tq = rintf(v[i] * scale);
        tq = fminf(fmaxf(tq, -128.f), 127.f);
        qv[i] = f2bf(tq);
    }
    *reinterpret_cast<u16x8*>(out + (size_t)r * DD + lane * 8) = qv;
    if (lane == 0) a_inv[r] = mx / 127.f;
}

// ---------------- merged Q + KV projection GEMM (one launch, 1920 blocks) ----------------
// XCD-affinity swizzle: all col-blocks of one A-row-panel share blockid%8 -> same XCD L2.
__global__ __launch_bounds__(256) void k_gemm_qkv(
    const unsigned short* __restrict__ a3_a, const unsigned short* __restrict__ a3_b,
    const unsigned short* __restrict__ w3_a, const unsigned short* __restrict__ w3_b,
    const float* __restrict__ ai3_a, const float* __restrict__ ai3_b,
    const float* __restrict__ mag_a, const float* __restrict__ mag_b,
    const unsigned short* __restrict__ dl_a, const unsigned short* __restrict__ dl_b,
    unsigned short* __restrict__ Qb_a, unsigned short* __restrict__ Qb_b,
    const unsigned short* __restrict__ a4_a, const unsigned short* __restrict__ a4_b,
    const unsigned short* __restrict__ w4_a, const unsigned short* __restrict__ w4_b,
    const float* __restrict__ ai4_a, const float* __restrict__ ai4_b,
    unsigned short* __restrict__ Kb_a, unsigned short* __restrict__ Kb_b,
    unsigned short* __restrict__ Vt_a, unsigned short* __restrict__ Vt_b,
    const float* __restrict__ part) {
    __shared__ __align__(16) unsigned short sA[128 * 32];
    __shared__ __align__(16) unsigned short sB[128 * 32];
    int bid = blockIdx.x;
    bool isQ = (bid >= 1280);
    const unsigned short *Aq, *Wq;
    const float* a_inv;
    int m0, n0, logn, mid;
    float cnt;
    bool pb;
    if (!isQ) {
        int g = bid & 7, k = bid >> 3;       // XCD-affine: my%8 == g
        n0 = (k & 7) * 128;
        int my = (k >> 3) * 8 + g;           // 0..159
        pb = my >= 32;
        m0 = (pb ? my - 32 : my) * 128;
        Aq = pb ? a4_b : a4_a;  Wq = pb ? w4_b : w4_a;
        a_inv = pb ? ai4_b : ai4_a;
        logn = pb ? 12 : 10;
        mid = pb ? 4 : 1; cnt = 524288.f;
    } else {
        int b2 = bid - 1280;                 // 1280%8==0: preserves XCD phase
        int g = b2 & 7, k = b2 >> 3;
        n0 = (k & 3) * 128;
        int my = (k >> 2) * 8 + g;           // 0..159
        pb = my >= 128;
        m0 = (pb ? my - 128 : my) * 128;
        Aq = pb ? a3_b : a3_a;  Wq = pb ? w3_b : w3_a;
        a_inv = pb ? ai3_b : ai3_a;
        logn = pb ? 10 : 12;
        mid = pb ? 3 : 0; cnt = 262144.f;
    }
    float wv = fmaxf(wsum32(part, mid) / cnt, 1e-5f);

    int t = threadIdx.x;
    int w = t >> 6, lane = t & 63;
    int wm = w >> 1, wn = w & 1;
    int lr = lane & 15, lg = lane >> 4;
    int row_st = t >> 2, chunk = t & 3;
    f32x4 acc[4][4] = {};

    for (int k0 = 0; k0 < 512; k0 += 32) {
        __syncthreads();
#pragma unroll
        for (int i = 0; i < 2; ++i) {
            int row = i * 64 + row_st;
            GLOAD16(Aq + (size_t)(m0 + row) * 512 + k0 + chunk * 8, sA + ((size_t)i * 256 + t) * 8);
            GLOAD16(Wq + (size_t)(n0 + row) * 512 + k0 + chunk * 8, sB + ((size_t)i * 256 + t) * 8);
        }
        asm volatile("s_waitcnt vmcnt(0)" ::: "memory");
        __syncthreads();
        bf16x8 af[4], bfr[4];
#pragma unroll
        for (int mt = 0; mt < 4; ++mt)
            af[mt] = *reinterpret_cast<const bf16x8*>(&sA[(wm * 64 + mt * 16 + lr) * 32 + lg * 8]);
#pragma unroll
        for (int nt = 0; nt < 4; ++nt)
            bfr[nt] = *reinterpret_cast<const bf16x8*>(&sB[(wn * 64 + nt * 16 + lr) * 32 + lg * 8]);
#pragma unroll
        for (int mt = 0; mt < 4; ++mt)
#pragma unroll
            for (int nt = 0; nt < 4; ++nt)
                acc[mt][nt] = __builtin_amdgcn_mfma_f32_16x16x32_bf16(af[mt], bfr[nt], acc[mt][nt], 0, 0, 0);
    }

    if (!isQ) {
        unsigned short* OutB = pb ? Kb_b : Kb_a;
        unsigned short* OutB2 = pb ? Vt_b : Vt_a;
        const bool isV = (n0 >= 512);
        const int Nc = 1 << logn;
#pragma unroll
        for (int mt = 0; mt < 4; ++mt) {
            int mb = m0 + wm * 64 + mt * 16 + lg * 4;
            int b = mb >> logn, key = mb & (Nc - 1);
            float as_[4];
#pragma unroll
            for (int r = 0; r < 4; ++r) as_[r] = a_inv[mb + r] * wv;
#pragma unroll
            for (int nt = 0; nt < 4; ++nt) {
                int n = n0 + wn * 64 + nt * 16 + lr;
                int n2 = isV ? (n - 512) : n;
                int h = n2 >> 6, dd = n2 & 63;
                if (isV) {
                    int i0 = key & 31;
                    int keyp = (key & ~31) | (((i0 >> 2) & 3) * 8 + ((i0 >> 4) & 1) * 4);
                    ushort4 v;
                    v.x = f2bf(acc[mt][nt][0] * as_[0]);
                    v.y = f2bf(acc[mt][nt][1] * as_[1]);
                    v.z = f2bf(acc[mt][nt][2] * as_[2]);
                    v.w = f2bf(acc[mt][nt][3] * as_[3]);
                    *reinterpret_cast<ushort4*>(
                        OutB2 + ((size_t)(b * NHEAD + h) * 64 + dd) * Nc + keyp) = v;
                } else {
#pragma unroll
                    for (int r = 0; r < 4; ++r)
                        OutB[((size_t)(b * NHEAD + h) * Nc + key + r) * 64 + dd] =
                            f2bf(acc[mt][nt][r] * as_[r]);
                }
            }
        }
    } else {
        const float* Extra = pb ? mag_b : mag_a;
        const unsigned short* Dlt = pb ? dl_b : dl_a;
        unsigned short* OutB = pb ? Qb_b : Qb_a;
#pragma unroll
        for (int mt = 0; mt < 4; ++mt) {
#pragma unroll
            for (int r = 0; r < 4; ++r) {
                int m = m0 + wm * 64 + mt * 16 + lg * 4 + r;
                float as = a_inv[m] * wv;
                int b = m >> logn, q = m & ((1 << logn) - 1);
#pragma unroll
                for (int nt = 0; nt < 4; ++nt) {
                    int n = n0 + wn * 64 + nt * 16 + lr;
                    float dl = bf2f(Dlt[(size_t)m * 512 + n]);
                    float val = acc[mt][nt][r] * as + Extra[n >> 6] * dl;
                    int h = n >> 6, d = n & 63;
                    OutB[((((size_t)(b * NHEAD + h)) << logn) + q) * 64 + d] =
                        f2bf(val * QSCALE);
                }
            }
        }
    }
}

// ---------------- output projection GEMM + residual, both passes (1D, XCD-affine) ----------------
__global__ __launch_bounds__(256) void k_gemm_out(
    const unsigned short* __restrict__ a_a, const unsigned short* __restrict__ a_b,
    const unsigned short* __restrict__ w_a, const unsigned short* __restrict__ w_b,
    const float* __restrict__ ai_a, const float* __restrict__ ai_b,
    const float* __restrict__ part,
    const float* __restrict__ Ex_a, const float* __restrict__ Ex_b,
    float* __restrict__ OF_a, float* __restrict__ OF_b) {
    __shared__ __align__(16) unsigned short sA[128 * 32];
    __shared__ __align__(16) unsigned short sB[128 * 32];
    int bid = blockIdx.x;                    // 0..639
    int g = bid & 7, k = bid >> 3;           // XCD-affine: my%8 == g
    int n0 = (k & 3) * 128;
    int my = (k >> 2) * 8 + g;               // 0..159
    bool pb = (my >= 128);
    int m0 = (pb ? my - 128 : my) * 128;
    const unsigned short* Aq = pb ? a_b : a_a;
    const unsigned short* Wq = pb ? w_b : w_a;
    const float* a_inv = pb ? ai_b : ai_a;
    const float* Extra = pb ? Ex_b : Ex_a;
    float* OutF = pb ? OF_b : OF_a;
    float wv = fmaxf(wsum32(part, pb ? 5 : 2) / 262144.f, 1e-5f);

    int t = threadIdx.x;
    int w = t >> 6, lane = t & 63;
    int wm = w >> 1, wn = w & 1;
    int lr = lane & 15, lg = lane >> 4;
    int row_st = t >> 2, chunk = t & 3;
    f32x4 acc[4][4] = {};

    for (int k0 = 0; k0 < 512; k0 += 32) {
        __syncthreads();
#pragma unroll
        for (int i = 0; i < 2; ++i) {
            int row = i * 64 + row_st;
            GLOAD16(Aq + (size_t)(m0 + row) * 512 + k0 + chunk * 8, sA + ((size_t)i * 256 + t) * 8);
            GLOAD16(Wq + (size_t)(n0 + row) * 512 + k0 + chunk * 8, sB + ((size_t)i * 256 + t) * 8);
        }
        asm volatile("s_waitcnt vmcnt(0)" ::: "memory");
        __syncthreads();
        bf16x8 af[4], bfr[4];
#pragma unroll
        for (int mt = 0; mt < 4; ++mt)
            af[mt] = *reinterpret_cast<const bf16x8*>(&sA[(wm * 64 + mt * 16 + lr) * 32 + lg * 8]);
#pragma unroll
        for (int nt = 0; nt < 4; ++nt)
            bfr[nt] = *reinterpret_cast<const bf16x8*>(&sB[(wn * 64 + nt * 16 + lr) * 32 + lg * 8]);
#pragma unroll
        for (int mt = 0; mt < 4; ++mt)
#pragma unroll
            for (int nt = 0; nt < 4; ++nt)
                acc[mt][nt] = __builtin_amdgcn_mfma_f32_16x16x32_bf16(af[mt], bfr[nt], acc[mt][nt], 0, 0, 0);
    }

#pragma unroll
    for (int mt = 0; mt < 4; ++mt) {
#pragma unroll
        for (int r = 0; r < 4; ++r) {
            int m = m0 + wm * 64 + mt * 16 + lg * 4 + r;
            float as = a_inv[m] * wv;
#pragma unroll
            for (int nt = 0; nt < 4; ++nt) {
                int n = n0 + wn * 64 + nt * 16 + lr;
                size_t idx = (size_t)m * 512 + n;
                OutF[idx] = acc[mt][nt][r] * as + Extra[idx];
            }
        }
    }
}

// ---------------- flash attention: swapped-QK^T, in-register P, dbuf LDS ----------------
// 1024 uniform blocks (16 tiles each, 4 blocks/CU): bid<512 = pass2 (S=4 key-splits),
// bid>=512 = pass1 (S=1). 512 threads = 8 waves, 32 q/wave.
__global__ __launch_bounds__(512) void k_attn_mfma(
    const unsigned short* __restrict__ Qb_a, const unsigned short* __restrict__ Kb_a,
    const unsigned short* __restrict__ Vt_a, unsigned short* __restrict__ Op_a,
    float* __restrict__ Lp_a,
    const unsigned short* __restrict__ Qb_b, const unsigned short* __restrict__ Kb_b,
    const unsigned short* __restrict__ Vt_b, unsigned short* __restrict__ Op_b,
    float* __restrict__ Lp_b) {
    __shared__ unsigned short sK[2][64][72];
    __shared__ unsigned short sVt[2][64][72];
    int t = threadIdx.x;
    int w = t >> 6, lane = t & 63;
    int lr = lane & 15, lg = lane >> 4;

    int bid = blockIdx.x;
    bool pb = (bid < 512);
    int lb = pb ? bid : bid - 512;
    const unsigned short* Qb = pb ? Qb_b : Qb_a;
    const unsigned short* Kb = pb ? Kb_b : Kb_a;
    const unsigned short* Vt = pb ? Vt_b : Vt_a;
    unsigned short* Opart = pb ? Op_b : Op_a;
    float* Lpart = pb ? Lp_b : Lp_a;
    int Nq = pb ? 1024 : 4096;
    int Nc = pb ? 4096 : 1024;
    int S = pb ? 4 : 1;
    int LOGS = pb ? 2 : 0;
    int nqs = pb ? 2 : 4;

    int j = lb >> 3;
    int s = j & (S - 1);
    int j2 = j >> LOGS;
    int qblk = j2 & ((1 << nqs) - 1);
    int bh = ((lb & 7) << 2) | (j2 >> nqs);   // XCD-local bh groups
    int b = bh >> 3, h = bh & 7;
    int q0 = qblk * 256 + w * 32;

    bf16x8 aq[2][2];
#pragma unroll
    for (int qt = 0; qt < 2; ++qt) {
        const unsigned short* qbase = Qb + ((size_t)bh * Nq + q0 + qt * 16 + lr) * 64 + lg * 8;
        aq[qt][0] = *reinterpret_cast<const bf16x8*>(qbase);
        aq[qt][1] = *reinterpret_cast<const bf16x8*>(qbase + 32);
    }

    u16x8 ou;
#pragma unroll
    for (int jj = 0; jj < 8; ++jj) ou[jj] = (lr == 0) ? 0x3F80 : 0;
    bf16x8 onesf = __builtin_bit_cast(bf16x8, ou);

    f32x4 o[2][4] = {};
    f32x4 osum[2] = {};

    const unsigned short* kglob = Kb + (size_t)bh * Nc * 64;
    const unsigned short* vglob = Vt + (size_t)bh * 64 * (size_t)Nc;

    int srow = t >> 3, sseg = t & 7;
    const unsigned short* kptr = kglob + (size_t)srow * 64 + sseg * 8;
    const unsigned short* vptr = vglob + (size_t)srow * Nc + sseg * 8;

    int kts = s * (Nc >> LOGS);
    int nt = (Nc >> LOGS) >> 6;   // 16 for both passes

    bf16x8 rK = *reinterpret_cast<const bf16x8*>(kptr + (size_t)kts * 64);
    bf16x8 rV = *reinterpret_cast<const bf16x8*>(vptr + kts);
    *reinterpret_cast<bf16x8*>(&sK[0][srow][sseg * 8]) = rK;
    *reinterpret_cast<bf16x8*>(&sVt[0][srow][sseg * 8]) = rV;
    rK = *reinterpret_cast<const bf16x8*>(kptr + (size_t)(kts + 64) * 64);
    rV = *reinterpret_cast<const bf16x8*>(vptr + kts + 64);
    __syncthreads();

    int cur = 0;
    for (int ti = 0; ti < nt; ++ti) {
        if (ti + 1 < nt) {
            *reinterpret_cast<bf16x8*>(&sK[cur ^ 1][srow][sseg * 8]) = rK;
            *reinterpret_cast<bf16x8*>(&sVt[cur ^ 1][srow][sseg * 8]) = rV;
            if (ti + 2 < nt) {
                int knext = kts + (ti + 2) * 64;
                rK = *reinterpret_cast<const bf16x8*>(kptr + (size_t)knext * 64);
                rV = *reinterpret_cast<const bf16x8*>(vptr + knext);
            }
        }
#pragma unroll
        for (int half = 0; half < 2; ++half) {
            bf16x8 pa0, pa1;
#pragma unroll
            for (int ki = 0; ki < 2; ++ki) {
                int kt = half * 2 + ki;
                bf16x8 bk0 = *reinterpret_cast<const bf16x8*>(&sK[cur][kt * 16 + lr][lg * 8]);
                bf16x8 bk1 = *reinterpret_cast<const bf16x8*>(&sK[cur][kt * 16 + lr][32 + lg * 8]);
                f32x4 a0 = {}, a1 = {};
                __builtin_amdgcn_s_setprio(1);
                a0 = __builtin_amdgcn_mfma_f32_16x16x32_bf16(bk0, aq[0][0], a0, 0, 0, 0);
                a1 = __builtin_amdgcn_mfma_f32_16x16x32_bf16(bk0, aq[1][0], a1, 0, 0, 0);
                a0 = __builtin_amdgcn_mfma_f32_16x16x32_bf16(bk1, aq[0][1], a0, 0, 0, 0);
                a1 = __builtin_amdgcn_mfma_f32_16x16x32_bf16(bk1, aq[1][1], a1, 0, 0, 0);
                __builtin_amdgcn_s_setprio(0);
                const int hb = ki * 4;
#pragma unroll
                for (int r = 0; r < 4; ++r) {
                    pa0[hb + r] = (__bf16)EXP2F(a0[r]);
                    pa1[hb + r] = (__bf16)EXP2F(a1[r]);
                }
            }
            __builtin_amdgcn_s_setprio(1);
#pragma unroll
            for (int dt = 0; dt < 4; ++dt) {
                bf16x8 vb = *reinterpret_cast<const bf16x8*>(&sVt[cur][dt * 16 + lr][half * 32 + lg * 8]);
                o[0][dt] = __builtin_amdgcn_mfma_f32_16x16x32_bf16(pa0, vb, o[0][dt], 0, 0, 0);
                o[1][dt] = __builtin_amdgcn_mfma_f32_16x16x32_bf16(pa1, vb, o[1][dt], 0, 0, 0);
            }
            osum[0] = __builtin_amdgcn_mfma_f32_16x16x32_bf16(pa0, onesf, osum[0], 0, 0, 0);
            osum[1] = __builtin_amdgcn_mfma_f32_16x16x32_bf16(pa1, onesf, osum[1], 0, 0, 0);
            __builtin_amdgcn_s_setprio(0);
        }
        __syncthreads();
        cur ^= 1;
    }
    unsigned short* obase = Opart + ((size_t)(s * 4 + b) * Nq + q0) * 512 + h * 64;
#pragma unroll
    for (int qt = 0; qt < 2; ++qt)
#pragma unroll
        for (int dt = 0; dt < 4; ++dt)
#pragma unroll
            for (int r = 0; r < 4; ++r)
                obase[(size_t)(qt * 16 + lg * 4 + r) * 512 + dt * 16 + lr] = f2bf(o[qt][dt][r]);
    if (lr == 0) {
        float* lbase = Lpart + ((size_t)(s * 4 + b) * 8 + h) * Nq + q0;
#pragma unroll
        for (int qt = 0; qt < 2; ++qt)
#pragma unroll
            for (int r = 0; r < 4; ++r)
                lbase[qt * 16 + lg * 4 + r] = osum[qt][r];
    }
}

// ---------------- host side ----------------
extern "C" void kernel_launch(void* const* d_in, const int* in_sizes, int n_in,
                              void* d_out, int out_size, void* d_ws, size_t ws_size,
                              hipStream_t stream) {
    const float* x     = (const float*)d_in[0];
    const float* c     = (const float*)d_in[1];
    const float* Wq_x  = (const float*)d_in[2];
    const float* g_qx  = (const float*)d_in[3];
    const float* Wkv_c = (const float*)d_in[4];
    const float* g_kvc = (const float*)d_in[5];
    const float* A_x   = (const float*)d_in[6];
    const float* B_x   = (const float*)d_in[7];
    const float* mag_x = (const float*)d_in[8];
    const float* Wp_x  = (const float*)d_in[9];
    const float* g_px  = (const float*)d_in[10];
    const float* Wq_c  = (const float*)d_in[11];
    const float* g_qc  = (const float*)d_in[12];
    const float* Wkv_x = (const float*)d_in[13];
    const float* g_kvx = (const float*)d_in[14];
    const float* A_c   = (const float*)d_in[15];
    const float* B_c   = (const float*)d_in[16];
    const float* mag_c = (const float*)d_in[17];
    const float* Wp_c  = (const float*)d_in[18];
    const float* g_pc  = (const float*)d_in[19];

    float* ws = (float*)d_ws;
    unsigned short* Wb = (unsigned short*)ws;
    const size_t Woff[6] = {0, 262144, 786432, 1048576, 1310720, 1835008}; // u16 units
    float* part  = ws + 1048576;
    float* sc_xq  = ws + 1049600;
    float* sc_xkv = sc_xq + 16384;
    float* sc_cq  = sc_xkv + 16384;
    float* sc_ckv = sc_cq + 4096;
    float* sc_o1  = sc_ckv + 4096;
    float* sc_o2  = sc_o1 + 16384;
    float* tmp_x  = ws + 1111040;                    // 262144
    float* tmp_c  = tmp_x + 262144;                  // 65536  -> ends 1438720
    float* actblk = ws + 1438720;                    // acts / Opart1 overlay
    unsigned short* act_xq  = (unsigned short*)actblk;                  // 4194304 f
    unsigned short* act_xkv = (unsigned short*)(actblk + 4194304);      // 4194304 f
    unsigned short* act_cq  = (unsigned short*)(actblk + 8388608);      // 1048576 f
    unsigned short* act_ckv = (unsigned short*)(actblk + 9437184);      // 1048576 f
    unsigned short* Opart1 = (unsigned short*)actblk;  // 8.4M u16 over act_xq (dead)
    float* qf1_f  = ws + 11924480;                   // 4194304 f
    unsigned short* Opart2 = (unsigned short*)qf1_f; // 8.4M u16 (S=4; qf1 dead by attn)
    float* qf2_f  = ws + 16118784;                   // 1048576 f
    float* Qb1_f  = ws + 17167360;                   // 4194304 f (-> act_o1)
    float* Qb2_f  = ws + 21361664;                   // 1048576 f (-> act_o2)
    float* Kb1_f  = ws + 22410240;                   // 1048576 f
    float* Vt1_f  = ws + 23458816;                   // 1048576 f
    float* Kb2_f  = ws + 24507392;                   // 4194304 f
    float* Vt2_f  = ws + 28701696;                   // 4194304 f
    float* Lpart1 = ws + 32896000;                   // 131072 f
    float* Lpart2 = ws + 33027072;                   // 131072 f -> ends 33158144

    unsigned short* qf1 = (unsigned short*)qf1_f;
    unsigned short* qf2 = (unsigned short*)qf2_f;
    unsigned short* Qb1 = (unsigned short*)Qb1_f;
    unsigned short* Qb2 = (unsigned short*)Qb2_f;
    unsigned short* Kb1 = (unsigned short*)Kb1_f;
    unsigned short* Vt1 = (unsigned short*)Vt1_f;
    unsigned short* Kb2 = (unsigned short*)Kb2_f;
    unsigned short* Vt2 = (unsigned short*)Vt2_f;
    unsigned short* act_o1 = Qb1;
    unsigned short* act_o2 = Qb2;

    size_t need = (size_t)33158144 * sizeof(float);   // ~132.6 MB
    if (ws_size < need) return;

    float* outx = (float*)d_out;
    float* outc = outx + (size_t)4 * 4096 * 512;

    // L1: weight |.| partials + RMSNorm/quant/DoRA-tmp for both passes
    k_prep1<<<5312, 256, 0, stream>>>(Wq_x, Wkv_c, Wp_x, Wq_c, Wkv_x, Wp_c, part,
                                      x, c, g_qx, g_kvx, g_qc, g_kvc,
                                      act_xq, act_xkv, act_cq, act_ckv,
                                      sc_xq, sc_xkv, sc_cq, sc_ckv,
                                      A_x, A_c, tmp_x, tmp_c);
    // L2: weight ternarize + DoRA delta
    k_prep2<<<49152, 256, 0, stream>>>(Wq_x, Wkv_c, Wp_x, Wq_c, Wkv_x, Wp_c, part, Wb,
                                       tmp_x, tmp_c, B_x, B_c, qf1, qf2);
    // L3: merged Q + KV projections, both passes (KV blocks first, XCD-affine)
    k_gemm_qkv<<<1920, 256, 0, stream>>>(
        act_xq, act_cq, Wb + Woff[0], Wb + Woff[3], sc_xq, sc_cq,
        mag_x, mag_c, qf1, qf2, Qb1, Qb2,
        act_ckv, act_xkv, Wb + Woff[1], Wb + Woff[4], sc_ckv, sc_xkv,
        Kb1, Kb2, Vt1, Vt2, part);
    // L4: attention, both passes, 1024 uniform blocks
    k_attn_mfma<<<1024, 512, 0, stream>>>(Qb1, Kb1, Vt1, Opart1, Lpart1,
                                          Qb2, Kb2, Vt2, Opart2, Lpart2);
    // L5: combine + RMSNorm + quant
    k_rmsq_combine<<<5120, 256, 0, stream>>>(Opart1, Lpart1, g_px, act_o1, sc_o1,
                                             Opart2, Lpart2, g_pc, act_o2, sc_o2);
    // L6: output projections + residual (XCD-affine 1D)
    k_gemm_out<<<640, 256, 0, stream>>>(
        act_o1, act_o2, Wb + Woff[2], Wb + Woff[5], sc_o1, sc_o2, part,
        x, c, outx, outc);
}

// Round 14
// 271.364 us; speedup vs baseline: 61.7341x; 1.0038x over previous
//
#include <hip/hip_runtime.h>
#include <math.h>

#define DD 512
#define NHEAD 8
#define HDIM 64

typedef __bf16 bf16x8 __attribute__((ext_vector_type(8)));
typedef unsigned short u16x8 __attribute__((ext_vector_type(8)));
typedef float f32x4 __attribute__((ext_vector_type(4)));

#if __has_builtin(__builtin_amdgcn_exp2f)
#define EXP2F(x) __builtin_amdgcn_exp2f(x)
#else
#define EXP2F(x) exp2f(x)
#endif

#define QSCALE 0.18033688f  /* (1/8) * log2(e): exp2 domain */

static __device__ __forceinline__ unsigned short f2bf(float f) {
    unsigned u = __builtin_bit_cast(unsigned, f);
    u += 0x7fffu + ((u >> 16) & 1u);   // round-to-nearest-even
    return (unsigned short)(u >> 16);
}
static __device__ __forceinline__ float bf2f(unsigned short u) {
    return __builtin_bit_cast(float, (unsigned)u << 16);
}

// sum of part[mid*32 .. +31] via wave butterfly; deterministic, same order everywhere
static __device__ __forceinline__ float wsum32(const float* __restrict__ part, int mid) {
    int l = threadIdx.x & 63;
    float v = (l < 32) ? part[mid * 32 + l] : 0.f;
#pragma unroll
    for (int o = 16; o > 0; o >>= 1) v += __shfl_xor(v, o);
    return __shfl(v, 0);
}

#define GLOAD16(g, l)                                                          \
    __builtin_amdgcn_global_load_lds(                                          \
        (__attribute__((address_space(1))) void*)(g),                          \
        (__attribute__((address_space(3))) void*)(l), 16, 0, 0)

#define BSTEP(s, hc)                                                           \
    {                                                                          \
        _Pragma("unroll")                                                      \
        for (int i = 0; i < (hc); ++i) {                                       \
            float send = (lane & (s)) ? p[i] : p[i + (hc)];                    \
            float recv = __shfl_xor(send, (s));                                \
            p[i] = ((lane & (s)) ? p[i + (hc)] : p[i]) + recv;                 \
        }                                                                      \
    }

// double-buffered MFMA GEMM K-loop over K=512, BK=32 (T3 minimum 2-phase):
// issue next tile's global_load_lds BEFORE computing current; one barrier/step.
#define GEMM_KLOOP(Aq, Wq, m0, n0)                                             \
    {                                                                          \
        _Pragma("unroll")                                                      \
        for (int i = 0; i < 2; ++i) {                                          \
            int row = i * 64 + row_st;                                         \
            GLOAD16(Aq + (size_t)((m0) + row) * 512 + chunk * 8,               \
                    sA[0] + ((size_t)i * 256 + t) * 8);                        \
            GLOAD16(Wq + (size_t)((n0) + row) * 512 + chunk * 8,               \
                    sB[0] + ((size_t)i * 256 + t) * 8);                        \
        }                                                                      \
        asm volatile("s_waitcnt vmcnt(0)" ::: "memory");                       \
        __syncthreads();                                                       \
        int cur = 0;                                                           \
        for (int k0 = 0; k0 < 512; k0 += 32) {                                 \
            if (k0 + 32 < 512) {                                               \
                _Pragma("unroll")                                              \
                for (int i = 0; i < 2; ++i) {                                  \
                    int row = i * 64 + row_st;                                 \
                    GLOAD16(Aq + (size_t)((m0) + row) * 512 + k0 + 32 + chunk * 8, \
                            sA[cur ^ 1] + ((size_t)i * 256 + t) * 8);          \
                    GLOAD16(Wq + (size_t)((n0) + row) * 512 + k0 + 32 + chunk * 8, \
                            sB[cur ^ 1] + ((size_t)i * 256 + t) * 8);          \
                }                                                              \
            }                                                                  \
            bf16x8 af[4], bfr[4];                                              \
            _Pragma("unroll")                                                  \
            for (int mt = 0; mt < 4; ++mt)                                     \
                af[mt] = *reinterpret_cast<const bf16x8*>(                     \
                    &sA[cur][(wm * 64 + mt * 16 + lr) * 32 + lg * 8]);         \
            _Pragma("unroll")                                                  \
            for (int nt = 0; nt < 4; ++nt)                                     \
                bfr[nt] = *reinterpret_cast<const bf16x8*>(                    \
                    &sB[cur][(wn * 64 + nt * 16 + lr) * 32 + lg * 8]);         \
            __builtin_amdgcn_s_setprio(1);                                     \
            _Pragma("unroll")                                                  \
            for (int mt = 0; mt < 4; ++mt)                                     \
                _Pragma("unroll")                                              \
                for (int nt = 0; nt < 4; ++nt)                                 \
                    acc[mt][nt] = __builtin_amdgcn_mfma_f32_16x16x32_bf16(     \
                        af[mt], bfr[nt], acc[mt][nt], 0, 0, 0);                \
            __builtin_amdgcn_s_setprio(0);                                     \
            asm volatile("s_waitcnt vmcnt(0)" ::: "memory");                   \
            __syncthreads();                                                   \
            cur ^= 1;                                                          \
        }                                                                      \
    }

// ---------------- prep1: weight |.| partials (192 blocks) + RMSNorm/quant/DoRA (5120 blocks) ----------------
__global__ __launch_bounds__(256) void k_prep1(
    const float* __restrict__ W0, const float* __restrict__ W1,
    const float* __restrict__ W2, const float* __restrict__ W3,
    const float* __restrict__ W4, const float* __restrict__ W5,
    float* __restrict__ part,
    const float* __restrict__ x, const float* __restrict__ c,
    const float* __restrict__ g_qx, const float* __restrict__ g_kvx,
    const float* __restrict__ g_qc, const float* __restrict__ g_kvc,
    unsigned short* __restrict__ a_xq, unsigned short* __restrict__ a_xkv,
    unsigned short* __restrict__ a_cq, unsigned short* __restrict__ a_ckv,
    float* __restrict__ s_xq, float* __restrict__ s_xkv,
    float* __restrict__ s_cq, float* __restrict__ s_ckv,
    const float* __restrict__ A_x, const float* __restrict__ A_c,
    float* __restrict__ tmp_x, float* __restrict__ tmp_c) {
    int t = threadIdx.x;
    if (blockIdx.x < 192) {
        const float* Ws[6] = {W0, W1, W2, W3, W4, W5};
        const int cnt[6] = {262144, 524288, 262144, 262144, 524288, 262144};
        int mid = blockIdx.x >> 5, lb = blockIdx.x & 31;
        const float* W = Ws[mid];
        int n = cnt[mid];
        float s = 0.f;
        for (int i = lb * 256 + t; i < n; i += 32 * 256) s += fabsf(W[i]);
        __shared__ float red[4];
#pragma unroll
        for (int o = 32; o > 0; o >>= 1) s += __shfl_down(s, o);
        if ((t & 63) == 0) red[t >> 6] = s;
        __syncthreads();
        if (t == 0) part[blockIdx.x] = red[0] + red[1] + red[2] + red[3];
        return;
    }
    int w = t >> 6, lane = t & 63;
    int row = (int)(blockIdx.x - 192) * 4 + w;
    bool pc = (row >= 16384);
    int r = pc ? row - 16384 : row;
    const float* xr = (pc ? c : x) + (size_t)r * DD;
    const float* G1 = pc ? g_qc : g_qx;
    const float* G2 = pc ? g_kvc : g_kvx;
    unsigned short* O1 = pc ? a_cq : a_xq;
    unsigned short* O2 = pc ? a_ckv : a_xkv;
    float* S1 = pc ? s_cq : s_xq;
    float* S2 = pc ? s_ckv : s_xkv;
    const float* AM = pc ? A_c : A_x;
    float* TMP = pc ? tmp_c : tmp_x;

    float4 a = *(const float4*)(xr + lane * 8);
    float4 b = *(const float4*)(xr + lane * 8 + 4);
    float p[16];
#pragma unroll
    for (int cc = 0; cc < 16; ++cc) {
        const float4* ar = (const float4*)(AM + (size_t)cc * DD + lane * 8);
        float4 aa = ar[0], ab = ar[1];
        p[cc] = a.x*aa.x + a.y*aa.y + a.z*aa.z + a.w*aa.w
              + b.x*ab.x + b.y*ab.y + b.z*ab.z + b.w*ab.w;
    }
    BSTEP(1, 8) BSTEP(2, 4) BSTEP(4, 2) BSTEP(8, 1)
    p[0] += __shfl_xor(p[0], 16);
    p[0] += __shfl_xor(p[0], 32);
    if (lane < 16) {
        int cidx = ((lane & 1) << 3) | ((lane & 2) << 1) | ((lane & 4) >> 1) | ((lane & 8) >> 3);
        TMP[(size_t)r * 16 + cidx] = p[0];
    }
    float ss = a.x*a.x + a.y*a.y + a.z*a.z + a.w*a.w
             + b.x*b.x + b.y*b.y + b.z*b.z + b.w*b.w;
#pragma unroll
    for (int o = 32; o > 0; o >>= 1) ss += __shfl_xor(ss, o);
    float rn = 1.f / sqrtf(ss * (1.f / 512.f) + 1e-8f);
    const float* gs[2] = {G1, G2};
    unsigned short* os[2] = {O1, O2};
    float* scs[2] = {S1, S2};
#pragma unroll
    for (int pass = 0; pass < 2; ++pass) {
        float4 ga = *(const float4*)(gs[pass] + lane * 8);
        float4 gb = *(const float4*)(gs[pass] + lane * 8 + 4);
        float v[8] = {a.x*rn*ga.x, a.y*rn*ga.y, a.z*rn*ga.z, a.w*rn*ga.w,
                      b.x*rn*gb.x, b.y*rn*gb.y, b.z*rn*gb.z, b.w*rn*gb.w};
        float amax = 0.f;
#pragma unroll
        for (int i = 0; i < 8; ++i) amax = fmaxf(amax, fabsf(v[i]));
#pragma unroll
        for (int o = 32; o > 0; o >>= 1) amax = fmaxf(amax, __shfl_xor(amax, o));
        float mx = fmaxf(amax, 1e-5f);
        float scale = 127.f / mx;
        u16x8 qv;
#pragma unroll
        for (int i = 0; i < 8; ++i) {
            float tq = rintf(v[i] * scale);
            tq = fminf(fmaxf(tq, -128.f), 127.f);
            qv[i] = f2bf(tq);
        }
        *reinterpret_cast<u16x8*>(os[pass] + (size_t)r * DD + lane * 8) = qv;
        if (lane == 0) scs[pass][r] = mx / 127.f;
    }
}

// ---------------- prep2: weight ternarize (8192 blocks) + DoRA delta (40960 blocks) ----------------
__global__ __launch_bounds__(256) void k_prep2(
    const float* __restrict__ W0, const float* __restrict__ W1,
    const float* __restrict__ W2, const float* __restrict__ W3,
    const float* __restrict__ W4, const float* __restrict__ W5,
    const float* __restrict__ part, unsigned short* __restrict__ Wq,
    const float* __restrict__ tmp_x, const float* __restrict__ tmp_c,
    const float* __restrict__ B_x, const float* __restrict__ B_c,
    unsigned short* __restrict__ qf1, unsigned short* __restrict__ qf2) {
    if (blockIdx.x < 8192) {
        int e = blockIdx.x * 256 + threadIdx.x;
        const float* Ws[6] = {W0, W1, W2, W3, W4, W5};
        int mid, base;
        if (e < 262144)       { mid = 0; base = 0; }
        else if (e < 786432)  { mid = 1; base = 262144; }
        else if (e < 1048576) { mid = 2; base = 786432; }
        else if (e < 1310720) { mid = 3; base = 1048576; }
        else if (e < 1835008) { mid = 4; base = 1310720; }
        else                  { mid = 5; base = 1835008; }
        float cnt = (mid == 1 || mid == 4) ? 524288.f : 262144.f;
        float mean = fmaxf(wsum32(part, mid) / cnt, 1e-5f);
        float sc = 1.f / mean;
        float t = rintf(Ws[mid][e - base] * sc);
        t = fminf(fmaxf(t, -1.f), 1.f);
        Wq[e] = f2bf(t);
        return;
    }
    int idx = (int)(blockIdx.x - 8192) * 256 + threadIdx.x;   // over 20480*512
    int m2 = idx >> 9, n2 = idx & 511;
    const float* tr;
    const float* br;
    unsigned short* out;
    if (m2 < 16384) {
        tr = tmp_x + (size_t)m2 * 16; br = B_x + (size_t)n2 * 16; out = qf1 + idx;
    } else {
        tr = tmp_c + (size_t)(m2 - 16384) * 16; br = B_c + (size_t)n2 * 16;
        out = qf2 + (idx - 8388608);
    }
    const float4* t4 = (const float4*)tr;
    const float4* b4 = (const float4*)br;
    float acc = 0.f;
#pragma unroll
    for (int rr = 0; rr < 4; ++rr) {
        float4 ta = t4[rr], ba = b4[rr];
        acc += ta.x*ba.x + ta.y*ba.y + ta.z*ba.z + ta.w*ba.w;
    }
    *out = f2bf(acc);
}

// ---------------- combine attn partials (bf16) + RMSNorm + quant, both passes, 4 rows/block ----------------
__global__ __launch_bounds__(256) void k_rmsq_combine(
    const unsigned short* __restrict__ Op_a, const float* __restrict__ Lp_a,
    const float* __restrict__ g_a, unsigned short* __restrict__ out_a,
    float* __restrict__ sc_a,
    const unsigned short* __restrict__ Op_b, const float* __restrict__ Lp_b,
    const float* __restrict__ g_b, unsigned short* __restrict__ out_b,
    float* __restrict__ sc_b) {
    int w = threadIdx.x >> 6, lane = threadIdx.x & 63;
    int row = (int)blockIdx.x * 4 + w;
    bool pb = (row >= 16384);
    int r = pb ? row - 16384 : row;
    int S = pb ? 4 : 1;
    int lognq = pb ? 10 : 12;
    const unsigned short* Op = pb ? Op_b : Op_a;
    const float* Lp = pb ? Lp_b : Lp_a;
    const float* g  = pb ? g_b : g_a;
    unsigned short* out = pb ? out_b : out_a;
    float* a_inv = pb ? sc_b : sc_a;

    int Nq = 1 << lognq;
    int b = r >> lognq, q = r & (Nq - 1);
    int h = lane >> 3;
    float l = 0.f;
    float u[8] = {};
    for (int s = 0; s < S; ++s) {
        l += Lp[((size_t)(s * 4 + b) * 8 + h) * Nq + q];
        u16x8 ov = *reinterpret_cast<const u16x8*>(
            Op + ((size_t)(s * 4 + b) * Nq + q) * 512 + lane * 8);
#pragma unroll
        for (int i = 0; i < 8; ++i) u[i] += bf2f(ov[i]);
    }
    float invl = 1.f / l;
#pragma unroll
    for (int i = 0; i < 8; ++i) u[i] *= invl;
    float ss = 0.f;
#pragma unroll
    for (int i = 0; i < 8; ++i) ss += u[i] * u[i];
#pragma unroll
    for (int o = 32; o > 0; o >>= 1) ss += __shfl_xor(ss, o);
    float rn = 1.f / sqrtf(ss * (1.f / 512.f) + 1e-8f);
    float4 ga = *(const float4*)(g + lane * 8);
    float4 gb = *(const float4*)(g + lane * 8 + 4);
    float v[8] = {u[0]*rn*ga.x, u[1]*rn*ga.y, u[2]*rn*ga.z, u[3]*rn*ga.w,
                  u[4]*rn*gb.x, u[5]*rn*gb.y, u[6]*rn*gb.z, u[7]*rn*gb.w};
    float amax = 0.f;
#pragma unroll
    for (int i = 0; i < 8; ++i) amax = fmaxf(amax, fabsf(v[i]));
#pragma unroll
    for (int o = 32; o > 0; o >>= 1) amax = fmaxf(amax, __shfl_xor(amax, o));
    float mx = fmaxf(amax, 1e-5f);
    float scale = 127.f / mx;
    u16x8 qv;
#pragma unroll
    for (int i = 0; i < 8; ++i) {
        float tq = rintf(v[i] * scale);
        tq = fminf(fmaxf(tq, -128.f), 127.f);
        qv[i] = f2bf(tq);
    }
    *reinterpret_cast<u16x8*>(out + (size_t)r * DD + lane * 8) = qv;
    if (lane == 0) a_inv[r] = mx / 127.f;
}

// ---------------- merged Q + KV projection GEMM (one launch, 1920 blocks) ----------------
// XCD-affinity swizzle + double-buffered single-barrier K-loop.
__global__ __launch_bounds__(256) void k_gemm_qkv(
    const unsigned short* __restrict__ a3_a, const unsigned short* __restrict__ a3_b,
    const unsigned short* __restrict__ w3_a, const unsigned short* __restrict__ w3_b,
    const float* __restrict__ ai3_a, const float* __restrict__ ai3_b,
    const float* __restrict__ mag_a, const float* __restrict__ mag_b,
    const unsigned short* __restrict__ dl_a, const unsigned short* __restrict__ dl_b,
    unsigned short* __restrict__ Qb_a, unsigned short* __restrict__ Qb_b,
    const unsigned short* __restrict__ a4_a, const unsigned short* __restrict__ a4_b,
    const unsigned short* __restrict__ w4_a, const unsigned short* __restrict__ w4_b,
    const float* __restrict__ ai4_a, const float* __restrict__ ai4_b,
    unsigned short* __restrict__ Kb_a, unsigned short* __restrict__ Kb_b,
    unsigned short* __restrict__ Vt_a, unsigned short* __restrict__ Vt_b,
    const float* __restrict__ part) {
    __shared__ __align__(16) unsigned short sA[2][128 * 32];
    __shared__ __align__(16) unsigned short sB[2][128 * 32];
    int bid = blockIdx.x;
    bool isQ = (bid >= 1280);
    const unsigned short *Aq, *Wq;
    const float* a_inv;
    int m0, n0, logn, mid;
    float cnt;
    bool pb;
    if (!isQ) {
        int g = bid & 7, k = bid >> 3;       // XCD-affine: my%8 == g
        n0 = (k & 7) * 128;
        int my = (k >> 3) * 8 + g;           // 0..159
        pb = my >= 32;
        m0 = (pb ? my - 32 : my) * 128;
        Aq = pb ? a4_b : a4_a;  Wq = pb ? w4_b : w4_a;
        a_inv = pb ? ai4_b : ai4_a;
        logn = pb ? 12 : 10;
        mid = pb ? 4 : 1; cnt = 524288.f;
    } else {
        int b2 = bid - 1280;                 // 1280%8==0: preserves XCD phase
        int g = b2 & 7, k = b2 >> 3;
        n0 = (k & 3) * 128;
        int my = (k >> 2) * 8 + g;           // 0..159
        pb = my >= 128;
        m0 = (pb ? my - 128 : my) * 128;
        Aq = pb ? a3_b : a3_a;  Wq = pb ? w3_b : w3_a;
        a_inv = pb ? ai3_b : ai3_a;
        logn = pb ? 10 : 12;
        mid = pb ? 3 : 0; cnt = 262144.f;
    }
    float wv = fmaxf(wsum32(part, mid) / cnt, 1e-5f);

    int t = threadIdx.x;
    int w = t >> 6, lane = t & 63;
    int wm = w >> 1, wn = w & 1;
    int lr = lane & 15, lg = lane >> 4;
    int row_st = t >> 2, chunk = t & 3;
    f32x4 acc[4][4] = {};

    GEMM_KLOOP(Aq, Wq, m0, n0)

    if (!isQ) {
        unsigned short* OutB = pb ? Kb_b : Kb_a;
        unsigned short* OutB2 = pb ? Vt_b : Vt_a;
        const bool isV = (n0 >= 512);
        const int Nc = 1 << logn;
#pragma unroll
        for (int mt = 0; mt < 4; ++mt) {
            int mb = m0 + wm * 64 + mt * 16 + lg * 4;
            int b = mb >> logn, key = mb & (Nc - 1);
            float as_[4];
#pragma unroll
            for (int r = 0; r < 4; ++r) as_[r] = a_inv[mb + r] * wv;
#pragma unroll
            for (int nt = 0; nt < 4; ++nt) {
                int n = n0 + wn * 64 + nt * 16 + lr;
                int n2 = isV ? (n - 512) : n;
                int h = n2 >> 6, dd = n2 & 63;
                if (isV) {
                    int i0 = key & 31;
                    int keyp = (key & ~31) | (((i0 >> 2) & 3) * 8 + ((i0 >> 4) & 1) * 4);
                    ushort4 v;
                    v.x = f2bf(acc[mt][nt][0] * as_[0]);
                    v.y = f2bf(acc[mt][nt][1] * as_[1]);
                    v.z = f2bf(acc[mt][nt][2] * as_[2]);
                    v.w = f2bf(acc[mt][nt][3] * as_[3]);
                    *reinterpret_cast<ushort4*>(
                        OutB2 + ((size_t)(b * NHEAD + h) * 64 + dd) * Nc + keyp) = v;
                } else {
#pragma unroll
                    for (int r = 0; r < 4; ++r)
                        OutB[((size_t)(b * NHEAD + h) * Nc + key + r) * 64 + dd] =
                            f2bf(acc[mt][nt][r] * as_[r]);
                }
            }
        }
    } else {
        const float* Extra = pb ? mag_b : mag_a;
        const unsigned short* Dlt = pb ? dl_b : dl_a;
        unsigned short* OutB = pb ? Qb_b : Qb_a;
#pragma unroll
        for (int mt = 0; mt < 4; ++mt) {
#pragma unroll
            for (int r = 0; r < 4; ++r) {
                int m = m0 + wm * 64 + mt * 16 + lg * 4 + r;
                float as = a_inv[m] * wv;
                int b = m >> logn, q = m & ((1 << logn) - 1);
#pragma unroll
                for (int nt = 0; nt < 4; ++nt) {
                    int n = n0 + wn * 64 + nt * 16 + lr;
                    float dl = bf2f(Dlt[(size_t)m * 512 + n]);
                    float val = acc[mt][nt][r] * as + Extra[n >> 6] * dl;
                    int h = n >> 6, d = n & 63;
                    OutB[((((size_t)(b * NHEAD + h)) << logn) + q) * 64 + d] =
                        f2bf(val * QSCALE);
                }
            }
        }
    }
}

// ---------------- output projection GEMM + residual, both passes (1D, XCD-affine) ----------------
__global__ __launch_bounds__(256) void k_gemm_out(
    const unsigned short* __restrict__ a_a, const unsigned short* __restrict__ a_b,
    const unsigned short* __restrict__ w_a, const unsigned short* __restrict__ w_b,
    const float* __restrict__ ai_a, const float* __restrict__ ai_b,
    const float* __restrict__ part,
    const float* __restrict__ Ex_a, const float* __restrict__ Ex_b,
    float* __restrict__ OF_a, float* __restrict__ OF_b) {
    __shared__ __align__(16) unsigned short sA[2][128 * 32];
    __shared__ __align__(16) unsigned short sB[2][128 * 32];
    int bid = blockIdx.x;                    // 0..639
    int g = bid & 7, k = bid >> 3;           // XCD-affine: my%8 == g
    int n0 = (k & 3) * 128;
    int my = (k >> 2) * 8 + g;               // 0..159
    bool pb = (my >= 128);
    int m0 = (pb ? my - 128 : my) * 128;
    const unsigned short* Aq = pb ? a_b : a_a;
    const unsigned short* Wq = pb ? w_b : w_a;
    const float* a_inv = pb ? ai_b : ai_a;
    const float* Extra = pb ? Ex_b : Ex_a;
    float* OutF = pb ? OF_b : OF_a;
    float wv = fmaxf(wsum32(part, pb ? 5 : 2) / 262144.f, 1e-5f);

    int t = threadIdx.x;
    int w = t >> 6, lane = t & 63;
    int wm = w >> 1, wn = w & 1;
    int lr = lane & 15, lg = lane >> 4;
    int row_st = t >> 2, chunk = t & 3;
    f32x4 acc[4][4] = {};

    GEMM_KLOOP(Aq, Wq, m0, n0)

#pragma unroll
    for (int mt = 0; mt < 4; ++mt) {
#pragma unroll
        for (int r = 0; r < 4; ++r) {
            int m = m0 + wm * 64 + mt * 16 + lg * 4 + r;
            float as = a_inv[m] * wv;
#pragma unroll
            for (int nt = 0; nt < 4; ++nt) {
                int n = n0 + wn * 64 + nt * 16 + lr;
                size_t idx = (size_t)m * 512 + n;
                OutF[idx] = acc[mt][nt][r] * as + Extra[idx];
            }
        }
    }
}

// ---------------- flash attention: swapped-QK^T, in-register P, dbuf LDS ----------------
// 1024 uniform blocks (16 tiles each, 4 blocks/CU): bid<512 = pass2 (S=4 key-splits),
// bid>=512 = pass1 (S=1). 512 threads = 8 waves, 32 q/wave.
__global__ __launch_bounds__(512) void k_attn_mfma(
    const unsigned short* __restrict__ Qb_a, const unsigned short* __restrict__ Kb_a,
    const unsigned short* __restrict__ Vt_a, unsigned short* __restrict__ Op_a,
    float* __restrict__ Lp_a,
    const unsigned short* __restrict__ Qb_b, const unsigned short* __restrict__ Kb_b,
    const unsigned short* __restrict__ Vt_b, unsigned short* __restrict__ Op_b,
    float* __restrict__ Lp_b) {
    __shared__ unsigned short sK[2][64][72];
    __shared__ unsigned short sVt[2][64][72];
    int t = threadIdx.x;
    int w = t >> 6, lane = t & 63;
    int lr = lane & 15, lg = lane >> 4;

    int bid = blockIdx.x;
    bool pb = (bid < 512);
    int lb = pb ? bid : bid - 512;
    const unsigned short* Qb = pb ? Qb_b : Qb_a;
    const unsigned short* Kb = pb ? Kb_b : Kb_a;
    const unsigned short* Vt = pb ? Vt_b : Vt_a;
    unsigned short* Opart = pb ? Op_b : Op_a;
    float* Lpart = pb ? Lp_b : Lp_a;
    int Nq = pb ? 1024 : 4096;
    int Nc = pb ? 4096 : 1024;
    int S = pb ? 4 : 1;
    int LOGS = pb ? 2 : 0;
    int nqs = pb ? 2 : 4;

    int j = lb >> 3;
    int s = j & (S - 1);
    int j2 = j >> LOGS;
    int qblk = j2 & ((1 << nqs) - 1);
    int bh = ((lb & 7) << 2) | (j2 >> nqs);   // XCD-local bh groups
    int b = bh >> 3, h = bh & 7;
    int q0 = qblk * 256 + w * 32;

    bf16x8 aq[2][2];
#pragma unroll
    for (int qt = 0; qt < 2; ++qt) {
        const unsigned short* qbase = Qb + ((size_t)bh * Nq + q0 + qt * 16 + lr) * 64 + lg * 8;
        aq[qt][0] = *reinterpret_cast<const bf16x8*>(qbase);
        aq[qt][1] = *reinterpret_cast<const bf16x8*>(qbase + 32);
    }

    u16x8 ou;
#pragma unroll
    for (int jj = 0; jj < 8; ++jj) ou[jj] = (lr == 0) ? 0x3F80 : 0;
    bf16x8 onesf = __builtin_bit_cast(bf16x8, ou);

    f32x4 o[2][4] = {};
    f32x4 osum[2] = {};

    const unsigned short* kglob = Kb + (size_t)bh * Nc * 64;
    const unsigned short* vglob = Vt + (size_t)bh * 64 * (size_t)Nc;

    int srow = t >> 3, sseg = t & 7;
    const unsigned short* kptr = kglob + (size_t)srow * 64 + sseg * 8;
    const unsigned short* vptr = vglob + (size_t)srow * Nc + sseg * 8;

    int kts = s * (Nc >> LOGS);
    int nt = (Nc >> LOGS) >> 6;   // 16 for both passes

    bf16x8 rK = *reinterpret_cast<const bf16x8*>(kptr + (size_t)kts * 64);
    bf16x8 rV = *reinterpret_cast<const bf16x8*>(vptr + kts);
    *reinterpret_cast<bf16x8*>(&sK[0][srow][sseg * 8]) = rK;
    *reinterpret_cast<bf16x8*>(&sVt[0][srow][sseg * 8]) = rV;
    rK = *reinterpret_cast<const bf16x8*>(kptr + (size_t)(kts + 64) * 64);
    rV = *reinterpret_cast<const bf16x8*>(vptr + kts + 64);
    __syncthreads();

    int cur = 0;
    for (int ti = 0; ti < nt; ++ti) {
        if (ti + 1 < nt) {
            *reinterpret_cast<bf16x8*>(&sK[cur ^ 1][srow][sseg * 8]) = rK;
            *reinterpret_cast<bf16x8*>(&sVt[cur ^ 1][srow][sseg * 8]) = rV;
            if (ti + 2 < nt) {
                int knext = kts + (ti + 2) * 64;
                rK = *reinterpret_cast<const bf16x8*>(kptr + (size_t)knext * 64);
                rV = *reinterpret_cast<const bf16x8*>(vptr + knext);
            }
        }
#pragma unroll
        for (int half = 0; half < 2; ++half) {
            bf16x8 pa0, pa1;
#pragma unroll
            for (int ki = 0; ki < 2; ++ki) {
                int kt = half * 2 + ki;
                bf16x8 bk0 = *reinterpret_cast<const bf16x8*>(&sK[cur][kt * 16 + lr][lg * 8]);
                bf16x8 bk1 = *reinterpret_cast<const bf16x8*>(&sK[cur][kt * 16 + lr][32 + lg * 8]);
                f32x4 a0 = {}, a1 = {};
                __builtin_amdgcn_s_setprio(1);
                a0 = __builtin_amdgcn_mfma_f32_16x16x32_bf16(bk0, aq[0][0], a0, 0, 0, 0);
                a1 = __builtin_amdgcn_mfma_f32_16x16x32_bf16(bk0, aq[1][0], a1, 0, 0, 0);
                a0 = __builtin_amdgcn_mfma_f32_16x16x32_bf16(bk1, aq[0][1], a0, 0, 0, 0);
                a1 = __builtin_amdgcn_mfma_f32_16x16x32_bf16(bk1, aq[1][1], a1, 0, 0, 0);
                __builtin_amdgcn_s_setprio(0);
                const int hb = ki * 4;
#pragma unroll
                for (int r = 0; r < 4; ++r) {
                    pa0[hb + r] = (__bf16)EXP2F(a0[r]);
                    pa1[hb + r] = (__bf16)EXP2F(a1[r]);
                }
            }
            __builtin_amdgcn_s_setprio(1);
#pragma unroll
            for (int dt = 0; dt < 4; ++dt) {
                bf16x8 vb = *reinterpret_cast<const bf16x8*>(&sVt[cur][dt * 16 + lr][half * 32 + lg * 8]);
                o[0][dt] = __builtin_amdgcn_mfma_f32_16x16x32_bf16(pa0, vb, o[0][dt], 0, 0, 0);
                o[1][dt] = __builtin_amdgcn_mfma_f32_16x16x32_bf16(pa1, vb, o[1][dt], 0, 0, 0);
            }
            osum[0] = __builtin_amdgcn_mfma_f32_16x16x32_bf16(pa0, onesf, osum[0], 0, 0, 0);
            osum[1] = __builtin_amdgcn_mfma_f32_16x16x32_bf16(pa1, onesf, osum[1], 0, 0, 0);
            __builtin_amdgcn_s_setprio(0);
        }
        __syncthreads();
        cur ^= 1;
    }
    unsigned short* obase = Opart + ((size_t)(s * 4 + b) * Nq + q0) * 512 + h * 64;
#pragma unroll
    for (int qt = 0; qt < 2; ++qt)
#pragma unroll
        for (int dt = 0; dt < 4; ++dt)
#pragma unroll
            for (int r = 0; r < 4; ++r)
                obase[(size_t)(qt * 16 + lg * 4 + r) * 512 + dt * 16 + lr] = f2bf(o[qt][dt][r]);
    if (lr == 0) {
        float* lbase = Lpart + ((size_t)(s * 4 + b) * 8 + h) * Nq + q0;
#pragma unroll
        for (int qt = 0; qt < 2; ++qt)
#pragma unroll
            for (int r = 0; r < 4; ++r)
                lbase[qt * 16 + lg * 4 + r] = osum[qt][r];
    }
}

// ---------------- host side ----------------
extern "C" void kernel_launch(void* const* d_in, const int* in_sizes, int n_in,
                              void* d_out, int out_size, void* d_ws, size_t ws_size,
                              hipStream_t stream) {
    const float* x     = (const float*)d_in[0];
    const float* c     = (const float*)d_in[1];
    const float* Wq_x  = (const float*)d_in[2];
    const float* g_qx  = (const float*)d_in[3];
    const float* Wkv_c = (const float*)d_in[4];
    const float* g_kvc = (const float*)d_in[5];
    const float* A_x   = (const float*)d_in[6];
    const float* B_x   = (const float*)d_in[7];
    const float* mag_x = (const float*)d_in[8];
    const float* Wp_x  = (const float*)d_in[9];
    const float* g_px  = (const float*)d_in[10];
    const float* Wq_c  = (const float*)d_in[11];
    const float* g_qc  = (const float*)d_in[12];
    const float* Wkv_x = (const float*)d_in[13];
    const float* g_kvx = (const float*)d_in[14];
    const float* A_c   = (const float*)d_in[15];
    const float* B_c   = (const float*)d_in[16];
    const float* mag_c = (const float*)d_in[17];
    const float* Wp_c  = (const float*)d_in[18];
    const float* g_pc  = (const float*)d_in[19];

    float* ws = (float*)d_ws;
    unsigned short* Wb = (unsigned short*)ws;
    const size_t Woff[6] = {0, 262144, 786432, 1048576, 1310720, 1835008}; // u16 units
    float* part  = ws + 1048576;
    float* sc_xq  = ws + 1049600;
    float* sc_xkv = sc_xq + 16384;
    float* sc_cq  = sc_xkv + 16384;
    float* sc_ckv = sc_cq + 4096;
    float* sc_o1  = sc_ckv + 4096;
    float* sc_o2  = sc_o1 + 16384;
    float* tmp_x  = ws + 1111040;                    // 262144
    float* tmp_c  = tmp_x + 262144;                  // 65536  -> ends 1438720
    float* actblk = ws + 1438720;                    // acts / Opart1 overlay
    unsigned short* act_xq  = (unsigned short*)actblk;                  // 4194304 f
    unsigned short* act_xkv = (unsigned short*)(actblk + 4194304);      // 4194304 f
    unsigned short* act_cq  = (unsigned short*)(actblk + 8388608);      // 1048576 f
    unsigned short* act_ckv = (unsigned short*)(actblk + 9437184);      // 1048576 f
    unsigned short* Opart1 = (unsigned short*)actblk;  // 8.4M u16 over act_xq (dead)
    float* qf1_f  = ws + 11924480;                   // 4194304 f
    unsigned short* Opart2 = (unsigned short*)qf1_f; // 8.4M u16 (S=4; qf1 dead by attn)
    float* qf2_f  = ws + 16118784;                   // 1048576 f
    float* Qb1_f  = ws + 17167360;                   // 4194304 f (-> act_o1)
    float* Qb2_f  = ws + 21361664;                   // 1048576 f (-> act_o2)
    float* Kb1_f  = ws + 22410240;                   // 1048576 f
    float* Vt1_f  = ws + 23458816;                   // 1048576 f
    float* Kb2_f  = ws + 24507392;                   // 4194304 f
    float* Vt2_f  = ws + 28701696;                   // 4194304 f
    float* Lpart1 = ws + 32896000;                   // 131072 f
    float* Lpart2 = ws + 33027072;                   // 131072 f -> ends 33158144

    unsigned short* qf1 = (unsigned short*)qf1_f;
    unsigned short* qf2 = (unsigned short*)qf2_f;
    unsigned short* Qb1 = (unsigned short*)Qb1_f;
    unsigned short* Qb2 = (unsigned short*)Qb2_f;
    unsigned short* Kb1 = (unsigned short*)Kb1_f;
    unsigned short* Vt1 = (unsigned short*)Vt1_f;
    unsigned short* Kb2 = (unsigned short*)Kb2_f;
    unsigned short* Vt2 = (unsigned short*)Vt2_f;
    unsigned short* act_o1 = Qb1;
    unsigned short* act_o2 = Qb2;

    size_t need = (size_t)33158144 * sizeof(float);   // ~132.6 MB
    if (ws_size < need) return;

    float* outx = (float*)d_out;
    float* outc = outx + (size_t)4 * 4096 * 512;

    // L1: weight |.| partials + RMSNorm/quant/DoRA-tmp for both passes
    k_prep1<<<5312, 256, 0, stream>>>(Wq_x, Wkv_c, Wp_x, Wq_c, Wkv_x, Wp_c, part,
                                      x, c, g_qx, g_kvx, g_qc, g_kvc,
                                      act_xq, act_xkv, act_cq, act_ckv,
                                      sc_xq, sc_xkv, sc_cq, sc_ckv,
                                      A_x, A_c, tmp_x, tmp_c);
    // L2: weight ternarize + DoRA delta
    k_prep2<<<49152, 256, 0, stream>>>(Wq_x, Wkv_c, Wp_x, Wq_c, Wkv_x, Wp_c, part, Wb,
                                       tmp_x, tmp_c, B_x, B_c, qf1, qf2);
    // L3: merged Q + KV projections, both passes (KV blocks first, XCD-affine, dbuf)
    k_gemm_qkv<<<1920, 256, 0, stream>>>(
        act_xq, act_cq, Wb + Woff[0], Wb + Woff[3], sc_xq, sc_cq,
        mag_x, mag_c, qf1, qf2, Qb1, Qb2,
        act_ckv, act_xkv, Wb + Woff[1], Wb + Woff[4], sc_ckv, sc_xkv,
        Kb1, Kb2, Vt1, Vt2, part);
    // L4: attention, both passes, 1024 uniform blocks
    k_attn_mfma<<<1024, 512, 0, stream>>>(Qb1, Kb1, Vt1, Opart1, Lpart1,
                                          Qb2, Kb2, Vt2, Opart2, Lpart2);
    // L5: combine + RMSNorm + quant
    k_rmsq_combine<<<5120, 256, 0, stream>>>(Opart1, Lpart1, g_px, act_o1, sc_o1,
                                             Opart2, Lpart2, g_pc, act_o2, sc_o2);
    // L6: output projections + residual (XCD-affine 1D, dbuf)
    k_gemm_out<<<640, 256, 0, stream>>>(
        act_o1, act_o2, Wb + Woff[2], Wb + Woff[5], sc_o1, sc_o2, part,
        x, c, outx, outc);
}

// Round 15
// 244.957 us; speedup vs baseline: 68.3893x; 1.1078x over previous
//
#include <hip/hip_runtime.h>
#include <math.h>

#define DD 512
#define NHEAD 8
#define HDIM 64

typedef __bf16 bf16x8 __attribute__((ext_vector_type(8)));
typedef unsigned short u16x8 __attribute__((ext_vector_type(8)));
typedef float f32x4 __attribute__((ext_vector_type(4)));
typedef int i32x4 __attribute__((ext_vector_type(4)));
typedef signed char i8x8 __attribute__((ext_vector_type(8)));

#if __has_builtin(__builtin_amdgcn_exp2f)
#define EXP2F(x) __builtin_amdgcn_exp2f(x)
#else
#define EXP2F(x) exp2f(x)
#endif

#define QSCALE 0.18033688f  /* (1/8) * log2(e): exp2 domain */

static __device__ __forceinline__ unsigned short f2bf(float f) {
    unsigned u = __builtin_bit_cast(unsigned, f);
    u += 0x7fffu + ((u >> 16) & 1u);   // round-to-nearest-even
    return (unsigned short)(u >> 16);
}
static __device__ __forceinline__ float bf2f(unsigned short u) {
    return __builtin_bit_cast(float, (unsigned)u << 16);
}

// sum of part[mid*32 .. +31] via wave butterfly; deterministic, same order everywhere
static __device__ __forceinline__ float wsum32(const float* __restrict__ part, int mid) {
    int l = threadIdx.x & 63;
    float v = (l < 32) ? part[mid * 32 + l] : 0.f;
#pragma unroll
    for (int o = 16; o > 0; o >>= 1) v += __shfl_xor(v, o);
    return __shfl(v, 0);
}

#define GLOAD16(g, l)                                                          \
    __builtin_amdgcn_global_load_lds(                                          \
        (__attribute__((address_space(1))) void*)(g),                          \
        (__attribute__((address_space(3))) void*)(l), 16, 0, 0)

#define BSTEP(s, hc)                                                           \
    {                                                                          \
        _Pragma("unroll")                                                      \
        for (int i = 0; i < (hc); ++i) {                                       \
            float send = (lane & (s)) ? p[i] : p[i + (hc)];                    \
            float recv = __shfl_xor(send, (s));                                \
            p[i] = ((lane & (s)) ? p[i + (hc)] : p[i]) + recv;                 \
        }                                                                      \
    }

// int8 double-buffered MFMA GEMM K-loop over K=512, BK=64 (8 steps).
// A/B tiles 128x64 int8 (8KB each); per-lane 16B frags feed mfma_i32_16x16x64_i8.
// Identical (row,chunk) addressing on A and B -> internal k-permutation cancels.
#define GEMM_KLOOP_I8(Aq, Wq, m0, n0)                                          \
    {                                                                          \
        _Pragma("unroll")                                                      \
        for (int i = 0; i < 2; ++i) {                                          \
            GLOAD16(Aq + (size_t)((m0) + i * 64 + row_st) * 512 + chunk * 16,  \
                    sA[0] + ((size_t)i * 256 + t) * 16);                       \
            GLOAD16(Wq + (size_t)((n0) + i * 64 + row_st) * 512 + chunk * 16,  \
                    sB[0] + ((size_t)i * 256 + t) * 16);                       \
        }                                                                      \
        asm volatile("s_waitcnt vmcnt(0)" ::: "memory");                       \
        __syncthreads();                                                       \
        int cur = 0;                                                           \
        for (int k0 = 0; k0 < 512; k0 += 64) {                                 \
            if (k0 + 64 < 512) {                                               \
                _Pragma("unroll")                                              \
                for (int i = 0; i < 2; ++i) {                                  \
                    GLOAD16(Aq + (size_t)((m0) + i * 64 + row_st) * 512 + k0 + 64 + chunk * 16, \
                            sA[cur ^ 1] + ((size_t)i * 256 + t) * 16);         \
                    GLOAD16(Wq + (size_t)((n0) + i * 64 + row_st) * 512 + k0 + 64 + chunk * 16, \
                            sB[cur ^ 1] + ((size_t)i * 256 + t) * 16);         \
                }                                                              \
            }                                                                  \
            i32x4 af[4], bfr[4];                                               \
            _Pragma("unroll")                                                  \
            for (int mt = 0; mt < 4; ++mt)                                     \
                af[mt] = *reinterpret_cast<const i32x4*>(                      \
                    &sA[cur][(wm * 64 + mt * 16 + lr) * 64 + lg * 16]);        \
            _Pragma("unroll")                                                  \
            for (int nt = 0; nt < 4; ++nt)                                     \
                bfr[nt] = *reinterpret_cast<const i32x4*>(                     \
                    &sB[cur][(wn * 64 + nt * 16 + lr) * 64 + lg * 16]);        \
            __builtin_amdgcn_s_setprio(1);                                     \
            _Pragma("unroll")                                                  \
            for (int mt = 0; mt < 4; ++mt)                                     \
                _Pragma("unroll")                                              \
                for (int nt = 0; nt < 4; ++nt)                                 \
                    acc[mt][nt] = __builtin_amdgcn_mfma_i32_16x16x64_i8(       \
                        af[mt], bfr[nt], acc[mt][nt], 0, 0, 0);                \
            __builtin_amdgcn_s_setprio(0);                                     \
            asm volatile("s_waitcnt vmcnt(0)" ::: "memory");                   \
            __syncthreads();                                                   \
            cur ^= 1;                                                          \
        }                                                                      \
    }

// ---------------- prep1: weight |.| partials (192 blocks) + RMSNorm/quant/DoRA (5120 blocks) ----------------
__global__ __launch_bounds__(256) void k_prep1(
    const float* __restrict__ W0, const float* __restrict__ W1,
    const float* __restrict__ W2, const float* __restrict__ W3,
    const float* __restrict__ W4, const float* __restrict__ W5,
    float* __restrict__ part,
    const float* __restrict__ x, const float* __restrict__ c,
    const float* __restrict__ g_qx, const float* __restrict__ g_kvx,
    const float* __restrict__ g_qc, const float* __restrict__ g_kvc,
    signed char* __restrict__ a_xq, signed char* __restrict__ a_xkv,
    signed char* __restrict__ a_cq, signed char* __restrict__ a_ckv,
    float* __restrict__ s_xq, float* __restrict__ s_xkv,
    float* __restrict__ s_cq, float* __restrict__ s_ckv,
    const float* __restrict__ A_x, const float* __restrict__ A_c,
    float* __restrict__ tmp_x, float* __restrict__ tmp_c) {
    int t = threadIdx.x;
    if (blockIdx.x < 192) {
        const float* Ws[6] = {W0, W1, W2, W3, W4, W5};
        const int cnt[6] = {262144, 524288, 262144, 262144, 524288, 262144};
        int mid = blockIdx.x >> 5, lb = blockIdx.x & 31;
        const float* W = Ws[mid];
        int n = cnt[mid];
        float s = 0.f;
        for (int i = lb * 256 + t; i < n; i += 32 * 256) s += fabsf(W[i]);
        __shared__ float red[4];
#pragma unroll
        for (int o = 32; o > 0; o >>= 1) s += __shfl_down(s, o);
        if ((t & 63) == 0) red[t >> 6] = s;
        __syncthreads();
        if (t == 0) part[blockIdx.x] = red[0] + red[1] + red[2] + red[3];
        return;
    }
    int w = t >> 6, lane = t & 63;
    int row = (int)(blockIdx.x - 192) * 4 + w;
    bool pc = (row >= 16384);
    int r = pc ? row - 16384 : row;
    const float* xr = (pc ? c : x) + (size_t)r * DD;
    const float* G1 = pc ? g_qc : g_qx;
    const float* G2 = pc ? g_kvc : g_kvx;
    signed char* O1 = pc ? a_cq : a_xq;
    signed char* O2 = pc ? a_ckv : a_xkv;
    float* S1 = pc ? s_cq : s_xq;
    float* S2 = pc ? s_ckv : s_xkv;
    const float* AM = pc ? A_c : A_x;
    float* TMP = pc ? tmp_c : tmp_x;

    float4 a = *(const float4*)(xr + lane * 8);
    float4 b = *(const float4*)(xr + lane * 8 + 4);
    float p[16];
#pragma unroll
    for (int cc = 0; cc < 16; ++cc) {
        const float4* ar = (const float4*)(AM + (size_t)cc * DD + lane * 8);
        float4 aa = ar[0], ab = ar[1];
        p[cc] = a.x*aa.x + a.y*aa.y + a.z*aa.z + a.w*aa.w
              + b.x*ab.x + b.y*ab.y + b.z*ab.z + b.w*ab.w;
    }
    BSTEP(1, 8) BSTEP(2, 4) BSTEP(4, 2) BSTEP(8, 1)
    p[0] += __shfl_xor(p[0], 16);
    p[0] += __shfl_xor(p[0], 32);
    if (lane < 16) {
        int cidx = ((lane & 1) << 3) | ((lane & 2) << 1) | ((lane & 4) >> 1) | ((lane & 8) >> 3);
        TMP[(size_t)r * 16 + cidx] = p[0];
    }
    float ss = a.x*a.x + a.y*a.y + a.z*a.z + a.w*a.w
             + b.x*b.x + b.y*b.y + b.z*b.z + b.w*b.w;
#pragma unroll
    for (int o = 32; o > 0; o >>= 1) ss += __shfl_xor(ss, o);
    float rn = 1.f / sqrtf(ss * (1.f / 512.f) + 1e-8f);
    const float* gs[2] = {G1, G2};
    signed char* os[2] = {O1, O2};
    float* scs[2] = {S1, S2};
#pragma unroll
    for (int pass = 0; pass < 2; ++pass) {
        float4 ga = *(const float4*)(gs[pass] + lane * 8);
        float4 gb = *(const float4*)(gs[pass] + lane * 8 + 4);
        float v[8] = {a.x*rn*ga.x, a.y*rn*ga.y, a.z*rn*ga.z, a.w*rn*ga.w,
                      b.x*rn*gb.x, b.y*rn*gb.y, b.z*rn*gb.z, b.w*rn*gb.w};
        float amax = 0.f;
#pragma unroll
        for (int i = 0; i < 8; ++i) amax = fmaxf(amax, fabsf(v[i]));
#pragma unroll
        for (int o = 32; o > 0; o >>= 1) amax = fmaxf(amax, __shfl_xor(amax, o));
        float mx = fmaxf(amax, 1e-5f);
        float scale = 127.f / mx;
        i8x8 qv;
#pragma unroll
        for (int i = 0; i < 8; ++i) {
            float tq = rintf(v[i] * scale);
            tq = fminf(fmaxf(tq, -128.f), 127.f);
            qv[i] = (signed char)(int)tq;
        }
        *reinterpret_cast<i8x8*>(os[pass] + (size_t)r * DD + lane * 8) = qv;
        if (lane == 0) scs[pass][r] = mx / 127.f;
    }
}

// ---------------- prep2: weight ternarize int8 (8192 blocks) + DoRA delta (40960 blocks) ----------------
__global__ __launch_bounds__(256) void k_prep2(
    const float* __restrict__ W0, const float* __restrict__ W1,
    const float* __restrict__ W2, const float* __restrict__ W3,
    const float* __restrict__ W4, const float* __restrict__ W5,
    const float* __restrict__ part, signed char* __restrict__ Wq,
    const float* __restrict__ tmp_x, const float* __restrict__ tmp_c,
    const float* __restrict__ B_x, const float* __restrict__ B_c,
    unsigned short* __restrict__ qf1, unsigned short* __restrict__ qf2) {
    if (blockIdx.x < 8192) {
        int e = blockIdx.x * 256 + threadIdx.x;
        const float* Ws[6] = {W0, W1, W2, W3, W4, W5};
        int mid, base;
        if (e < 262144)       { mid = 0; base = 0; }
        else if (e < 786432)  { mid = 1; base = 262144; }
        else if (e < 1048576) { mid = 2; base = 786432; }
        else if (e < 1310720) { mid = 3; base = 1048576; }
        else if (e < 1835008) { mid = 4; base = 1310720; }
        else                  { mid = 5; base = 1835008; }
        float cnt = (mid == 1 || mid == 4) ? 524288.f : 262144.f;
        float mean = fmaxf(wsum32(part, mid) / cnt, 1e-5f);
        float sc = 1.f / mean;
        float t = rintf(Ws[mid][e - base] * sc);
        t = fminf(fmaxf(t, -1.f), 1.f);
        Wq[e] = (signed char)(int)t;
        return;
    }
    int idx = (int)(blockIdx.x - 8192) * 256 + threadIdx.x;   // over 20480*512
    int m2 = idx >> 9, n2 = idx & 511;
    const float* tr;
    const float* br;
    unsigned short* out;
    if (m2 < 16384) {
        tr = tmp_x + (size_t)m2 * 16; br = B_x + (size_t)n2 * 16; out = qf1 + idx;
    } else {
        tr = tmp_c + (size_t)(m2 - 16384) * 16; br = B_c + (size_t)n2 * 16;
        out = qf2 + (idx - 8388608);
    }
    const float4* t4 = (const float4*)tr;
    const float4* b4 = (const float4*)br;
    float acc = 0.f;
#pragma unroll
    for (int rr = 0; rr < 4; ++rr) {
        float4 ta = t4[rr], ba = b4[rr];
        acc += ta.x*ba.x + ta.y*ba.y + ta.z*ba.z + ta.w*ba.w;
    }
    *out = f2bf(acc);
}

// ---------------- combine attn partials (bf16) + RMSNorm + quant(int8), both passes ----------------
__global__ __launch_bounds__(256) void k_rmsq_combine(
    const unsigned short* __restrict__ Op_a, const float* __restrict__ Lp_a,
    const float* __restrict__ g_a, signed char* __restrict__ out_a,
    float* __restrict__ sc_a,
    const unsigned short* __restrict__ Op_b, const float* __restrict__ Lp_b,
    const float* __restrict__ g_b, signed char* __restrict__ out_b,
    float* __restrict__ sc_b) {
    int w = threadIdx.x >> 6, lane = threadIdx.x & 63;
    int row = (int)blockIdx.x * 4 + w;
    bool pb = (row >= 16384);
    int r = pb ? row - 16384 : row;
    int S = pb ? 4 : 1;
    int lognq = pb ? 10 : 12;
    const unsigned short* Op = pb ? Op_b : Op_a;
    const float* Lp = pb ? Lp_b : Lp_a;
    const float* g  = pb ? g_b : g_a;
    signed char* out = pb ? out_b : out_a;
    float* a_inv = pb ? sc_b : sc_a;

    int Nq = 1 << lognq;
    int b = r >> lognq, q = r & (Nq - 1);
    int h = lane >> 3;
    float l = 0.f;
    float u[8] = {};
    for (int s = 0; s < S; ++s) {
        l += Lp[((size_t)(s * 4 + b) * 8 + h) * Nq + q];
        u16x8 ov = *reinterpret_cast<const u16x8*>(
            Op + ((size_t)(s * 4 + b) * Nq + q) * 512 + lane * 8);
#pragma unroll
        for (int i = 0; i < 8; ++i) u[i] += bf2f(ov[i]);
    }
    float invl = 1.f / l;
#pragma unroll
    for (int i = 0; i < 8; ++i) u[i] *= invl;
    float ss = 0.f;
#pragma unroll
    for (int i = 0; i < 8; ++i) ss += u[i] * u[i];
#pragma unroll
    for (int o = 32; o > 0; o >>= 1) ss += __shfl_xor(ss, o);
    float rn = 1.f / sqrtf(ss * (1.f / 512.f) + 1e-8f);
    float4 ga = *(const float4*)(g + lane * 8);
    float4 gb = *(const float4*)(g + lane * 8 + 4);
    float v[8] = {u[0]*rn*ga.x, u[1]*rn*ga.y, u[2]*rn*ga.z, u[3]*rn*ga.w,
                  u[4]*rn*gb.x, u[5]*rn*gb.y, u[6]*rn*gb.z, u[7]*rn*gb.w};
    float amax = 0.f;
#pragma unroll
    for (int i = 0; i < 8; ++i) amax = fmaxf(amax, fabsf(v[i]));
#pragma unroll
    for (int o = 32; o > 0; o >>= 1) amax = fmaxf(amax, __shfl_xor(amax, o));
    float mx = fmaxf(amax, 1e-5f);
    float scale = 127.f / mx;
    i8x8 qv;
#pragma unroll
    for (int i = 0; i < 8; ++i) {
        float tq = rintf(v[i] * scale);
        tq = fminf(fmaxf(tq, -128.f), 127.f);
        qv[i] = (signed char)(int)tq;
    }
    *reinterpret_cast<i8x8*>(out + (size_t)r * DD + lane * 8) = qv;
    if (lane == 0) a_inv[r] = mx / 127.f;
}

// ---------------- merged Q + KV projection GEMM, int8 (one launch, 1920 blocks) ----------------
// XCD-affinity swizzle + double-buffered K-loop, mfma_i32_16x16x64_i8.
__global__ __launch_bounds__(256) void k_gemm_qkv(
    const signed char* __restrict__ a3_a, const signed char* __restrict__ a3_b,
    const signed char* __restrict__ w3_a, const signed char* __restrict__ w3_b,
    const float* __restrict__ ai3_a, const float* __restrict__ ai3_b,
    const float* __restrict__ mag_a, const float* __restrict__ mag_b,
    const unsigned short* __restrict__ dl_a, const unsigned short* __restrict__ dl_b,
    unsigned short* __restrict__ Qb_a, unsigned short* __restrict__ Qb_b,
    const signed char* __restrict__ a4_a, const signed char* __restrict__ a4_b,
    const signed char* __restrict__ w4_a, const signed char* __restrict__ w4_b,
    const float* __restrict__ ai4_a, const float* __restrict__ ai4_b,
    unsigned short* __restrict__ Kb_a, unsigned short* __restrict__ Kb_b,
    unsigned short* __restrict__ Vt_a, unsigned short* __restrict__ Vt_b,
    const float* __restrict__ part) {
    __shared__ __align__(16) unsigned char sA[2][128 * 64];
    __shared__ __align__(16) unsigned char sB[2][128 * 64];
    int bid = blockIdx.x;
    bool isQ = (bid >= 1280);
    const signed char *Aq, *Wq;
    const float* a_inv;
    int m0, n0, logn, mid;
    float cnt;
    bool pb;
    if (!isQ) {
        int g = bid & 7, k = bid >> 3;       // XCD-affine: my%8 == g
        n0 = (k & 7) * 128;
        int my = (k >> 3) * 8 + g;           // 0..159
        pb = my >= 32;
        m0 = (pb ? my - 32 : my) * 128;
        Aq = pb ? a4_b : a4_a;  Wq = pb ? w4_b : w4_a;
        a_inv = pb ? ai4_b : ai4_a;
        logn = pb ? 12 : 10;
        mid = pb ? 4 : 1; cnt = 524288.f;
    } else {
        int b2 = bid - 1280;                 // 1280%8==0: preserves XCD phase
        int g = b2 & 7, k = b2 >> 3;
        n0 = (k & 3) * 128;
        int my = (k >> 2) * 8 + g;           // 0..159
        pb = my >= 128;
        m0 = (pb ? my - 128 : my) * 128;
        Aq = pb ? a3_b : a3_a;  Wq = pb ? w3_b : w3_a;
        a_inv = pb ? ai3_b : ai3_a;
        logn = pb ? 10 : 12;
        mid = pb ? 3 : 0; cnt = 262144.f;
    }
    float wv = fmaxf(wsum32(part, mid) / cnt, 1e-5f);

    int t = threadIdx.x;
    int w = t >> 6, lane = t & 63;
    int wm = w >> 1, wn = w & 1;
    int lr = lane & 15, lg = lane >> 4;
    int row_st = t >> 2, chunk = t & 3;
    i32x4 acc[4][4] = {};

    GEMM_KLOOP_I8(Aq, Wq, m0, n0)

    if (!isQ) {
        unsigned short* OutB = pb ? Kb_b : Kb_a;
        unsigned short* OutB2 = pb ? Vt_b : Vt_a;
        const bool isV = (n0 >= 512);
        const int Nc = 1 << logn;
#pragma unroll
        for (int mt = 0; mt < 4; ++mt) {
            int mb = m0 + wm * 64 + mt * 16 + lg * 4;
            int b = mb >> logn, key = mb & (Nc - 1);
            float as_[4];
#pragma unroll
            for (int r = 0; r < 4; ++r) as_[r] = a_inv[mb + r] * wv;
#pragma unroll
            for (int nt = 0; nt < 4; ++nt) {
                int n = n0 + wn * 64 + nt * 16 + lr;
                int n2 = isV ? (n - 512) : n;
                int h = n2 >> 6, dd = n2 & 63;
                if (isV) {
                    int i0 = key & 31;
                    int keyp = (key & ~31) | (((i0 >> 2) & 3) * 8 + ((i0 >> 4) & 1) * 4);
                    ushort4 v;
                    v.x = f2bf((float)acc[mt][nt][0] * as_[0]);
                    v.y = f2bf((float)acc[mt][nt][1] * as_[1]);
                    v.z = f2bf((float)acc[mt][nt][2] * as_[2]);
                    v.w = f2bf((float)acc[mt][nt][3] * as_[3]);
                    *reinterpret_cast<ushort4*>(
                        OutB2 + ((size_t)(b * NHEAD + h) * 64 + dd) * Nc + keyp) = v;
                } else {
#pragma unroll
                    for (int r = 0; r < 4; ++r)
                        OutB[((size_t)(b * NHEAD + h) * Nc + key + r) * 64 + dd] =
                            f2bf((float)acc[mt][nt][r] * as_[r]);
                }
            }
        }
    } else {
        const float* Extra = pb ? mag_b : mag_a;
        const unsigned short* Dlt = pb ? dl_b : dl_a;
        unsigned short* OutB = pb ? Qb_b : Qb_a;
#pragma unroll
        for (int mt = 0; mt < 4; ++mt) {
#pragma unroll
            for (int r = 0; r < 4; ++r) {
                int m = m0 + wm * 64 + mt * 16 + lg * 4 + r;
                float as = a_inv[m] * wv;
                int b = m >> logn, q = m & ((1 << logn) - 1);
#pragma unroll
                for (int nt = 0; nt < 4; ++nt) {
                    int n = n0 + wn * 64 + nt * 16 + lr;
                    float dl = bf2f(Dlt[(size_t)m * 512 + n]);
                    float val = (float)acc[mt][nt][r] * as + Extra[n >> 6] * dl;
                    int h = n >> 6, d = n & 63;
                    OutB[((((size_t)(b * NHEAD + h)) << logn) + q) * 64 + d] =
                        f2bf(val * QSCALE);
                }
            }
        }
    }
}

// ---------------- output projection GEMM + residual, int8, both passes ----------------
__global__ __launch_bounds__(256) void k_gemm_out(
    const signed char* __restrict__ a_a, const signed char* __restrict__ a_b,
    const signed char* __restrict__ w_a, const signed char* __restrict__ w_b,
    const float* __restrict__ ai_a, const float* __restrict__ ai_b,
    const float* __restrict__ part,
    const float* __restrict__ Ex_a, const float* __restrict__ Ex_b,
    float* __restrict__ OF_a, float* __restrict__ OF_b) {
    __shared__ __align__(16) unsigned char sA[2][128 * 64];
    __shared__ __align__(16) unsigned char sB[2][128 * 64];
    int bid = blockIdx.x;                    // 0..639
    int g = bid & 7, k = bid >> 3;           // XCD-affine: my%8 == g
    int n0 = (k & 3) * 128;
    int my = (k >> 2) * 8 + g;               // 0..159
    bool pb = (my >= 128);
    int m0 = (pb ? my - 128 : my) * 128;
    const signed char* Aq = pb ? a_b : a_a;
    const signed char* Wq = pb ? w_b : w_a;
    const float* a_inv = pb ? ai_b : ai_a;
    const float* Extra = pb ? Ex_b : Ex_a;
    float* OutF = pb ? OF_b : OF_a;
    float wv = fmaxf(wsum32(part, pb ? 5 : 2) / 262144.f, 1e-5f);

    int t = threadIdx.x;
    int w = t >> 6, lane = t & 63;
    int wm = w >> 1, wn = w & 1;
    int lr = lane & 15, lg = lane >> 4;
    int row_st = t >> 2, chunk = t & 3;
    i32x4 acc[4][4] = {};

    GEMM_KLOOP_I8(Aq, Wq, m0, n0)

#pragma unroll
    for (int mt = 0; mt < 4; ++mt) {
#pragma unroll
        for (int r = 0; r < 4; ++r) {
            int m = m0 + wm * 64 + mt * 16 + lg * 4 + r;
            float as = a_inv[m] * wv;
#pragma unroll
            for (int nt = 0; nt < 4; ++nt) {
                int n = n0 + wn * 64 + nt * 16 + lr;
                size_t idx = (size_t)m * 512 + n;
                OutF[idx] = (float)acc[mt][nt][r] * as + Extra[idx];
            }
        }
    }
}

// ---------------- flash attention: swapped-QK^T, in-register P, dbuf LDS ----------------
// 1024 uniform blocks (16 tiles each, 4 blocks/CU): bid<512 = pass2 (S=4 key-splits),
// bid>=512 = pass1 (S=1). 512 threads = 8 waves, 32 q/wave.
__global__ __launch_bounds__(512) void k_attn_mfma(
    const unsigned short* __restrict__ Qb_a, const unsigned short* __restrict__ Kb_a,
    const unsigned short* __restrict__ Vt_a, unsigned short* __restrict__ Op_a,
    float* __restrict__ Lp_a,
    const unsigned short* __restrict__ Qb_b, const unsigned short* __restrict__ Kb_b,
    const unsigned short* __restrict__ Vt_b, unsigned short* __restrict__ Op_b,
    float* __restrict__ Lp_b) {
    __shared__ unsigned short sK[2][64][72];
    __shared__ unsigned short sVt[2][64][72];
    int t = threadIdx.x;
    int w = t >> 6, lane = t & 63;
    int lr = lane & 15, lg = lane >> 4;

    int bid = blockIdx.x;
    bool pb = (bid < 512);
    int lb = pb ? bid : bid - 512;
    const unsigned short* Qb = pb ? Qb_b : Qb_a;
    const unsigned short* Kb = pb ? Kb_b : Kb_a;
    const unsigned short* Vt = pb ? Vt_b : Vt_a;
    unsigned short* Opart = pb ? Op_b : Op_a;
    float* Lpart = pb ? Lp_b : Lp_a;
    int Nq = pb ? 1024 : 4096;
    int Nc = pb ? 4096 : 1024;
    int S = pb ? 4 : 1;
    int LOGS = pb ? 2 : 0;
    int nqs = pb ? 2 : 4;

    int j = lb >> 3;
    int s = j & (S - 1);
    int j2 = j >> LOGS;
    int qblk = j2 & ((1 << nqs) - 1);
    int bh = ((lb & 7) << 2) | (j2 >> nqs);   // XCD-local bh groups
    int b = bh >> 3, h = bh & 7;
    int q0 = qblk * 256 + w * 32;

    bf16x8 aq[2][2];
#pragma unroll
    for (int qt = 0; qt < 2; ++qt) {
        const unsigned short* qbase = Qb + ((size_t)bh * Nq + q0 + qt * 16 + lr) * 64 + lg * 8;
        aq[qt][0] = *reinterpret_cast<const bf16x8*>(qbase);
        aq[qt][1] = *reinterpret_cast<const bf16x8*>(qbase + 32);
    }

    u16x8 ou;
#pragma unroll
    for (int jj = 0; jj < 8; ++jj) ou[jj] = (lr == 0) ? 0x3F80 : 0;
    bf16x8 onesf = __builtin_bit_cast(bf16x8, ou);

    f32x4 o[2][4] = {};
    f32x4 osum[2] = {};

    const unsigned short* kglob = Kb + (size_t)bh * Nc * 64;
    const unsigned short* vglob = Vt + (size_t)bh * 64 * (size_t)Nc;

    int srow = t >> 3, sseg = t & 7;
    const unsigned short* kptr = kglob + (size_t)srow * 64 + sseg * 8;
    const unsigned short* vptr = vglob + (size_t)srow * Nc + sseg * 8;

    int kts = s * (Nc >> LOGS);
    int nt = (Nc >> LOGS) >> 6;   // 16 for both passes

    bf16x8 rK = *reinterpret_cast<const bf16x8*>(kptr + (size_t)kts * 64);
    bf16x8 rV = *reinterpret_cast<const bf16x8*>(vptr + kts);
    *reinterpret_cast<bf16x8*>(&sK[0][srow][sseg * 8]) = rK;
    *reinterpret_cast<bf16x8*>(&sVt[0][srow][sseg * 8]) = rV;
    rK = *reinterpret_cast<const bf16x8*>(kptr + (size_t)(kts + 64) * 64);
    rV = *reinterpret_cast<const bf16x8*>(vptr + kts + 64);
    __syncthreads();

    int cur = 0;
    for (int ti = 0; ti < nt; ++ti) {
        if (ti + 1 < nt) {
            *reinterpret_cast<bf16x8*>(&sK[cur ^ 1][srow][sseg * 8]) = rK;
            *reinterpret_cast<bf16x8*>(&sVt[cur ^ 1][srow][sseg * 8]) = rV;
            if (ti + 2 < nt) {
                int knext = kts + (ti + 2) * 64;
                rK = *reinterpret_cast<const bf16x8*>(kptr + (size_t)knext * 64);
                rV = *reinterpret_cast<const bf16x8*>(vptr + knext);
            }
        }
#pragma unroll
        for (int half = 0; half < 2; ++half) {
            bf16x8 pa0, pa1;
#pragma unroll
            for (int ki = 0; ki < 2; ++ki) {
                int kt = half * 2 + ki;
                bf16x8 bk0 = *reinterpret_cast<const bf16x8*>(&sK[cur][kt * 16 + lr][lg * 8]);
                bf16x8 bk1 = *reinterpret_cast<const bf16x8*>(&sK[cur][kt * 16 + lr][32 + lg * 8]);
                f32x4 a0 = {}, a1 = {};
                __builtin_amdgcn_s_setprio(1);
                a0 = __builtin_amdgcn_mfma_f32_16x16x32_bf16(bk0, aq[0][0], a0, 0, 0, 0);
                a1 = __builtin_amdgcn_mfma_f32_16x16x32_bf16(bk0, aq[1][0], a1, 0, 0, 0);
                a0 = __builtin_amdgcn_mfma_f32_16x16x32_bf16(bk1, aq[0][1], a0, 0, 0, 0);
                a1 = __builtin_amdgcn_mfma_f32_16x16x32_bf16(bk1, aq[1][1], a1, 0, 0, 0);
                __builtin_amdgcn_s_setprio(0);
                const int hb = ki * 4;
#pragma unroll
                for (int r = 0; r < 4; ++r) {
                    pa0[hb + r] = (__bf16)EXP2F(a0[r]);
                    pa1[hb + r] = (__bf16)EXP2F(a1[r]);
                }
            }
            __builtin_amdgcn_s_setprio(1);
#pragma unroll
            for (int dt = 0; dt < 4; ++dt) {
                bf16x8 vb = *reinterpret_cast<const bf16x8*>(&sVt[cur][dt * 16 + lr][half * 32 + lg * 8]);
                o[0][dt] = __builtin_amdgcn_mfma_f32_16x16x32_bf16(pa0, vb, o[0][dt], 0, 0, 0);
                o[1][dt] = __builtin_amdgcn_mfma_f32_16x16x32_bf16(pa1, vb, o[1][dt], 0, 0, 0);
            }
            osum[0] = __builtin_amdgcn_mfma_f32_16x16x32_bf16(pa0, onesf, osum[0], 0, 0, 0);
            osum[1] = __builtin_amdgcn_mfma_f32_16x16x32_bf16(pa1, onesf, osum[1], 0, 0, 0);
            __builtin_amdgcn_s_setprio(0);
        }
        __syncthreads();
        cur ^= 1;
    }
    unsigned short* obase = Opart + ((size_t)(s * 4 + b) * Nq + q0) * 512 + h * 64;
#pragma unroll
    for (int qt = 0; qt < 2; ++qt)
#pragma unroll
        for (int dt = 0; dt < 4; ++dt)
#pragma unroll
            for (int r = 0; r < 4; ++r)
                obase[(size_t)(qt * 16 + lg * 4 + r) * 512 + dt * 16 + lr] = f2bf(o[qt][dt][r]);
    if (lr == 0) {
        float* lbase = Lpart + ((size_t)(s * 4 + b) * 8 + h) * Nq + q0;
#pragma unroll
        for (int qt = 0; qt < 2; ++qt)
#pragma unroll
            for (int r = 0; r < 4; ++r)
                lbase[qt * 16 + lg * 4 + r] = osum[qt][r];
    }
}

// ---------------- host side ----------------
extern "C" void kernel_launch(void* const* d_in, const int* in_sizes, int n_in,
                              void* d_out, int out_size, void* d_ws, size_t ws_size,
                              hipStream_t stream) {
    const float* x     = (const float*)d_in[0];
    const float* c     = (const float*)d_in[1];
    const float* Wq_x  = (const float*)d_in[2];
    const float* g_qx  = (const float*)d_in[3];
    const float* Wkv_c = (const float*)d_in[4];
    const float* g_kvc = (const float*)d_in[5];
    const float* A_x   = (const float*)d_in[6];
    const float* B_x   = (const float*)d_in[7];
    const float* mag_x = (const float*)d_in[8];
    const float* Wp_x  = (const float*)d_in[9];
    const float* g_px  = (const float*)d_in[10];
    const float* Wq_c  = (const float*)d_in[11];
    const float* g_qc  = (const float*)d_in[12];
    const float* Wkv_x = (const float*)d_in[13];
    const float* g_kvx = (const float*)d_in[14];
    const float* A_c   = (const float*)d_in[15];
    const float* B_c   = (const float*)d_in[16];
    const float* mag_c = (const float*)d_in[17];
    const float* Wp_c  = (const float*)d_in[18];
    const float* g_pc  = (const float*)d_in[19];

    float* ws = (float*)d_ws;
    signed char* Wb = (signed char*)ws;               // int8 weights, 2.3MB in 4MB region
    const size_t Woff[6] = {0, 262144, 786432, 1048576, 1310720, 1835008}; // int8 units
    float* part  = ws + 1048576;
    float* sc_xq  = ws + 1049600;
    float* sc_xkv = sc_xq + 16384;
    float* sc_cq  = sc_xkv + 16384;
    float* sc_ckv = sc_cq + 4096;
    float* sc_o1  = sc_ckv + 4096;
    float* sc_o2  = sc_o1 + 16384;
    float* tmp_x  = ws + 1111040;                    // 262144
    float* tmp_c  = tmp_x + 262144;                  // 65536  -> ends 1438720
    float* actblk = ws + 1438720;                    // acts / Opart1 overlay
    signed char* act_xq  = (signed char*)actblk;                     // int8, 8MB region slot
    signed char* act_xkv = (signed char*)(actblk + 4194304);
    signed char* act_cq  = (signed char*)(actblk + 8388608);
    signed char* act_ckv = (signed char*)(actblk + 9437184);
    unsigned short* Opart1 = (unsigned short*)actblk;  // 8.4M u16 over act_xq (dead)
    float* qf1_f  = ws + 11924480;                   // 4194304 f
    unsigned short* Opart2 = (unsigned short*)qf1_f; // 8.4M u16 (S=4; qf1 dead by attn)
    float* qf2_f  = ws + 16118784;                   // 1048576 f
    float* Qb1_f  = ws + 17167360;                   // 4194304 f (-> act_o1)
    float* Qb2_f  = ws + 21361664;                   // 1048576 f (-> act_o2)
    float* Kb1_f  = ws + 22410240;                   // 1048576 f
    float* Vt1_f  = ws + 23458816;                   // 1048576 f
    float* Kb2_f  = ws + 24507392;                   // 4194304 f
    float* Vt2_f  = ws + 28701696;                   // 4194304 f
    float* Lpart1 = ws + 32896000;                   // 131072 f
    float* Lpart2 = ws + 33027072;                   // 131072 f -> ends 33158144

    unsigned short* qf1 = (unsigned short*)qf1_f;
    unsigned short* qf2 = (unsigned short*)qf2_f;
    unsigned short* Qb1 = (unsigned short*)Qb1_f;
    unsigned short* Qb2 = (unsigned short*)Qb2_f;
    unsigned short* Kb1 = (unsigned short*)Kb1_f;
    unsigned short* Vt1 = (unsigned short*)Vt1_f;
    unsigned short* Kb2 = (unsigned short*)Kb2_f;
    unsigned short* Vt2 = (unsigned short*)Vt2_f;
    signed char* act_o1 = (signed char*)Qb1;
    signed char* act_o2 = (signed char*)Qb2;

    size_t need = (size_t)33158144 * sizeof(float);   // ~132.6 MB
    if (ws_size < need) return;

    float* outx = (float*)d_out;
    float* outc = outx + (size_t)4 * 4096 * 512;

    // L1: weight |.| partials + RMSNorm/quant(int8)/DoRA-tmp for both passes
    k_prep1<<<5312, 256, 0, stream>>>(Wq_x, Wkv_c, Wp_x, Wq_c, Wkv_x, Wp_c, part,
                                      x, c, g_qx, g_kvx, g_qc, g_kvc,
                                      act_xq, act_xkv, act_cq, act_ckv,
                                      sc_xq, sc_xkv, sc_cq, sc_ckv,
                                      A_x, A_c, tmp_x, tmp_c);
    // L2: weight ternarize (int8) + DoRA delta
    k_prep2<<<49152, 256, 0, stream>>>(Wq_x, Wkv_c, Wp_x, Wq_c, Wkv_x, Wp_c, part, Wb,
                                       tmp_x, tmp_c, B_x, B_c, qf1, qf2);
    // L3: merged Q + KV projections, int8 MFMA (KV blocks first, XCD-affine, dbuf)
    k_gemm_qkv<<<1920, 256, 0, stream>>>(
        act_xq, act_cq, Wb + Woff[0], Wb + Woff[3], sc_xq, sc_cq,
        mag_x, mag_c, qf1, qf2, Qb1, Qb2,
        act_ckv, act_xkv, Wb + Woff[1], Wb + Woff[4], sc_ckv, sc_xkv,
        Kb1, Kb2, Vt1, Vt2, part);
    // L4: attention, both passes, 1024 uniform blocks
    k_attn_mfma<<<1024, 512, 0, stream>>>(Qb1, Kb1, Vt1, Opart1, Lpart1,
                                          Qb2, Kb2, Vt2, Opart2, Lpart2);
    // L5: combine + RMSNorm + quant(int8)
    k_rmsq_combine<<<5120, 256, 0, stream>>>(Opart1, Lpart1, g_px, act_o1, sc_o1,
                                             Opart2, Lpart2, g_pc, act_o2, sc_o2);
    // L6: output projections + residual (int8 MFMA, XCD-affine 1D, dbuf)
    k_gemm_out<<<640, 256, 0, stream>>>(
        act_o1, act_o2, Wb + Woff[2], Wb + Woff[5], sc_o1, sc_o2, part,
        x, c, outx, outc);
}